// Round 2
// baseline (827.620 us; speedup 1.0000x reference)
//
#include <hip/hip_runtime.h>
#include <cstdint>

// ---------------------------------------------------------------------------
// SS-MSA fused implementation, round 2.
// grid_shift(sim) factorizes: shifted[i,j] = SCALE*(q_{i-1}.k_{j-1} + q~_i.k~_j) + P[i,j]
// => both branches are plain attention with 56-dim augmented Q/K + bias P.
//
// Round-2 changes vs round 1:
//  - k_qkv writes branch-split, branch-layout arrays:
//      q1/k1/v1 [b][n][64][28]  (window-major, branch 1)
//      q2/k2/v2 [b][m][256][28] (position-major, branch 2)
//    -> all attention staging loads are contiguous.
//  - k_attn2: ONE 1024-thread block per (b,m) (was 4 blocks re-loading
//    everything). LDS 146KB: stage buf [256][29] (reused as vT [28][260]),
//    augqT/augkT [56][260]. P in registers, PV via shfl butterfly.
//  - bank-conflict-free j-mapping: each thread covers j in 4 groups of 4
//    consecutive (16B lane stride), V transposed for contiguous PV reads.
//
// Workspace (floats), total 34,127,904 f (~136.5 MB):
//   q1,k1,v1,q2,k2,v2: 6 x 3,670,016  @ 0
//   ssum [8][256][64][56] @ 22,020,096   (reused as attn_out)
//   c1o  @ 29,360,128 ; part @ 33,554,432 ; shif @ 33,570,816
//   P1T  @ 33,570,848 ; P2T @ 33,603,616
// ---------------------------------------------------------------------------

#define SCALE_ 0.18898223650461364f  // 28^-0.5

__device__ __forceinline__ void coords_(int idx, int S, float s,
                                        int& i0, int& i1, float& w0, float& w1) {
    float g = -1.0f + 2.0f * (float)idx / (float)(S - 1);
    float c = (g + s * 2.0f / (float)S + 1.0f) * 0.5f * (float)(S - 1);
    float span = (float)(S - 1);
    c = fabsf(c);
    c = fmodf(c, 2.0f * span);
    if (c > span) c = 2.0f * span - c;
    int f = (int)floorf(c);
    f = max(0, min(f, S - 1));
    i0 = f;
    i1 = min(f + 1, S - 1);
    w1 = c - (float)f;
    w0 = 1.0f - w1;
}

// ------------------------------- K1: QKV GEMM ------------------------------
template <int RS, int C0>
__device__ __forceinline__ void qkv_chunk(const float* xrow, const float* __restrict__ W,
                                          float* __restrict__ outp, float* ss) {
    float acc[28];
#pragma unroll
    for (int c = 0; c < 28; ++c) acc[c] = 0.f;
    for (int d = 0; d < 56; ++d) {
        float xv = xrow[d];
        const float4* wr = (const float4*)(W + d * RS + C0);
#pragma unroll
        for (int k = 0; k < 7; ++k) {
            float4 w = wr[k];
            acc[4 * k + 0] += xv * w.x;
            acc[4 * k + 1] += xv * w.y;
            acc[4 * k + 2] += xv * w.z;
            acc[4 * k + 3] += xv * w.w;
        }
    }
    float4* op = (float4*)outp;
#pragma unroll
    for (int k = 0; k < 7; ++k)
        op[k] = make_float4(acc[4 * k + 0], acc[4 * k + 1], acc[4 * k + 2], acc[4 * k + 3]);
#pragma unroll
    for (int c = 0; c < 28; ++c) ss[c] += acc[c];
}

__global__ __launch_bounds__(256) void k_qkv(const float* __restrict__ x,
                                             const float* __restrict__ Wq,
                                             const float* __restrict__ Wkv,
                                             float* __restrict__ q1, float* __restrict__ k1,
                                             float* __restrict__ v1, float* __restrict__ q2,
                                             float* __restrict__ k2, float* __restrict__ v2,
                                             float* __restrict__ ssum) {
    __shared__ __align__(16) float xlds[256 * 57];
    int tid = threadIdx.x;
    int pix = blockIdx.x * 256 + tid;
    int b = pix >> 14;
    int rem = pix & 16383;
    int hh = rem >> 7;
    int ww = rem & 127;
    int n = ((hh >> 3) << 4) + (ww >> 3);
    int m = ((hh & 7) << 3) + (ww & 7);
    float* xrow = xlds + tid * 57;
    const float4* xp = (const float4*)(x + (size_t)pix * 56);
#pragma unroll
    for (int k = 0; k < 14; ++k) {
        float4 t = xp[k];
        xrow[4 * k + 0] = t.x;
        xrow[4 * k + 1] = t.y;
        xrow[4 * k + 2] = t.z;
        xrow[4 * k + 3] = t.w;
    }
    size_t p1 = ((size_t)(b * 256 + n) * 64 + m) * 28;   // branch1 layout
    size_t p2 = ((size_t)(b * 64 + m) * 256 + n) * 28;   // branch2 layout
    size_t ob = ((size_t)(b * 256 + n) * 64 + m) * 56;   // ssum layout
    float ssA[28], ssB[28];
#pragma unroll
    for (int c = 0; c < 28; ++c) { ssA[c] = 0.f; ssB[c] = 0.f; }
    qkv_chunk<56, 0>(xrow, Wq, q1 + p1, ssA);
    qkv_chunk<56, 28>(xrow, Wq, q2 + p2, ssB);
    qkv_chunk<112, 0>(xrow, Wkv, k1 + p1, ssA);
    qkv_chunk<112, 28>(xrow, Wkv, k2 + p2, ssB);
    qkv_chunk<112, 56>(xrow, Wkv, v1 + p1, ssA);
    qkv_chunk<112, 84>(xrow, Wkv, v2 + p2, ssB);
    float4* sp = (float4*)(ssum + ob);
#pragma unroll
    for (int k = 0; k < 7; ++k)
        sp[k] = make_float4(ssA[4 * k + 0], ssA[4 * k + 1], ssA[4 * k + 2], ssA[4 * k + 3]);
#pragma unroll
    for (int k = 0; k < 7; ++k)
        sp[7 + k] = make_float4(ssB[4 * k + 0], ssB[4 * k + 1], ssB[4 * k + 2], ssB[4 * k + 3]);
}

// ------------------------------- K2: conv1 ---------------------------------
__global__ __launch_bounds__(256) void k_conv1(const float* __restrict__ ssum,
                                               const float* __restrict__ c1w,
                                               const float* __restrict__ c1b,
                                               float* __restrict__ c1o) {
    __shared__ __align__(16) float tile[6 * 66 * 29];
    __shared__ __align__(16) float wl[4032];
    int tid = threadIdx.x;
    int wg = blockIdx.x;
    int br = wg >> 9;
    int b = (wg >> 6) & 7;
    int nt = wg & 63;
    int n0 = nt * 4;
    for (int e = tid; e < 11088; e += 256) {
        int c = e % 28;
        int rest = e / 28;
        int mm = rest % 66;
        int nr = rest / 66;
        int n = n0 - 1 + nr;
        int m = mm - 1;
        float v = 0.f;
        if (n >= 0 && n < 256 && m >= 0 && m < 64)
            v = ssum[(((size_t)b * 256 + n) * 64 + m) * 56 + br * 28 + c];
        tile[(nr * 66 + mm) * 29 + c] = v;
    }
    for (int e = tid; e < 4032; e += 256) {
        int o = e & 15;
        int tap = e >> 4;
        wl[e] = c1w[o * 252 + tap];
    }
    __syncthreads();
    int ny = tid >> 6;
    int m = tid & 63;
    float acc[16];
#pragma unroll
    for (int o = 0; o < 16; ++o) acc[o] = 0.f;
    for (int c = 0; c < 28; ++c) {
#pragma unroll
        for (int ky = 0; ky < 3; ++ky) {
#pragma unroll
            for (int kx = 0; kx < 3; ++kx) {
                float iv = tile[((ny + ky) * 66 + (m + kx)) * 29 + c];
                const float4* wp = (const float4*)(wl + (c * 9 + ky * 3 + kx) * 16);
                float4 w0 = wp[0], w1 = wp[1], w2 = wp[2], w3 = wp[3];
                acc[0] += iv * w0.x;  acc[1] += iv * w0.y;  acc[2] += iv * w0.z;  acc[3] += iv * w0.w;
                acc[4] += iv * w1.x;  acc[5] += iv * w1.y;  acc[6] += iv * w1.z;  acc[7] += iv * w1.w;
                acc[8] += iv * w2.x;  acc[9] += iv * w2.y;  acc[10] += iv * w2.z; acc[11] += iv * w2.w;
                acc[12] += iv * w3.x; acc[13] += iv * w3.y; acc[14] += iv * w3.z; acc[15] += iv * w3.w;
            }
        }
    }
    float4 b0 = *(const float4*)(c1b + 0);
    float4 b1 = *(const float4*)(c1b + 4);
    float4 b2 = *(const float4*)(c1b + 8);
    float4 b3 = *(const float4*)(c1b + 12);
    size_t ob = (((size_t)(br * 8 + b) * 16384) + (size_t)(n0 + ny) * 64 + m) * 16;
    float4* op = (float4*)(c1o + ob);
    op[0] = make_float4(fmaxf(acc[0] + b0.x, 0.f), fmaxf(acc[1] + b0.y, 0.f),
                        fmaxf(acc[2] + b0.z, 0.f), fmaxf(acc[3] + b0.w, 0.f));
    op[1] = make_float4(fmaxf(acc[4] + b1.x, 0.f), fmaxf(acc[5] + b1.y, 0.f),
                        fmaxf(acc[6] + b1.z, 0.f), fmaxf(acc[7] + b1.w, 0.f));
    op[2] = make_float4(fmaxf(acc[8] + b2.x, 0.f), fmaxf(acc[9] + b2.y, 0.f),
                        fmaxf(acc[10] + b2.z, 0.f), fmaxf(acc[11] + b2.w, 0.f));
    op[3] = make_float4(fmaxf(acc[12] + b3.x, 0.f), fmaxf(acc[13] + b3.y, 0.f),
                        fmaxf(acc[14] + b3.z, 0.f), fmaxf(acc[15] + b3.w, 0.f));
}

// ------------------------- K3: conv2 + pooled partials ---------------------
__global__ __launch_bounds__(256) void k_conv2(const float* __restrict__ c1o,
                                               const float* __restrict__ c2w,
                                               const float* __restrict__ c2b,
                                               float* __restrict__ part) {
    __shared__ __align__(16) float tile[6 * 66 * 17];
    __shared__ __align__(16) float wl[2304];
    __shared__ float pbuf[4][16];
    int tid = threadIdx.x;
    int wg = blockIdx.x;
    int br = wg >> 9;
    int b = (wg >> 6) & 7;
    int nt = wg & 63;
    int n0 = nt * 4;
    for (int e = tid; e < 6336; e += 256) {
        int c = e & 15;
        int rest = e >> 4;
        int mm = rest % 66;
        int nr = rest / 66;
        int n = n0 - 1 + nr;
        int m = mm - 1;
        float v = 0.f;
        if (n >= 0 && n < 256 && m >= 0 && m < 64)
            v = c1o[(((size_t)(br * 8 + b) * 16384) + (size_t)n * 64 + m) * 16 + c];
        tile[(nr * 66 + mm) * 17 + c] = v;
    }
    for (int e = tid; e < 2304; e += 256) {
        int o = e & 15;
        int tap = e >> 4;
        wl[e] = c2w[o * 144 + tap];
    }
    __syncthreads();
    int ny = tid >> 6;
    int m = tid & 63;
    float acc[16];
#pragma unroll
    for (int o = 0; o < 16; ++o) acc[o] = 0.f;
    for (int c = 0; c < 16; ++c) {
#pragma unroll
        for (int ky = 0; ky < 3; ++ky) {
#pragma unroll
            for (int kx = 0; kx < 3; ++kx) {
                float iv = tile[((ny + ky) * 66 + (m + kx)) * 17 + c];
                const float4* wp = (const float4*)(wl + (c * 9 + ky * 3 + kx) * 16);
                float4 w0 = wp[0], w1 = wp[1], w2 = wp[2], w3 = wp[3];
                acc[0] += iv * w0.x;  acc[1] += iv * w0.y;  acc[2] += iv * w0.z;  acc[3] += iv * w0.w;
                acc[4] += iv * w1.x;  acc[5] += iv * w1.y;  acc[6] += iv * w1.z;  acc[7] += iv * w1.w;
                acc[8] += iv * w2.x;  acc[9] += iv * w2.y;  acc[10] += iv * w2.z; acc[11] += iv * w2.w;
                acc[12] += iv * w3.x; acc[13] += iv * w3.y; acc[14] += iv * w3.z; acc[15] += iv * w3.w;
            }
        }
    }
    int lane = tid & 63;
    int wid = tid >> 6;
#pragma unroll
    for (int o = 0; o < 16; ++o) {
        float s = fmaxf(acc[o] + c2b[o], 0.f);
#pragma unroll
        for (int msk = 1; msk < 64; msk <<= 1) s += __shfl_xor(s, msk);
        if (lane == 0) pbuf[wid][o] = s;
    }
    __syncthreads();
    if (tid < 16) {
        float s = pbuf[0][tid] + pbuf[1][tid] + pbuf[2][tid] + pbuf[3][tid];
        part[(((size_t)(br * 8 + b)) * 64 + nt) * 16 + tid] = s;
    }
}

// ------------------------- K4: reduce + FC -> shifts -----------------------
__global__ void k_fc(const float* __restrict__ part, const float* __restrict__ f1w,
                     const float* __restrict__ f1b, const float* __restrict__ f2w,
                     const float* __restrict__ f2b, float* __restrict__ shif) {
    __shared__ float sb[16][16];
    int t = threadIdx.x;
    int combo = t >> 4;
    int o = t & 15;
    float s = 0.f;
    for (int nt = 0; nt < 64; ++nt) s += part[((size_t)combo * 64 + nt) * 16 + o];
    sb[combo][o] = s * (1.0f / 16384.0f);
    __syncthreads();
    if (t < 16) {
        float p0 = f1b[0], p1 = f1b[1], rg = f2b[0];
        for (int oo = 0; oo < 16; ++oo) {
            float sv = sb[t][oo];
            p0 += sv * f1w[oo * 2 + 0];
            p1 += sv * f1w[oo * 2 + 1];
            rg += sv * f2w[oo];
        }
        shif[t * 2 + 0] = rg * tanhf(p0);
        shif[t * 2 + 1] = rg * tanhf(p1);
    }
}

// ------------------------- K5a/b: shifted pos precompute -------------------
__global__ __launch_bounds__(256) void k_pos1(const float* __restrict__ pos1,
                                              const float* __restrict__ shif,
                                              float* __restrict__ P1T) {
    int b = blockIdx.x;
    float sx = shif[b * 2 + 0];
    float sy = shif[b * 2 + 1];
    for (int e = threadIdx.x; e < 4096; e += 256) {
        int j = e >> 6;
        int i = e & 63;
        int y0, y1, x0, x1;
        float wy0, wy1, wx0, wx1;
        coords_(i, 64, sy, y0, y1, wy0, wy1);
        coords_(j, 64, sx, x0, x1, wx0, wx1);
        float v = pos1[((i - 1) & 63) * 64 + ((j - 1) & 63)] +
                  wy0 * (wx0 * pos1[y0 * 64 + x0] + wx1 * pos1[y0 * 64 + x1]) +
                  wy1 * (wx0 * pos1[y1 * 64 + x0] + wx1 * pos1[y1 * 64 + x1]);
        P1T[(size_t)b * 4096 + j * 64 + i] = v;
    }
}

__global__ __launch_bounds__(256) void k_pos2(const float* __restrict__ pos2,
                                              const float* __restrict__ shif,
                                              float* __restrict__ P2T) {
    int wg = blockIdx.x;
    int b = wg >> 8;
    int j = wg & 255;
    float sx = shif[16 + b * 2 + 0];
    float sy = shif[16 + b * 2 + 1];
    int i = threadIdx.x;
    int y0, y1, x0, x1;
    float wy0, wy1, wx0, wx1;
    coords_(i, 256, sy, y0, y1, wy0, wy1);
    coords_(j, 256, sx, x0, x1, wx0, wx1);
    float v = pos2[((i - 1) & 255) * 256 + ((j - 1) & 255)] +
              wy0 * (wx0 * pos2[y0 * 256 + x0] + wx1 * pos2[y0 * 256 + x1]) +
              wy1 * (wx0 * pos2[y1 * 256 + x0] + wx1 * pos2[y1 * 256 + x1]);
    P2T[(size_t)b * 65536 + (size_t)j * 256 + i] = v;
}

// --------------------- K6: branch-1 window attention (64x64) ---------------
__global__ __launch_bounds__(256) void k_attn1(const float* __restrict__ q1,
                                               const float* __restrict__ k1,
                                               const float* __restrict__ v1,
                                               const float* __restrict__ P1T,
                                               const float* __restrict__ shif,
                                               float* __restrict__ aout) {
    __shared__ __align__(16) float rawq[64 * 29];
    __shared__ __align__(16) float rawk[64 * 29];
    __shared__ __align__(16) float rawv[64 * 30];
    __shared__ __align__(16) float augu[7616];  // augqT[56][68] | augkT[56][68]; pT[64][68] overlays
    float* augqT = augu;
    float* augkT = augu + 3808;
    float* pT = augu;
    int tid = threadIdx.x;
    int wg = blockIdx.x;
    int b = wg >> 8;
    int n = wg & 255;
    size_t gb = (size_t)(b * 256 + n) * 1792;
    for (int e = tid; e < 1792; e += 256) {
        int r = e / 28;
        int c = e - r * 28;
        rawq[r * 29 + c] = q1[gb + e];
        rawk[r * 29 + c] = k1[gb + e];
        rawv[r * 30 + c] = v1[gb + e];
    }
    __syncthreads();
    float sx = shif[b * 2 + 0];
    float sy = shif[b * 2 + 1];
    {
        int i = tid & 63;
        int dc = tid >> 6;
        int y0, y1;
        float wy0, wy1;
        coords_(i, 64, sy, y0, y1, wy0, wy1);
        int rm = (i - 1) & 63;
        for (int d = dc * 14; d < dc * 14 + 14; ++d) {
            float v;
            if (d < 28) v = SCALE_ * rawq[rm * 29 + d];
            else {
                int c = d - 28;
                v = SCALE_ * (wy0 * rawq[y0 * 29 + c] + wy1 * rawq[y1 * 29 + c]);
            }
            augqT[d * 68 + i] = v;
        }
        int x0, x1;
        float wx0, wx1;
        coords_(i, 64, sx, x0, x1, wx0, wx1);
        for (int d = dc * 14; d < dc * 14 + 14; ++d) {
            float v;
            if (d < 28) v = rawk[rm * 29 + d];
            else {
                int c = d - 28;
                v = wx0 * rawk[x0 * 29 + c] + wx1 * rawk[x1 * 29 + c];
            }
            augkT[d * 68 + i] = v;
        }
    }
    __syncthreads();
    int ig = tid >> 4, jg = tid & 15;
    int i0 = ig * 4, j0 = jg * 4;
    float p[4][4];
#pragma unroll
    for (int jj = 0; jj < 4; ++jj) {
        float4 t = *(const float4*)(P1T + (size_t)b * 4096 + (size_t)(j0 + jj) * 64 + i0);
        p[0][jj] = t.x; p[1][jj] = t.y; p[2][jj] = t.z; p[3][jj] = t.w;
    }
    for (int d = 0; d < 56; ++d) {
        float4 aq = *(const float4*)(augqT + d * 68 + i0);
        float4 ak = *(const float4*)(augkT + d * 68 + j0);
        float aqv[4] = {aq.x, aq.y, aq.z, aq.w};
        float akv[4] = {ak.x, ak.y, ak.z, ak.w};
#pragma unroll
        for (int r = 0; r < 4; ++r)
#pragma unroll
            for (int jj = 0; jj < 4; ++jj) p[r][jj] += aqv[r] * akv[jj];
    }
    float inv[4];
#pragma unroll
    for (int r = 0; r < 4; ++r) {
        float mx = fmaxf(fmaxf(p[r][0], p[r][1]), fmaxf(p[r][2], p[r][3]));
#pragma unroll
        for (int msk = 1; msk < 16; msk <<= 1) mx = fmaxf(mx, __shfl_xor(mx, msk));
        float s = 0.f;
#pragma unroll
        for (int jj = 0; jj < 4; ++jj) {
            p[r][jj] = __expf(p[r][jj] - mx);
            s += p[r][jj];
        }
#pragma unroll
        for (int msk = 1; msk < 16; msk <<= 1) s += __shfl_xor(s, msk);
        inv[r] = 1.0f / s;
    }
    __syncthreads();  // aug reads done; pT overlays augu
#pragma unroll
    for (int jj = 0; jj < 4; ++jj)
        *(float4*)(pT + (size_t)(j0 + jj) * 68 + i0) =
            make_float4(p[0][jj] * inv[0], p[1][jj] * inv[1], p[2][jj] * inv[2], p[3][jj] * inv[3]);
    __syncthreads();
    if (tid < 224) {
        int rg = tid / 14;
        int cg = tid - rg * 14;
        float o00 = 0, o01 = 0, o10 = 0, o11 = 0, o20 = 0, o21 = 0, o30 = 0, o31 = 0;
        for (int j = 0; j < 64; ++j) {
            float4 pv = *(const float4*)(pT + (size_t)j * 68 + rg * 4);
            float2 vv = *(const float2*)(rawv + j * 30 + cg * 2);
            o00 += pv.x * vv.x; o01 += pv.x * vv.y;
            o10 += pv.y * vv.x; o11 += pv.y * vv.y;
            o20 += pv.z * vv.x; o21 += pv.z * vv.y;
            o30 += pv.w * vv.x; o31 += pv.w * vv.y;
        }
        size_t base56 = (size_t)(b * 256 + n) * 64 * 56;
        size_t wb = base56 + (size_t)(rg * 4) * 56 + cg * 2;
        *(float2*)(aout + wb) = make_float2(o00, o01);
        *(float2*)(aout + wb + 56) = make_float2(o10, o11);
        *(float2*)(aout + wb + 112) = make_float2(o20, o21);
        *(float2*)(aout + wb + 168) = make_float2(o30, o31);
    }
}

// -------------------- K7: branch-2 cross-window attn (256x256) -------------
// One 1024-thread block per (b,m). LDS: buf[256][29] (staging; later vT[28][260]),
// augqT[56][260], augkT[56][260]. 146,176 B dynamic.
__global__ __launch_bounds__(1024) void k_attn2(const float* __restrict__ q2,
                                                const float* __restrict__ k2,
                                                const float* __restrict__ v2,
                                                const float* __restrict__ P2T,
                                                const float* __restrict__ shif,
                                                float* __restrict__ aout) {
    extern __shared__ __align__(16) float lds[];
    float* buf = lds;               // 7424 f  (staging [256][29]; later vT [28][260])
    float* augqT = lds + 7424;      // 14560 f [56][260]
    float* augkT = lds + 21984;     // 14560 f [56][260]
    int tid = threadIdx.x;
    int bm = blockIdx.x;
    int b = bm >> 6;
    int m = bm & 63;
    size_t gbase = (size_t)bm * 7168;
    float sx = shif[16 + b * 2 + 0];
    float sy = shif[16 + b * 2 + 1];
    int i = tid & 255;
    int dc = tid >> 8;
    int y0, y1, x0, x1;
    float wy0, wy1, wx0, wx1;
    coords_(i, 256, sy, y0, y1, wy0, wy1);
    coords_(i, 256, sx, x0, x1, wx0, wx1);
    int rm = (i - 1) & 255;
    // stage q -> buf, build augqT
    for (int e = tid; e < 7168; e += 1024) {
        int r = e / 28;
        int c = e - r * 28;
        buf[r * 29 + c] = q2[gbase + e];
    }
    __syncthreads();
    for (int d = dc * 14; d < dc * 14 + 14; ++d) {
        float v;
        if (d < 28) v = SCALE_ * buf[rm * 29 + d];
        else {
            int c = d - 28;
            v = SCALE_ * (wy0 * buf[y0 * 29 + c] + wy1 * buf[y1 * 29 + c]);
        }
        augqT[d * 260 + i] = v;
    }
    __syncthreads();
    // stage k -> buf, build augkT
    for (int e = tid; e < 7168; e += 1024) {
        int r = e / 28;
        int c = e - r * 28;
        buf[r * 29 + c] = k2[gbase + e];
    }
    __syncthreads();
    for (int d = dc * 14; d < dc * 14 + 14; ++d) {
        float v;
        if (d < 28) v = buf[rm * 29 + d];
        else {
            int c = d - 28;
            v = wx0 * buf[x0 * 29 + c] + wx1 * buf[x1 * 29 + c];
        }
        augkT[d * 260 + i] = v;
    }
    __syncthreads();
    // stage v transposed: vT[28][260] into buf region
    for (int e = tid; e < 7168; e += 1024) {
        int r = e / 28;
        int c = e - r * 28;
        buf[c * 260 + r] = v2[gbase + e];
    }
    __syncthreads();
    // sim: thread (ig 0..63, jg 0..15): rows i0..i0+3, j in 4 groups of 4
    int ig = tid >> 4, jg = tid & 15;
    int i0 = ig * 4;
    float p[4][16];
    {
        size_t pb = (size_t)b * 65536 + i0;
#pragma unroll
        for (int g = 0; g < 4; ++g)
#pragma unroll
            for (int jj = 0; jj < 4; ++jj) {
                int j = g * 64 + jg * 4 + jj;
                float4 t = *(const float4*)(P2T + pb + (size_t)j * 256);
                p[0][g * 4 + jj] = t.x; p[1][g * 4 + jj] = t.y;
                p[2][g * 4 + jj] = t.z; p[3][g * 4 + jj] = t.w;
            }
    }
    for (int d = 0; d < 56; ++d) {
        float4 aq = *(const float4*)(augqT + d * 260 + i0);
        float aqv[4] = {aq.x, aq.y, aq.z, aq.w};
#pragma unroll
        for (int g = 0; g < 4; ++g) {
            float4 ak = *(const float4*)(augkT + d * 260 + g * 64 + jg * 4);
            float akv[4] = {ak.x, ak.y, ak.z, ak.w};
#pragma unroll
            for (int r = 0; r < 4; ++r)
#pragma unroll
                for (int jj = 0; jj < 4; ++jj) p[r][g * 4 + jj] += aqv[r] * akv[jj];
        }
    }
    float inv[4];
#pragma unroll
    for (int r = 0; r < 4; ++r) {
        float mx = p[r][0];
#pragma unroll
        for (int jj = 1; jj < 16; ++jj) mx = fmaxf(mx, p[r][jj]);
#pragma unroll
        for (int msk = 1; msk < 16; msk <<= 1) mx = fmaxf(mx, __shfl_xor(mx, msk));
        float s = 0.f;
#pragma unroll
        for (int jj = 0; jj < 16; ++jj) {
            p[r][jj] = __expf(p[r][jj] - mx);
            s += p[r][jj];
        }
#pragma unroll
        for (int msk = 1; msk < 16; msk <<= 1) s += __shfl_xor(s, msk);
        inv[r] = 1.0f / s;
    }
    // PV: per d-chunk c, partial o over this thread's 16 j, butterfly over jg lanes
    float oo[4][4];
#pragma unroll
    for (int r = 0; r < 4; ++r)
#pragma unroll
        for (int dd = 0; dd < 4; ++dd) oo[r][dd] = 0.f;
#pragma unroll
    for (int c = 0; c < 7; ++c) {
        float o[4][4];
#pragma unroll
        for (int r = 0; r < 4; ++r)
#pragma unroll
            for (int dd = 0; dd < 4; ++dd) o[r][dd] = 0.f;
#pragma unroll
        for (int g = 0; g < 4; ++g)
#pragma unroll
            for (int dd = 0; dd < 4; ++dd) {
                float4 vv = *(const float4*)(buf + (size_t)(c * 4 + dd) * 260 + g * 64 + jg * 4);
#pragma unroll
                for (int r = 0; r < 4; ++r)
                    o[r][dd] += p[r][g * 4 + 0] * vv.x + p[r][g * 4 + 1] * vv.y +
                                p[r][g * 4 + 2] * vv.z + p[r][g * 4 + 3] * vv.w;
            }
#pragma unroll
        for (int msk = 1; msk < 16; msk <<= 1)
#pragma unroll
            for (int r = 0; r < 4; ++r)
#pragma unroll
                for (int dd = 0; dd < 4; ++dd) o[r][dd] += __shfl_xor(o[r][dd], msk);
        if (jg == c) {
#pragma unroll
            for (int r = 0; r < 4; ++r)
#pragma unroll
                for (int dd = 0; dd < 4; ++dd) oo[r][dd] = o[r][dd] * inv[r];
        }
    }
    if (jg < 7) {
#pragma unroll
        for (int r = 0; r < 4; ++r) {
            size_t wb = (((size_t)b * 256 + i0 + r) * 64 + m) * 56 + 28 + jg * 4;
            *(float4*)(aout + wb) = make_float4(oo[r][0], oo[r][1], oo[r][2], oo[r][3]);
        }
    }
}

// ----------------------- K8: output projection + unwindow ------------------
template <int C0>
__device__ __forceinline__ void out_chunk(const float* xrow, const float* __restrict__ W,
                                          const float* __restrict__ bout, float* __restrict__ dst) {
    float acc[28];
#pragma unroll
    for (int c = 0; c < 28; ++c) acc[c] = 0.f;
    for (int d = 0; d < 56; ++d) {
        float xv = xrow[d];
        const float4* wr = (const float4*)(W + d * 56 + C0);
#pragma unroll
        for (int k = 0; k < 7; ++k) {
            float4 w = wr[k];
            acc[4 * k + 0] += xv * w.x;
            acc[4 * k + 1] += xv * w.y;
            acc[4 * k + 2] += xv * w.z;
            acc[4 * k + 3] += xv * w.w;
        }
    }
    float4* op = (float4*)(dst + C0);
#pragma unroll
    for (int k = 0; k < 7; ++k) {
        float4 bb = *(const float4*)(bout + C0 + 4 * k);
        op[k] = make_float4(acc[4 * k + 0] + bb.x, acc[4 * k + 1] + bb.y,
                            acc[4 * k + 2] + bb.z, acc[4 * k + 3] + bb.w);
    }
}

__global__ __launch_bounds__(256) void k_out(const float* __restrict__ aout,
                                             const float* __restrict__ Wout,
                                             const float* __restrict__ bout,
                                             float* __restrict__ out) {
    __shared__ __align__(16) float xlds[256 * 57];
    int tid = threadIdx.x;
    int pix = blockIdx.x * 256 + tid;
    int b = pix >> 14;
    int r2 = pix & 16383;
    int n = r2 >> 6;
    int m = r2 & 63;
    float* xrow = xlds + tid * 57;
    const float4* ap = (const float4*)(aout + (size_t)pix * 56);
#pragma unroll
    for (int k = 0; k < 14; ++k) {
        float4 t = ap[k];
        xrow[4 * k + 0] = t.x;
        xrow[4 * k + 1] = t.y;
        xrow[4 * k + 2] = t.z;
        xrow[4 * k + 3] = t.w;
    }
    int h = ((n >> 4) << 3) + (m >> 3);
    int w = ((n & 15) << 3) + (m & 7);
    float* dst = out + (((size_t)b * 128 + h) * 128 + w) * 56;
    out_chunk<0>(xrow, Wout, bout, dst);
    out_chunk<28>(xrow, Wout, bout, dst);
}

// ---------------------------------------------------------------------------
extern "C" void kernel_launch(void* const* d_in, const int* in_sizes, int n_in,
                              void* d_out, int out_size, void* d_ws, size_t ws_size,
                              hipStream_t stream) {
    const float* x = (const float*)d_in[0];
    const float* pos1 = (const float*)d_in[1];
    const float* pos2 = (const float*)d_in[2];
    const float* Wq = (const float*)d_in[3];
    const float* Wkv = (const float*)d_in[4];
    const float* Wout = (const float*)d_in[5];
    const float* bout = (const float*)d_in[6];
    const float* c1w = (const float*)d_in[7];
    const float* c1b = (const float*)d_in[8];
    const float* c2w = (const float*)d_in[9];
    const float* c2b = (const float*)d_in[10];
    const float* f1w = (const float*)d_in[11];
    const float* f1b = (const float*)d_in[12];
    const float* f2w = (const float*)d_in[13];
    const float* f2b = (const float*)d_in[14];

    float* ws = (float*)d_ws;
    float* q1 = ws;
    float* k1 = q1 + 3670016;
    float* v1 = k1 + 3670016;
    float* q2 = v1 + 3670016;
    float* k2 = q2 + 3670016;
    float* v2 = k2 + 3670016;
    float* ssum = v2 + 3670016;
    float* aout = ssum;  // reuse after conv1 consumed ssum
    float* c1o = ssum + 7340032;
    float* part = c1o + 4194304;
    float* shif = part + 16384;
    float* P1T = shif + 32;
    float* P2T = P1T + 32768;
    float* outp = (float*)d_out;

    (void)hipFuncSetAttribute((const void*)k_attn2,
                              hipFuncAttributeMaxDynamicSharedMemorySize, 146176);

    k_qkv<<<512, 256, 0, stream>>>(x, Wq, Wkv, q1, k1, v1, q2, k2, v2, ssum);
    k_conv1<<<1024, 256, 0, stream>>>(ssum, c1w, c1b, c1o);
    k_conv2<<<1024, 256, 0, stream>>>(c1o, c2w, c2b, part);
    k_fc<<<1, 256, 0, stream>>>(part, f1w, f1b, f2w, f2b, shif);
    k_pos1<<<8, 256, 0, stream>>>(pos1, shif, P1T);
    k_pos2<<<2048, 256, 0, stream>>>(pos2, shif, P2T);
    k_attn1<<<2048, 256, 0, stream>>>(q1, k1, v1, P1T, shif, aout);
    k_attn2<<<512, 1024, 146176, stream>>>(q2, k2, v2, P2T, shif, aout);
    k_out<<<512, 256, 0, stream>>>(aout, Wout, bout, outp);
}

// Round 3
// 421.927 us; speedup vs baseline: 1.9615x; 1.9615x over previous
//
#include <hip/hip_runtime.h>
#include <cstdint>

// ---------------------------------------------------------------------------
// SS-MSA fused implementation, round 3.
// grid_shift(sim) factorizes: shifted[i,j] = SCALE*(q_{i-1}.k_{j-1} + q~_i.k~_j) + P[i,j]
// => both branches are plain attention with 56-dim augmented Q/K + bias P.
//
// Round-3 changes vs round 2 (which spilled: attn2 p[4][16] at VGPR=64 ->
// 1.7 GB scratch traffic):
//  - k_attn2: flash-style, ONE ROW PER THREAD. q row in 56 VGPRs (static
//    unroll), augK f32 [56][264] + V bf16 [28][264] in LDS (73.9 KB ->
//    2 blocks/CU), online softmax over j-tiles of 8, O[28] in regs. No spill.
//  - P2 bias row-major (P2R[b][i][j]) for contiguous per-row bias loads.
//  - k_qkv/k_out: weights staged in LDS (was: per-thread L2 streams of
//    37.6/12.5 KB -> multi-GB L2 traffic).
// ---------------------------------------------------------------------------

#define SCALE_ 0.18898223650461364f  // 28^-0.5

__device__ __forceinline__ void coords_(int idx, int S, float s,
                                        int& i0, int& i1, float& w0, float& w1) {
    float g = -1.0f + 2.0f * (float)idx / (float)(S - 1);
    float c = (g + s * 2.0f / (float)S + 1.0f) * 0.5f * (float)(S - 1);
    float span = (float)(S - 1);
    c = fabsf(c);
    c = fmodf(c, 2.0f * span);
    if (c > span) c = 2.0f * span - c;
    int f = (int)floorf(c);
    f = max(0, min(f, S - 1));
    i0 = f;
    i1 = min(f + 1, S - 1);
    w1 = c - (float)f;
    w0 = 1.0f - w1;
}

// ------------------------------- K1: QKV GEMM ------------------------------
// W staged in LDS (56x56 at a time); x row per-thread in LDS.
template <int C0>
__device__ __forceinline__ void qkv_chunk56(const float* xrow, const float* wl,
                                            float* __restrict__ outp, float* ss) {
    float acc[28];
#pragma unroll
    for (int c = 0; c < 28; ++c) acc[c] = 0.f;
    for (int d = 0; d < 56; ++d) {
        float xv = xrow[d];
        const float4* wr = (const float4*)(wl + d * 56 + C0);
#pragma unroll
        for (int k = 0; k < 7; ++k) {
            float4 w = wr[k];
            acc[4 * k + 0] += xv * w.x;
            acc[4 * k + 1] += xv * w.y;
            acc[4 * k + 2] += xv * w.z;
            acc[4 * k + 3] += xv * w.w;
        }
    }
    float4* op = (float4*)outp;
#pragma unroll
    for (int k = 0; k < 7; ++k)
        op[k] = make_float4(acc[4 * k + 0], acc[4 * k + 1], acc[4 * k + 2], acc[4 * k + 3]);
#pragma unroll
    for (int c = 0; c < 28; ++c) ss[c] += acc[c];
}

__global__ __launch_bounds__(256, 2) void k_qkv(const float* __restrict__ x,
                                                const float* __restrict__ Wq,
                                                const float* __restrict__ Wkv,
                                                float* __restrict__ q1, float* __restrict__ k1,
                                                float* __restrict__ v1, float* __restrict__ q2,
                                                float* __restrict__ k2, float* __restrict__ v2,
                                                float* __restrict__ ssum) {
    __shared__ __align__(16) float xl[256 * 57];
    __shared__ __align__(16) float wl[3136];
    int tid = threadIdx.x;
    int pix = blockIdx.x * 256 + tid;
    int b = pix >> 14;
    int rem = pix & 16383;
    int hh = rem >> 7;
    int ww = rem & 127;
    int n = ((hh >> 3) << 4) + (ww >> 3);
    int m = ((hh & 7) << 3) + (ww & 7);
    float* xrow = xl + tid * 57;
    const float4* xp = (const float4*)(x + (size_t)pix * 56);
#pragma unroll
    for (int k = 0; k < 14; ++k) {
        float4 t = xp[k];
        xrow[4 * k + 0] = t.x;
        xrow[4 * k + 1] = t.y;
        xrow[4 * k + 2] = t.z;
        xrow[4 * k + 3] = t.w;
    }
    size_t p1 = ((size_t)(b * 256 + n) * 64 + m) * 28;   // branch1 layout
    size_t p2 = ((size_t)(b * 64 + m) * 256 + n) * 28;   // branch2 layout
    size_t ob = ((size_t)(b * 256 + n) * 64 + m) * 56;   // ssum layout
    float ssA[28], ssB[28];
#pragma unroll
    for (int c = 0; c < 28; ++c) { ssA[c] = 0.f; ssB[c] = 0.f; }
    // stage Wq
    for (int e = tid; e < 3136; e += 256) wl[e] = Wq[e];
    __syncthreads();
    qkv_chunk56<0>(xrow, wl, q1 + p1, ssA);
    qkv_chunk56<28>(xrow, wl, q2 + p2, ssB);
    __syncthreads();
    // stage Wk (Wkv cols 0..55)
    for (int e = tid; e < 3136; e += 256) {
        int d = e / 56;
        int c = e - d * 56;
        wl[e] = Wkv[d * 112 + c];
    }
    __syncthreads();
    qkv_chunk56<0>(xrow, wl, k1 + p1, ssA);
    qkv_chunk56<28>(xrow, wl, k2 + p2, ssB);
    __syncthreads();
    // stage Wv (Wkv cols 56..111)
    for (int e = tid; e < 3136; e += 256) {
        int d = e / 56;
        int c = e - d * 56;
        wl[e] = Wkv[d * 112 + 56 + c];
    }
    __syncthreads();
    qkv_chunk56<0>(xrow, wl, v1 + p1, ssA);
    qkv_chunk56<28>(xrow, wl, v2 + p2, ssB);
    float4* sp = (float4*)(ssum + ob);
#pragma unroll
    for (int k = 0; k < 7; ++k)
        sp[k] = make_float4(ssA[4 * k + 0], ssA[4 * k + 1], ssA[4 * k + 2], ssA[4 * k + 3]);
#pragma unroll
    for (int k = 0; k < 7; ++k)
        sp[7 + k] = make_float4(ssB[4 * k + 0], ssB[4 * k + 1], ssB[4 * k + 2], ssB[4 * k + 3]);
}

// ------------------------------- K2: conv1 ---------------------------------
__global__ __launch_bounds__(256) void k_conv1(const float* __restrict__ ssum,
                                               const float* __restrict__ c1w,
                                               const float* __restrict__ c1b,
                                               float* __restrict__ c1o) {
    __shared__ __align__(16) float tile[6 * 66 * 29];
    __shared__ __align__(16) float wl[4032];
    int tid = threadIdx.x;
    int wg = blockIdx.x;
    int br = wg >> 9;
    int b = (wg >> 6) & 7;
    int nt = wg & 63;
    int n0 = nt * 4;
    for (int e = tid; e < 11088; e += 256) {
        int c = e % 28;
        int rest = e / 28;
        int mm = rest % 66;
        int nr = rest / 66;
        int n = n0 - 1 + nr;
        int m = mm - 1;
        float v = 0.f;
        if (n >= 0 && n < 256 && m >= 0 && m < 64)
            v = ssum[(((size_t)b * 256 + n) * 64 + m) * 56 + br * 28 + c];
        tile[(nr * 66 + mm) * 29 + c] = v;
    }
    for (int e = tid; e < 4032; e += 256) {
        int o = e & 15;
        int tap = e >> 4;
        wl[e] = c1w[o * 252 + tap];
    }
    __syncthreads();
    int ny = tid >> 6;
    int m = tid & 63;
    float acc[16];
#pragma unroll
    for (int o = 0; o < 16; ++o) acc[o] = 0.f;
    for (int c = 0; c < 28; ++c) {
#pragma unroll
        for (int ky = 0; ky < 3; ++ky) {
#pragma unroll
            for (int kx = 0; kx < 3; ++kx) {
                float iv = tile[((ny + ky) * 66 + (m + kx)) * 29 + c];
                const float4* wp = (const float4*)(wl + (c * 9 + ky * 3 + kx) * 16);
                float4 w0 = wp[0], w1 = wp[1], w2 = wp[2], w3 = wp[3];
                acc[0] += iv * w0.x;  acc[1] += iv * w0.y;  acc[2] += iv * w0.z;  acc[3] += iv * w0.w;
                acc[4] += iv * w1.x;  acc[5] += iv * w1.y;  acc[6] += iv * w1.z;  acc[7] += iv * w1.w;
                acc[8] += iv * w2.x;  acc[9] += iv * w2.y;  acc[10] += iv * w2.z; acc[11] += iv * w2.w;
                acc[12] += iv * w3.x; acc[13] += iv * w3.y; acc[14] += iv * w3.z; acc[15] += iv * w3.w;
            }
        }
    }
    float4 b0 = *(const float4*)(c1b + 0);
    float4 b1 = *(const float4*)(c1b + 4);
    float4 b2 = *(const float4*)(c1b + 8);
    float4 b3 = *(const float4*)(c1b + 12);
    size_t ob = (((size_t)(br * 8 + b) * 16384) + (size_t)(n0 + ny) * 64 + m) * 16;
    float4* op = (float4*)(c1o + ob);
    op[0] = make_float4(fmaxf(acc[0] + b0.x, 0.f), fmaxf(acc[1] + b0.y, 0.f),
                        fmaxf(acc[2] + b0.z, 0.f), fmaxf(acc[3] + b0.w, 0.f));
    op[1] = make_float4(fmaxf(acc[4] + b1.x, 0.f), fmaxf(acc[5] + b1.y, 0.f),
                        fmaxf(acc[6] + b1.z, 0.f), fmaxf(acc[7] + b1.w, 0.f));
    op[2] = make_float4(fmaxf(acc[8] + b2.x, 0.f), fmaxf(acc[9] + b2.y, 0.f),
                        fmaxf(acc[10] + b2.z, 0.f), fmaxf(acc[11] + b2.w, 0.f));
    op[3] = make_float4(fmaxf(acc[12] + b3.x, 0.f), fmaxf(acc[13] + b3.y, 0.f),
                        fmaxf(acc[14] + b3.z, 0.f), fmaxf(acc[15] + b3.w, 0.f));
}

// ------------------------- K3: conv2 + pooled partials ---------------------
__global__ __launch_bounds__(256) void k_conv2(const float* __restrict__ c1o,
                                               const float* __restrict__ c2w,
                                               const float* __restrict__ c2b,
                                               float* __restrict__ part) {
    __shared__ __align__(16) float tile[6 * 66 * 17];
    __shared__ __align__(16) float wl[2304];
    __shared__ float pbuf[4][16];
    int tid = threadIdx.x;
    int wg = blockIdx.x;
    int br = wg >> 9;
    int b = (wg >> 6) & 7;
    int nt = wg & 63;
    int n0 = nt * 4;
    for (int e = tid; e < 6336; e += 256) {
        int c = e & 15;
        int rest = e >> 4;
        int mm = rest % 66;
        int nr = rest / 66;
        int n = n0 - 1 + nr;
        int m = mm - 1;
        float v = 0.f;
        if (n >= 0 && n < 256 && m >= 0 && m < 64)
            v = c1o[(((size_t)(br * 8 + b) * 16384) + (size_t)n * 64 + m) * 16 + c];
        tile[(nr * 66 + mm) * 17 + c] = v;
    }
    for (int e = tid; e < 2304; e += 256) {
        int o = e & 15;
        int tap = e >> 4;
        wl[e] = c2w[o * 144 + tap];
    }
    __syncthreads();
    int ny = tid >> 6;
    int m = tid & 63;
    float acc[16];
#pragma unroll
    for (int o = 0; o < 16; ++o) acc[o] = 0.f;
    for (int c = 0; c < 16; ++c) {
#pragma unroll
        for (int ky = 0; ky < 3; ++ky) {
#pragma unroll
            for (int kx = 0; kx < 3; ++kx) {
                float iv = tile[((ny + ky) * 66 + (m + kx)) * 17 + c];
                const float4* wp = (const float4*)(wl + (c * 9 + ky * 3 + kx) * 16);
                float4 w0 = wp[0], w1 = wp[1], w2 = wp[2], w3 = wp[3];
                acc[0] += iv * w0.x;  acc[1] += iv * w0.y;  acc[2] += iv * w0.z;  acc[3] += iv * w0.w;
                acc[4] += iv * w1.x;  acc[5] += iv * w1.y;  acc[6] += iv * w1.z;  acc[7] += iv * w1.w;
                acc[8] += iv * w2.x;  acc[9] += iv * w2.y;  acc[10] += iv * w2.z; acc[11] += iv * w2.w;
                acc[12] += iv * w3.x; acc[13] += iv * w3.y; acc[14] += iv * w3.z; acc[15] += iv * w3.w;
            }
        }
    }
    int lane = tid & 63;
    int wid = tid >> 6;
#pragma unroll
    for (int o = 0; o < 16; ++o) {
        float s = fmaxf(acc[o] + c2b[o], 0.f);
#pragma unroll
        for (int msk = 1; msk < 64; msk <<= 1) s += __shfl_xor(s, msk);
        if (lane == 0) pbuf[wid][o] = s;
    }
    __syncthreads();
    if (tid < 16) {
        float s = pbuf[0][tid] + pbuf[1][tid] + pbuf[2][tid] + pbuf[3][tid];
        part[(((size_t)(br * 8 + b)) * 64 + nt) * 16 + tid] = s;
    }
}

// ------------------------- K4: reduce + FC -> shifts -----------------------
__global__ void k_fc(const float* __restrict__ part, const float* __restrict__ f1w,
                     const float* __restrict__ f1b, const float* __restrict__ f2w,
                     const float* __restrict__ f2b, float* __restrict__ shif) {
    __shared__ float sb[16][16];
    int t = threadIdx.x;
    int combo = t >> 4;
    int o = t & 15;
    float s = 0.f;
    for (int nt = 0; nt < 64; ++nt) s += part[((size_t)combo * 64 + nt) * 16 + o];
    sb[combo][o] = s * (1.0f / 16384.0f);
    __syncthreads();
    if (t < 16) {
        float p0 = f1b[0], p1 = f1b[1], rg = f2b[0];
        for (int oo = 0; oo < 16; ++oo) {
            float sv = sb[t][oo];
            p0 += sv * f1w[oo * 2 + 0];
            p1 += sv * f1w[oo * 2 + 1];
            rg += sv * f2w[oo];
        }
        shif[t * 2 + 0] = rg * tanhf(p0);
        shif[t * 2 + 1] = rg * tanhf(p1);
    }
}

// ------------------------- K5a/b: shifted pos precompute -------------------
__global__ __launch_bounds__(256) void k_pos1(const float* __restrict__ pos1,
                                              const float* __restrict__ shif,
                                              float* __restrict__ P1T) {
    int b = blockIdx.x;
    float sx = shif[b * 2 + 0];
    float sy = shif[b * 2 + 1];
    for (int e = threadIdx.x; e < 4096; e += 256) {
        int j = e >> 6;
        int i = e & 63;
        int y0, y1, x0, x1;
        float wy0, wy1, wx0, wx1;
        coords_(i, 64, sy, y0, y1, wy0, wy1);
        coords_(j, 64, sx, x0, x1, wx0, wx1);
        float v = pos1[((i - 1) & 63) * 64 + ((j - 1) & 63)] +
                  wy0 * (wx0 * pos1[y0 * 64 + x0] + wx1 * pos1[y0 * 64 + x1]) +
                  wy1 * (wx0 * pos1[y1 * 64 + x0] + wx1 * pos1[y1 * 64 + x1]);
        P1T[(size_t)b * 4096 + j * 64 + i] = v;
    }
}

// P2 bias, ROW-major: P2R[b][i][j]. Block = (b,i), thread = j -> coalesced.
__global__ __launch_bounds__(256) void k_pos2(const float* __restrict__ pos2,
                                              const float* __restrict__ shif,
                                              float* __restrict__ P2R) {
    int wg = blockIdx.x;
    int b = wg >> 8;
    int i = wg & 255;
    float sx = shif[16 + b * 2 + 0];
    float sy = shif[16 + b * 2 + 1];
    int j = threadIdx.x;
    int y0, y1, x0, x1;
    float wy0, wy1, wx0, wx1;
    coords_(i, 256, sy, y0, y1, wy0, wy1);
    coords_(j, 256, sx, x0, x1, wx0, wx1);
    float v = pos2[((i - 1) & 255) * 256 + ((j - 1) & 255)] +
              wy0 * (wx0 * pos2[y0 * 256 + x0] + wx1 * pos2[y0 * 256 + x1]) +
              wy1 * (wx0 * pos2[y1 * 256 + x0] + wx1 * pos2[y1 * 256 + x1]);
    P2R[(size_t)b * 65536 + (size_t)i * 256 + j] = v;
}

// --------------------- K6: branch-1 window attention (64x64) ---------------
__global__ __launch_bounds__(256) void k_attn1(const float* __restrict__ q1,
                                               const float* __restrict__ k1,
                                               const float* __restrict__ v1,
                                               const float* __restrict__ P1T,
                                               const float* __restrict__ shif,
                                               float* __restrict__ aout) {
    __shared__ __align__(16) float rawq[64 * 29];
    __shared__ __align__(16) float rawk[64 * 29];
    __shared__ __align__(16) float rawv[64 * 30];
    __shared__ __align__(16) float augu[7616];  // augqT[56][68] | augkT[56][68]; pT[64][68] overlays
    float* augqT = augu;
    float* augkT = augu + 3808;
    float* pT = augu;
    int tid = threadIdx.x;
    int wg = blockIdx.x;
    int b = wg >> 8;
    int n = wg & 255;
    size_t gb = (size_t)(b * 256 + n) * 1792;
    for (int e = tid; e < 1792; e += 256) {
        int r = e / 28;
        int c = e - r * 28;
        rawq[r * 29 + c] = q1[gb + e];
        rawk[r * 29 + c] = k1[gb + e];
        rawv[r * 30 + c] = v1[gb + e];
    }
    __syncthreads();
    float sx = shif[b * 2 + 0];
    float sy = shif[b * 2 + 1];
    {
        int i = tid & 63;
        int dc = tid >> 6;
        int y0, y1;
        float wy0, wy1;
        coords_(i, 64, sy, y0, y1, wy0, wy1);
        int rm = (i - 1) & 63;
        for (int d = dc * 14; d < dc * 14 + 14; ++d) {
            float v;
            if (d < 28) v = SCALE_ * rawq[rm * 29 + d];
            else {
                int c = d - 28;
                v = SCALE_ * (wy0 * rawq[y0 * 29 + c] + wy1 * rawq[y1 * 29 + c]);
            }
            augqT[d * 68 + i] = v;
        }
        int x0, x1;
        float wx0, wx1;
        coords_(i, 64, sx, x0, x1, wx0, wx1);
        for (int d = dc * 14; d < dc * 14 + 14; ++d) {
            float v;
            if (d < 28) v = rawk[rm * 29 + d];
            else {
                int c = d - 28;
                v = wx0 * rawk[x0 * 29 + c] + wx1 * rawk[x1 * 29 + c];
            }
            augkT[d * 68 + i] = v;
        }
    }
    __syncthreads();
    int ig = tid >> 4, jg = tid & 15;
    int i0 = ig * 4, j0 = jg * 4;
    float p[4][4];
#pragma unroll
    for (int jj = 0; jj < 4; ++jj) {
        float4 t = *(const float4*)(P1T + (size_t)b * 4096 + (size_t)(j0 + jj) * 64 + i0);
        p[0][jj] = t.x; p[1][jj] = t.y; p[2][jj] = t.z; p[3][jj] = t.w;
    }
    for (int d = 0; d < 56; ++d) {
        float4 aq = *(const float4*)(augqT + d * 68 + i0);
        float4 ak = *(const float4*)(augkT + d * 68 + j0);
        float aqv[4] = {aq.x, aq.y, aq.z, aq.w};
        float akv[4] = {ak.x, ak.y, ak.z, ak.w};
#pragma unroll
        for (int r = 0; r < 4; ++r)
#pragma unroll
            for (int jj = 0; jj < 4; ++jj) p[r][jj] += aqv[r] * akv[jj];
    }
    float inv[4];
#pragma unroll
    for (int r = 0; r < 4; ++r) {
        float mx = fmaxf(fmaxf(p[r][0], p[r][1]), fmaxf(p[r][2], p[r][3]));
#pragma unroll
        for (int msk = 1; msk < 16; msk <<= 1) mx = fmaxf(mx, __shfl_xor(mx, msk));
        float s = 0.f;
#pragma unroll
        for (int jj = 0; jj < 4; ++jj) {
            p[r][jj] = __expf(p[r][jj] - mx);
            s += p[r][jj];
        }
#pragma unroll
        for (int msk = 1; msk < 16; msk <<= 1) s += __shfl_xor(s, msk);
        inv[r] = 1.0f / s;
    }
    __syncthreads();  // aug reads done; pT overlays augu
#pragma unroll
    for (int jj = 0; jj < 4; ++jj)
        *(float4*)(pT + (size_t)(j0 + jj) * 68 + i0) =
            make_float4(p[0][jj] * inv[0], p[1][jj] * inv[1], p[2][jj] * inv[2], p[3][jj] * inv[3]);
    __syncthreads();
    if (tid < 224) {
        int rg = tid / 14;
        int cg = tid - rg * 14;
        float o00 = 0, o01 = 0, o10 = 0, o11 = 0, o20 = 0, o21 = 0, o30 = 0, o31 = 0;
        for (int j = 0; j < 64; ++j) {
            float4 pv = *(const float4*)(pT + (size_t)j * 68 + rg * 4);
            float2 vv = *(const float2*)(rawv + j * 30 + cg * 2);
            o00 += pv.x * vv.x; o01 += pv.x * vv.y;
            o10 += pv.y * vv.x; o11 += pv.y * vv.y;
            o20 += pv.z * vv.x; o21 += pv.z * vv.y;
            o30 += pv.w * vv.x; o31 += pv.w * vv.y;
        }
        size_t base56 = (size_t)(b * 256 + n) * 64 * 56;
        size_t wb = base56 + (size_t)(rg * 4) * 56 + cg * 2;
        *(float2*)(aout + wb) = make_float2(o00, o01);
        *(float2*)(aout + wb + 56) = make_float2(o10, o11);
        *(float2*)(aout + wb + 112) = make_float2(o20, o21);
        *(float2*)(aout + wb + 168) = make_float2(o30, o31);
    }
}

// -------------------- K7: branch-2 cross-window attn (256x256) -------------
// Flash, one row per thread. Block 256 thr = (b,m). LDS: augK f32 [56][264]
// + V bf16 [28][264] = 73,920 B -> 2 blocks/CU. No spills.
__global__ __launch_bounds__(256, 2) void k_attn2(const float* __restrict__ q2,
                                                  const float* __restrict__ k2,
                                                  const float* __restrict__ v2,
                                                  const float* __restrict__ P2R,
                                                  const float* __restrict__ shif,
                                                  float* __restrict__ aout) {
    extern __shared__ __align__(16) float lds[];
    float* augk = lds;                                    // [56][264] f32
    unsigned short* vT = (unsigned short*)(lds + 14784);  // [28][264] bf16
    int tid = threadIdx.x;
    int bm = blockIdx.x;
    int b = bm >> 6;
    int m = bm & 63;
    size_t gbase = (size_t)bm * 7168;
    float sx = shif[16 + b * 2 + 0];
    float sy = shif[16 + b * 2 + 1];
    // ---- build augK col j = tid, and V^T (bf16) ----
    {
        int j = tid;
        int x0, x1;
        float wx0, wx1;
        coords_(j, 256, sx, x0, x1, wx0, wx1);
        int rm = (j - 1) & 255;
        const float* krm = k2 + gbase + (size_t)rm * 28;
        const float* ka = k2 + gbase + (size_t)x0 * 28;
        const float* kb = k2 + gbase + (size_t)x1 * 28;
#pragma unroll
        for (int c = 0; c < 28; ++c) augk[c * 264 + j] = krm[c];
#pragma unroll
        for (int c = 0; c < 28; ++c) augk[(28 + c) * 264 + j] = wx0 * ka[c] + wx1 * kb[c];
        const float* vr = v2 + gbase + (size_t)j * 28;
#pragma unroll
        for (int c = 0; c < 28; ++c) {
            union { float f; unsigned u; } cv;
            cv.f = vr[c];
            unsigned u = cv.u + 0x7fffu + ((cv.u >> 16) & 1u);  // RTNE to bf16
            vT[c * 264 + j] = (unsigned short)(u >> 16);
        }
    }
    // ---- per-thread augQ row i = tid (56 VGPRs, static indexing) ----
    float q[56];
    {
        int i = tid;
        int y0, y1;
        float wy0, wy1;
        coords_(i, 256, sy, y0, y1, wy0, wy1);
        int rm = (i - 1) & 255;
        const float* qrm = q2 + gbase + (size_t)rm * 28;
        const float* qa = q2 + gbase + (size_t)y0 * 28;
        const float* qb = q2 + gbase + (size_t)y1 * 28;
#pragma unroll
        for (int c = 0; c < 28; ++c) q[c] = SCALE_ * qrm[c];
#pragma unroll
        for (int c = 0; c < 28; ++c) q[28 + c] = SCALE_ * (wy0 * qa[c] + wy1 * qb[c]);
    }
    __syncthreads();
    // ---- flash loop over 32 j-tiles of 8 ----
    float O[28];
#pragma unroll
    for (int c = 0; c < 28; ++c) O[c] = 0.f;
    float mrun = -1e30f, lrun = 0.f;
    const float* prow = P2R + (size_t)b * 65536 + (size_t)tid * 256;
    for (int jt = 0; jt < 256; jt += 8) {
        float s[8];
        float4 pa = *(const float4*)(prow + jt);
        float4 pb = *(const float4*)(prow + jt + 4);
        s[0] = pa.x; s[1] = pa.y; s[2] = pa.z; s[3] = pa.w;
        s[4] = pb.x; s[5] = pb.y; s[6] = pb.z; s[7] = pb.w;
#pragma unroll
        for (int d = 0; d < 56; ++d) {
            float4 ka = *(const float4*)(augk + d * 264 + jt);
            float4 kb = *(const float4*)(augk + d * 264 + jt + 4);
            float qa = q[d];
            s[0] += qa * ka.x; s[1] += qa * ka.y; s[2] += qa * ka.z; s[3] += qa * ka.w;
            s[4] += qa * kb.x; s[5] += qa * kb.y; s[6] += qa * kb.z; s[7] += qa * kb.w;
        }
        float tm = fmaxf(fmaxf(fmaxf(s[0], s[1]), fmaxf(s[2], s[3])),
                         fmaxf(fmaxf(s[4], s[5]), fmaxf(s[6], s[7])));
        float mn = fmaxf(mrun, tm);
        float corr = __expf(mrun - mn);
        mrun = mn;
        lrun *= corr;
#pragma unroll
        for (int jj = 0; jj < 8; ++jj) {
            s[jj] = __expf(s[jj] - mn);
            lrun += s[jj];
        }
#pragma unroll
        for (int c = 0; c < 28; ++c) O[c] *= corr;
#pragma unroll
        for (int c = 0; c < 28; ++c) {
            uint4 vv = *(const uint4*)(vT + c * 264 + jt);
            float v0 = __uint_as_float(vv.x << 16);
            float v1 = __uint_as_float(vv.x & 0xffff0000u);
            float v2f = __uint_as_float(vv.y << 16);
            float v3 = __uint_as_float(vv.y & 0xffff0000u);
            float v4 = __uint_as_float(vv.z << 16);
            float v5 = __uint_as_float(vv.z & 0xffff0000u);
            float v6 = __uint_as_float(vv.w << 16);
            float v7 = __uint_as_float(vv.w & 0xffff0000u);
            O[c] += s[0] * v0 + s[1] * v1 + s[2] * v2f + s[3] * v3 +
                    s[4] * v4 + s[5] * v5 + s[6] * v6 + s[7] * v7;
        }
    }
    float invl = 1.0f / lrun;
    size_t wb = (((size_t)b * 256 + tid) * 64 + m) * 56 + 28;
#pragma unroll
    for (int c = 0; c < 28; c += 4)
        *(float4*)(aout + wb + c) =
            make_float4(O[c] * invl, O[c + 1] * invl, O[c + 2] * invl, O[c + 3] * invl);
}

// ----------------------- K8: output projection + unwindow ------------------
template <int C0>
__device__ __forceinline__ void out_chunk56(const float* xrow, const float* wl,
                                            const float* bl, float* __restrict__ dst) {
    float acc[28];
#pragma unroll
    for (int c = 0; c < 28; ++c) acc[c] = 0.f;
    for (int d = 0; d < 56; ++d) {
        float xv = xrow[d];
        const float4* wr = (const float4*)(wl + d * 56 + C0);
#pragma unroll
        for (int k = 0; k < 7; ++k) {
            float4 w = wr[k];
            acc[4 * k + 0] += xv * w.x;
            acc[4 * k + 1] += xv * w.y;
            acc[4 * k + 2] += xv * w.z;
            acc[4 * k + 3] += xv * w.w;
        }
    }
    float4* op = (float4*)(dst + C0);
#pragma unroll
    for (int k = 0; k < 7; ++k)
        op[k] = make_float4(acc[4 * k + 0] + bl[C0 + 4 * k + 0],
                            acc[4 * k + 1] + bl[C0 + 4 * k + 1],
                            acc[4 * k + 2] + bl[C0 + 4 * k + 2],
                            acc[4 * k + 3] + bl[C0 + 4 * k + 3]);
}

__global__ __launch_bounds__(256, 2) void k_out(const float* __restrict__ aout,
                                                const float* __restrict__ Wout,
                                                const float* __restrict__ bout,
                                                float* __restrict__ out) {
    __shared__ __align__(16) float xl[256 * 57];
    __shared__ __align__(16) float wl[3136];
    __shared__ float bl[56];
    int tid = threadIdx.x;
    for (int e = tid; e < 3136; e += 256) wl[e] = Wout[e];
    if (tid < 56) bl[tid] = bout[tid];
    int pix = blockIdx.x * 256 + tid;
    int b = pix >> 14;
    int r2 = pix & 16383;
    int n = r2 >> 6;
    int m = r2 & 63;
    float* xrow = xl + tid * 57;
    const float4* ap = (const float4*)(aout + (size_t)pix * 56);
#pragma unroll
    for (int k = 0; k < 14; ++k) {
        float4 t = ap[k];
        xrow[4 * k + 0] = t.x;
        xrow[4 * k + 1] = t.y;
        xrow[4 * k + 2] = t.z;
        xrow[4 * k + 3] = t.w;
    }
    __syncthreads();
    int h = ((n >> 4) << 3) + (m >> 3);
    int w = ((n & 15) << 3) + (m & 7);
    float* dst = out + (((size_t)b * 128 + h) * 128 + w) * 56;
    out_chunk56<0>(xrow, wl, bl, dst);
    out_chunk56<28>(xrow, wl, bl, dst);
}

// ---------------------------------------------------------------------------
extern "C" void kernel_launch(void* const* d_in, const int* in_sizes, int n_in,
                              void* d_out, int out_size, void* d_ws, size_t ws_size,
                              hipStream_t stream) {
    const float* x = (const float*)d_in[0];
    const float* pos1 = (const float*)d_in[1];
    const float* pos2 = (const float*)d_in[2];
    const float* Wq = (const float*)d_in[3];
    const float* Wkv = (const float*)d_in[4];
    const float* Wout = (const float*)d_in[5];
    const float* bout = (const float*)d_in[6];
    const float* c1w = (const float*)d_in[7];
    const float* c1b = (const float*)d_in[8];
    const float* c2w = (const float*)d_in[9];
    const float* c2b = (const float*)d_in[10];
    const float* f1w = (const float*)d_in[11];
    const float* f1b = (const float*)d_in[12];
    const float* f2w = (const float*)d_in[13];
    const float* f2b = (const float*)d_in[14];

    float* ws = (float*)d_ws;
    float* q1 = ws;
    float* k1 = q1 + 3670016;
    float* v1 = k1 + 3670016;
    float* q2 = v1 + 3670016;
    float* k2 = q2 + 3670016;
    float* v2 = k2 + 3670016;
    float* ssum = v2 + 3670016;
    float* aout = ssum;  // reuse after conv1 consumed ssum
    float* c1o = ssum + 7340032;
    float* part = c1o + 4194304;
    float* shif = part + 16384;
    float* P1T = shif + 32;
    float* P2R = P1T + 32768;
    float* outp = (float*)d_out;

    (void)hipFuncSetAttribute((const void*)k_attn2,
                              hipFuncAttributeMaxDynamicSharedMemorySize, 73920);

    k_qkv<<<512, 256, 0, stream>>>(x, Wq, Wkv, q1, k1, v1, q2, k2, v2, ssum);
    k_conv1<<<1024, 256, 0, stream>>>(ssum, c1w, c1b, c1o);
    k_conv2<<<1024, 256, 0, stream>>>(c1o, c2w, c2b, part);
    k_fc<<<1, 256, 0, stream>>>(part, f1w, f1b, f2w, f2b, shif);
    k_pos1<<<8, 256, 0, stream>>>(pos1, shif, P1T);
    k_pos2<<<2048, 256, 0, stream>>>(pos2, shif, P2R);
    k_attn1<<<2048, 256, 0, stream>>>(q1, k1, v1, P1T, shif, aout);
    k_attn2<<<512, 256, 73920, stream>>>(q2, k2, v2, P2R, shif, aout);
    k_out<<<512, 256, 0, stream>>>(aout, Wout, bout, outp);
}

// Round 4
// 310.160 us; speedup vs baseline: 2.6684x; 1.3604x over previous
//
#include <hip/hip_runtime.h>
#include <cstdint>

// ---------------------------------------------------------------------------
// SS-MSA fused implementation, round 4.
// grid_shift(sim) factorizes: shifted[i,j] = SCALE*(q_{i-1}.k_{j-1} + q~_i.k~_j) + P[i,j]
// => both branches are plain attention with 56-dim augmented Q/K + bias P.
//
// Round-4 changes vs round 3 (attn2 was LDS-BW-bound: every thread re-read
// the whole K/V from LDS):
//  - k_attn2 rewritten on v_mfma_f32_16x16x16_bf16 (classic verified layouts:
//    A: a[e]=A[l%16][4*(l/16)+e]; B: b[e]=B[4*(l/16)+e][l%16];
//    C/D: col=l&15, row=4*(l>>4)+r). 512-thr block per (b,m), wave owns 32
//    rows; augK bf16 [256][68] + V^T bf16 [28][260] staged once; Q-frags in
//    registers; P via per-wave LDS tile [32][68]. 82 KB LDS, no in-loop
//    __syncthreads.
//  - Fixed-max softmax: P2M[b][i]=rowmax(P2R) precomputed in k_pos2; no
//    online rescale (uniform offset cancels in normalization; f32 can't
//    overflow for realistic qk residuals).
// ---------------------------------------------------------------------------

#define SCALE_ 0.18898223650461364f  // 28^-0.5

using f4 = __attribute__((ext_vector_type(4))) float;
using bf4 = __attribute__((ext_vector_type(4))) short;

__device__ __forceinline__ f4 mfma16(bf4 a, bf4 b, f4 c) {
#if __has_builtin(__builtin_amdgcn_mfma_f32_16x16x16bf16_1k)
    return __builtin_amdgcn_mfma_f32_16x16x16bf16_1k(a, b, c, 0, 0, 0);
#else
    f4 d;
    asm("v_mfma_f32_16x16x16_bf16 %0, %1, %2, %3" : "=v"(d) : "v"(a), "v"(b), "v"(c));
    return d;
#endif
}

__device__ __forceinline__ unsigned pk_bf16(float lo, float hi) {
    unsigned r;
    asm("v_cvt_pk_bf16_f32 %0, %1, %2" : "=v"(r) : "v"(lo), "v"(hi));
    return r;
}

__device__ __forceinline__ unsigned short f2bf(float f) {
    return (unsigned short)pk_bf16(f, f);
}

__device__ __forceinline__ void coords_(int idx, int S, float s,
                                        int& i0, int& i1, float& w0, float& w1) {
    float g = -1.0f + 2.0f * (float)idx / (float)(S - 1);
    float c = (g + s * 2.0f / (float)S + 1.0f) * 0.5f * (float)(S - 1);
    float span = (float)(S - 1);
    c = fabsf(c);
    c = fmodf(c, 2.0f * span);
    if (c > span) c = 2.0f * span - c;
    int f = (int)floorf(c);
    f = max(0, min(f, S - 1));
    i0 = f;
    i1 = min(f + 1, S - 1);
    w1 = c - (float)f;
    w0 = 1.0f - w1;
}

// ------------------------------- K1: QKV GEMM ------------------------------
template <int C0>
__device__ __forceinline__ void qkv_chunk56(const float* xrow, const float* wl,
                                            float* __restrict__ outp, float* ss) {
    float acc[28];
#pragma unroll
    for (int c = 0; c < 28; ++c) acc[c] = 0.f;
    for (int d = 0; d < 56; ++d) {
        float xv = xrow[d];
        const float4* wr = (const float4*)(wl + d * 56 + C0);
#pragma unroll
        for (int k = 0; k < 7; ++k) {
            float4 w = wr[k];
            acc[4 * k + 0] += xv * w.x;
            acc[4 * k + 1] += xv * w.y;
            acc[4 * k + 2] += xv * w.z;
            acc[4 * k + 3] += xv * w.w;
        }
    }
    float4* op = (float4*)outp;
#pragma unroll
    for (int k = 0; k < 7; ++k)
        op[k] = make_float4(acc[4 * k + 0], acc[4 * k + 1], acc[4 * k + 2], acc[4 * k + 3]);
#pragma unroll
    for (int c = 0; c < 28; ++c) ss[c] += acc[c];
}

__global__ __launch_bounds__(256, 2) void k_qkv(const float* __restrict__ x,
                                                const float* __restrict__ Wq,
                                                const float* __restrict__ Wkv,
                                                float* __restrict__ q1, float* __restrict__ k1,
                                                float* __restrict__ v1, float* __restrict__ q2,
                                                float* __restrict__ k2, float* __restrict__ v2,
                                                float* __restrict__ ssum) {
    __shared__ __align__(16) float xl[256 * 57];
    __shared__ __align__(16) float wl[3136];
    int tid = threadIdx.x;
    int pix = blockIdx.x * 256 + tid;
    int b = pix >> 14;
    int rem = pix & 16383;
    int hh = rem >> 7;
    int ww = rem & 127;
    int n = ((hh >> 3) << 4) + (ww >> 3);
    int m = ((hh & 7) << 3) + (ww & 7);
    float* xrow = xl + tid * 57;
    const float4* xp = (const float4*)(x + (size_t)pix * 56);
#pragma unroll
    for (int k = 0; k < 14; ++k) {
        float4 t = xp[k];
        xrow[4 * k + 0] = t.x;
        xrow[4 * k + 1] = t.y;
        xrow[4 * k + 2] = t.z;
        xrow[4 * k + 3] = t.w;
    }
    size_t p1 = ((size_t)(b * 256 + n) * 64 + m) * 28;   // branch1 layout
    size_t p2 = ((size_t)(b * 64 + m) * 256 + n) * 28;   // branch2 layout
    size_t ob = ((size_t)(b * 256 + n) * 64 + m) * 56;   // ssum layout
    float ssA[28], ssB[28];
#pragma unroll
    for (int c = 0; c < 28; ++c) { ssA[c] = 0.f; ssB[c] = 0.f; }
    for (int e = tid; e < 3136; e += 256) wl[e] = Wq[e];
    __syncthreads();
    qkv_chunk56<0>(xrow, wl, q1 + p1, ssA);
    qkv_chunk56<28>(xrow, wl, q2 + p2, ssB);
    __syncthreads();
    for (int e = tid; e < 3136; e += 256) {
        int d = e / 56;
        int c = e - d * 56;
        wl[e] = Wkv[d * 112 + c];
    }
    __syncthreads();
    qkv_chunk56<0>(xrow, wl, k1 + p1, ssA);
    qkv_chunk56<28>(xrow, wl, k2 + p2, ssB);
    __syncthreads();
    for (int e = tid; e < 3136; e += 256) {
        int d = e / 56;
        int c = e - d * 56;
        wl[e] = Wkv[d * 112 + 56 + c];
    }
    __syncthreads();
    qkv_chunk56<0>(xrow, wl, v1 + p1, ssA);
    qkv_chunk56<28>(xrow, wl, v2 + p2, ssB);
    float4* sp = (float4*)(ssum + ob);
#pragma unroll
    for (int k = 0; k < 7; ++k)
        sp[k] = make_float4(ssA[4 * k + 0], ssA[4 * k + 1], ssA[4 * k + 2], ssA[4 * k + 3]);
#pragma unroll
    for (int k = 0; k < 7; ++k)
        sp[7 + k] = make_float4(ssB[4 * k + 0], ssB[4 * k + 1], ssB[4 * k + 2], ssB[4 * k + 3]);
}

// ------------------------------- K2: conv1 ---------------------------------
__global__ __launch_bounds__(256) void k_conv1(const float* __restrict__ ssum,
                                               const float* __restrict__ c1w,
                                               const float* __restrict__ c1b,
                                               float* __restrict__ c1o) {
    __shared__ __align__(16) float tile[6 * 66 * 29];
    __shared__ __align__(16) float wl[4032];
    int tid = threadIdx.x;
    int wg = blockIdx.x;
    int br = wg >> 9;
    int b = (wg >> 6) & 7;
    int nt = wg & 63;
    int n0 = nt * 4;
    for (int e = tid; e < 11088; e += 256) {
        int c = e % 28;
        int rest = e / 28;
        int mm = rest % 66;
        int nr = rest / 66;
        int n = n0 - 1 + nr;
        int m = mm - 1;
        float v = 0.f;
        if (n >= 0 && n < 256 && m >= 0 && m < 64)
            v = ssum[(((size_t)b * 256 + n) * 64 + m) * 56 + br * 28 + c];
        tile[(nr * 66 + mm) * 29 + c] = v;
    }
    for (int e = tid; e < 4032; e += 256) {
        int o = e & 15;
        int tap = e >> 4;
        wl[e] = c1w[o * 252 + tap];
    }
    __syncthreads();
    int ny = tid >> 6;
    int m = tid & 63;
    float acc[16];
#pragma unroll
    for (int o = 0; o < 16; ++o) acc[o] = 0.f;
    for (int c = 0; c < 28; ++c) {
#pragma unroll
        for (int ky = 0; ky < 3; ++ky) {
#pragma unroll
            for (int kx = 0; kx < 3; ++kx) {
                float iv = tile[((ny + ky) * 66 + (m + kx)) * 29 + c];
                const float4* wp = (const float4*)(wl + (c * 9 + ky * 3 + kx) * 16);
                float4 w0 = wp[0], w1 = wp[1], w2 = wp[2], w3 = wp[3];
                acc[0] += iv * w0.x;  acc[1] += iv * w0.y;  acc[2] += iv * w0.z;  acc[3] += iv * w0.w;
                acc[4] += iv * w1.x;  acc[5] += iv * w1.y;  acc[6] += iv * w1.z;  acc[7] += iv * w1.w;
                acc[8] += iv * w2.x;  acc[9] += iv * w2.y;  acc[10] += iv * w2.z; acc[11] += iv * w2.w;
                acc[12] += iv * w3.x; acc[13] += iv * w3.y; acc[14] += iv * w3.z; acc[15] += iv * w3.w;
            }
        }
    }
    float4 b0 = *(const float4*)(c1b + 0);
    float4 b1 = *(const float4*)(c1b + 4);
    float4 b2 = *(const float4*)(c1b + 8);
    float4 b3 = *(const float4*)(c1b + 12);
    size_t ob = (((size_t)(br * 8 + b) * 16384) + (size_t)(n0 + ny) * 64 + m) * 16;
    float4* op = (float4*)(c1o + ob);
    op[0] = make_float4(fmaxf(acc[0] + b0.x, 0.f), fmaxf(acc[1] + b0.y, 0.f),
                        fmaxf(acc[2] + b0.z, 0.f), fmaxf(acc[3] + b0.w, 0.f));
    op[1] = make_float4(fmaxf(acc[4] + b1.x, 0.f), fmaxf(acc[5] + b1.y, 0.f),
                        fmaxf(acc[6] + b1.z, 0.f), fmaxf(acc[7] + b1.w, 0.f));
    op[2] = make_float4(fmaxf(acc[8] + b2.x, 0.f), fmaxf(acc[9] + b2.y, 0.f),
                        fmaxf(acc[10] + b2.z, 0.f), fmaxf(acc[11] + b2.w, 0.f));
    op[3] = make_float4(fmaxf(acc[12] + b3.x, 0.f), fmaxf(acc[13] + b3.y, 0.f),
                        fmaxf(acc[14] + b3.z, 0.f), fmaxf(acc[15] + b3.w, 0.f));
}

// ------------------------- K3: conv2 + pooled partials ---------------------
__global__ __launch_bounds__(256) void k_conv2(const float* __restrict__ c1o,
                                               const float* __restrict__ c2w,
                                               const float* __restrict__ c2b,
                                               float* __restrict__ part) {
    __shared__ __align__(16) float tile[6 * 66 * 17];
    __shared__ __align__(16) float wl[2304];
    __shared__ float pbuf[4][16];
    int tid = threadIdx.x;
    int wg = blockIdx.x;
    int br = wg >> 9;
    int b = (wg >> 6) & 7;
    int nt = wg & 63;
    int n0 = nt * 4;
    for (int e = tid; e < 6336; e += 256) {
        int c = e & 15;
        int rest = e >> 4;
        int mm = rest % 66;
        int nr = rest / 66;
        int n = n0 - 1 + nr;
        int m = mm - 1;
        float v = 0.f;
        if (n >= 0 && n < 256 && m >= 0 && m < 64)
            v = c1o[(((size_t)(br * 8 + b) * 16384) + (size_t)n * 64 + m) * 16 + c];
        tile[(nr * 66 + mm) * 17 + c] = v;
    }
    for (int e = tid; e < 2304; e += 256) {
        int o = e & 15;
        int tap = e >> 4;
        wl[e] = c2w[o * 144 + tap];
    }
    __syncthreads();
    int ny = tid >> 6;
    int m = tid & 63;
    float acc[16];
#pragma unroll
    for (int o = 0; o < 16; ++o) acc[o] = 0.f;
    for (int c = 0; c < 16; ++c) {
#pragma unroll
        for (int ky = 0; ky < 3; ++ky) {
#pragma unroll
            for (int kx = 0; kx < 3; ++kx) {
                float iv = tile[((ny + ky) * 66 + (m + kx)) * 17 + c];
                const float4* wp = (const float4*)(wl + (c * 9 + ky * 3 + kx) * 16);
                float4 w0 = wp[0], w1 = wp[1], w2 = wp[2], w3 = wp[3];
                acc[0] += iv * w0.x;  acc[1] += iv * w0.y;  acc[2] += iv * w0.z;  acc[3] += iv * w0.w;
                acc[4] += iv * w1.x;  acc[5] += iv * w1.y;  acc[6] += iv * w1.z;  acc[7] += iv * w1.w;
                acc[8] += iv * w2.x;  acc[9] += iv * w2.y;  acc[10] += iv * w2.z; acc[11] += iv * w2.w;
                acc[12] += iv * w3.x; acc[13] += iv * w3.y; acc[14] += iv * w3.z; acc[15] += iv * w3.w;
            }
        }
    }
    int lane = tid & 63;
    int wid = tid >> 6;
#pragma unroll
    for (int o = 0; o < 16; ++o) {
        float s = fmaxf(acc[o] + c2b[o], 0.f);
#pragma unroll
        for (int msk = 1; msk < 64; msk <<= 1) s += __shfl_xor(s, msk);
        if (lane == 0) pbuf[wid][o] = s;
    }
    __syncthreads();
    if (tid < 16) {
        float s = pbuf[0][tid] + pbuf[1][tid] + pbuf[2][tid] + pbuf[3][tid];
        part[(((size_t)(br * 8 + b)) * 64 + nt) * 16 + tid] = s;
    }
}

// ------------------------- K4: reduce + FC -> shifts -----------------------
__global__ void k_fc(const float* __restrict__ part, const float* __restrict__ f1w,
                     const float* __restrict__ f1b, const float* __restrict__ f2w,
                     const float* __restrict__ f2b, float* __restrict__ shif) {
    __shared__ float sb[16][16];
    int t = threadIdx.x;
    int combo = t >> 4;
    int o = t & 15;
    float s = 0.f;
    for (int nt = 0; nt < 64; ++nt) s += part[((size_t)combo * 64 + nt) * 16 + o];
    sb[combo][o] = s * (1.0f / 16384.0f);
    __syncthreads();
    if (t < 16) {
        float p0 = f1b[0], p1 = f1b[1], rg = f2b[0];
        for (int oo = 0; oo < 16; ++oo) {
            float sv = sb[t][oo];
            p0 += sv * f1w[oo * 2 + 0];
            p1 += sv * f1w[oo * 2 + 1];
            rg += sv * f2w[oo];
        }
        shif[t * 2 + 0] = rg * tanhf(p0);
        shif[t * 2 + 1] = rg * tanhf(p1);
    }
}

// ------------------------- K5a/b: shifted pos precompute -------------------
__global__ __launch_bounds__(256) void k_pos1(const float* __restrict__ pos1,
                                              const float* __restrict__ shif,
                                              float* __restrict__ P1T) {
    int b = blockIdx.x;
    float sx = shif[b * 2 + 0];
    float sy = shif[b * 2 + 1];
    for (int e = threadIdx.x; e < 4096; e += 256) {
        int j = e >> 6;
        int i = e & 63;
        int y0, y1, x0, x1;
        float wy0, wy1, wx0, wx1;
        coords_(i, 64, sy, y0, y1, wy0, wy1);
        coords_(j, 64, sx, x0, x1, wx0, wx1);
        float v = pos1[((i - 1) & 63) * 64 + ((j - 1) & 63)] +
                  wy0 * (wx0 * pos1[y0 * 64 + x0] + wx1 * pos1[y0 * 64 + x1]) +
                  wy1 * (wx0 * pos1[y1 * 64 + x0] + wx1 * pos1[y1 * 64 + x1]);
        P1T[(size_t)b * 4096 + j * 64 + i] = v;
    }
}

// P2 bias row-major P2R[b][i][j] + per-row max P2M[b][i].
__global__ __launch_bounds__(256) void k_pos2(const float* __restrict__ pos2,
                                              const float* __restrict__ shif,
                                              float* __restrict__ P2R,
                                              float* __restrict__ P2M) {
    __shared__ float red[4];
    int wg = blockIdx.x;
    int b = wg >> 8;
    int i = wg & 255;
    float sx = shif[16 + b * 2 + 0];
    float sy = shif[16 + b * 2 + 1];
    int j = threadIdx.x;
    int y0, y1, x0, x1;
    float wy0, wy1, wx0, wx1;
    coords_(i, 256, sy, y0, y1, wy0, wy1);
    coords_(j, 256, sx, x0, x1, wx0, wx1);
    float v = pos2[((i - 1) & 255) * 256 + ((j - 1) & 255)] +
              wy0 * (wx0 * pos2[y0 * 256 + x0] + wx1 * pos2[y0 * 256 + x1]) +
              wy1 * (wx0 * pos2[y1 * 256 + x0] + wx1 * pos2[y1 * 256 + x1]);
    P2R[(size_t)b * 65536 + (size_t)i * 256 + j] = v;
    float mx = v;
#pragma unroll
    for (int msk = 1; msk < 64; msk <<= 1) mx = fmaxf(mx, __shfl_xor(mx, msk));
    if ((threadIdx.x & 63) == 0) red[threadIdx.x >> 6] = mx;
    __syncthreads();
    if (threadIdx.x == 0)
        P2M[b * 256 + i] = fmaxf(fmaxf(red[0], red[1]), fmaxf(red[2], red[3]));
}

// --------------------- K6: branch-1 window attention (64x64) ---------------
__global__ __launch_bounds__(256) void k_attn1(const float* __restrict__ q1,
                                               const float* __restrict__ k1,
                                               const float* __restrict__ v1,
                                               const float* __restrict__ P1T,
                                               const float* __restrict__ shif,
                                               float* __restrict__ aout) {
    __shared__ __align__(16) float rawq[64 * 29];
    __shared__ __align__(16) float rawk[64 * 29];
    __shared__ __align__(16) float rawv[64 * 30];
    __shared__ __align__(16) float augu[7616];  // augqT[56][68] | augkT[56][68]; pT[64][68] overlays
    float* augqT = augu;
    float* augkT = augu + 3808;
    float* pT = augu;
    int tid = threadIdx.x;
    int wg = blockIdx.x;
    int b = wg >> 8;
    int n = wg & 255;
    size_t gb = (size_t)(b * 256 + n) * 1792;
    for (int e = tid; e < 1792; e += 256) {
        int r = e / 28;
        int c = e - r * 28;
        rawq[r * 29 + c] = q1[gb + e];
        rawk[r * 29 + c] = k1[gb + e];
        rawv[r * 30 + c] = v1[gb + e];
    }
    __syncthreads();
    float sx = shif[b * 2 + 0];
    float sy = shif[b * 2 + 1];
    {
        int i = tid & 63;
        int dc = tid >> 6;
        int y0, y1;
        float wy0, wy1;
        coords_(i, 64, sy, y0, y1, wy0, wy1);
        int rm = (i - 1) & 63;
        for (int d = dc * 14; d < dc * 14 + 14; ++d) {
            float v;
            if (d < 28) v = SCALE_ * rawq[rm * 29 + d];
            else {
                int c = d - 28;
                v = SCALE_ * (wy0 * rawq[y0 * 29 + c] + wy1 * rawq[y1 * 29 + c]);
            }
            augqT[d * 68 + i] = v;
        }
        int x0, x1;
        float wx0, wx1;
        coords_(i, 64, sx, x0, x1, wx0, wx1);
        for (int d = dc * 14; d < dc * 14 + 14; ++d) {
            float v;
            if (d < 28) v = rawk[rm * 29 + d];
            else {
                int c = d - 28;
                v = wx0 * rawk[x0 * 29 + c] + wx1 * rawk[x1 * 29 + c];
            }
            augkT[d * 68 + i] = v;
        }
    }
    __syncthreads();
    int ig = tid >> 4, jg = tid & 15;
    int i0 = ig * 4, j0 = jg * 4;
    float p[4][4];
#pragma unroll
    for (int jj = 0; jj < 4; ++jj) {
        float4 t = *(const float4*)(P1T + (size_t)b * 4096 + (size_t)(j0 + jj) * 64 + i0);
        p[0][jj] = t.x; p[1][jj] = t.y; p[2][jj] = t.z; p[3][jj] = t.w;
    }
    for (int d = 0; d < 56; ++d) {
        float4 aq = *(const float4*)(augqT + d * 68 + i0);
        float4 ak = *(const float4*)(augkT + d * 68 + j0);
        float aqv[4] = {aq.x, aq.y, aq.z, aq.w};
        float akv[4] = {ak.x, ak.y, ak.z, ak.w};
#pragma unroll
        for (int r = 0; r < 4; ++r)
#pragma unroll
            for (int jj = 0; jj < 4; ++jj) p[r][jj] += aqv[r] * akv[jj];
    }
    float inv[4];
#pragma unroll
    for (int r = 0; r < 4; ++r) {
        float mx = fmaxf(fmaxf(p[r][0], p[r][1]), fmaxf(p[r][2], p[r][3]));
#pragma unroll
        for (int msk = 1; msk < 16; msk <<= 1) mx = fmaxf(mx, __shfl_xor(mx, msk));
        float s = 0.f;
#pragma unroll
        for (int jj = 0; jj < 4; ++jj) {
            p[r][jj] = __expf(p[r][jj] - mx);
            s += p[r][jj];
        }
#pragma unroll
        for (int msk = 1; msk < 16; msk <<= 1) s += __shfl_xor(s, msk);
        inv[r] = 1.0f / s;
    }
    __syncthreads();  // aug reads done; pT overlays augu
#pragma unroll
    for (int jj = 0; jj < 4; ++jj)
        *(float4*)(pT + (size_t)(j0 + jj) * 68 + i0) =
            make_float4(p[0][jj] * inv[0], p[1][jj] * inv[1], p[2][jj] * inv[2], p[3][jj] * inv[3]);
    __syncthreads();
    if (tid < 224) {
        int rg = tid / 14;
        int cg = tid - rg * 14;
        float o00 = 0, o01 = 0, o10 = 0, o11 = 0, o20 = 0, o21 = 0, o30 = 0, o31 = 0;
        for (int j = 0; j < 64; ++j) {
            float4 pv = *(const float4*)(pT + (size_t)j * 68 + rg * 4);
            float2 vv = *(const float2*)(rawv + j * 30 + cg * 2);
            o00 += pv.x * vv.x; o01 += pv.x * vv.y;
            o10 += pv.y * vv.x; o11 += pv.y * vv.y;
            o20 += pv.z * vv.x; o21 += pv.z * vv.y;
            o30 += pv.w * vv.x; o31 += pv.w * vv.y;
        }
        size_t base56 = (size_t)(b * 256 + n) * 64 * 56;
        size_t wb = base56 + (size_t)(rg * 4) * 56 + cg * 2;
        *(float2*)(aout + wb) = make_float2(o00, o01);
        *(float2*)(aout + wb + 56) = make_float2(o10, o11);
        *(float2*)(aout + wb + 112) = make_float2(o20, o21);
        *(float2*)(aout + wb + 168) = make_float2(o30, o31);
    }
}

// -------------------- K7: branch-2 cross-window attn, MFMA -----------------
// 512 threads per (b,m); wave w owns rows [32w,32w+32). LDS:
//   augK bf16 [256][68] @0 (34816B), V^T bf16 [28][260] @34816 (14560B),
//   P per-wave bf16 [32][68] @49376+w*4352 (34816B). Total 84192B.
__global__ __launch_bounds__(512) void k_attn2(const float* __restrict__ q2,
                                               const float* __restrict__ k2,
                                               const float* __restrict__ v2,
                                               const float* __restrict__ P2R,
                                               const float* __restrict__ P2M,
                                               const float* __restrict__ shif,
                                               float* __restrict__ aout) {
    extern __shared__ __align__(16) char smem[];
    unsigned short* augK = (unsigned short*)smem;                  // [256][68]
    unsigned short* vT = (unsigned short*)(smem + 34816);          // [28][260]
    int tid = threadIdx.x;
    int w = tid >> 6;
    int l = tid & 63;
    int g = l >> 4;
    int li = l & 15;
    unsigned short* Pw = (unsigned short*)(smem + 49376) + w * 2176;  // [32][68]
    int bm = blockIdx.x;
    int b = bm >> 6;
    int m = bm & 63;
    size_t gbase = (size_t)bm * 7168;
    float sx = shif[16 + b * 2 + 0];
    float sy = shif[16 + b * 2 + 1];
    // ---- stage augK (threads 0..255) / V^T (threads 256..511) ----
    if (tid < 256) {
        int j = tid;
        int x0, x1;
        float wx0, wx1;
        coords_(j, 256, sx, x0, x1, wx0, wx1);
        int rm = (j - 1) & 255;
        const float* krm = k2 + gbase + (size_t)rm * 28;
        const float* ka = k2 + gbase + (size_t)x0 * 28;
        const float* kb = k2 + gbase + (size_t)x1 * 28;
        unsigned* row = (unsigned*)(augK + j * 68);
#pragma unroll
        for (int h = 0; h < 14; ++h)
            row[h] = pk_bf16(krm[2 * h], krm[2 * h + 1]);
#pragma unroll
        for (int h = 0; h < 14; ++h)
            row[14 + h] = pk_bf16(wx0 * ka[2 * h] + wx1 * kb[2 * h],
                                  wx0 * ka[2 * h + 1] + wx1 * kb[2 * h + 1]);
#pragma unroll
        for (int h = 28; h < 34; ++h) row[h] = 0;
    } else {
        int j = tid - 256;
        const float* vr = v2 + gbase + (size_t)j * 28;
#pragma unroll
        for (int c = 0; c < 28; ++c) vT[c * 260 + j] = f2bf(vr[c]);
    }
    // ---- Q fragments in registers: A[i][d], i = 32w+16mi+li, d = 16kt+4g+e ----
    bf4 qf[2][4];
#pragma unroll
    for (int mi = 0; mi < 2; ++mi) {
        int i = 32 * w + 16 * mi + li;
        int y0, y1;
        float wy0, wy1;
        coords_(i, 256, sy, y0, y1, wy0, wy1);
        int rm = (i - 1) & 255;
        const float* qrm = q2 + gbase + (size_t)rm * 28;
        const float* qa = q2 + gbase + (size_t)y0 * 28;
        const float* qb = q2 + gbase + (size_t)y1 * 28;
        float qv[16];
#pragma unroll
        for (int kt = 0; kt < 4; ++kt)
#pragma unroll
            for (int e = 0; e < 4; ++e) {
                int d = 16 * kt + 4 * g + e;
                float v;
                if (d < 28) v = SCALE_ * qrm[d];
                else if (d < 56) v = SCALE_ * (wy0 * qa[d - 28] + wy1 * qb[d - 28]);
                else v = 0.f;
                qv[kt * 4 + e] = v;
            }
#pragma unroll
        for (int kt = 0; kt < 4; ++kt) {
            union { unsigned u[2]; bf4 v; } cv;
            cv.u[0] = pk_bf16(qv[kt * 4 + 0], qv[kt * 4 + 1]);
            cv.u[1] = pk_bf16(qv[kt * 4 + 2], qv[kt * 4 + 3]);
            qf[mi][kt] = cv.v;
        }
    }
    // ---- row maxima (fixed softmax offset) ----
    float M[2][4];
#pragma unroll
    for (int mi = 0; mi < 2; ++mi)
#pragma unroll
        for (int r = 0; r < 4; ++r)
            M[mi][r] = P2M[b * 256 + 32 * w + 16 * mi + 4 * g + r];
    __syncthreads();
    // ---- main loop over 4 j-tiles of 64 ----
    f4 accv[2][2];
#pragma unroll
    for (int mi = 0; mi < 2; ++mi)
#pragma unroll
        for (int nc = 0; nc < 2; ++nc) accv[mi][nc] = (f4){0.f, 0.f, 0.f, 0.f};
    float lrun[2][4];
#pragma unroll
    for (int mi = 0; mi < 2; ++mi)
#pragma unroll
        for (int r = 0; r < 4; ++r) lrun[mi][r] = 0.f;

    for (int jt = 0; jt < 4; ++jt) {
        // QK^T: acc[mi][nj] init with P2R bias, then 4 K-steps of MFMA
        f4 acc[2][4];
#pragma unroll
        for (int mi = 0; mi < 2; ++mi) {
            const float* pr = P2R + (size_t)b * 65536 +
                              (size_t)(32 * w + 16 * mi + 4 * g) * 256 + 64 * jt + li;
#pragma unroll
            for (int nj = 0; nj < 4; ++nj)
                acc[mi][nj] = (f4){pr[16 * nj], pr[16 * nj + 256],
                                   pr[16 * nj + 512], pr[16 * nj + 768]};
        }
#pragma unroll
        for (int nj = 0; nj < 4; ++nj) {
            const unsigned short* kr = augK + (64 * jt + 16 * nj + li) * 68 + 4 * g;
            bf4 bk[4];
#pragma unroll
            for (int kt = 0; kt < 4; ++kt) bk[kt] = *(const bf4*)(kr + 16 * kt);
#pragma unroll
            for (int mi = 0; mi < 2; ++mi)
#pragma unroll
                for (int kt = 0; kt < 4; ++kt)
                    acc[mi][nj] = mfma16(qf[mi][kt], bk[kt], acc[mi][nj]);
        }
        // softmax: p = exp(s - M_row); write P tile (bf16) to wave-private LDS
#pragma unroll
        for (int mi = 0; mi < 2; ++mi)
#pragma unroll
            for (int nj = 0; nj < 4; ++nj)
#pragma unroll
                for (int r = 0; r < 4; ++r) {
                    float p = __expf(acc[mi][nj][r] - M[mi][r]);
                    lrun[mi][r] += p;
                    Pw[(16 * mi + 4 * g + r) * 68 + 16 * nj + li] = f2bf(p);
                }
        // PV: A = P (per-wave LDS), B = V^T tile
#pragma unroll
        for (int kt = 0; kt < 4; ++kt) {
            bf4 pa[2];
#pragma unroll
            for (int mi = 0; mi < 2; ++mi)
                pa[mi] = *(const bf4*)(Pw + (16 * mi + li) * 68 + 16 * kt + 4 * g);
#pragma unroll
            for (int nc = 0; nc < 2; ++nc) {
                bf4 bv = *(const bf4*)(vT + (16 * nc + li) * 260 + 64 * jt + 16 * kt + 4 * g);
#pragma unroll
                for (int mi = 0; mi < 2; ++mi)
                    accv[mi][nc] = mfma16(pa[mi], bv, accv[mi][nc]);
            }
        }
    }
    // ---- normalize + write ----
#pragma unroll
    for (int mi = 0; mi < 2; ++mi)
#pragma unroll
        for (int r = 0; r < 4; ++r) {
#pragma unroll
            for (int msk = 1; msk < 16; msk <<= 1)
                lrun[mi][r] += __shfl_xor(lrun[mi][r], msk);
            float invl = 1.0f / lrun[mi][r];
            int gi = 32 * w + 16 * mi + 4 * g + r;
            size_t wb = (((size_t)b * 256 + gi) * 64 + m) * 56 + 28;
            aout[wb + li] = accv[mi][0][r] * invl;
            if (li < 12) aout[wb + 16 + li] = accv[mi][1][r] * invl;
        }
}

// ----------------------- K8: output projection + unwindow ------------------
template <int C0>
__device__ __forceinline__ void out_chunk56(const float* xrow, const float* wl,
                                            const float* bl, float* __restrict__ dst) {
    float acc[28];
#pragma unroll
    for (int c = 0; c < 28; ++c) acc[c] = 0.f;
    for (int d = 0; d < 56; ++d) {
        float xv = xrow[d];
        const float4* wr = (const float4*)(wl + d * 56 + C0);
#pragma unroll
        for (int k = 0; k < 7; ++k) {
            float4 w = wr[k];
            acc[4 * k + 0] += xv * w.x;
            acc[4 * k + 1] += xv * w.y;
            acc[4 * k + 2] += xv * w.z;
            acc[4 * k + 3] += xv * w.w;
        }
    }
    float4* op = (float4*)(dst + C0);
#pragma unroll
    for (int k = 0; k < 7; ++k)
        op[k] = make_float4(acc[4 * k + 0] + bl[C0 + 4 * k + 0],
                            acc[4 * k + 1] + bl[C0 + 4 * k + 1],
                            acc[4 * k + 2] + bl[C0 + 4 * k + 2],
                            acc[4 * k + 3] + bl[C0 + 4 * k + 3]);
}

__global__ __launch_bounds__(256, 2) void k_out(const float* __restrict__ aout,
                                                const float* __restrict__ Wout,
                                                const float* __restrict__ bout,
                                                float* __restrict__ out) {
    __shared__ __align__(16) float xl[256 * 57];
    __shared__ __align__(16) float wl[3136];
    __shared__ float bl[56];
    int tid = threadIdx.x;
    for (int e = tid; e < 3136; e += 256) wl[e] = Wout[e];
    if (tid < 56) bl[tid] = bout[tid];
    int pix = blockIdx.x * 256 + tid;
    int b = pix >> 14;
    int r2 = pix & 16383;
    int n = r2 >> 6;
    int m = r2 & 63;
    float* xrow = xl + tid * 57;
    const float4* ap = (const float4*)(aout + (size_t)pix * 56);
#pragma unroll
    for (int k = 0; k < 14; ++k) {
        float4 t = ap[k];
        xrow[4 * k + 0] = t.x;
        xrow[4 * k + 1] = t.y;
        xrow[4 * k + 2] = t.z;
        xrow[4 * k + 3] = t.w;
    }
    __syncthreads();
    int h = ((n >> 4) << 3) + (m >> 3);
    int w = ((n & 15) << 3) + (m & 7);
    float* dst = out + (((size_t)b * 128 + h) * 128 + w) * 56;
    out_chunk56<0>(xrow, wl, bl, dst);
    out_chunk56<28>(xrow, wl, bl, dst);
}

// ---------------------------------------------------------------------------
extern "C" void kernel_launch(void* const* d_in, const int* in_sizes, int n_in,
                              void* d_out, int out_size, void* d_ws, size_t ws_size,
                              hipStream_t stream) {
    const float* x = (const float*)d_in[0];
    const float* pos1 = (const float*)d_in[1];
    const float* pos2 = (const float*)d_in[2];
    const float* Wq = (const float*)d_in[3];
    const float* Wkv = (const float*)d_in[4];
    const float* Wout = (const float*)d_in[5];
    const float* bout = (const float*)d_in[6];
    const float* c1w = (const float*)d_in[7];
    const float* c1b = (const float*)d_in[8];
    const float* c2w = (const float*)d_in[9];
    const float* c2b = (const float*)d_in[10];
    const float* f1w = (const float*)d_in[11];
    const float* f1b = (const float*)d_in[12];
    const float* f2w = (const float*)d_in[13];
    const float* f2b = (const float*)d_in[14];

    float* ws = (float*)d_ws;
    float* q1 = ws;
    float* k1 = q1 + 3670016;
    float* v1 = k1 + 3670016;
    float* q2 = v1 + 3670016;
    float* k2 = q2 + 3670016;
    float* v2 = k2 + 3670016;
    float* ssum = v2 + 3670016;
    float* aout = ssum;  // reuse after conv1 consumed ssum
    float* c1o = ssum + 7340032;
    float* part = c1o + 4194304;
    float* shif = part + 16384;
    float* P1T = shif + 32;
    float* P2R = P1T + 32768;
    float* P2M = c1o;  // c1o region free after k_conv2
    float* outp = (float*)d_out;

    (void)hipFuncSetAttribute((const void*)k_attn2,
                              hipFuncAttributeMaxDynamicSharedMemorySize, 84192);

    k_qkv<<<512, 256, 0, stream>>>(x, Wq, Wkv, q1, k1, v1, q2, k2, v2, ssum);
    k_conv1<<<1024, 256, 0, stream>>>(ssum, c1w, c1b, c1o);
    k_conv2<<<1024, 256, 0, stream>>>(c1o, c2w, c2b, part);
    k_fc<<<1, 256, 0, stream>>>(part, f1w, f1b, f2w, f2b, shif);
    k_pos1<<<8, 256, 0, stream>>>(pos1, shif, P1T);
    k_pos2<<<2048, 256, 0, stream>>>(pos2, shif, P2R, P2M);
    k_attn1<<<2048, 256, 0, stream>>>(q1, k1, v1, P1T, shif, aout);
    k_attn2<<<512, 512, 84192, stream>>>(q2, k2, v2, P2R, P2M, shif, aout);
    k_out<<<512, 256, 0, stream>>>(aout, Wout, bout, outp);
}

// Round 5
// 293.963 us; speedup vs baseline: 2.8154x; 1.0551x over previous
//
#include <hip/hip_runtime.h>
#include <cstdint>

// ---------------------------------------------------------------------------
// SS-MSA fused implementation, round 5.
// grid_shift(sim) factorizes: shifted[i,j] = SCALE*(q_{i-1}.k_{j-1} + q~_i.k~_j) + P[i,j]
// => both branches are plain attention with 56-dim augmented Q/K + bias P.
//
// Round-5: MFMA everywhere matmul-shaped.
//  - k_qkv: bf16x3 MFMA GEMM (f32-accurate acc for ssum); q1..v2 stored bf16.
//  - k_attn1: MFMA (attn2's verified 16x16x16 layouts), fixed-max softmax via
//    P1M rowmax, wave-private P tile, zero-padded vT.
//  - k_out: bf16x3 MFMA + coalesced unwindow through LDS.
//  - k_attn2: round-4 kernel adapted to bf16 q2/k2/v2 inputs.
// ---------------------------------------------------------------------------

#define SCALE_ 0.18898223650461364f  // 28^-0.5

using f4 = __attribute__((ext_vector_type(4))) float;
using bf4 = __attribute__((ext_vector_type(4))) short;

__device__ __forceinline__ f4 mfma16(bf4 a, bf4 b, f4 c) {
#if __has_builtin(__builtin_amdgcn_mfma_f32_16x16x16bf16_1k)
    return __builtin_amdgcn_mfma_f32_16x16x16bf16_1k(a, b, c, 0, 0, 0);
#else
    f4 d;
    asm("v_mfma_f32_16x16x16_bf16 %0, %1, %2, %3" : "=v"(d) : "v"(a), "v"(b), "v"(c));
    return d;
#endif
}

__device__ __forceinline__ unsigned pk_bf16(float lo, float hi) {
    unsigned r;
    asm("v_cvt_pk_bf16_f32 %0, %1, %2" : "=v"(r) : "v"(lo), "v"(hi));
    return r;
}
__device__ __forceinline__ unsigned short f2bf(float f) {
    return (unsigned short)pk_bf16(f, f);
}
__device__ __forceinline__ float bf2f(unsigned short h) {
    return __uint_as_float(((unsigned)h) << 16);
}

__device__ __forceinline__ void coords_(int idx, int S, float s,
                                        int& i0, int& i1, float& w0, float& w1) {
    float g = -1.0f + 2.0f * (float)idx / (float)(S - 1);
    float c = (g + s * 2.0f / (float)S + 1.0f) * 0.5f * (float)(S - 1);
    float span = (float)(S - 1);
    c = fabsf(c);
    c = fmodf(c, 2.0f * span);
    if (c > span) c = 2.0f * span - c;
    int f = (int)floorf(c);
    f = max(0, min(f, S - 1));
    i0 = f;
    i1 = min(f + 1, S - 1);
    w1 = c - (float)f;
    w0 = 1.0f - w1;
}

// ------------------- K1: QKV GEMM (bf16x3 MFMA) ----------------------------
// Block: 64 pixels x 168 cols (56 q | 56 k | 56 v). 4 waves; wave w owns
// N-tiles {3w..3w+nnt}. A hi/lo staged in LDS [64][68]; B-frags from global.
// Dynamic LDS: Ah 17408B | Al 17408B | st f32 [64][172] 44032B = 78848B.
__global__ __launch_bounds__(256) void k_qkv(const float* __restrict__ x,
                                             const float* __restrict__ Wq,
                                             const float* __restrict__ Wkv,
                                             unsigned short* __restrict__ q1,
                                             unsigned short* __restrict__ k1,
                                             unsigned short* __restrict__ v1,
                                             unsigned short* __restrict__ q2,
                                             unsigned short* __restrict__ k2,
                                             unsigned short* __restrict__ v2,
                                             float* __restrict__ ssum) {
    extern __shared__ __align__(16) char smem[];
    unsigned short* Ah = (unsigned short*)smem;            // [64][68]
    unsigned short* Al = Ah + 4352;                        // [64][68]
    float* st = (float*)(smem + 17408);                    // [64][172]
    int tid = threadIdx.x;
    int w = tid >> 6;
    int l = tid & 63;
    int g = l >> 4;
    int li = l & 15;
    int pix0 = blockIdx.x * 64;
    // stage A hi/lo
    for (int e = tid; e < 3584; e += 256) {
        int row = e / 56;
        int c = e - row * 56;
        float v = x[(size_t)pix0 * 56 + e];
        unsigned short hi = f2bf(v);
        Ah[row * 68 + c] = hi;
        Al[row * 68 + c] = f2bf(v - bf2f(hi));
    }
    for (int e = tid; e < 768; e += 256) {
        int row = e / 12;
        int c = 56 + e - row * 12;
        Ah[row * 68 + c] = 0;
        Al[row * 68 + c] = 0;
    }
    // B-frags from global (wave-private N-slice)
    int nnt = (w < 3) ? 3 : 2;
    bf4 Bh[3][4], Bl[3][4];
#pragma unroll
    for (int t = 0; t < 3; ++t) {
        if (t >= nnt) break;
        int col = 16 * (3 * w + t) + li;
#pragma unroll
        for (int kt = 0; kt < 4; ++kt) {
            float wv[4];
#pragma unroll
            for (int e = 0; e < 4; ++e) {
                int k = 16 * kt + 4 * g + e;
                float v = 0.f;
                if (k < 56 && col < 168)
                    v = (col < 56) ? Wq[k * 56 + col] : Wkv[k * 112 + col - 56];
                wv[e] = v;
            }
            float hv[4], lv[4];
#pragma unroll
            for (int e = 0; e < 4; ++e) {
                unsigned short h = f2bf(wv[e]);
                hv[e] = bf2f(h);
                lv[e] = wv[e] - hv[e];
            }
            union { unsigned u[2]; bf4 v; } ch, cl;
            ch.u[0] = pk_bf16(hv[0], hv[1]);
            ch.u[1] = pk_bf16(hv[2], hv[3]);
            cl.u[0] = pk_bf16(lv[0], lv[1]);
            cl.u[1] = pk_bf16(lv[2], lv[3]);
            Bh[t][kt] = ch.v;
            Bl[t][kt] = cl.v;
        }
    }
    __syncthreads();
    f4 acc[4][3];
#pragma unroll
    for (int mi = 0; mi < 4; ++mi)
#pragma unroll
        for (int t = 0; t < 3; ++t) acc[mi][t] = (f4){0.f, 0.f, 0.f, 0.f};
#pragma unroll
    for (int mi = 0; mi < 4; ++mi) {
        bf4 ah[4], al[4];
#pragma unroll
        for (int kt = 0; kt < 4; ++kt) {
            ah[kt] = *(const bf4*)(Ah + (16 * mi + li) * 68 + 16 * kt + 4 * g);
            al[kt] = *(const bf4*)(Al + (16 * mi + li) * 68 + 16 * kt + 4 * g);
        }
#pragma unroll
        for (int t = 0; t < 3; ++t) {
            if (t >= nnt) break;
#pragma unroll
            for (int kt = 0; kt < 4; ++kt) {
                acc[mi][t] = mfma16(ah[kt], Bh[t][kt], acc[mi][t]);
                acc[mi][t] = mfma16(al[kt], Bh[t][kt], acc[mi][t]);
                acc[mi][t] = mfma16(ah[kt], Bl[t][kt], acc[mi][t]);
            }
        }
    }
    // write to st
#pragma unroll
    for (int mi = 0; mi < 4; ++mi)
#pragma unroll
        for (int t = 0; t < 3; ++t) {
            if (t >= nnt) break;
            int col = 16 * (3 * w + t) + li;
            if (col < 168) {
#pragma unroll
                for (int r = 0; r < 4; ++r)
                    st[(16 * mi + 4 * g + r) * 172 + col] = acc[mi][t][r];
            }
        }
    __syncthreads();
    // output phase
    int row = tid >> 2;
    int qq = tid & 3;
    int pixel = pix0 + row;
    int b = pixel >> 14;
    int rem = pixel & 16383;
    int hh = rem >> 7;
    int ww = rem & 127;
    int n = ((hh >> 3) << 4) + (ww >> 3);
    int m = ((hh & 7) << 3) + (ww & 7);
    size_t p1 = ((size_t)(b * 256 + n) * 64 + m) * 28;
    size_t p2 = ((size_t)(b * 64 + m) * 256 + n) * 28;
    size_t ob = ((size_t)(b * 256 + n) * 64 + m) * 56;
    const float* sr = st + row * 172;
#pragma unroll
    for (int h = 0; h < 7; ++h) {
        int c = 14 * qq + 2 * h;
        float q0 = sr[c], q1v = sr[c + 1];
        float k0 = sr[56 + c], k1v = sr[57 + c];
        float v0 = sr[112 + c], v1v = sr[113 + c];
        ssum[ob + c] = q0 + k0 + v0;
        ssum[ob + c + 1] = q1v + k1v + v1v;
        unsigned qp = pk_bf16(q0, q1v);
        unsigned kp = pk_bf16(k0, k1v);
        unsigned vp = pk_bf16(v0, v1v);
        if (qq < 2) {
            *(unsigned*)(q1 + p1 + c) = qp;
            *(unsigned*)(k1 + p1 + c) = kp;
            *(unsigned*)(v1 + p1 + c) = vp;
        } else {
            *(unsigned*)(q2 + p2 + c - 28) = qp;
            *(unsigned*)(k2 + p2 + c - 28) = kp;
            *(unsigned*)(v2 + p2 + c - 28) = vp;
        }
    }
}

// ------------------------------- K2: conv1 ---------------------------------
__global__ __launch_bounds__(256) void k_conv1(const float* __restrict__ ssum,
                                               const float* __restrict__ c1w,
                                               const float* __restrict__ c1b,
                                               float* __restrict__ c1o) {
    __shared__ __align__(16) float tile[6 * 66 * 29];
    __shared__ __align__(16) float wl[4032];
    int tid = threadIdx.x;
    int wg = blockIdx.x;
    int br = wg >> 9;
    int b = (wg >> 6) & 7;
    int nt = wg & 63;
    int n0 = nt * 4;
    for (int e = tid; e < 11088; e += 256) {
        int c = e % 28;
        int rest = e / 28;
        int mm = rest % 66;
        int nr = rest / 66;
        int n = n0 - 1 + nr;
        int m = mm - 1;
        float v = 0.f;
        if (n >= 0 && n < 256 && m >= 0 && m < 64)
            v = ssum[(((size_t)b * 256 + n) * 64 + m) * 56 + br * 28 + c];
        tile[(nr * 66 + mm) * 29 + c] = v;
    }
    for (int e = tid; e < 4032; e += 256) {
        int o = e & 15;
        int tap = e >> 4;
        wl[e] = c1w[o * 252 + tap];
    }
    __syncthreads();
    int ny = tid >> 6;
    int m = tid & 63;
    float acc[16];
#pragma unroll
    for (int o = 0; o < 16; ++o) acc[o] = 0.f;
    for (int c = 0; c < 28; ++c) {
#pragma unroll
        for (int ky = 0; ky < 3; ++ky) {
#pragma unroll
            for (int kx = 0; kx < 3; ++kx) {
                float iv = tile[((ny + ky) * 66 + (m + kx)) * 29 + c];
                const float4* wp = (const float4*)(wl + (c * 9 + ky * 3 + kx) * 16);
                float4 w0 = wp[0], w1 = wp[1], w2 = wp[2], w3 = wp[3];
                acc[0] += iv * w0.x;  acc[1] += iv * w0.y;  acc[2] += iv * w0.z;  acc[3] += iv * w0.w;
                acc[4] += iv * w1.x;  acc[5] += iv * w1.y;  acc[6] += iv * w1.z;  acc[7] += iv * w1.w;
                acc[8] += iv * w2.x;  acc[9] += iv * w2.y;  acc[10] += iv * w2.z; acc[11] += iv * w2.w;
                acc[12] += iv * w3.x; acc[13] += iv * w3.y; acc[14] += iv * w3.z; acc[15] += iv * w3.w;
            }
        }
    }
    float4 b0 = *(const float4*)(c1b + 0);
    float4 b1 = *(const float4*)(c1b + 4);
    float4 b2 = *(const float4*)(c1b + 8);
    float4 b3 = *(const float4*)(c1b + 12);
    size_t ob = (((size_t)(br * 8 + b) * 16384) + (size_t)(n0 + ny) * 64 + m) * 16;
    float4* op = (float4*)(c1o + ob);
    op[0] = make_float4(fmaxf(acc[0] + b0.x, 0.f), fmaxf(acc[1] + b0.y, 0.f),
                        fmaxf(acc[2] + b0.z, 0.f), fmaxf(acc[3] + b0.w, 0.f));
    op[1] = make_float4(fmaxf(acc[4] + b1.x, 0.f), fmaxf(acc[5] + b1.y, 0.f),
                        fmaxf(acc[6] + b1.z, 0.f), fmaxf(acc[7] + b1.w, 0.f));
    op[2] = make_float4(fmaxf(acc[8] + b2.x, 0.f), fmaxf(acc[9] + b2.y, 0.f),
                        fmaxf(acc[10] + b2.z, 0.f), fmaxf(acc[11] + b2.w, 0.f));
    op[3] = make_float4(fmaxf(acc[12] + b3.x, 0.f), fmaxf(acc[13] + b3.y, 0.f),
                        fmaxf(acc[14] + b3.z, 0.f), fmaxf(acc[15] + b3.w, 0.f));
}

// ------------------------- K3: conv2 + pooled partials ---------------------
__global__ __launch_bounds__(256) void k_conv2(const float* __restrict__ c1o,
                                               const float* __restrict__ c2w,
                                               const float* __restrict__ c2b,
                                               float* __restrict__ part) {
    __shared__ __align__(16) float tile[6 * 66 * 17];
    __shared__ __align__(16) float wl[2304];
    __shared__ float pbuf[4][16];
    int tid = threadIdx.x;
    int wg = blockIdx.x;
    int br = wg >> 9;
    int b = (wg >> 6) & 7;
    int nt = wg & 63;
    int n0 = nt * 4;
    for (int e = tid; e < 6336; e += 256) {
        int c = e & 15;
        int rest = e >> 4;
        int mm = rest % 66;
        int nr = rest / 66;
        int n = n0 - 1 + nr;
        int m = mm - 1;
        float v = 0.f;
        if (n >= 0 && n < 256 && m >= 0 && m < 64)
            v = c1o[(((size_t)(br * 8 + b) * 16384) + (size_t)n * 64 + m) * 16 + c];
        tile[(nr * 66 + mm) * 17 + c] = v;
    }
    for (int e = tid; e < 2304; e += 256) {
        int o = e & 15;
        int tap = e >> 4;
        wl[e] = c2w[o * 144 + tap];
    }
    __syncthreads();
    int ny = tid >> 6;
    int m = tid & 63;
    float acc[16];
#pragma unroll
    for (int o = 0; o < 16; ++o) acc[o] = 0.f;
    for (int c = 0; c < 16; ++c) {
#pragma unroll
        for (int ky = 0; ky < 3; ++ky) {
#pragma unroll
            for (int kx = 0; kx < 3; ++kx) {
                float iv = tile[((ny + ky) * 66 + (m + kx)) * 17 + c];
                const float4* wp = (const float4*)(wl + (c * 9 + ky * 3 + kx) * 16);
                float4 w0 = wp[0], w1 = wp[1], w2 = wp[2], w3 = wp[3];
                acc[0] += iv * w0.x;  acc[1] += iv * w0.y;  acc[2] += iv * w0.z;  acc[3] += iv * w0.w;
                acc[4] += iv * w1.x;  acc[5] += iv * w1.y;  acc[6] += iv * w1.z;  acc[7] += iv * w1.w;
                acc[8] += iv * w2.x;  acc[9] += iv * w2.y;  acc[10] += iv * w2.z; acc[11] += iv * w2.w;
                acc[12] += iv * w3.x; acc[13] += iv * w3.y; acc[14] += iv * w3.z; acc[15] += iv * w3.w;
            }
        }
    }
    int lane = tid & 63;
    int wid = tid >> 6;
#pragma unroll
    for (int o = 0; o < 16; ++o) {
        float s = fmaxf(acc[o] + c2b[o], 0.f);
#pragma unroll
        for (int msk = 1; msk < 64; msk <<= 1) s += __shfl_xor(s, msk);
        if (lane == 0) pbuf[wid][o] = s;
    }
    __syncthreads();
    if (tid < 16) {
        float s = pbuf[0][tid] + pbuf[1][tid] + pbuf[2][tid] + pbuf[3][tid];
        part[(((size_t)(br * 8 + b)) * 64 + nt) * 16 + tid] = s;
    }
}

// ------------------------- K4: reduce + FC -> shifts -----------------------
__global__ void k_fc(const float* __restrict__ part, const float* __restrict__ f1w,
                     const float* __restrict__ f1b, const float* __restrict__ f2w,
                     const float* __restrict__ f2b, float* __restrict__ shif) {
    __shared__ float sb[16][16];
    int t = threadIdx.x;
    int combo = t >> 4;
    int o = t & 15;
    float s = 0.f;
    for (int nt = 0; nt < 64; ++nt) s += part[((size_t)combo * 64 + nt) * 16 + o];
    sb[combo][o] = s * (1.0f / 16384.0f);
    __syncthreads();
    if (t < 16) {
        float p0 = f1b[0], p1 = f1b[1], rg = f2b[0];
        for (int oo = 0; oo < 16; ++oo) {
            float sv = sb[t][oo];
            p0 += sv * f1w[oo * 2 + 0];
            p1 += sv * f1w[oo * 2 + 1];
            rg += sv * f2w[oo];
        }
        shif[t * 2 + 0] = rg * tanhf(p0);
        shif[t * 2 + 1] = rg * tanhf(p1);
    }
}

// ------------------------- K5a/b: shifted pos precompute -------------------
__global__ __launch_bounds__(256) void k_pos1(const float* __restrict__ pos1,
                                              const float* __restrict__ shif,
                                              float* __restrict__ P1T,
                                              float* __restrict__ P1M) {
    __shared__ float plds[64 * 64];
    int b = blockIdx.x;
    float sx = shif[b * 2 + 0];
    float sy = shif[b * 2 + 1];
    for (int e = threadIdx.x; e < 4096; e += 256) {
        int j = e >> 6;
        int i = e & 63;
        int y0, y1, x0, x1;
        float wy0, wy1, wx0, wx1;
        coords_(i, 64, sy, y0, y1, wy0, wy1);
        coords_(j, 64, sx, x0, x1, wx0, wx1);
        float v = pos1[((i - 1) & 63) * 64 + ((j - 1) & 63)] +
                  wy0 * (wx0 * pos1[y0 * 64 + x0] + wx1 * pos1[y0 * 64 + x1]) +
                  wy1 * (wx0 * pos1[y1 * 64 + x0] + wx1 * pos1[y1 * 64 + x1]);
        P1T[(size_t)b * 4096 + j * 64 + i] = v;
        plds[j * 64 + i] = v;
    }
    __syncthreads();
    if (threadIdx.x < 64) {
        float mx = plds[threadIdx.x];
        for (int j = 1; j < 64; ++j) mx = fmaxf(mx, plds[j * 64 + threadIdx.x]);
        P1M[b * 64 + threadIdx.x] = mx;
    }
}

__global__ __launch_bounds__(256) void k_pos2(const float* __restrict__ pos2,
                                              const float* __restrict__ shif,
                                              float* __restrict__ P2R,
                                              float* __restrict__ P2M) {
    __shared__ float red[4];
    int wg = blockIdx.x;
    int b = wg >> 8;
    int i = wg & 255;
    float sx = shif[16 + b * 2 + 0];
    float sy = shif[16 + b * 2 + 1];
    int j = threadIdx.x;
    int y0, y1, x0, x1;
    float wy0, wy1, wx0, wx1;
    coords_(i, 256, sy, y0, y1, wy0, wy1);
    coords_(j, 256, sx, x0, x1, wx0, wx1);
    float v = pos2[((i - 1) & 255) * 256 + ((j - 1) & 255)] +
              wy0 * (wx0 * pos2[y0 * 256 + x0] + wx1 * pos2[y0 * 256 + x1]) +
              wy1 * (wx0 * pos2[y1 * 256 + x0] + wx1 * pos2[y1 * 256 + x1]);
    P2R[(size_t)b * 65536 + (size_t)i * 256 + j] = v;
    float mx = v;
#pragma unroll
    for (int msk = 1; msk < 64; msk <<= 1) mx = fmaxf(mx, __shfl_xor(mx, msk));
    if ((threadIdx.x & 63) == 0) red[threadIdx.x >> 6] = mx;
    __syncthreads();
    if (threadIdx.x == 0)
        P2M[b * 256 + i] = fmaxf(fmaxf(red[0], red[1]), fmaxf(red[2], red[3]));
}

// --------------- K6: branch-1 window attention (64x64), MFMA ---------------
// Block = one window, 4 waves; wave w owns rows [16w,16w+16).
__global__ __launch_bounds__(256) void k_attn1(const unsigned short* __restrict__ q1,
                                               const unsigned short* __restrict__ k1,
                                               const unsigned short* __restrict__ v1,
                                               const float* __restrict__ P1T,
                                               const float* __restrict__ P1M,
                                               const float* __restrict__ shif,
                                               float* __restrict__ aout) {
    __shared__ __align__(16) unsigned short qraw[64 * 28];
    __shared__ __align__(16) unsigned short kraw[64 * 28];
    __shared__ __align__(16) unsigned short augK[64 * 68];
    __shared__ __align__(16) unsigned short vT[32 * 68];
    __shared__ __align__(16) unsigned short Pw[4][16 * 68];
    int tid = threadIdx.x;
    int w = tid >> 6;
    int l = tid & 63;
    int g = l >> 4;
    int li = l & 15;
    int wg = blockIdx.x;
    int b = wg >> 8;
    int n = wg & 255;
    size_t gb = (size_t)(b * 256 + n) * 1792;
    float sx = shif[b * 2 + 0];
    float sy = shif[b * 2 + 1];
    // phase A: stage raw q/k + vT (+ zero-pad vT rows 28..31)
    for (int e = tid; e < 1792; e += 256) {
        qraw[e] = q1[gb + e];
        kraw[e] = k1[gb + e];
        int j = e / 28;
        int c = e - j * 28;
        vT[c * 68 + j] = v1[gb + e];
    }
    for (int e = tid; e < 272; e += 256) vT[28 * 68 + e] = 0;
    __syncthreads();
    // phase B: build augK rows (tid<64)
    if (tid < 64) {
        int j = tid;
        int x0, x1;
        float wx0, wx1;
        coords_(j, 64, sx, x0, x1, wx0, wx1);
        int rm = (j - 1) & 63;
        unsigned* row = (unsigned*)(augK + j * 68);
        const unsigned* src = (const unsigned*)(kraw + rm * 28);
#pragma unroll
        for (int h = 0; h < 14; ++h) row[h] = src[h];
#pragma unroll
        for (int h = 0; h < 14; ++h) {
            float a0 = wx0 * bf2f(kraw[x0 * 28 + 2 * h]) + wx1 * bf2f(kraw[x1 * 28 + 2 * h]);
            float a1 = wx0 * bf2f(kraw[x0 * 28 + 2 * h + 1]) + wx1 * bf2f(kraw[x1 * 28 + 2 * h + 1]);
            row[14 + h] = pk_bf16(a0, a1);
        }
#pragma unroll
        for (int h = 28; h < 34; ++h) row[h] = 0;
    }
    // Q fragments (reads qraw; staged in phase A)
    bf4 qf[4];
    {
        int i = 16 * w + li;
        int y0, y1;
        float wy0, wy1;
        coords_(i, 64, sy, y0, y1, wy0, wy1);
        int rm = (i - 1) & 63;
#pragma unroll
        for (int kt = 0; kt < 4; ++kt) {
            float qv[4];
#pragma unroll
            for (int e = 0; e < 4; ++e) {
                int d = 16 * kt + 4 * g + e;
                float v;
                if (d < 28) v = SCALE_ * bf2f(qraw[rm * 28 + d]);
                else if (d < 56)
                    v = SCALE_ * (wy0 * bf2f(qraw[y0 * 28 + d - 28]) +
                                  wy1 * bf2f(qraw[y1 * 28 + d - 28]));
                else v = 0.f;
                qv[e] = v;
            }
            union { unsigned u[2]; bf4 v; } cv;
            cv.u[0] = pk_bf16(qv[0], qv[1]);
            cv.u[1] = pk_bf16(qv[2], qv[3]);
            qf[kt] = cv.v;
        }
    }
    f4 Mv = *(const f4*)(P1M + b * 64 + 16 * w + 4 * g);
    __syncthreads();
    // QK^T with bias init
    f4 acc[4];
#pragma unroll
    for (int nj = 0; nj < 4; ++nj)
        acc[nj] = *(const f4*)(P1T + (size_t)b * 4096 + (16 * nj + li) * 64 + 16 * w + 4 * g);
#pragma unroll
    for (int nj = 0; nj < 4; ++nj) {
        const unsigned short* kr = augK + (16 * nj + li) * 68 + 4 * g;
#pragma unroll
        for (int kt = 0; kt < 4; ++kt) {
            bf4 bk = *(const bf4*)(kr + 16 * kt);
            acc[nj] = mfma16(qf[kt], bk, acc[nj]);
        }
    }
    // softmax (fixed offset) + P tile
    float lr[4] = {0.f, 0.f, 0.f, 0.f};
    unsigned short* Pww = Pw[w];
#pragma unroll
    for (int nj = 0; nj < 4; ++nj)
#pragma unroll
        for (int r = 0; r < 4; ++r) {
            float p = __expf(acc[nj][r] - Mv[r]);
            lr[r] += p;
            Pww[(4 * g + r) * 68 + 16 * nj + li] = f2bf(p);
        }
    // PV
    f4 accv[2];
    accv[0] = (f4){0.f, 0.f, 0.f, 0.f};
    accv[1] = (f4){0.f, 0.f, 0.f, 0.f};
#pragma unroll
    for (int kt = 0; kt < 4; ++kt) {
        bf4 pa = *(const bf4*)(Pww + li * 68 + 16 * kt + 4 * g);
#pragma unroll
        for (int nc = 0; nc < 2; ++nc) {
            bf4 bv = *(const bf4*)(vT + (16 * nc + li) * 68 + 16 * kt + 4 * g);
            accv[nc] = mfma16(pa, bv, accv[nc]);
        }
    }
    // reduce l over the 16 lanes of li, normalize, write
#pragma unroll
    for (int r = 0; r < 4; ++r) {
#pragma unroll
        for (int msk = 1; msk < 16; msk <<= 1) lr[r] += __shfl_xor(lr[r], msk);
        float invl = 1.0f / lr[r];
        int i = 16 * w + 4 * g + r;
        size_t wb = ((size_t)(b * 256 + n) * 64 + i) * 56;
        aout[wb + li] = accv[0][r] * invl;
        if (li < 12) aout[wb + 16 + li] = accv[1][r] * invl;
    }
}

// -------------------- K7: branch-2 cross-window attn, MFMA -----------------
// 512 threads per (b,m); wave w owns rows [32w,32w+32). bf16 inputs. LDS:
//   augK bf16 [256][68] @0, V^T bf16 [28][260] @34816, P per-wave [32][68].
__global__ __launch_bounds__(512) void k_attn2(const unsigned short* __restrict__ q2,
                                               const unsigned short* __restrict__ k2,
                                               const unsigned short* __restrict__ v2,
                                               const float* __restrict__ P2R,
                                               const float* __restrict__ P2M,
                                               const float* __restrict__ shif,
                                               float* __restrict__ aout) {
    extern __shared__ __align__(16) char smem[];
    unsigned short* augK = (unsigned short*)smem;                  // [256][68]
    unsigned short* vT = (unsigned short*)(smem + 34816);          // [28][260]
    int tid = threadIdx.x;
    int w = tid >> 6;
    int l = tid & 63;
    int g = l >> 4;
    int li = l & 15;
    unsigned short* Pw = (unsigned short*)(smem + 49376) + w * 2176;  // [32][68]
    int bm = blockIdx.x;
    int b = bm >> 6;
    int m = bm & 63;
    size_t gbase = (size_t)bm * 7168;
    float sx = shif[16 + b * 2 + 0];
    float sy = shif[16 + b * 2 + 1];
    if (tid < 256) {
        int j = tid;
        int x0, x1;
        float wx0, wx1;
        coords_(j, 256, sx, x0, x1, wx0, wx1);
        int rm = (j - 1) & 255;
        const unsigned short* krm = k2 + gbase + (size_t)rm * 28;
        const unsigned short* ka = k2 + gbase + (size_t)x0 * 28;
        const unsigned short* kb = k2 + gbase + (size_t)x1 * 28;
        unsigned* row = (unsigned*)(augK + j * 68);
        const unsigned* src = (const unsigned*)krm;
#pragma unroll
        for (int h = 0; h < 14; ++h) row[h] = src[h];
#pragma unroll
        for (int h = 0; h < 14; ++h) {
            float a0 = wx0 * bf2f(ka[2 * h]) + wx1 * bf2f(kb[2 * h]);
            float a1 = wx0 * bf2f(ka[2 * h + 1]) + wx1 * bf2f(kb[2 * h + 1]);
            row[14 + h] = pk_bf16(a0, a1);
        }
#pragma unroll
        for (int h = 28; h < 34; ++h) row[h] = 0;
    } else {
        int j = tid - 256;
        const unsigned short* vr = v2 + gbase + (size_t)j * 28;
#pragma unroll
        for (int c = 0; c < 28; ++c) vT[c * 260 + j] = vr[c];
    }
    // Q fragments
    bf4 qf[2][4];
#pragma unroll
    for (int mi = 0; mi < 2; ++mi) {
        int i = 32 * w + 16 * mi + li;
        int y0, y1;
        float wy0, wy1;
        coords_(i, 256, sy, y0, y1, wy0, wy1);
        int rm = (i - 1) & 255;
        const unsigned short* qrm = q2 + gbase + (size_t)rm * 28;
        const unsigned short* qa = q2 + gbase + (size_t)y0 * 28;
        const unsigned short* qb = q2 + gbase + (size_t)y1 * 28;
#pragma unroll
        for (int kt = 0; kt < 4; ++kt) {
            float qv[4];
#pragma unroll
            for (int e = 0; e < 4; ++e) {
                int d = 16 * kt + 4 * g + e;
                float v;
                if (d < 28) v = SCALE_ * bf2f(qrm[d]);
                else if (d < 56)
                    v = SCALE_ * (wy0 * bf2f(qa[d - 28]) + wy1 * bf2f(qb[d - 28]));
                else v = 0.f;
                qv[e] = v;
            }
            union { unsigned u[2]; bf4 v; } cv;
            cv.u[0] = pk_bf16(qv[0], qv[1]);
            cv.u[1] = pk_bf16(qv[2], qv[3]);
            qf[mi][kt] = cv.v;
        }
    }
    float M[2][4];
#pragma unroll
    for (int mi = 0; mi < 2; ++mi)
#pragma unroll
        for (int r = 0; r < 4; ++r)
            M[mi][r] = P2M[b * 256 + 32 * w + 16 * mi + 4 * g + r];
    __syncthreads();
    f4 accv[2][2];
#pragma unroll
    for (int mi = 0; mi < 2; ++mi)
#pragma unroll
        for (int nc = 0; nc < 2; ++nc) accv[mi][nc] = (f4){0.f, 0.f, 0.f, 0.f};
    float lrun[2][4];
#pragma unroll
    for (int mi = 0; mi < 2; ++mi)
#pragma unroll
        for (int r = 0; r < 4; ++r) lrun[mi][r] = 0.f;

    for (int jt = 0; jt < 4; ++jt) {
        f4 acc[2][4];
#pragma unroll
        for (int mi = 0; mi < 2; ++mi) {
            const float* pr = P2R + (size_t)b * 65536 +
                              (size_t)(32 * w + 16 * mi + 4 * g) * 256 + 64 * jt + li;
#pragma unroll
            for (int nj = 0; nj < 4; ++nj)
                acc[mi][nj] = (f4){pr[16 * nj], pr[16 * nj + 256],
                                   pr[16 * nj + 512], pr[16 * nj + 768]};
        }
#pragma unroll
        for (int nj = 0; nj < 4; ++nj) {
            const unsigned short* kr = augK + (64 * jt + 16 * nj + li) * 68 + 4 * g;
            bf4 bk[4];
#pragma unroll
            for (int kt = 0; kt < 4; ++kt) bk[kt] = *(const bf4*)(kr + 16 * kt);
#pragma unroll
            for (int mi = 0; mi < 2; ++mi)
#pragma unroll
                for (int kt = 0; kt < 4; ++kt)
                    acc[mi][nj] = mfma16(qf[mi][kt], bk[kt], acc[mi][nj]);
        }
#pragma unroll
        for (int mi = 0; mi < 2; ++mi)
#pragma unroll
            for (int nj = 0; nj < 4; ++nj)
#pragma unroll
                for (int r = 0; r < 4; ++r) {
                    float p = __expf(acc[mi][nj][r] - M[mi][r]);
                    lrun[mi][r] += p;
                    Pw[(16 * mi + 4 * g + r) * 68 + 16 * nj + li] = f2bf(p);
                }
#pragma unroll
        for (int kt = 0; kt < 4; ++kt) {
            bf4 pa[2];
#pragma unroll
            for (int mi = 0; mi < 2; ++mi)
                pa[mi] = *(const bf4*)(Pw + (16 * mi + li) * 68 + 16 * kt + 4 * g);
#pragma unroll
            for (int nc = 0; nc < 2; ++nc) {
                bf4 bv = *(const bf4*)(vT + (16 * nc + li) * 260 + 64 * jt + 16 * kt + 4 * g);
#pragma unroll
                for (int mi = 0; mi < 2; ++mi)
                    accv[mi][nc] = mfma16(pa[mi], bv, accv[mi][nc]);
            }
        }
    }
#pragma unroll
    for (int mi = 0; mi < 2; ++mi)
#pragma unroll
        for (int r = 0; r < 4; ++r) {
#pragma unroll
            for (int msk = 1; msk < 16; msk <<= 1)
                lrun[mi][r] += __shfl_xor(lrun[mi][r], msk);
            float invl = 1.0f / lrun[mi][r];
            int gi = 32 * w + 16 * mi + 4 * g + r;
            size_t wb = (((size_t)b * 256 + gi) * 64 + m) * 56 + 28;
            aout[wb + li] = accv[mi][0][r] * invl;
            if (li < 12) aout[wb + 16 + li] = accv[mi][1][r] * invl;
        }
}

// ---------------- K8: output projection + unwindow (bf16x3 MFMA) -----------
__global__ __launch_bounds__(256) void k_out(const float* __restrict__ aout,
                                             const float* __restrict__ Wout,
                                             const float* __restrict__ bout,
                                             float* __restrict__ out) {
    __shared__ __align__(16) unsigned short Ah[64 * 68];
    __shared__ __align__(16) unsigned short Al[64 * 68];
    __shared__ __align__(16) float st[64 * 60];
    int tid = threadIdx.x;
    int w = tid >> 6;
    int l = tid & 63;
    int g = l >> 4;
    int li = l & 15;
    int pix0 = blockIdx.x * 64;
    for (int e = tid; e < 3584; e += 256) {
        int row = e / 56;
        int c = e - row * 56;
        float v = aout[(size_t)pix0 * 56 + e];
        unsigned short hi = f2bf(v);
        Ah[row * 68 + c] = hi;
        Al[row * 68 + c] = f2bf(v - bf2f(hi));
    }
    for (int e = tid; e < 768; e += 256) {
        int row = e / 12;
        int c = 56 + e - row * 12;
        Ah[row * 68 + c] = 0;
        Al[row * 68 + c] = 0;
    }
    // B-frags (all 4 N-tiles; wave = M-tile)
    bf4 Bh[4][4], Bl[4][4];
#pragma unroll
    for (int nt = 0; nt < 4; ++nt) {
        int col = 16 * nt + li;
#pragma unroll
        for (int kt = 0; kt < 4; ++kt) {
            float hv[4], lv[4];
#pragma unroll
            for (int e = 0; e < 4; ++e) {
                int k = 16 * kt + 4 * g + e;
                float v = (k < 56 && col < 56) ? Wout[k * 56 + col] : 0.f;
                unsigned short h = f2bf(v);
                hv[e] = bf2f(h);
                lv[e] = v - hv[e];
            }
            union { unsigned u[2]; bf4 v; } ch, cl;
            ch.u[0] = pk_bf16(hv[0], hv[1]);
            ch.u[1] = pk_bf16(hv[2], hv[3]);
            cl.u[0] = pk_bf16(lv[0], lv[1]);
            cl.u[1] = pk_bf16(lv[2], lv[3]);
            Bh[nt][kt] = ch.v;
            Bl[nt][kt] = cl.v;
        }
    }
    __syncthreads();
    f4 acc[4];
#pragma unroll
    for (int nt = 0; nt < 4; ++nt) acc[nt] = (f4){0.f, 0.f, 0.f, 0.f};
    bf4 ah[4], al[4];
#pragma unroll
    for (int kt = 0; kt < 4; ++kt) {
        ah[kt] = *(const bf4*)(Ah + (16 * w + li) * 68 + 16 * kt + 4 * g);
        al[kt] = *(const bf4*)(Al + (16 * w + li) * 68 + 16 * kt + 4 * g);
    }
#pragma unroll
    for (int nt = 0; nt < 4; ++nt)
#pragma unroll
        for (int kt = 0; kt < 4; ++kt) {
            acc[nt] = mfma16(ah[kt], Bh[nt][kt], acc[nt]);
            acc[nt] = mfma16(al[kt], Bh[nt][kt], acc[nt]);
            acc[nt] = mfma16(ah[kt], Bl[nt][kt], acc[nt]);
        }
#pragma unroll
    for (int nt = 0; nt < 4; ++nt) {
        int col = 16 * nt + li;
        if (col < 56) {
#pragma unroll
            for (int r = 0; r < 4; ++r)
                st[(16 * w + 4 * g + r) * 60 + col] = acc[nt][r];
        }
    }
    __syncthreads();
    int row = tid >> 2;
    int qq = tid & 3;
    int pixel = pix0 + row;
    int b = pixel >> 14;
    int n = (pixel >> 6) & 255;
    int m = pixel & 63;
    int h = ((n >> 4) << 3) + (m >> 3);
    int ww = ((n & 15) << 3) + (m & 7);
    float* dst = out + (((size_t)b * 128 + h) * 128 + ww) * 56;
    const float* sr = st + row * 60;
#pragma unroll
    for (int cc = 0; cc < 14; ++cc) {
        int c = 14 * qq + cc;
        dst[c] = sr[c] + bout[c];
    }
}

// ---------------------------------------------------------------------------
extern "C" void kernel_launch(void* const* d_in, const int* in_sizes, int n_in,
                              void* d_out, int out_size, void* d_ws, size_t ws_size,
                              hipStream_t stream) {
    const float* x = (const float*)d_in[0];
    const float* pos1 = (const float*)d_in[1];
    const float* pos2 = (const float*)d_in[2];
    const float* Wq = (const float*)d_in[3];
    const float* Wkv = (const float*)d_in[4];
    const float* Wout = (const float*)d_in[5];
    const float* bout = (const float*)d_in[6];
    const float* c1w = (const float*)d_in[7];
    const float* c1b = (const float*)d_in[8];
    const float* c2w = (const float*)d_in[9];
    const float* c2b = (const float*)d_in[10];
    const float* f1w = (const float*)d_in[11];
    const float* f1b = (const float*)d_in[12];
    const float* f2w = (const float*)d_in[13];
    const float* f2b = (const float*)d_in[14];

    unsigned short* us = (unsigned short*)d_ws;
    unsigned short* q1 = us;
    unsigned short* k1 = us + 3670016;
    unsigned short* v1 = us + 7340032;
    unsigned short* q2 = us + 11010048;
    unsigned short* k2 = us + 14680064;
    unsigned short* v2 = us + 18350080;
    float* fb = (float*)d_ws + 11010048;
    float* ssum = fb;            // reused as aout after conv1
    float* aout = fb;
    float* c1o = fb + 7340032;
    float* part = fb + 11534336;
    float* shif = fb + 11550720;
    float* P1T = fb + 11550752;
    float* P1M = fb + 11583520;
    float* P2R = fb + 11584032;
    float* P2M = fb + 12108320;
    float* outp = (float*)d_out;

    (void)hipFuncSetAttribute((const void*)k_qkv,
                              hipFuncAttributeMaxDynamicSharedMemorySize, 78848);
    (void)hipFuncSetAttribute((const void*)k_attn2,
                              hipFuncAttributeMaxDynamicSharedMemorySize, 84192);

    k_qkv<<<2048, 256, 78848, stream>>>(x, Wq, Wkv, q1, k1, v1, q2, k2, v2, ssum);
    k_conv1<<<1024, 256, 0, stream>>>(ssum, c1w, c1b, c1o);
    k_conv2<<<1024, 256, 0, stream>>>(c1o, c2w, c2b, part);
    k_fc<<<1, 256, 0, stream>>>(part, f1w, f1b, f2w, f2b, shif);
    k_pos1<<<8, 256, 0, stream>>>(pos1, shif, P1T, P1M);
    k_pos2<<<2048, 256, 0, stream>>>(pos2, shif, P2R, P2M);
    k_attn1<<<2048, 256, 0, stream>>>(q1, k1, v1, P1T, P1M, shif, aout);
    k_attn2<<<512, 512, 84192, stream>>>(q2, k2, v2, P2R, P2M, shif, aout);
    k_out<<<2048, 256, 0, stream>>>(aout, Wout, bout, outp);
}

// Round 6
// 261.495 us; speedup vs baseline: 3.1650x; 1.1242x over previous
//
#include <hip/hip_runtime.h>
#include <cstdint>

// ---------------------------------------------------------------------------
// SS-MSA fused implementation, round 6.
// grid_shift(sim) factorizes: shifted[i,j] = SCALE*(q_{i-1}.k_{j-1} + q~_i.k~_j) + P[i,j]
// => both branches are plain attention with 56-dim augmented Q/K + bias P.
//
// Round-6 changes vs round 5 (k_qkv was latency-bound on per-block scalar
// W loads + hi/lo conversion: MfmaUtil 7%, VALUBusy 18%, Occ 20%):
//  - k_prep: one-time conversion of Wq/Wkv/Wout into fragment-ordered bf16
//    (WF/WFo) -> B-frag loads become coalesced b64 loads, no per-block VALU.
//  - k_qkv: single bf16 product (ssum error analysis: shift path tolerance
//    >> bf16; q/k/v consumed as bf16 anyway). LDS 78.8->52.7 KB (3 blk/CU).
//  - k_out: (Ah+Al)*W_bf16 (2 products), prepped B.
// ---------------------------------------------------------------------------

#define SCALE_ 0.18898223650461364f  // 28^-0.5

using f4 = __attribute__((ext_vector_type(4))) float;
using bf4 = __attribute__((ext_vector_type(4))) short;

__device__ __forceinline__ f4 mfma16(bf4 a, bf4 b, f4 c) {
#if __has_builtin(__builtin_amdgcn_mfma_f32_16x16x16bf16_1k)
    return __builtin_amdgcn_mfma_f32_16x16x16bf16_1k(a, b, c, 0, 0, 0);
#else
    f4 d;
    asm("v_mfma_f32_16x16x16_bf16 %0, %1, %2, %3" : "=v"(d) : "v"(a), "v"(b), "v"(c));
    return d;
#endif
}

__device__ __forceinline__ unsigned pk_bf16(float lo, float hi) {
    unsigned r;
    asm("v_cvt_pk_bf16_f32 %0, %1, %2" : "=v"(r) : "v"(lo), "v"(hi));
    return r;
}
__device__ __forceinline__ unsigned short f2bf(float f) {
    return (unsigned short)pk_bf16(f, f);
}
__device__ __forceinline__ float bf2f(unsigned short h) {
    return __uint_as_float(((unsigned)h) << 16);
}

__device__ __forceinline__ void coords_(int idx, int S, float s,
                                        int& i0, int& i1, float& w0, float& w1) {
    float g = -1.0f + 2.0f * (float)idx / (float)(S - 1);
    float c = (g + s * 2.0f / (float)S + 1.0f) * 0.5f * (float)(S - 1);
    float span = (float)(S - 1);
    c = fabsf(c);
    c = fmodf(c, 2.0f * span);
    if (c > span) c = 2.0f * span - c;
    int f = (int)floorf(c);
    f = max(0, min(f, S - 1));
    i0 = f;
    i1 = min(f + 1, S - 1);
    w1 = c - (float)f;
    w0 = 1.0f - w1;
}

// ------------------ K0: weight prep (fragment-ordered bf16) ----------------
// WF: 11 N-tiles x 4 kt x 64 lanes x 4 e  (cols 0..55 Wq | 56..167 Wkv)
// WFo: 4 N-tiles x 4 kt x 64 lanes x 4 e  (Wout, cols 0..55)
__global__ __launch_bounds__(256) void k_prep(const float* __restrict__ Wq,
                                              const float* __restrict__ Wkv,
                                              const float* __restrict__ Wout,
                                              unsigned short* __restrict__ WF,
                                              unsigned short* __restrict__ WFo) {
    int tid = blockIdx.x * 256 + threadIdx.x;
    if (tid < 11264) {
        int e = tid & 3;
        int l = (tid >> 2) & 63;
        int kt = (tid >> 8) & 3;
        int nt = tid >> 10;
        int g = l >> 4, li = l & 15;
        int k = 16 * kt + 4 * g + e;
        int col = 16 * nt + li;
        float v = 0.f;
        if (k < 56 && col < 168)
            v = (col < 56) ? Wq[k * 56 + col] : Wkv[k * 112 + (col - 56)];
        WF[tid] = f2bf(v);
    } else if (tid < 15360) {
        int t2 = tid - 11264;
        int e = t2 & 3;
        int l = (t2 >> 2) & 63;
        int kt = (t2 >> 8) & 3;
        int nt = t2 >> 10;
        int g = l >> 4, li = l & 15;
        int k = 16 * kt + 4 * g + e;
        int col = 16 * nt + li;
        float v = (k < 56 && col < 56) ? Wout[k * 56 + col] : 0.f;
        WFo[t2] = f2bf(v);
    }
}

// ------------------- K1: QKV GEMM (bf16 MFMA, prepped B) -------------------
// Block: 64 pixels x 168 cols. 4 waves; wave w owns N-tiles {3w..}.
// Dynamic LDS: Ah bf16 [64][68] 8704B | st f32 [64][172] 44032B = 52736B.
__global__ __launch_bounds__(256) void k_qkv(const float* __restrict__ x,
                                             const unsigned short* __restrict__ WF,
                                             unsigned short* __restrict__ q1,
                                             unsigned short* __restrict__ k1,
                                             unsigned short* __restrict__ v1,
                                             unsigned short* __restrict__ q2,
                                             unsigned short* __restrict__ k2,
                                             unsigned short* __restrict__ v2,
                                             float* __restrict__ ssum) {
    extern __shared__ __align__(16) char smem[];
    unsigned short* Ah = (unsigned short*)smem;   // [64][68]
    float* st = (float*)(smem + 8704);            // [64][172]
    int tid = threadIdx.x;
    int w = tid >> 6;
    int l = tid & 63;
    int g = l >> 4;
    int li = l & 15;
    int pix0 = blockIdx.x * 64;
    // stage A bf16 (paired)
    for (int e = tid; e < 1792; e += 256) {
        int row = e / 28;
        int hp = e - row * 28;
        float2 v = *(const float2*)(x + (size_t)pix0 * 56 + 2 * e);
        ((unsigned*)Ah)[row * 34 + hp] = pk_bf16(v.x, v.y);
    }
    for (int e = tid; e < 384; e += 256) {
        int row = e / 6;
        ((unsigned*)Ah)[row * 34 + 28 + (e - row * 6)] = 0;
    }
    // B fragments: coalesced b64 loads from prepped WF
    int nt0 = 3 * w;
    int nnt = (w < 3) ? 3 : 2;
    bf4 B[3][4];
#pragma unroll
    for (int t = 0; t < 3; ++t) {
        if (t >= nnt) break;
#pragma unroll
        for (int kt = 0; kt < 4; ++kt)
            B[t][kt] = *(const bf4*)(WF + (((nt0 + t) * 4 + kt) * 64 + l) * 4);
    }
    __syncthreads();
    f4 acc[4][3];
#pragma unroll
    for (int mi = 0; mi < 4; ++mi)
#pragma unroll
        for (int t = 0; t < 3; ++t) acc[mi][t] = (f4){0.f, 0.f, 0.f, 0.f};
#pragma unroll
    for (int mi = 0; mi < 4; ++mi) {
        bf4 a[4];
#pragma unroll
        for (int kt = 0; kt < 4; ++kt)
            a[kt] = *(const bf4*)(Ah + (16 * mi + li) * 68 + 16 * kt + 4 * g);
#pragma unroll
        for (int t = 0; t < 3; ++t) {
            if (t >= nnt) break;
#pragma unroll
            for (int kt = 0; kt < 4; ++kt)
                acc[mi][t] = mfma16(a[kt], B[t][kt], acc[mi][t]);
        }
    }
#pragma unroll
    for (int mi = 0; mi < 4; ++mi)
#pragma unroll
        for (int t = 0; t < 3; ++t) {
            if (t >= nnt) break;
            int col = 16 * (nt0 + t) + li;
            if (col < 168) {
#pragma unroll
                for (int r = 0; r < 4; ++r)
                    st[(16 * mi + 4 * g + r) * 172 + col] = acc[mi][t][r];
            }
        }
    __syncthreads();
    // output phase
    int row = tid >> 2;
    int qq = tid & 3;
    int pixel = pix0 + row;
    int b = pixel >> 14;
    int rem = pixel & 16383;
    int hh = rem >> 7;
    int ww = rem & 127;
    int n = ((hh >> 3) << 4) + (ww >> 3);
    int m = ((hh & 7) << 3) + (ww & 7);
    size_t p1 = ((size_t)(b * 256 + n) * 64 + m) * 28;
    size_t p2 = ((size_t)(b * 64 + m) * 256 + n) * 28;
    size_t ob = ((size_t)(b * 256 + n) * 64 + m) * 56;
    const float* sr = st + row * 172;
#pragma unroll
    for (int h = 0; h < 7; ++h) {
        int c = 14 * qq + 2 * h;
        float q0 = sr[c], q1v = sr[c + 1];
        float k0 = sr[56 + c], k1v = sr[57 + c];
        float v0 = sr[112 + c], v1v = sr[113 + c];
        ssum[ob + c] = q0 + k0 + v0;
        ssum[ob + c + 1] = q1v + k1v + v1v;
        unsigned qp = pk_bf16(q0, q1v);
        unsigned kp = pk_bf16(k0, k1v);
        unsigned vp = pk_bf16(v0, v1v);
        if (qq < 2) {
            *(unsigned*)(q1 + p1 + c) = qp;
            *(unsigned*)(k1 + p1 + c) = kp;
            *(unsigned*)(v1 + p1 + c) = vp;
        } else {
            *(unsigned*)(q2 + p2 + c - 28) = qp;
            *(unsigned*)(k2 + p2 + c - 28) = kp;
            *(unsigned*)(v2 + p2 + c - 28) = vp;
        }
    }
}

// ------------------------------- K2: conv1 ---------------------------------
__global__ __launch_bounds__(256) void k_conv1(const float* __restrict__ ssum,
                                               const float* __restrict__ c1w,
                                               const float* __restrict__ c1b,
                                               float* __restrict__ c1o) {
    __shared__ __align__(16) float tile[6 * 66 * 29];
    __shared__ __align__(16) float wl[4032];
    int tid = threadIdx.x;
    int wg = blockIdx.x;
    int br = wg >> 9;
    int b = (wg >> 6) & 7;
    int nt = wg & 63;
    int n0 = nt * 4;
    for (int e = tid; e < 11088; e += 256) {
        int c = e % 28;
        int rest = e / 28;
        int mm = rest % 66;
        int nr = rest / 66;
        int n = n0 - 1 + nr;
        int m = mm - 1;
        float v = 0.f;
        if (n >= 0 && n < 256 && m >= 0 && m < 64)
            v = ssum[(((size_t)b * 256 + n) * 64 + m) * 56 + br * 28 + c];
        tile[(nr * 66 + mm) * 29 + c] = v;
    }
    for (int e = tid; e < 4032; e += 256) {
        int o = e & 15;
        int tap = e >> 4;
        wl[e] = c1w[o * 252 + tap];
    }
    __syncthreads();
    int ny = tid >> 6;
    int m = tid & 63;
    float acc[16];
#pragma unroll
    for (int o = 0; o < 16; ++o) acc[o] = 0.f;
    for (int c = 0; c < 28; ++c) {
#pragma unroll
        for (int ky = 0; ky < 3; ++ky) {
#pragma unroll
            for (int kx = 0; kx < 3; ++kx) {
                float iv = tile[((ny + ky) * 66 + (m + kx)) * 29 + c];
                const float4* wp = (const float4*)(wl + (c * 9 + ky * 3 + kx) * 16);
                float4 w0 = wp[0], w1 = wp[1], w2 = wp[2], w3 = wp[3];
                acc[0] += iv * w0.x;  acc[1] += iv * w0.y;  acc[2] += iv * w0.z;  acc[3] += iv * w0.w;
                acc[4] += iv * w1.x;  acc[5] += iv * w1.y;  acc[6] += iv * w1.z;  acc[7] += iv * w1.w;
                acc[8] += iv * w2.x;  acc[9] += iv * w2.y;  acc[10] += iv * w2.z; acc[11] += iv * w2.w;
                acc[12] += iv * w3.x; acc[13] += iv * w3.y; acc[14] += iv * w3.z; acc[15] += iv * w3.w;
            }
        }
    }
    float4 b0 = *(const float4*)(c1b + 0);
    float4 b1 = *(const float4*)(c1b + 4);
    float4 b2 = *(const float4*)(c1b + 8);
    float4 b3 = *(const float4*)(c1b + 12);
    size_t ob = (((size_t)(br * 8 + b) * 16384) + (size_t)(n0 + ny) * 64 + m) * 16;
    float4* op = (float4*)(c1o + ob);
    op[0] = make_float4(fmaxf(acc[0] + b0.x, 0.f), fmaxf(acc[1] + b0.y, 0.f),
                        fmaxf(acc[2] + b0.z, 0.f), fmaxf(acc[3] + b0.w, 0.f));
    op[1] = make_float4(fmaxf(acc[4] + b1.x, 0.f), fmaxf(acc[5] + b1.y, 0.f),
                        fmaxf(acc[6] + b1.z, 0.f), fmaxf(acc[7] + b1.w, 0.f));
    op[2] = make_float4(fmaxf(acc[8] + b2.x, 0.f), fmaxf(acc[9] + b2.y, 0.f),
                        fmaxf(acc[10] + b2.z, 0.f), fmaxf(acc[11] + b2.w, 0.f));
    op[3] = make_float4(fmaxf(acc[12] + b3.x, 0.f), fmaxf(acc[13] + b3.y, 0.f),
                        fmaxf(acc[14] + b3.z, 0.f), fmaxf(acc[15] + b3.w, 0.f));
}

// ------------------------- K3: conv2 + pooled partials ---------------------
__global__ __launch_bounds__(256) void k_conv2(const float* __restrict__ c1o,
                                               const float* __restrict__ c2w,
                                               const float* __restrict__ c2b,
                                               float* __restrict__ part) {
    __shared__ __align__(16) float tile[6 * 66 * 17];
    __shared__ __align__(16) float wl[2304];
    __shared__ float pbuf[4][16];
    int tid = threadIdx.x;
    int wg = blockIdx.x;
    int br = wg >> 9;
    int b = (wg >> 6) & 7;
    int nt = wg & 63;
    int n0 = nt * 4;
    for (int e = tid; e < 6336; e += 256) {
        int c = e & 15;
        int rest = e >> 4;
        int mm = rest % 66;
        int nr = rest / 66;
        int n = n0 - 1 + nr;
        int m = mm - 1;
        float v = 0.f;
        if (n >= 0 && n < 256 && m >= 0 && m < 64)
            v = c1o[(((size_t)(br * 8 + b) * 16384) + (size_t)n * 64 + m) * 16 + c];
        tile[(nr * 66 + mm) * 17 + c] = v;
    }
    for (int e = tid; e < 2304; e += 256) {
        int o = e & 15;
        int tap = e >> 4;
        wl[e] = c2w[o * 144 + tap];
    }
    __syncthreads();
    int ny = tid >> 6;
    int m = tid & 63;
    float acc[16];
#pragma unroll
    for (int o = 0; o < 16; ++o) acc[o] = 0.f;
    for (int c = 0; c < 16; ++c) {
#pragma unroll
        for (int ky = 0; ky < 3; ++ky) {
#pragma unroll
            for (int kx = 0; kx < 3; ++kx) {
                float iv = tile[((ny + ky) * 66 + (m + kx)) * 17 + c];
                const float4* wp = (const float4*)(wl + (c * 9 + ky * 3 + kx) * 16);
                float4 w0 = wp[0], w1 = wp[1], w2 = wp[2], w3 = wp[3];
                acc[0] += iv * w0.x;  acc[1] += iv * w0.y;  acc[2] += iv * w0.z;  acc[3] += iv * w0.w;
                acc[4] += iv * w1.x;  acc[5] += iv * w1.y;  acc[6] += iv * w1.z;  acc[7] += iv * w1.w;
                acc[8] += iv * w2.x;  acc[9] += iv * w2.y;  acc[10] += iv * w2.z; acc[11] += iv * w2.w;
                acc[12] += iv * w3.x; acc[13] += iv * w3.y; acc[14] += iv * w3.z; acc[15] += iv * w3.w;
            }
        }
    }
    int lane = tid & 63;
    int wid = tid >> 6;
#pragma unroll
    for (int o = 0; o < 16; ++o) {
        float s = fmaxf(acc[o] + c2b[o], 0.f);
#pragma unroll
        for (int msk = 1; msk < 64; msk <<= 1) s += __shfl_xor(s, msk);
        if (lane == 0) pbuf[wid][o] = s;
    }
    __syncthreads();
    if (tid < 16) {
        float s = pbuf[0][tid] + pbuf[1][tid] + pbuf[2][tid] + pbuf[3][tid];
        part[(((size_t)(br * 8 + b)) * 64 + nt) * 16 + tid] = s;
    }
}

// ------------------------- K4: reduce + FC -> shifts -----------------------
__global__ void k_fc(const float* __restrict__ part, const float* __restrict__ f1w,
                     const float* __restrict__ f1b, const float* __restrict__ f2w,
                     const float* __restrict__ f2b, float* __restrict__ shif) {
    __shared__ float sb[16][16];
    int t = threadIdx.x;
    int combo = t >> 4;
    int o = t & 15;
    float s = 0.f;
    for (int nt = 0; nt < 64; ++nt) s += part[((size_t)combo * 64 + nt) * 16 + o];
    sb[combo][o] = s * (1.0f / 16384.0f);
    __syncthreads();
    if (t < 16) {
        float p0 = f1b[0], p1 = f1b[1], rg = f2b[0];
        for (int oo = 0; oo < 16; ++oo) {
            float sv = sb[t][oo];
            p0 += sv * f1w[oo * 2 + 0];
            p1 += sv * f1w[oo * 2 + 1];
            rg += sv * f2w[oo];
        }
        shif[t * 2 + 0] = rg * tanhf(p0);
        shif[t * 2 + 1] = rg * tanhf(p1);
    }
}

// ------------------------- K5a/b: shifted pos precompute -------------------
__global__ __launch_bounds__(256) void k_pos1(const float* __restrict__ pos1,
                                              const float* __restrict__ shif,
                                              float* __restrict__ P1T,
                                              float* __restrict__ P1M) {
    __shared__ float plds[64 * 64];
    int b = blockIdx.x;
    float sx = shif[b * 2 + 0];
    float sy = shif[b * 2 + 1];
    for (int e = threadIdx.x; e < 4096; e += 256) {
        int j = e >> 6;
        int i = e & 63;
        int y0, y1, x0, x1;
        float wy0, wy1, wx0, wx1;
        coords_(i, 64, sy, y0, y1, wy0, wy1);
        coords_(j, 64, sx, x0, x1, wx0, wx1);
        float v = pos1[((i - 1) & 63) * 64 + ((j - 1) & 63)] +
                  wy0 * (wx0 * pos1[y0 * 64 + x0] + wx1 * pos1[y0 * 64 + x1]) +
                  wy1 * (wx0 * pos1[y1 * 64 + x0] + wx1 * pos1[y1 * 64 + x1]);
        P1T[(size_t)b * 4096 + j * 64 + i] = v;
        plds[j * 64 + i] = v;
    }
    __syncthreads();
    if (threadIdx.x < 64) {
        float mx = plds[threadIdx.x];
        for (int j = 1; j < 64; ++j) mx = fmaxf(mx, plds[j * 64 + threadIdx.x]);
        P1M[b * 64 + threadIdx.x] = mx;
    }
}

__global__ __launch_bounds__(256) void k_pos2(const float* __restrict__ pos2,
                                              const float* __restrict__ shif,
                                              float* __restrict__ P2R,
                                              float* __restrict__ P2M) {
    __shared__ float red[4];
    int wg = blockIdx.x;
    int b = wg >> 8;
    int i = wg & 255;
    float sx = shif[16 + b * 2 + 0];
    float sy = shif[16 + b * 2 + 1];
    int j = threadIdx.x;
    int y0, y1, x0, x1;
    float wy0, wy1, wx0, wx1;
    coords_(i, 256, sy, y0, y1, wy0, wy1);
    coords_(j, 256, sx, x0, x1, wx0, wx1);
    float v = pos2[((i - 1) & 255) * 256 + ((j - 1) & 255)] +
              wy0 * (wx0 * pos2[y0 * 256 + x0] + wx1 * pos2[y0 * 256 + x1]) +
              wy1 * (wx0 * pos2[y1 * 256 + x0] + wx1 * pos2[y1 * 256 + x1]);
    P2R[(size_t)b * 65536 + (size_t)i * 256 + j] = v;
    float mx = v;
#pragma unroll
    for (int msk = 1; msk < 64; msk <<= 1) mx = fmaxf(mx, __shfl_xor(mx, msk));
    if ((threadIdx.x & 63) == 0) red[threadIdx.x >> 6] = mx;
    __syncthreads();
    if (threadIdx.x == 0)
        P2M[b * 256 + i] = fmaxf(fmaxf(red[0], red[1]), fmaxf(red[2], red[3]));
}

// --------------- K6: branch-1 window attention (64x64), MFMA ---------------
__global__ __launch_bounds__(256) void k_attn1(const unsigned short* __restrict__ q1,
                                               const unsigned short* __restrict__ k1,
                                               const unsigned short* __restrict__ v1,
                                               const float* __restrict__ P1T,
                                               const float* __restrict__ P1M,
                                               const float* __restrict__ shif,
                                               float* __restrict__ aout) {
    __shared__ __align__(16) unsigned short qraw[64 * 28];
    __shared__ __align__(16) unsigned short kraw[64 * 28];
    __shared__ __align__(16) unsigned short augK[64 * 68];
    __shared__ __align__(16) unsigned short vT[32 * 68];
    __shared__ __align__(16) unsigned short Pw[4][16 * 68];
    int tid = threadIdx.x;
    int w = tid >> 6;
    int l = tid & 63;
    int g = l >> 4;
    int li = l & 15;
    int wg = blockIdx.x;
    int b = wg >> 8;
    int n = wg & 255;
    size_t gb = (size_t)(b * 256 + n) * 1792;
    float sx = shif[b * 2 + 0];
    float sy = shif[b * 2 + 1];
    for (int e = tid; e < 1792; e += 256) {
        qraw[e] = q1[gb + e];
        kraw[e] = k1[gb + e];
        int j = e / 28;
        int c = e - j * 28;
        vT[c * 68 + j] = v1[gb + e];
    }
    for (int e = tid; e < 272; e += 256) vT[28 * 68 + e] = 0;
    __syncthreads();
    if (tid < 64) {
        int j = tid;
        int x0, x1;
        float wx0, wx1;
        coords_(j, 64, sx, x0, x1, wx0, wx1);
        int rm = (j - 1) & 63;
        unsigned* row = (unsigned*)(augK + j * 68);
        const unsigned* src = (const unsigned*)(kraw + rm * 28);
#pragma unroll
        for (int h = 0; h < 14; ++h) row[h] = src[h];
#pragma unroll
        for (int h = 0; h < 14; ++h) {
            float a0 = wx0 * bf2f(kraw[x0 * 28 + 2 * h]) + wx1 * bf2f(kraw[x1 * 28 + 2 * h]);
            float a1 = wx0 * bf2f(kraw[x0 * 28 + 2 * h + 1]) + wx1 * bf2f(kraw[x1 * 28 + 2 * h + 1]);
            row[14 + h] = pk_bf16(a0, a1);
        }
#pragma unroll
        for (int h = 28; h < 34; ++h) row[h] = 0;
    }
    bf4 qf[4];
    {
        int i = 16 * w + li;
        int y0, y1;
        float wy0, wy1;
        coords_(i, 64, sy, y0, y1, wy0, wy1);
        int rm = (i - 1) & 63;
#pragma unroll
        for (int kt = 0; kt < 4; ++kt) {
            float qv[4];
#pragma unroll
            for (int e = 0; e < 4; ++e) {
                int d = 16 * kt + 4 * g + e;
                float v;
                if (d < 28) v = SCALE_ * bf2f(qraw[rm * 28 + d]);
                else if (d < 56)
                    v = SCALE_ * (wy0 * bf2f(qraw[y0 * 28 + d - 28]) +
                                  wy1 * bf2f(qraw[y1 * 28 + d - 28]));
                else v = 0.f;
                qv[e] = v;
            }
            union { unsigned u[2]; bf4 v; } cv;
            cv.u[0] = pk_bf16(qv[0], qv[1]);
            cv.u[1] = pk_bf16(qv[2], qv[3]);
            qf[kt] = cv.v;
        }
    }
    f4 Mv = *(const f4*)(P1M + b * 64 + 16 * w + 4 * g);
    __syncthreads();
    f4 acc[4];
#pragma unroll
    for (int nj = 0; nj < 4; ++nj)
        acc[nj] = *(const f4*)(P1T + (size_t)b * 4096 + (16 * nj + li) * 64 + 16 * w + 4 * g);
#pragma unroll
    for (int nj = 0; nj < 4; ++nj) {
        const unsigned short* kr = augK + (16 * nj + li) * 68 + 4 * g;
#pragma unroll
        for (int kt = 0; kt < 4; ++kt) {
            bf4 bk = *(const bf4*)(kr + 16 * kt);
            acc[nj] = mfma16(qf[kt], bk, acc[nj]);
        }
    }
    float lr[4] = {0.f, 0.f, 0.f, 0.f};
    unsigned short* Pww = Pw[w];
#pragma unroll
    for (int nj = 0; nj < 4; ++nj)
#pragma unroll
        for (int r = 0; r < 4; ++r) {
            float p = __expf(acc[nj][r] - Mv[r]);
            lr[r] += p;
            Pww[(4 * g + r) * 68 + 16 * nj + li] = f2bf(p);
        }
    f4 accv[2];
    accv[0] = (f4){0.f, 0.f, 0.f, 0.f};
    accv[1] = (f4){0.f, 0.f, 0.f, 0.f};
#pragma unroll
    for (int kt = 0; kt < 4; ++kt) {
        bf4 pa = *(const bf4*)(Pww + li * 68 + 16 * kt + 4 * g);
#pragma unroll
        for (int nc = 0; nc < 2; ++nc) {
            bf4 bv = *(const bf4*)(vT + (16 * nc + li) * 68 + 16 * kt + 4 * g);
            accv[nc] = mfma16(pa, bv, accv[nc]);
        }
    }
#pragma unroll
    for (int r = 0; r < 4; ++r) {
#pragma unroll
        for (int msk = 1; msk < 16; msk <<= 1) lr[r] += __shfl_xor(lr[r], msk);
        float invl = 1.0f / lr[r];
        int i = 16 * w + 4 * g + r;
        size_t wb = ((size_t)(b * 256 + n) * 64 + i) * 56;
        aout[wb + li] = accv[0][r] * invl;
        if (li < 12) aout[wb + 16 + li] = accv[1][r] * invl;
    }
}

// -------------------- K7: branch-2 cross-window attn, MFMA -----------------
__global__ __launch_bounds__(512) void k_attn2(const unsigned short* __restrict__ q2,
                                               const unsigned short* __restrict__ k2,
                                               const unsigned short* __restrict__ v2,
                                               const float* __restrict__ P2R,
                                               const float* __restrict__ P2M,
                                               const float* __restrict__ shif,
                                               float* __restrict__ aout) {
    extern __shared__ __align__(16) char smem[];
    unsigned short* augK = (unsigned short*)smem;                  // [256][68]
    unsigned short* vT = (unsigned short*)(smem + 34816);          // [28][260]
    int tid = threadIdx.x;
    int w = tid >> 6;
    int l = tid & 63;
    int g = l >> 4;
    int li = l & 15;
    unsigned short* Pw = (unsigned short*)(smem + 49376) + w * 2176;  // [32][68]
    int bm = blockIdx.x;
    int b = bm >> 6;
    int m = bm & 63;
    size_t gbase = (size_t)bm * 7168;
    float sx = shif[16 + b * 2 + 0];
    float sy = shif[16 + b * 2 + 1];
    if (tid < 256) {
        int j = tid;
        int x0, x1;
        float wx0, wx1;
        coords_(j, 256, sx, x0, x1, wx0, wx1);
        int rm = (j - 1) & 255;
        const unsigned short* krm = k2 + gbase + (size_t)rm * 28;
        const unsigned short* ka = k2 + gbase + (size_t)x0 * 28;
        const unsigned short* kb = k2 + gbase + (size_t)x1 * 28;
        unsigned* row = (unsigned*)(augK + j * 68);
        const unsigned* src = (const unsigned*)krm;
#pragma unroll
        for (int h = 0; h < 14; ++h) row[h] = src[h];
#pragma unroll
        for (int h = 0; h < 14; ++h) {
            float a0 = wx0 * bf2f(ka[2 * h]) + wx1 * bf2f(kb[2 * h]);
            float a1 = wx0 * bf2f(ka[2 * h + 1]) + wx1 * bf2f(kb[2 * h + 1]);
            row[14 + h] = pk_bf16(a0, a1);
        }
#pragma unroll
        for (int h = 28; h < 34; ++h) row[h] = 0;
    } else {
        int j = tid - 256;
        const unsigned short* vr = v2 + gbase + (size_t)j * 28;
#pragma unroll
        for (int c = 0; c < 28; ++c) vT[c * 260 + j] = vr[c];
    }
    bf4 qf[2][4];
#pragma unroll
    for (int mi = 0; mi < 2; ++mi) {
        int i = 32 * w + 16 * mi + li;
        int y0, y1;
        float wy0, wy1;
        coords_(i, 256, sy, y0, y1, wy0, wy1);
        int rm = (i - 1) & 255;
        const unsigned short* qrm = q2 + gbase + (size_t)rm * 28;
        const unsigned short* qa = q2 + gbase + (size_t)y0 * 28;
        const unsigned short* qb = q2 + gbase + (size_t)y1 * 28;
#pragma unroll
        for (int kt = 0; kt < 4; ++kt) {
            float qv[4];
#pragma unroll
            for (int e = 0; e < 4; ++e) {
                int d = 16 * kt + 4 * g + e;
                float v;
                if (d < 28) v = SCALE_ * bf2f(qrm[d]);
                else if (d < 56)
                    v = SCALE_ * (wy0 * bf2f(qa[d - 28]) + wy1 * bf2f(qb[d - 28]));
                else v = 0.f;
                qv[e] = v;
            }
            union { unsigned u[2]; bf4 v; } cv;
            cv.u[0] = pk_bf16(qv[0], qv[1]);
            cv.u[1] = pk_bf16(qv[2], qv[3]);
            qf[mi][kt] = cv.v;
        }
    }
    float M[2][4];
#pragma unroll
    for (int mi = 0; mi < 2; ++mi)
#pragma unroll
        for (int r = 0; r < 4; ++r)
            M[mi][r] = P2M[b * 256 + 32 * w + 16 * mi + 4 * g + r];
    __syncthreads();
    f4 accv[2][2];
#pragma unroll
    for (int mi = 0; mi < 2; ++mi)
#pragma unroll
        for (int nc = 0; nc < 2; ++nc) accv[mi][nc] = (f4){0.f, 0.f, 0.f, 0.f};
    float lrun[2][4];
#pragma unroll
    for (int mi = 0; mi < 2; ++mi)
#pragma unroll
        for (int r = 0; r < 4; ++r) lrun[mi][r] = 0.f;

    for (int jt = 0; jt < 4; ++jt) {
        f4 acc[2][4];
#pragma unroll
        for (int mi = 0; mi < 2; ++mi) {
            const float* pr = P2R + (size_t)b * 65536 +
                              (size_t)(32 * w + 16 * mi + 4 * g) * 256 + 64 * jt + li;
#pragma unroll
            for (int nj = 0; nj < 4; ++nj)
                acc[mi][nj] = (f4){pr[16 * nj], pr[16 * nj + 256],
                                   pr[16 * nj + 512], pr[16 * nj + 768]};
        }
#pragma unroll
        for (int nj = 0; nj < 4; ++nj) {
            const unsigned short* kr = augK + (64 * jt + 16 * nj + li) * 68 + 4 * g;
            bf4 bk[4];
#pragma unroll
            for (int kt = 0; kt < 4; ++kt) bk[kt] = *(const bf4*)(kr + 16 * kt);
#pragma unroll
            for (int mi = 0; mi < 2; ++mi)
#pragma unroll
                for (int kt = 0; kt < 4; ++kt)
                    acc[mi][nj] = mfma16(qf[mi][kt], bk[kt], acc[mi][nj]);
        }
#pragma unroll
        for (int mi = 0; mi < 2; ++mi)
#pragma unroll
            for (int nj = 0; nj < 4; ++nj)
#pragma unroll
                for (int r = 0; r < 4; ++r) {
                    float p = __expf(acc[mi][nj][r] - M[mi][r]);
                    lrun[mi][r] += p;
                    Pw[(16 * mi + 4 * g + r) * 68 + 16 * nj + li] = f2bf(p);
                }
#pragma unroll
        for (int kt = 0; kt < 4; ++kt) {
            bf4 pa[2];
#pragma unroll
            for (int mi = 0; mi < 2; ++mi)
                pa[mi] = *(const bf4*)(Pw + (16 * mi + li) * 68 + 16 * kt + 4 * g);
#pragma unroll
            for (int nc = 0; nc < 2; ++nc) {
                bf4 bv = *(const bf4*)(vT + (16 * nc + li) * 260 + 64 * jt + 16 * kt + 4 * g);
#pragma unroll
                for (int mi = 0; mi < 2; ++mi)
                    accv[mi][nc] = mfma16(pa[mi], bv, accv[mi][nc]);
            }
        }
    }
#pragma unroll
    for (int mi = 0; mi < 2; ++mi)
#pragma unroll
        for (int r = 0; r < 4; ++r) {
#pragma unroll
            for (int msk = 1; msk < 16; msk <<= 1)
                lrun[mi][r] += __shfl_xor(lrun[mi][r], msk);
            float invl = 1.0f / lrun[mi][r];
            int gi = 32 * w + 16 * mi + 4 * g + r;
            size_t wb = (((size_t)b * 256 + gi) * 64 + m) * 56 + 28;
            aout[wb + li] = accv[mi][0][r] * invl;
            if (li < 12) aout[wb + 16 + li] = accv[mi][1][r] * invl;
        }
}

// ---------------- K8: output projection + unwindow (MFMA, prepped B) -------
__global__ __launch_bounds__(256) void k_out(const float* __restrict__ aout,
                                             const unsigned short* __restrict__ WFo,
                                             const float* __restrict__ bout,
                                             float* __restrict__ out) {
    __shared__ __align__(16) unsigned short Ah[64 * 68];
    __shared__ __align__(16) unsigned short Al[64 * 68];
    __shared__ __align__(16) float st[64 * 60];
    int tid = threadIdx.x;
    int w = tid >> 6;
    int l = tid & 63;
    int g = l >> 4;
    int li = l & 15;
    int pix0 = blockIdx.x * 64;
    for (int e = tid; e < 1792; e += 256) {
        int row = e / 28;
        int hp = e - row * 28;
        float2 v = *(const float2*)(aout + (size_t)pix0 * 56 + 2 * e);
        unsigned hpk = pk_bf16(v.x, v.y);
        float r0 = v.x - __uint_as_float(hpk << 16);
        float r1 = v.y - __uint_as_float(hpk & 0xffff0000u);
        ((unsigned*)Ah)[row * 34 + hp] = hpk;
        ((unsigned*)Al)[row * 34 + hp] = pk_bf16(r0, r1);
    }
    for (int e = tid; e < 384; e += 256) {
        int row = e / 6;
        int c = 28 + (e - row * 6);
        ((unsigned*)Ah)[row * 34 + c] = 0;
        ((unsigned*)Al)[row * 34 + c] = 0;
    }
    bf4 Bo[4][4];
#pragma unroll
    for (int nt = 0; nt < 4; ++nt)
#pragma unroll
        for (int kt = 0; kt < 4; ++kt)
            Bo[nt][kt] = *(const bf4*)(WFo + ((nt * 4 + kt) * 64 + l) * 4);
    __syncthreads();
    f4 acc[4];
#pragma unroll
    for (int nt = 0; nt < 4; ++nt) acc[nt] = (f4){0.f, 0.f, 0.f, 0.f};
    bf4 ah[4], al[4];
#pragma unroll
    for (int kt = 0; kt < 4; ++kt) {
        ah[kt] = *(const bf4*)(Ah + (16 * w + li) * 68 + 16 * kt + 4 * g);
        al[kt] = *(const bf4*)(Al + (16 * w + li) * 68 + 16 * kt + 4 * g);
    }
#pragma unroll
    for (int nt = 0; nt < 4; ++nt)
#pragma unroll
        for (int kt = 0; kt < 4; ++kt) {
            acc[nt] = mfma16(ah[kt], Bo[nt][kt], acc[nt]);
            acc[nt] = mfma16(al[kt], Bo[nt][kt], acc[nt]);
        }
#pragma unroll
    for (int nt = 0; nt < 4; ++nt) {
        int col = 16 * nt + li;
        if (col < 56) {
#pragma unroll
            for (int r = 0; r < 4; ++r)
                st[(16 * w + 4 * g + r) * 60 + col] = acc[nt][r];
        }
    }
    __syncthreads();
    int row = tid >> 2;
    int qq = tid & 3;
    int pixel = pix0 + row;
    int b = pixel >> 14;
    int n = (pixel >> 6) & 255;
    int m = pixel & 63;
    int h = ((n >> 4) << 3) + (m >> 3);
    int ww = ((n & 15) << 3) + (m & 7);
    float* dst = out + (((size_t)b * 128 + h) * 128 + ww) * 56;
    const float* sr = st + row * 60;
#pragma unroll
    for (int cc = 0; cc < 14; ++cc) {
        int c = 14 * qq + cc;
        dst[c] = sr[c] + bout[c];
    }
}

// ---------------------------------------------------------------------------
extern "C" void kernel_launch(void* const* d_in, const int* in_sizes, int n_in,
                              void* d_out, int out_size, void* d_ws, size_t ws_size,
                              hipStream_t stream) {
    const float* x = (const float*)d_in[0];
    const float* pos1 = (const float*)d_in[1];
    const float* pos2 = (const float*)d_in[2];
    const float* Wq = (const float*)d_in[3];
    const float* Wkv = (const float*)d_in[4];
    const float* Wout = (const float*)d_in[5];
    const float* bout = (const float*)d_in[6];
    const float* c1w = (const float*)d_in[7];
    const float* c1b = (const float*)d_in[8];
    const float* c2w = (const float*)d_in[9];
    const float* c2b = (const float*)d_in[10];
    const float* f1w = (const float*)d_in[11];
    const float* f1b = (const float*)d_in[12];
    const float* f2w = (const float*)d_in[13];
    const float* f2b = (const float*)d_in[14];

    unsigned short* us = (unsigned short*)d_ws;
    unsigned short* q1 = us;
    unsigned short* k1 = us + 3670016;
    unsigned short* v1 = us + 7340032;
    unsigned short* q2 = us + 11010048;
    unsigned short* k2 = us + 14680064;
    unsigned short* v2 = us + 18350080;
    float* fb = (float*)d_ws + 11010048;
    float* ssum = fb;            // reused as aout after conv1
    float* aout = fb;
    float* c1o = fb + 7340032;
    float* part = fb + 11534336;
    float* shif = fb + 11550720;
    float* P1T = fb + 11550752;
    float* P1M = fb + 11583520;
    float* P2R = fb + 11584032;
    float* P2M = fb + 12108320;
    unsigned short* WF = (unsigned short*)(fb + 12110368);
    unsigned short* WFo = WF + 11264;
    float* outp = (float*)d_out;

    (void)hipFuncSetAttribute((const void*)k_qkv,
                              hipFuncAttributeMaxDynamicSharedMemorySize, 52736);
    (void)hipFuncSetAttribute((const void*)k_attn2,
                              hipFuncAttributeMaxDynamicSharedMemorySize, 84192);

    k_prep<<<60, 256, 0, stream>>>(Wq, Wkv, Wout, WF, WFo);
    k_qkv<<<2048, 256, 52736, stream>>>(x, WF, q1, k1, v1, q2, k2, v2, ssum);
    k_conv1<<<1024, 256, 0, stream>>>(ssum, c1w, c1b, c1o);
    k_conv2<<<1024, 256, 0, stream>>>(c1o, c2w, c2b, part);
    k_fc<<<1, 256, 0, stream>>>(part, f1w, f1b, f2w, f2b, shif);
    k_pos1<<<8, 256, 0, stream>>>(pos1, shif, P1T, P1M);
    k_pos2<<<2048, 256, 0, stream>>>(pos2, shif, P2R, P2M);
    k_attn1<<<2048, 256, 0, stream>>>(q1, k1, v1, P1T, P1M, shif, aout);
    k_attn2<<<512, 512, 84192, stream>>>(q2, k2, v2, P2R, P2M, shif, aout);
    k_out<<<2048, 256, 0, stream>>>(aout, WFo, bout, outp);
}

// Round 7
// 191.968 us; speedup vs baseline: 4.3112x; 1.3622x over previous
//
#include <hip/hip_runtime.h>
#include <cstdint>

// ---------------------------------------------------------------------------
// SS-MSA fused implementation, round 7.
// grid_shift(sim) factorizes: shifted[i,j] = SCALE*(q_{i-1}.k_{j-1} + q~_i.k~_j) + P[i,j]
// => both branches are plain attention with 56-dim augmented Q/K + bias P.
//
// Round-7 changes vs round 6 (conv1 was LDS-issue-bound: ~1260 LDS reads per
// thread in the f32 VALU loop, 81 us):
//  - k_conv1/k_conv2: implicit-GEMM on mfma_f32_16x16x16_bf16. A = bf16 LDS
//    tile (c-contiguous, b64 fragment reads), B = prepped fragment-ordered
//    weights in registers with hi/lo split (weights ~f32-accurate; A-side
//    bf16 rounding is per-pixel independent -> averages out in mean pool).
//  - ssum and c1o stored bf16 (consumers convert anyway): -47 MB HBM traffic.
//  - k_prep emits conv weight fragments (BF1 h+l, BF2 h+l).
// ---------------------------------------------------------------------------

#define SCALE_ 0.18898223650461364f  // 28^-0.5

using f4 = __attribute__((ext_vector_type(4))) float;
using bf4 = __attribute__((ext_vector_type(4))) short;

__device__ __forceinline__ f4 mfma16(bf4 a, bf4 b, f4 c) {
#if __has_builtin(__builtin_amdgcn_mfma_f32_16x16x16bf16_1k)
    return __builtin_amdgcn_mfma_f32_16x16x16bf16_1k(a, b, c, 0, 0, 0);
#else
    f4 d;
    asm("v_mfma_f32_16x16x16_bf16 %0, %1, %2, %3" : "=v"(d) : "v"(a), "v"(b), "v"(c));
    return d;
#endif
}

__device__ __forceinline__ unsigned pk_bf16(float lo, float hi) {
    unsigned r;
    asm("v_cvt_pk_bf16_f32 %0, %1, %2" : "=v"(r) : "v"(lo), "v"(hi));
    return r;
}
__device__ __forceinline__ unsigned short f2bf(float f) {
    return (unsigned short)pk_bf16(f, f);
}
__device__ __forceinline__ float bf2f(unsigned short h) {
    return __uint_as_float(((unsigned)h) << 16);
}

__device__ __forceinline__ void coords_(int idx, int S, float s,
                                        int& i0, int& i1, float& w0, float& w1) {
    float g = -1.0f + 2.0f * (float)idx / (float)(S - 1);
    float c = (g + s * 2.0f / (float)S + 1.0f) * 0.5f * (float)(S - 1);
    float span = (float)(S - 1);
    c = fabsf(c);
    c = fmodf(c, 2.0f * span);
    if (c > span) c = 2.0f * span - c;
    int f = (int)floorf(c);
    f = max(0, min(f, S - 1));
    i0 = f;
    i1 = min(f + 1, S - 1);
    w1 = c - (float)f;
    w0 = 1.0f - w1;
}

// ------------------ K0: weight prep (fragment-ordered bf16) ----------------
// WF : 11 nt x 4 kt x 64 l x 4 e   (cols 0..55 Wq | 56..167 Wkv)
// WFo:  4 nt x 4 kt x 64 l x 4 e   (Wout)
// BF1: [h|l] 9 t x 2 kg x 64 l x 4 e  (c1w; c = 16kg+4g+e, o = li)
// BF2: [h|l] 9 t x 64 l x 4 e         (c2w; c = 4g+e, o = li)
__global__ __launch_bounds__(256) void k_prep(const float* __restrict__ Wq,
                                              const float* __restrict__ Wkv,
                                              const float* __restrict__ Wout,
                                              const float* __restrict__ c1w,
                                              const float* __restrict__ c2w,
                                              unsigned short* __restrict__ WF,
                                              unsigned short* __restrict__ WFo,
                                              unsigned short* __restrict__ BF1,
                                              unsigned short* __restrict__ BF2) {
    int tid = blockIdx.x * 256 + threadIdx.x;
    if (tid < 11264) {
        int e = tid & 3;
        int l = (tid >> 2) & 63;
        int kt = (tid >> 8) & 3;
        int nt = tid >> 10;
        int g = l >> 4, li = l & 15;
        int k = 16 * kt + 4 * g + e;
        int col = 16 * nt + li;
        float v = 0.f;
        if (k < 56 && col < 168)
            v = (col < 56) ? Wq[k * 56 + col] : Wkv[k * 112 + (col - 56)];
        WF[tid] = f2bf(v);
    } else if (tid < 15360) {
        int t2 = tid - 11264;
        int e = t2 & 3;
        int l = (t2 >> 2) & 63;
        int kt = (t2 >> 8) & 3;
        int nt = t2 >> 10;
        int g = l >> 4, li = l & 15;
        int k = 16 * kt + 4 * g + e;
        int col = 16 * nt + li;
        float v = (k < 56 && col < 56) ? Wout[k * 56 + col] : 0.f;
        WFo[t2] = f2bf(v);
    } else if (tid < 19968) {
        int t2 = tid - 15360;  // 4608 entries
        int e = t2 & 3;
        int l = (t2 >> 2) & 63;
        int rest = t2 >> 8;    // t*2+kg
        int kg = rest & 1;
        int t = rest >> 1;
        int g = l >> 4, li = l & 15;
        int c = 16 * kg + 4 * g + e;
        float v = (c < 28) ? c1w[li * 252 + c * 9 + t] : 0.f;
        unsigned short h = f2bf(v);
        BF1[t2] = h;
        BF1[4608 + t2] = f2bf(v - bf2f(h));
    } else if (tid < 22272) {
        int t2 = tid - 19968;  // 2304 entries
        int e = t2 & 3;
        int l = (t2 >> 2) & 63;
        int t = t2 >> 8;
        int g = l >> 4, li = l & 15;
        int c = 4 * g + e;
        float v = c2w[li * 144 + c * 9 + t];
        unsigned short h = f2bf(v);
        BF2[t2] = h;
        BF2[2304 + t2] = f2bf(v - bf2f(h));
    }
}

// ------------------- K1: QKV GEMM (bf16 MFMA, prepped B) -------------------
__global__ __launch_bounds__(256) void k_qkv(const float* __restrict__ x,
                                             const unsigned short* __restrict__ WF,
                                             unsigned short* __restrict__ q1,
                                             unsigned short* __restrict__ k1,
                                             unsigned short* __restrict__ v1,
                                             unsigned short* __restrict__ q2,
                                             unsigned short* __restrict__ k2,
                                             unsigned short* __restrict__ v2,
                                             unsigned short* __restrict__ ssum) {
    extern __shared__ __align__(16) char smem[];
    unsigned short* Ah = (unsigned short*)smem;   // [64][68]
    float* st = (float*)(smem + 8704);            // [64][172]
    int tid = threadIdx.x;
    int w = tid >> 6;
    int l = tid & 63;
    int g = l >> 4;
    int li = l & 15;
    int pix0 = blockIdx.x * 64;
    for (int e = tid; e < 1792; e += 256) {
        int row = e / 28;
        int hp = e - row * 28;
        float2 v = *(const float2*)(x + (size_t)pix0 * 56 + 2 * e);
        ((unsigned*)Ah)[row * 34 + hp] = pk_bf16(v.x, v.y);
    }
    for (int e = tid; e < 384; e += 256) {
        int row = e / 6;
        ((unsigned*)Ah)[row * 34 + 28 + (e - row * 6)] = 0;
    }
    int nt0 = 3 * w;
    int nnt = (w < 3) ? 3 : 2;
    bf4 B[3][4];
#pragma unroll
    for (int t = 0; t < 3; ++t) {
        if (t >= nnt) break;
#pragma unroll
        for (int kt = 0; kt < 4; ++kt)
            B[t][kt] = *(const bf4*)(WF + (((nt0 + t) * 4 + kt) * 64 + l) * 4);
    }
    __syncthreads();
    f4 acc[4][3];
#pragma unroll
    for (int mi = 0; mi < 4; ++mi)
#pragma unroll
        for (int t = 0; t < 3; ++t) acc[mi][t] = (f4){0.f, 0.f, 0.f, 0.f};
#pragma unroll
    for (int mi = 0; mi < 4; ++mi) {
        bf4 a[4];
#pragma unroll
        for (int kt = 0; kt < 4; ++kt)
            a[kt] = *(const bf4*)(Ah + (16 * mi + li) * 68 + 16 * kt + 4 * g);
#pragma unroll
        for (int t = 0; t < 3; ++t) {
            if (t >= nnt) break;
#pragma unroll
            for (int kt = 0; kt < 4; ++kt)
                acc[mi][t] = mfma16(a[kt], B[t][kt], acc[mi][t]);
        }
    }
#pragma unroll
    for (int mi = 0; mi < 4; ++mi)
#pragma unroll
        for (int t = 0; t < 3; ++t) {
            if (t >= nnt) break;
            int col = 16 * (nt0 + t) + li;
            if (col < 168) {
#pragma unroll
                for (int r = 0; r < 4; ++r)
                    st[(16 * mi + 4 * g + r) * 172 + col] = acc[mi][t][r];
            }
        }
    __syncthreads();
    int row = tid >> 2;
    int qq = tid & 3;
    int pixel = pix0 + row;
    int b = pixel >> 14;
    int rem = pixel & 16383;
    int hh = rem >> 7;
    int ww = rem & 127;
    int n = ((hh >> 3) << 4) + (ww >> 3);
    int m = ((hh & 7) << 3) + (ww & 7);
    size_t p1 = ((size_t)(b * 256 + n) * 64 + m) * 28;
    size_t p2 = ((size_t)(b * 64 + m) * 256 + n) * 28;
    size_t ob = ((size_t)(b * 256 + n) * 64 + m) * 56;
    const float* sr = st + row * 172;
#pragma unroll
    for (int h = 0; h < 7; ++h) {
        int c = 14 * qq + 2 * h;
        float q0 = sr[c], q1v = sr[c + 1];
        float k0 = sr[56 + c], k1v = sr[57 + c];
        float v0 = sr[112 + c], v1v = sr[113 + c];
        *(unsigned*)(ssum + ob + c) = pk_bf16(q0 + k0 + v0, q1v + k1v + v1v);
        unsigned qp = pk_bf16(q0, q1v);
        unsigned kp = pk_bf16(k0, k1v);
        unsigned vp = pk_bf16(v0, v1v);
        if (qq < 2) {
            *(unsigned*)(q1 + p1 + c) = qp;
            *(unsigned*)(k1 + p1 + c) = kp;
            *(unsigned*)(v1 + p1 + c) = vp;
        } else {
            *(unsigned*)(q2 + p2 + c - 28) = qp;
            *(unsigned*)(k2 + p2 + c - 28) = kp;
            *(unsigned*)(v2 + p2 + c - 28) = vp;
        }
    }
}

// ---------------- K2: conv1, implicit-GEMM MFMA (bf16, hi/lo B) ------------
// Block = (br, b, 4 n-rows). Wave w = n-row; 4 M-tiles of 16 m. K = 9 taps x
// 32 padded ch = 18 kt. LDS tile bf16 [6][66][32].
__global__ __launch_bounds__(256) void k_conv1(const unsigned short* __restrict__ ssum,
                                               const unsigned short* __restrict__ BF1,
                                               const float* __restrict__ c1b,
                                               unsigned short* __restrict__ c1o) {
    __shared__ __align__(16) unsigned short tile[6 * 66 * 32];
    int tid = threadIdx.x;
    int w = tid >> 6;
    int l = tid & 63;
    int g = l >> 4;
    int li = l & 15;
    int wg = blockIdx.x;
    int br = wg >> 9;
    int b = (wg >> 6) & 7;
    int nt = wg & 63;
    int n0 = nt * 4;
    for (int e = tid; e < 11088; e += 256) {
        int c = e % 28;
        int rest = e / 28;
        int mm = rest % 66;
        int nr = rest / 66;
        int n = n0 - 1 + nr;
        int m = mm - 1;
        unsigned short v = 0;
        if (n >= 0 && n < 256 && m >= 0 && m < 64)
            v = ssum[(((size_t)b * 256 + n) * 64 + m) * 56 + br * 28 + c];
        tile[(nr * 66 + mm) * 32 + c] = v;
    }
    for (int e = tid; e < 1584; e += 256) {
        int rm = e >> 2;
        tile[rm * 32 + 28 + (e & 3)] = 0;
    }
    bf4 Bh[9][2], Bl[9][2];
#pragma unroll
    for (int t = 0; t < 9; ++t)
#pragma unroll
        for (int kg = 0; kg < 2; ++kg) {
            Bh[t][kg] = *(const bf4*)(BF1 + ((t * 2 + kg) * 64 + l) * 4);
            Bl[t][kg] = *(const bf4*)(BF1 + 4608 + ((t * 2 + kg) * 64 + l) * 4);
        }
    __syncthreads();
    f4 acc[4];
#pragma unroll
    for (int mt = 0; mt < 4; ++mt) acc[mt] = (f4){0.f, 0.f, 0.f, 0.f};
#pragma unroll
    for (int mt = 0; mt < 4; ++mt) {
#pragma unroll
        for (int t = 0; t < 9; ++t) {
            int ky = t / 3, kx = t - 3 * (t / 3);
#pragma unroll
            for (int kg = 0; kg < 2; ++kg) {
                bf4 a = *(const bf4*)(tile + ((w + ky) * 66 + 16 * mt + li + kx) * 32 +
                                      16 * kg + 4 * g);
                acc[mt] = mfma16(a, Bh[t][kg], acc[mt]);
                acc[mt] = mfma16(a, Bl[t][kg], acc[mt]);
            }
        }
    }
    float bias = c1b[li];
    size_t combo = (size_t)(br * 8 + b);
#pragma unroll
    for (int mt = 0; mt < 4; ++mt)
#pragma unroll
        for (int r = 0; r < 4; ++r) {
            int m = 16 * mt + 4 * g + r;
            float v = fmaxf(acc[mt][r] + bias, 0.f);
            c1o[(combo * 16384 + (size_t)(n0 + w) * 64 + m) * 16 + li] = f2bf(v);
        }
}

// ------------- K3: conv2 + pooled partials, implicit-GEMM MFMA -------------
// K = 9 taps x 16 ch = 9 kt. LDS tile bf16 [6][66][16].
__global__ __launch_bounds__(256) void k_conv2(const unsigned short* __restrict__ c1o,
                                               const unsigned short* __restrict__ BF2,
                                               const float* __restrict__ c2b,
                                               float* __restrict__ part) {
    __shared__ __align__(16) unsigned short tile[6 * 66 * 16];
    __shared__ float pbuf[4][16];
    int tid = threadIdx.x;
    int w = tid >> 6;
    int l = tid & 63;
    int g = l >> 4;
    int li = l & 15;
    int wg = blockIdx.x;
    int br = wg >> 9;
    int b = (wg >> 6) & 7;
    int nt = wg & 63;
    int n0 = nt * 4;
    size_t combo = (size_t)(br * 8 + b);
    for (int e = tid; e < 6336; e += 256) {
        int c = e & 15;
        int rest = e >> 4;
        int mm = rest % 66;
        int nr = rest / 66;
        int n = n0 - 1 + nr;
        int m = mm - 1;
        unsigned short v = 0;
        if (n >= 0 && n < 256 && m >= 0 && m < 64)
            v = c1o[(combo * 16384 + (size_t)n * 64 + m) * 16 + c];
        tile[(nr * 66 + mm) * 16 + c] = v;
    }
    bf4 Bh[9], Bl[9];
#pragma unroll
    for (int t = 0; t < 9; ++t) {
        Bh[t] = *(const bf4*)(BF2 + (t * 64 + l) * 4);
        Bl[t] = *(const bf4*)(BF2 + 2304 + (t * 64 + l) * 4);
    }
    __syncthreads();
    f4 acc[4];
#pragma unroll
    for (int mt = 0; mt < 4; ++mt) acc[mt] = (f4){0.f, 0.f, 0.f, 0.f};
#pragma unroll
    for (int mt = 0; mt < 4; ++mt) {
#pragma unroll
        for (int t = 0; t < 9; ++t) {
            int ky = t / 3, kx = t - 3 * (t / 3);
            bf4 a = *(const bf4*)(tile + ((w + ky) * 66 + 16 * mt + li + kx) * 16 + 4 * g);
            acc[mt] = mfma16(a, Bh[t], acc[mt]);
            acc[mt] = mfma16(a, Bl[t], acc[mt]);
        }
    }
    float bias = c2b[li];
    float s = 0.f;
#pragma unroll
    for (int mt = 0; mt < 4; ++mt)
#pragma unroll
        for (int r = 0; r < 4; ++r) s += fmaxf(acc[mt][r] + bias, 0.f);
    s += __shfl_xor(s, 16);
    s += __shfl_xor(s, 32);
    if (l < 16) pbuf[w][li] = s;
    __syncthreads();
    if (tid < 16) {
        float tot = pbuf[0][tid] + pbuf[1][tid] + pbuf[2][tid] + pbuf[3][tid];
        part[(combo * 64 + nt) * 16 + tid] = tot;
    }
}

// ------------------------- K4: reduce + FC -> shifts -----------------------
__global__ void k_fc(const float* __restrict__ part, const float* __restrict__ f1w,
                     const float* __restrict__ f1b, const float* __restrict__ f2w,
                     const float* __restrict__ f2b, float* __restrict__ shif) {
    __shared__ float sb[16][16];
    int t = threadIdx.x;
    int combo = t >> 4;
    int o = t & 15;
    float s = 0.f;
    for (int nt = 0; nt < 64; ++nt) s += part[((size_t)combo * 64 + nt) * 16 + o];
    sb[combo][o] = s * (1.0f / 16384.0f);
    __syncthreads();
    if (t < 16) {
        float p0 = f1b[0], p1 = f1b[1], rg = f2b[0];
        for (int oo = 0; oo < 16; ++oo) {
            float sv = sb[t][oo];
            p0 += sv * f1w[oo * 2 + 0];
            p1 += sv * f1w[oo * 2 + 1];
            rg += sv * f2w[oo];
        }
        shif[t * 2 + 0] = rg * tanhf(p0);
        shif[t * 2 + 1] = rg * tanhf(p1);
    }
}

// ------------------------- K5a/b: shifted pos precompute -------------------
__global__ __launch_bounds__(256) void k_pos1(const float* __restrict__ pos1,
                                              const float* __restrict__ shif,
                                              float* __restrict__ P1T,
                                              float* __restrict__ P1M) {
    __shared__ float plds[64 * 64];
    int b = blockIdx.x;
    float sx = shif[b * 2 + 0];
    float sy = shif[b * 2 + 1];
    for (int e = threadIdx.x; e < 4096; e += 256) {
        int j = e >> 6;
        int i = e & 63;
        int y0, y1, x0, x1;
        float wy0, wy1, wx0, wx1;
        coords_(i, 64, sy, y0, y1, wy0, wy1);
        coords_(j, 64, sx, x0, x1, wx0, wx1);
        float v = pos1[((i - 1) & 63) * 64 + ((j - 1) & 63)] +
                  wy0 * (wx0 * pos1[y0 * 64 + x0] + wx1 * pos1[y0 * 64 + x1]) +
                  wy1 * (wx0 * pos1[y1 * 64 + x0] + wx1 * pos1[y1 * 64 + x1]);
        P1T[(size_t)b * 4096 + j * 64 + i] = v;
        plds[j * 64 + i] = v;
    }
    __syncthreads();
    if (threadIdx.x < 64) {
        float mx = plds[threadIdx.x];
        for (int j = 1; j < 64; ++j) mx = fmaxf(mx, plds[j * 64 + threadIdx.x]);
        P1M[b * 64 + threadIdx.x] = mx;
    }
}

__global__ __launch_bounds__(256) void k_pos2(const float* __restrict__ pos2,
                                              const float* __restrict__ shif,
                                              float* __restrict__ P2R,
                                              float* __restrict__ P2M) {
    __shared__ float red[4];
    int wg = blockIdx.x;
    int b = wg >> 8;
    int i = wg & 255;
    float sx = shif[16 + b * 2 + 0];
    float sy = shif[16 + b * 2 + 1];
    int j = threadIdx.x;
    int y0, y1, x0, x1;
    float wy0, wy1, wx0, wx1;
    coords_(i, 256, sy, y0, y1, wy0, wy1);
    coords_(j, 256, sx, x0, x1, wx0, wx1);
    float v = pos2[((i - 1) & 255) * 256 + ((j - 1) & 255)] +
              wy0 * (wx0 * pos2[y0 * 256 + x0] + wx1 * pos2[y0 * 256 + x1]) +
              wy1 * (wx0 * pos2[y1 * 256 + x0] + wx1 * pos2[y1 * 256 + x1]);
    P2R[(size_t)b * 65536 + (size_t)i * 256 + j] = v;
    float mx = v;
#pragma unroll
    for (int msk = 1; msk < 64; msk <<= 1) mx = fmaxf(mx, __shfl_xor(mx, msk));
    if ((threadIdx.x & 63) == 0) red[threadIdx.x >> 6] = mx;
    __syncthreads();
    if (threadIdx.x == 0)
        P2M[b * 256 + i] = fmaxf(fmaxf(red[0], red[1]), fmaxf(red[2], red[3]));
}

// --------------- K6: branch-1 window attention (64x64), MFMA ---------------
__global__ __launch_bounds__(256) void k_attn1(const unsigned short* __restrict__ q1,
                                               const unsigned short* __restrict__ k1,
                                               const unsigned short* __restrict__ v1,
                                               const float* __restrict__ P1T,
                                               const float* __restrict__ P1M,
                                               const float* __restrict__ shif,
                                               float* __restrict__ aout) {
    __shared__ __align__(16) unsigned short qraw[64 * 28];
    __shared__ __align__(16) unsigned short kraw[64 * 28];
    __shared__ __align__(16) unsigned short augK[64 * 68];
    __shared__ __align__(16) unsigned short vT[32 * 68];
    __shared__ __align__(16) unsigned short Pw[4][16 * 68];
    int tid = threadIdx.x;
    int w = tid >> 6;
    int l = tid & 63;
    int g = l >> 4;
    int li = l & 15;
    int wg = blockIdx.x;
    int b = wg >> 8;
    int n = wg & 255;
    size_t gb = (size_t)(b * 256 + n) * 1792;
    float sx = shif[b * 2 + 0];
    float sy = shif[b * 2 + 1];
    for (int e = tid; e < 1792; e += 256) {
        qraw[e] = q1[gb + e];
        kraw[e] = k1[gb + e];
        int j = e / 28;
        int c = e - j * 28;
        vT[c * 68 + j] = v1[gb + e];
    }
    for (int e = tid; e < 272; e += 256) vT[28 * 68 + e] = 0;
    __syncthreads();
    if (tid < 64) {
        int j = tid;
        int x0, x1;
        float wx0, wx1;
        coords_(j, 64, sx, x0, x1, wx0, wx1);
        int rm = (j - 1) & 63;
        unsigned* row = (unsigned*)(augK + j * 68);
        const unsigned* src = (const unsigned*)(kraw + rm * 28);
#pragma unroll
        for (int h = 0; h < 14; ++h) row[h] = src[h];
#pragma unroll
        for (int h = 0; h < 14; ++h) {
            float a0 = wx0 * bf2f(kraw[x0 * 28 + 2 * h]) + wx1 * bf2f(kraw[x1 * 28 + 2 * h]);
            float a1 = wx0 * bf2f(kraw[x0 * 28 + 2 * h + 1]) + wx1 * bf2f(kraw[x1 * 28 + 2 * h + 1]);
            row[14 + h] = pk_bf16(a0, a1);
        }
#pragma unroll
        for (int h = 28; h < 34; ++h) row[h] = 0;
    }
    bf4 qf[4];
    {
        int i = 16 * w + li;
        int y0, y1;
        float wy0, wy1;
        coords_(i, 64, sy, y0, y1, wy0, wy1);
        int rm = (i - 1) & 63;
#pragma unroll
        for (int kt = 0; kt < 4; ++kt) {
            float qv[4];
#pragma unroll
            for (int e = 0; e < 4; ++e) {
                int d = 16 * kt + 4 * g + e;
                float v;
                if (d < 28) v = SCALE_ * bf2f(qraw[rm * 28 + d]);
                else if (d < 56)
                    v = SCALE_ * (wy0 * bf2f(qraw[y0 * 28 + d - 28]) +
                                  wy1 * bf2f(qraw[y1 * 28 + d - 28]));
                else v = 0.f;
                qv[e] = v;
            }
            union { unsigned u[2]; bf4 v; } cv;
            cv.u[0] = pk_bf16(qv[0], qv[1]);
            cv.u[1] = pk_bf16(qv[2], qv[3]);
            qf[kt] = cv.v;
        }
    }
    f4 Mv = *(const f4*)(P1M + b * 64 + 16 * w + 4 * g);
    __syncthreads();
    f4 acc[4];
#pragma unroll
    for (int nj = 0; nj < 4; ++nj)
        acc[nj] = *(const f4*)(P1T + (size_t)b * 4096 + (16 * nj + li) * 64 + 16 * w + 4 * g);
#pragma unroll
    for (int nj = 0; nj < 4; ++nj) {
        const unsigned short* kr = augK + (16 * nj + li) * 68 + 4 * g;
#pragma unroll
        for (int kt = 0; kt < 4; ++kt) {
            bf4 bk = *(const bf4*)(kr + 16 * kt);
            acc[nj] = mfma16(qf[kt], bk, acc[nj]);
        }
    }
    float lr[4] = {0.f, 0.f, 0.f, 0.f};
    unsigned short* Pww = Pw[w];
#pragma unroll
    for (int nj = 0; nj < 4; ++nj)
#pragma unroll
        for (int r = 0; r < 4; ++r) {
            float p = __expf(acc[nj][r] - Mv[r]);
            lr[r] += p;
            Pww[(4 * g + r) * 68 + 16 * nj + li] = f2bf(p);
        }
    f4 accv[2];
    accv[0] = (f4){0.f, 0.f, 0.f, 0.f};
    accv[1] = (f4){0.f, 0.f, 0.f, 0.f};
#pragma unroll
    for (int kt = 0; kt < 4; ++kt) {
        bf4 pa = *(const bf4*)(Pww + li * 68 + 16 * kt + 4 * g);
#pragma unroll
        for (int nc = 0; nc < 2; ++nc) {
            bf4 bv = *(const bf4*)(vT + (16 * nc + li) * 68 + 16 * kt + 4 * g);
            accv[nc] = mfma16(pa, bv, accv[nc]);
        }
    }
#pragma unroll
    for (int r = 0; r < 4; ++r) {
#pragma unroll
        for (int msk = 1; msk < 16; msk <<= 1) lr[r] += __shfl_xor(lr[r], msk);
        float invl = 1.0f / lr[r];
        int i = 16 * w + 4 * g + r;
        size_t wb = ((size_t)(b * 256 + n) * 64 + i) * 56;
        aout[wb + li] = accv[0][r] * invl;
        if (li < 12) aout[wb + 16 + li] = accv[1][r] * invl;
    }
}

// -------------------- K7: branch-2 cross-window attn, MFMA -----------------
__global__ __launch_bounds__(512) void k_attn2(const unsigned short* __restrict__ q2,
                                               const unsigned short* __restrict__ k2,
                                               const unsigned short* __restrict__ v2,
                                               const float* __restrict__ P2R,
                                               const float* __restrict__ P2M,
                                               const float* __restrict__ shif,
                                               float* __restrict__ aout) {
    extern __shared__ __align__(16) char smem[];
    unsigned short* augK = (unsigned short*)smem;                  // [256][68]
    unsigned short* vT = (unsigned short*)(smem + 34816);          // [28][260]
    int tid = threadIdx.x;
    int w = tid >> 6;
    int l = tid & 63;
    int g = l >> 4;
    int li = l & 15;
    unsigned short* Pw = (unsigned short*)(smem + 49376) + w * 2176;  // [32][68]
    int bm = blockIdx.x;
    int b = bm >> 6;
    int m = bm & 63;
    size_t gbase = (size_t)bm * 7168;
    float sx = shif[16 + b * 2 + 0];
    float sy = shif[16 + b * 2 + 1];
    if (tid < 256) {
        int j = tid;
        int x0, x1;
        float wx0, wx1;
        coords_(j, 256, sx, x0, x1, wx0, wx1);
        int rm = (j - 1) & 255;
        const unsigned short* krm = k2 + gbase + (size_t)rm * 28;
        const unsigned short* ka = k2 + gbase + (size_t)x0 * 28;
        const unsigned short* kb = k2 + gbase + (size_t)x1 * 28;
        unsigned* row = (unsigned*)(augK + j * 68);
        const unsigned* src = (const unsigned*)krm;
#pragma unroll
        for (int h = 0; h < 14; ++h) row[h] = src[h];
#pragma unroll
        for (int h = 0; h < 14; ++h) {
            float a0 = wx0 * bf2f(ka[2 * h]) + wx1 * bf2f(kb[2 * h]);
            float a1 = wx0 * bf2f(ka[2 * h + 1]) + wx1 * bf2f(kb[2 * h + 1]);
            row[14 + h] = pk_bf16(a0, a1);
        }
#pragma unroll
        for (int h = 28; h < 34; ++h) row[h] = 0;
    } else {
        int j = tid - 256;
        const unsigned short* vr = v2 + gbase + (size_t)j * 28;
#pragma unroll
        for (int c = 0; c < 28; ++c) vT[c * 260 + j] = vr[c];
    }
    bf4 qf[2][4];
#pragma unroll
    for (int mi = 0; mi < 2; ++mi) {
        int i = 32 * w + 16 * mi + li;
        int y0, y1;
        float wy0, wy1;
        coords_(i, 256, sy, y0, y1, wy0, wy1);
        int rm = (i - 1) & 255;
        const unsigned short* qrm = q2 + gbase + (size_t)rm * 28;
        const unsigned short* qa = q2 + gbase + (size_t)y0 * 28;
        const unsigned short* qb = q2 + gbase + (size_t)y1 * 28;
#pragma unroll
        for (int kt = 0; kt < 4; ++kt) {
            float qv[4];
#pragma unroll
            for (int e = 0; e < 4; ++e) {
                int d = 16 * kt + 4 * g + e;
                float v;
                if (d < 28) v = SCALE_ * bf2f(qrm[d]);
                else if (d < 56)
                    v = SCALE_ * (wy0 * bf2f(qa[d - 28]) + wy1 * bf2f(qb[d - 28]));
                else v = 0.f;
                qv[e] = v;
            }
            union { unsigned u[2]; bf4 v; } cv;
            cv.u[0] = pk_bf16(qv[0], qv[1]);
            cv.u[1] = pk_bf16(qv[2], qv[3]);
            qf[mi][kt] = cv.v;
        }
    }
    float M[2][4];
#pragma unroll
    for (int mi = 0; mi < 2; ++mi)
#pragma unroll
        for (int r = 0; r < 4; ++r)
            M[mi][r] = P2M[b * 256 + 32 * w + 16 * mi + 4 * g + r];
    __syncthreads();
    f4 accv[2][2];
#pragma unroll
    for (int mi = 0; mi < 2; ++mi)
#pragma unroll
        for (int nc = 0; nc < 2; ++nc) accv[mi][nc] = (f4){0.f, 0.f, 0.f, 0.f};
    float lrun[2][4];
#pragma unroll
    for (int mi = 0; mi < 2; ++mi)
#pragma unroll
        for (int r = 0; r < 4; ++r) lrun[mi][r] = 0.f;

    for (int jt = 0; jt < 4; ++jt) {
        f4 acc[2][4];
#pragma unroll
        for (int mi = 0; mi < 2; ++mi) {
            const float* pr = P2R + (size_t)b * 65536 +
                              (size_t)(32 * w + 16 * mi + 4 * g) * 256 + 64 * jt + li;
#pragma unroll
            for (int nj = 0; nj < 4; ++nj)
                acc[mi][nj] = (f4){pr[16 * nj], pr[16 * nj + 256],
                                   pr[16 * nj + 512], pr[16 * nj + 768]};
        }
#pragma unroll
        for (int nj = 0; nj < 4; ++nj) {
            const unsigned short* kr = augK + (64 * jt + 16 * nj + li) * 68 + 4 * g;
            bf4 bk[4];
#pragma unroll
            for (int kt = 0; kt < 4; ++kt) bk[kt] = *(const bf4*)(kr + 16 * kt);
#pragma unroll
            for (int mi = 0; mi < 2; ++mi)
#pragma unroll
                for (int kt = 0; kt < 4; ++kt)
                    acc[mi][nj] = mfma16(qf[mi][kt], bk[kt], acc[mi][nj]);
        }
#pragma unroll
        for (int mi = 0; mi < 2; ++mi)
#pragma unroll
            for (int nj = 0; nj < 4; ++nj)
#pragma unroll
                for (int r = 0; r < 4; ++r) {
                    float p = __expf(acc[mi][nj][r] - M[mi][r]);
                    lrun[mi][r] += p;
                    Pw[(16 * mi + 4 * g + r) * 68 + 16 * nj + li] = f2bf(p);
                }
#pragma unroll
        for (int kt = 0; kt < 4; ++kt) {
            bf4 pa[2];
#pragma unroll
            for (int mi = 0; mi < 2; ++mi)
                pa[mi] = *(const bf4*)(Pw + (16 * mi + li) * 68 + 16 * kt + 4 * g);
#pragma unroll
            for (int nc = 0; nc < 2; ++nc) {
                bf4 bv = *(const bf4*)(vT + (16 * nc + li) * 260 + 64 * jt + 16 * kt + 4 * g);
#pragma unroll
                for (int mi = 0; mi < 2; ++mi)
                    accv[mi][nc] = mfma16(pa[mi], bv, accv[mi][nc]);
            }
        }
    }
#pragma unroll
    for (int mi = 0; mi < 2; ++mi)
#pragma unroll
        for (int r = 0; r < 4; ++r) {
#pragma unroll
            for (int msk = 1; msk < 16; msk <<= 1)
                lrun[mi][r] += __shfl_xor(lrun[mi][r], msk);
            float invl = 1.0f / lrun[mi][r];
            int gi = 32 * w + 16 * mi + 4 * g + r;
            size_t wb = (((size_t)b * 256 + gi) * 64 + m) * 56 + 28;
            aout[wb + li] = accv[mi][0][r] * invl;
            if (li < 12) aout[wb + 16 + li] = accv[mi][1][r] * invl;
        }
}

// ---------------- K8: output projection + unwindow (MFMA, prepped B) -------
__global__ __launch_bounds__(256) void k_out(const float* __restrict__ aout,
                                             const unsigned short* __restrict__ WFo,
                                             const float* __restrict__ bout,
                                             float* __restrict__ out) {
    __shared__ __align__(16) unsigned short Ah[64 * 68];
    __shared__ __align__(16) unsigned short Al[64 * 68];
    __shared__ __align__(16) float st[64 * 60];
    int tid = threadIdx.x;
    int w = tid >> 6;
    int l = tid & 63;
    int g = l >> 4;
    int li = l & 15;
    int pix0 = blockIdx.x * 64;
    for (int e = tid; e < 1792; e += 256) {
        int row = e / 28;
        int hp = e - row * 28;
        float2 v = *(const float2*)(aout + (size_t)pix0 * 56 + 2 * e);
        unsigned hpk = pk_bf16(v.x, v.y);
        float r0 = v.x - __uint_as_float(hpk << 16);
        float r1 = v.y - __uint_as_float(hpk & 0xffff0000u);
        ((unsigned*)Ah)[row * 34 + hp] = hpk;
        ((unsigned*)Al)[row * 34 + hp] = pk_bf16(r0, r1);
    }
    for (int e = tid; e < 384; e += 256) {
        int row = e / 6;
        int c = 28 + (e - row * 6);
        ((unsigned*)Ah)[row * 34 + c] = 0;
        ((unsigned*)Al)[row * 34 + c] = 0;
    }
    bf4 Bo[4][4];
#pragma unroll
    for (int nt = 0; nt < 4; ++nt)
#pragma unroll
        for (int kt = 0; kt < 4; ++kt)
            Bo[nt][kt] = *(const bf4*)(WFo + ((nt * 4 + kt) * 64 + l) * 4);
    __syncthreads();
    f4 acc[4];
#pragma unroll
    for (int nt = 0; nt < 4; ++nt) acc[nt] = (f4){0.f, 0.f, 0.f, 0.f};
    bf4 ah[4], al[4];
#pragma unroll
    for (int kt = 0; kt < 4; ++kt) {
        ah[kt] = *(const bf4*)(Ah + (16 * w + li) * 68 + 16 * kt + 4 * g);
        al[kt] = *(const bf4*)(Al + (16 * w + li) * 68 + 16 * kt + 4 * g);
    }
#pragma unroll
    for (int nt = 0; nt < 4; ++nt)
#pragma unroll
        for (int kt = 0; kt < 4; ++kt) {
            acc[nt] = mfma16(ah[kt], Bo[nt][kt], acc[nt]);
            acc[nt] = mfma16(al[kt], Bo[nt][kt], acc[nt]);
        }
#pragma unroll
    for (int nt = 0; nt < 4; ++nt) {
        int col = 16 * nt + li;
        if (col < 56) {
#pragma unroll
            for (int r = 0; r < 4; ++r)
                st[(16 * w + 4 * g + r) * 60 + col] = acc[nt][r];
        }
    }
    __syncthreads();
    int row = tid >> 2;
    int qq = tid & 3;
    int pixel = pix0 + row;
    int b = pixel >> 14;
    int n = (pixel >> 6) & 255;
    int m = pixel & 63;
    int h = ((n >> 4) << 3) + (m >> 3);
    int ww = ((n & 15) << 3) + (m & 7);
    float* dst = out + (((size_t)b * 128 + h) * 128 + ww) * 56;
    const float* sr = st + row * 60;
#pragma unroll
    for (int cc = 0; cc < 14; ++cc) {
        int c = 14 * qq + cc;
        dst[c] = sr[c] + bout[c];
    }
}

// ---------------------------------------------------------------------------
extern "C" void kernel_launch(void* const* d_in, const int* in_sizes, int n_in,
                              void* d_out, int out_size, void* d_ws, size_t ws_size,
                              hipStream_t stream) {
    const float* x = (const float*)d_in[0];
    const float* pos1 = (const float*)d_in[1];
    const float* pos2 = (const float*)d_in[2];
    const float* Wq = (const float*)d_in[3];
    const float* Wkv = (const float*)d_in[4];
    const float* Wout = (const float*)d_in[5];
    const float* bout = (const float*)d_in[6];
    const float* c1w = (const float*)d_in[7];
    const float* c1b = (const float*)d_in[8];
    const float* c2w = (const float*)d_in[9];
    const float* c2b = (const float*)d_in[10];
    const float* f1w = (const float*)d_in[11];
    const float* f1b = (const float*)d_in[12];
    const float* f2w = (const float*)d_in[13];
    const float* f2b = (const float*)d_in[14];

    unsigned short* us = (unsigned short*)d_ws;
    unsigned short* q1 = us;
    unsigned short* k1 = us + 3670016;
    unsigned short* v1 = us + 7340032;
    unsigned short* q2 = us + 11010048;
    unsigned short* k2 = us + 14680064;
    unsigned short* v2 = us + 18350080;
    float* fb = (float*)d_ws + 11010048;
    unsigned short* ssb = (unsigned short*)fb;   // ssum bf16 [8*256*64*56]
    float* aout = fb;                            // f32, written after conv1 reads ssb
    unsigned short* c1o = (unsigned short*)(fb + 7340032);  // bf16 [16][16384][16]
    float* part = fb + 11534336;
    float* shif = fb + 11550720;
    float* P1T = fb + 11550752;
    float* P1M = fb + 11583520;
    float* P2R = fb + 11584032;
    float* P2M = fb + 12108320;
    unsigned short* WF = (unsigned short*)(fb + 12110368);
    unsigned short* WFo = WF + 11264;
    unsigned short* BF1 = WFo + 4096;   // 9216 u16 (hi 4608 | lo 4608)
    unsigned short* BF2 = BF1 + 9216;   // 4608 u16 (hi 2304 | lo 2304)
    float* outp = (float*)d_out;

    (void)hipFuncSetAttribute((const void*)k_qkv,
                              hipFuncAttributeMaxDynamicSharedMemorySize, 52736);
    (void)hipFuncSetAttribute((const void*)k_attn2,
                              hipFuncAttributeMaxDynamicSharedMemorySize, 84192);

    k_prep<<<87, 256, 0, stream>>>(Wq, Wkv, Wout, c1w, c2w, WF, WFo, BF1, BF2);
    k_qkv<<<2048, 256, 52736, stream>>>(x, WF, q1, k1, v1, q2, k2, v2, ssb);
    k_conv1<<<1024, 256, 0, stream>>>(ssb, BF1, c1b, c1o);
    k_conv2<<<1024, 256, 0, stream>>>(c1o, BF2, c2b, part);
    k_fc<<<1, 256, 0, stream>>>(part, f1w, f1b, f2w, f2b, shif);
    k_pos1<<<8, 256, 0, stream>>>(pos1, shif, P1T, P1M);
    k_pos2<<<2048, 256, 0, stream>>>(pos2, shif, P2R, P2M);
    k_attn1<<<2048, 256, 0, stream>>>(q1, k1, v1, P1T, P1M, shif, aout);
    k_attn2<<<512, 512, 84192, stream>>>(q2, k2, v2, P2R, P2M, shif, aout);
    k_out<<<2048, 256, 0, stream>>>(aout, WFo, bout, outp);
}

// Round 9
// 171.119 us; speedup vs baseline: 4.8365x; 1.1218x over previous
//
#include <hip/hip_runtime.h>
#include <cstdint>

// ---------------------------------------------------------------------------
// SS-MSA fused implementation, round 9 (= round 8 debugged).
// grid_shift(sim) factorizes: shifted[i,j] = SCALE*(q_{i-1}.k_{j-1} + q~_i.k~_j) + P[i,j]
// => both branches are plain attention with 56-dim augmented Q/K + bias P.
//
// Round-9 fixes vs round 8 (NaN):
//  - k_qkv ssum slice offsets: bf16 st uses element offsets +56/+112 (had
//    stale doubled +112/+224 -> read past row end -> NaN shifts).
//  - k_out A staging: 14 uint2 per 56-u16 row (had 7 -> LDS overflow + wrong
//    stride).
// Design (from round 8): st staged bf16 (LDS 30.7KB, ~5 blk/CU), uniform 8B
// uint2 store tasks; aout bf16; k_out single-product MFMA.
// ---------------------------------------------------------------------------

#define SCALE_ 0.18898223650461364f  // 28^-0.5

using f4 = __attribute__((ext_vector_type(4))) float;
using bf4 = __attribute__((ext_vector_type(4))) short;

__device__ __forceinline__ f4 mfma16(bf4 a, bf4 b, f4 c) {
#if __has_builtin(__builtin_amdgcn_mfma_f32_16x16x16bf16_1k)
    return __builtin_amdgcn_mfma_f32_16x16x16bf16_1k(a, b, c, 0, 0, 0);
#else
    f4 d;
    asm("v_mfma_f32_16x16x16_bf16 %0, %1, %2, %3" : "=v"(d) : "v"(a), "v"(b), "v"(c));
    return d;
#endif
}

__device__ __forceinline__ unsigned pk_bf16(float lo, float hi) {
    unsigned r;
    asm("v_cvt_pk_bf16_f32 %0, %1, %2" : "=v"(r) : "v"(lo), "v"(hi));
    return r;
}
__device__ __forceinline__ unsigned short f2bf(float f) {
    return (unsigned short)pk_bf16(f, f);
}
__device__ __forceinline__ float bf2f(unsigned short h) {
    return __uint_as_float(((unsigned)h) << 16);
}

__device__ __forceinline__ void coords_(int idx, int S, float s,
                                        int& i0, int& i1, float& w0, float& w1) {
    float g = -1.0f + 2.0f * (float)idx / (float)(S - 1);
    float c = (g + s * 2.0f / (float)S + 1.0f) * 0.5f * (float)(S - 1);
    float span = (float)(S - 1);
    c = fabsf(c);
    c = fmodf(c, 2.0f * span);
    if (c > span) c = 2.0f * span - c;
    int f = (int)floorf(c);
    f = max(0, min(f, S - 1));
    i0 = f;
    i1 = min(f + 1, S - 1);
    w1 = c - (float)f;
    w0 = 1.0f - w1;
}

// ------------------ K0: weight prep (fragment-ordered bf16) ----------------
__global__ __launch_bounds__(256) void k_prep(const float* __restrict__ Wq,
                                              const float* __restrict__ Wkv,
                                              const float* __restrict__ Wout,
                                              const float* __restrict__ c1w,
                                              const float* __restrict__ c2w,
                                              unsigned short* __restrict__ WF,
                                              unsigned short* __restrict__ WFo,
                                              unsigned short* __restrict__ BF1,
                                              unsigned short* __restrict__ BF2) {
    int tid = blockIdx.x * 256 + threadIdx.x;
    if (tid < 11264) {
        int e = tid & 3;
        int l = (tid >> 2) & 63;
        int kt = (tid >> 8) & 3;
        int nt = tid >> 10;
        int g = l >> 4, li = l & 15;
        int k = 16 * kt + 4 * g + e;
        int col = 16 * nt + li;
        float v = 0.f;
        if (k < 56 && col < 168)
            v = (col < 56) ? Wq[k * 56 + col] : Wkv[k * 112 + (col - 56)];
        WF[tid] = f2bf(v);
    } else if (tid < 15360) {
        int t2 = tid - 11264;
        int e = t2 & 3;
        int l = (t2 >> 2) & 63;
        int kt = (t2 >> 8) & 3;
        int nt = t2 >> 10;
        int g = l >> 4, li = l & 15;
        int k = 16 * kt + 4 * g + e;
        int col = 16 * nt + li;
        float v = (k < 56 && col < 56) ? Wout[k * 56 + col] : 0.f;
        WFo[t2] = f2bf(v);
    } else if (tid < 19968) {
        int t2 = tid - 15360;  // 4608 entries
        int e = t2 & 3;
        int l = (t2 >> 2) & 63;
        int rest = t2 >> 8;    // t*2+kg
        int kg = rest & 1;
        int t = rest >> 1;
        int g = l >> 4, li = l & 15;
        int c = 16 * kg + 4 * g + e;
        float v = (c < 28) ? c1w[li * 252 + c * 9 + t] : 0.f;
        unsigned short h = f2bf(v);
        BF1[t2] = h;
        BF1[4608 + t2] = f2bf(v - bf2f(h));
    } else if (tid < 22272) {
        int t2 = tid - 19968;  // 2304 entries
        int e = t2 & 3;
        int l = (t2 >> 2) & 63;
        int t = t2 >> 8;
        int g = l >> 4, li = l & 15;
        int c = 4 * g + e;
        float v = c2w[li * 144 + c * 9 + t];
        unsigned short h = f2bf(v);
        BF2[t2] = h;
        BF2[2304 + t2] = f2bf(v - bf2f(h));
    }
}

// ------------------- K1: QKV GEMM (bf16 MFMA, prepped B) -------------------
// Block: 64 pixels x 168 cols. LDS: Ah bf16 [64][68] 8704B | st bf16 [64][172]
// 22016B = 30720B total.
__global__ __launch_bounds__(256) void k_qkv(const float* __restrict__ x,
                                             const unsigned short* __restrict__ WF,
                                             unsigned short* __restrict__ q1,
                                             unsigned short* __restrict__ k1,
                                             unsigned short* __restrict__ v1,
                                             unsigned short* __restrict__ q2,
                                             unsigned short* __restrict__ k2,
                                             unsigned short* __restrict__ v2,
                                             unsigned short* __restrict__ ssum) {
    extern __shared__ __align__(16) char smem[];
    unsigned short* Ah = (unsigned short*)smem;            // [64][68]
    unsigned short* st = (unsigned short*)(smem + 8704);   // [64][172]
    int tid = threadIdx.x;
    int w = tid >> 6;
    int l = tid & 63;
    int g = l >> 4;
    int li = l & 15;
    int pix0 = blockIdx.x * 64;
    for (int e = tid; e < 1792; e += 256) {
        int row = e / 28;
        int hp = e - row * 28;
        float2 v = *(const float2*)(x + (size_t)pix0 * 56 + 2 * e);
        ((unsigned*)Ah)[row * 34 + hp] = pk_bf16(v.x, v.y);
    }
    for (int e = tid; e < 384; e += 256) {
        int row = e / 6;
        ((unsigned*)Ah)[row * 34 + 28 + (e - row * 6)] = 0;
    }
    int nt0 = 3 * w;
    int nnt = (w < 3) ? 3 : 2;
    bf4 B[3][4];
#pragma unroll
    for (int t = 0; t < 3; ++t) {
        if (t >= nnt) break;
#pragma unroll
        for (int kt = 0; kt < 4; ++kt)
            B[t][kt] = *(const bf4*)(WF + (((nt0 + t) * 4 + kt) * 64 + l) * 4);
    }
    __syncthreads();
    f4 acc[4][3];
#pragma unroll
    for (int mi = 0; mi < 4; ++mi)
#pragma unroll
        for (int t = 0; t < 3; ++t) acc[mi][t] = (f4){0.f, 0.f, 0.f, 0.f};
#pragma unroll
    for (int mi = 0; mi < 4; ++mi) {
        bf4 a[4];
#pragma unroll
        for (int kt = 0; kt < 4; ++kt)
            a[kt] = *(const bf4*)(Ah + (16 * mi + li) * 68 + 16 * kt + 4 * g);
#pragma unroll
        for (int t = 0; t < 3; ++t) {
            if (t >= nnt) break;
#pragma unroll
            for (int kt = 0; kt < 4; ++kt)
                acc[mi][t] = mfma16(a[kt], B[t][kt], acc[mi][t]);
        }
    }
#pragma unroll
    for (int mi = 0; mi < 4; ++mi)
#pragma unroll
        for (int t = 0; t < 3; ++t) {
            if (t >= nnt) break;
            int col = 16 * (nt0 + t) + li;
            if (col < 168) {
#pragma unroll
                for (int r = 0; r < 4; ++r)
                    st[(16 * mi + 4 * g + r) * 172 + col] = f2bf(acc[mi][t][r]);
            }
        }
    __syncthreads();
    // ---- ssum: one (row, 14-col slice) per thread; st cols: q|k|v at 0/56/112
    {
        int row = tid >> 2;
        int qq = tid & 3;
        int pixel = pix0 + row;
        int b = pixel >> 14;
        int rem = pixel & 16383;
        int hh = rem >> 7;
        int ww = rem & 127;
        int n = ((hh >> 3) << 4) + (ww >> 3);
        int m = ((hh & 7) << 3) + (ww & 7);
        size_t ob = ((size_t)(b * 256 + n) * 64 + m) * 56 + 14 * qq;
        const unsigned short* sr = st + row * 172 + 14 * qq;
#pragma unroll
        for (int h = 0; h < 7; ++h) {
            unsigned qw = *(const unsigned*)(sr + 2 * h);
            unsigned kw = *(const unsigned*)(sr + 56 + 2 * h);
            unsigned vw = *(const unsigned*)(sr + 112 + 2 * h);
            float s0 = __uint_as_float(qw << 16) + __uint_as_float(kw << 16) +
                       __uint_as_float(vw << 16);
            float s1 = __uint_as_float(qw & 0xffff0000u) + __uint_as_float(kw & 0xffff0000u) +
                       __uint_as_float(vw & 0xffff0000u);
            *(unsigned*)(ssum + ob + 2 * h) = pk_bf16(s0, s1);
        }
    }
    // ---- array half-rows: 384 tasks of 7 uint2 copies ----
    for (int e = tid; e < 384; e += 256) {
        int row = e / 6;
        int half = e - row * 6;
        int pixel = pix0 + row;
        int b = pixel >> 14;
        int rem = pixel & 16383;
        int hh = rem >> 7;
        int ww = rem & 127;
        int n = ((hh >> 3) << 4) + (ww >> 3);
        int m = ((hh & 7) << 3) + (ww & 7);
        size_t p1 = ((size_t)(b * 256 + n) * 64 + m) * 28;
        size_t p2 = ((size_t)(b * 64 + m) * 256 + n) * 28;
        unsigned short* base =
            (half < 2) ? (half == 0 ? q1 + p1 : q2 + p2)
                       : (half < 4) ? (half == 2 ? k1 + p1 : k2 + p2)
                                    : (half == 4 ? v1 + p1 : v2 + p2);
        const unsigned short* src = st + row * 172 + half * 28;
#pragma unroll
        for (int h = 0; h < 7; ++h)
            *(uint2*)(base + 4 * h) = *(const uint2*)(src + 4 * h);
    }
}

// ---------------- K2: conv1, implicit-GEMM MFMA (bf16, hi/lo B) ------------
__global__ __launch_bounds__(256) void k_conv1(const unsigned short* __restrict__ ssum,
                                               const unsigned short* __restrict__ BF1,
                                               const float* __restrict__ c1b,
                                               unsigned short* __restrict__ c1o) {
    __shared__ __align__(16) unsigned short tile[6 * 66 * 32];
    int tid = threadIdx.x;
    int w = tid >> 6;
    int l = tid & 63;
    int g = l >> 4;
    int li = l & 15;
    int wg = blockIdx.x;
    int br = wg >> 9;
    int b = (wg >> 6) & 7;
    int nt = wg & 63;
    int n0 = nt * 4;
    for (int e = tid; e < 11088; e += 256) {
        int c = e % 28;
        int rest = e / 28;
        int mm = rest % 66;
        int nr = rest / 66;
        int n = n0 - 1 + nr;
        int m = mm - 1;
        unsigned short v = 0;
        if (n >= 0 && n < 256 && m >= 0 && m < 64)
            v = ssum[(((size_t)b * 256 + n) * 64 + m) * 56 + br * 28 + c];
        tile[(nr * 66 + mm) * 32 + c] = v;
    }
    for (int e = tid; e < 1584; e += 256) {
        int rm = e >> 2;
        tile[rm * 32 + 28 + (e & 3)] = 0;
    }
    bf4 Bh[9][2], Bl[9][2];
#pragma unroll
    for (int t = 0; t < 9; ++t)
#pragma unroll
        for (int kg = 0; kg < 2; ++kg) {
            Bh[t][kg] = *(const bf4*)(BF1 + ((t * 2 + kg) * 64 + l) * 4);
            Bl[t][kg] = *(const bf4*)(BF1 + 4608 + ((t * 2 + kg) * 64 + l) * 4);
        }
    __syncthreads();
    f4 acc[4];
#pragma unroll
    for (int mt = 0; mt < 4; ++mt) acc[mt] = (f4){0.f, 0.f, 0.f, 0.f};
#pragma unroll
    for (int mt = 0; mt < 4; ++mt) {
#pragma unroll
        for (int t = 0; t < 9; ++t) {
            int ky = t / 3, kx = t - 3 * (t / 3);
#pragma unroll
            for (int kg = 0; kg < 2; ++kg) {
                bf4 a = *(const bf4*)(tile + ((w + ky) * 66 + 16 * mt + li + kx) * 32 +
                                      16 * kg + 4 * g);
                acc[mt] = mfma16(a, Bh[t][kg], acc[mt]);
                acc[mt] = mfma16(a, Bl[t][kg], acc[mt]);
            }
        }
    }
    float bias = c1b[li];
    size_t combo = (size_t)(br * 8 + b);
#pragma unroll
    for (int mt = 0; mt < 4; ++mt)
#pragma unroll
        for (int r = 0; r < 4; ++r) {
            int m = 16 * mt + 4 * g + r;
            float v = fmaxf(acc[mt][r] + bias, 0.f);
            c1o[(combo * 16384 + (size_t)(n0 + w) * 64 + m) * 16 + li] = f2bf(v);
        }
}

// ------------- K3: conv2 + pooled partials, implicit-GEMM MFMA -------------
__global__ __launch_bounds__(256) void k_conv2(const unsigned short* __restrict__ c1o,
                                               const unsigned short* __restrict__ BF2,
                                               const float* __restrict__ c2b,
                                               float* __restrict__ part) {
    __shared__ __align__(16) unsigned short tile[6 * 66 * 16];
    __shared__ float pbuf[4][16];
    int tid = threadIdx.x;
    int w = tid >> 6;
    int l = tid & 63;
    int g = l >> 4;
    int li = l & 15;
    int wg = blockIdx.x;
    int br = wg >> 9;
    int b = (wg >> 6) & 7;
    int nt = wg & 63;
    int n0 = nt * 4;
    size_t combo = (size_t)(br * 8 + b);
    for (int e = tid; e < 6336; e += 256) {
        int c = e & 15;
        int rest = e >> 4;
        int mm = rest % 66;
        int nr = rest / 66;
        int n = n0 - 1 + nr;
        int m = mm - 1;
        unsigned short v = 0;
        if (n >= 0 && n < 256 && m >= 0 && m < 64)
            v = c1o[(combo * 16384 + (size_t)n * 64 + m) * 16 + c];
        tile[(nr * 66 + mm) * 16 + c] = v;
    }
    bf4 Bh[9], Bl[9];
#pragma unroll
    for (int t = 0; t < 9; ++t) {
        Bh[t] = *(const bf4*)(BF2 + (t * 64 + l) * 4);
        Bl[t] = *(const bf4*)(BF2 + 2304 + (t * 64 + l) * 4);
    }
    __syncthreads();
    f4 acc[4];
#pragma unroll
    for (int mt = 0; mt < 4; ++mt) acc[mt] = (f4){0.f, 0.f, 0.f, 0.f};
#pragma unroll
    for (int mt = 0; mt < 4; ++mt) {
#pragma unroll
        for (int t = 0; t < 9; ++t) {
            int ky = t / 3, kx = t - 3 * (t / 3);
            bf4 a = *(const bf4*)(tile + ((w + ky) * 66 + 16 * mt + li + kx) * 16 + 4 * g);
            acc[mt] = mfma16(a, Bh[t], acc[mt]);
            acc[mt] = mfma16(a, Bl[t], acc[mt]);
        }
    }
    float bias = c2b[li];
    float s = 0.f;
#pragma unroll
    for (int mt = 0; mt < 4; ++mt)
#pragma unroll
        for (int r = 0; r < 4; ++r) s += fmaxf(acc[mt][r] + bias, 0.f);
    s += __shfl_xor(s, 16);
    s += __shfl_xor(s, 32);
    if (l < 16) pbuf[w][li] = s;
    __syncthreads();
    if (tid < 16) {
        float tot = pbuf[0][tid] + pbuf[1][tid] + pbuf[2][tid] + pbuf[3][tid];
        part[(combo * 64 + nt) * 16 + tid] = tot;
    }
}

// ------------------------- K4: reduce + FC -> shifts -----------------------
__global__ void k_fc(const float* __restrict__ part, const float* __restrict__ f1w,
                     const float* __restrict__ f1b, const float* __restrict__ f2w,
                     const float* __restrict__ f2b, float* __restrict__ shif) {
    __shared__ float sb[16][16];
    int t = threadIdx.x;
    int combo = t >> 4;
    int o = t & 15;
    float s = 0.f;
    for (int nt = 0; nt < 64; ++nt) s += part[((size_t)combo * 64 + nt) * 16 + o];
    sb[combo][o] = s * (1.0f / 16384.0f);
    __syncthreads();
    if (t < 16) {
        float p0 = f1b[0], p1 = f1b[1], rg = f2b[0];
        for (int oo = 0; oo < 16; ++oo) {
            float sv = sb[t][oo];
            p0 += sv * f1w[oo * 2 + 0];
            p1 += sv * f1w[oo * 2 + 1];
            rg += sv * f2w[oo];
        }
        shif[t * 2 + 0] = rg * tanhf(p0);
        shif[t * 2 + 1] = rg * tanhf(p1);
    }
}

// ------------------------- K5a/b: shifted pos precompute -------------------
__global__ __launch_bounds__(256) void k_pos1(const float* __restrict__ pos1,
                                              const float* __restrict__ shif,
                                              float* __restrict__ P1T,
                                              float* __restrict__ P1M) {
    __shared__ float plds[64 * 64];
    int b = blockIdx.x;
    float sx = shif[b * 2 + 0];
    float sy = shif[b * 2 + 1];
    for (int e = threadIdx.x; e < 4096; e += 256) {
        int j = e >> 6;
        int i = e & 63;
        int y0, y1, x0, x1;
        float wy0, wy1, wx0, wx1;
        coords_(i, 64, sy, y0, y1, wy0, wy1);
        coords_(j, 64, sx, x0, x1, wx0, wx1);
        float v = pos1[((i - 1) & 63) * 64 + ((j - 1) & 63)] +
                  wy0 * (wx0 * pos1[y0 * 64 + x0] + wx1 * pos1[y0 * 64 + x1]) +
                  wy1 * (wx0 * pos1[y1 * 64 + x0] + wx1 * pos1[y1 * 64 + x1]);
        P1T[(size_t)b * 4096 + j * 64 + i] = v;
        plds[j * 64 + i] = v;
    }
    __syncthreads();
    if (threadIdx.x < 64) {
        float mx = plds[threadIdx.x];
        for (int j = 1; j < 64; ++j) mx = fmaxf(mx, plds[j * 64 + threadIdx.x]);
        P1M[b * 64 + threadIdx.x] = mx;
    }
}

__global__ __launch_bounds__(256) void k_pos2(const float* __restrict__ pos2,
                                              const float* __restrict__ shif,
                                              float* __restrict__ P2R,
                                              float* __restrict__ P2M) {
    __shared__ float red[4];
    int wg = blockIdx.x;
    int b = wg >> 8;
    int i = wg & 255;
    float sx = shif[16 + b * 2 + 0];
    float sy = shif[16 + b * 2 + 1];
    int j = threadIdx.x;
    int y0, y1, x0, x1;
    float wy0, wy1, wx0, wx1;
    coords_(i, 256, sy, y0, y1, wy0, wy1);
    coords_(j, 256, sx, x0, x1, wx0, wx1);
    float v = pos2[((i - 1) & 255) * 256 + ((j - 1) & 255)] +
              wy0 * (wx0 * pos2[y0 * 256 + x0] + wx1 * pos2[y0 * 256 + x1]) +
              wy1 * (wx0 * pos2[y1 * 256 + x0] + wx1 * pos2[y1 * 256 + x1]);
    P2R[(size_t)b * 65536 + (size_t)i * 256 + j] = v;
    float mx = v;
#pragma unroll
    for (int msk = 1; msk < 64; msk <<= 1) mx = fmaxf(mx, __shfl_xor(mx, msk));
    if ((threadIdx.x & 63) == 0) red[threadIdx.x >> 6] = mx;
    __syncthreads();
    if (threadIdx.x == 0)
        P2M[b * 256 + i] = fmaxf(fmaxf(red[0], red[1]), fmaxf(red[2], red[3]));
}

// --------------- K6: branch-1 window attention (64x64), MFMA ---------------
__global__ __launch_bounds__(256) void k_attn1(const unsigned short* __restrict__ q1,
                                               const unsigned short* __restrict__ k1,
                                               const unsigned short* __restrict__ v1,
                                               const float* __restrict__ P1T,
                                               const float* __restrict__ P1M,
                                               const float* __restrict__ shif,
                                               unsigned short* __restrict__ aout) {
    __shared__ __align__(16) unsigned short qraw[64 * 28];
    __shared__ __align__(16) unsigned short kraw[64 * 28];
    __shared__ __align__(16) unsigned short augK[64 * 68];
    __shared__ __align__(16) unsigned short vT[32 * 68];
    __shared__ __align__(16) unsigned short Pw[4][16 * 68];
    int tid = threadIdx.x;
    int w = tid >> 6;
    int l = tid & 63;
    int g = l >> 4;
    int li = l & 15;
    int wg = blockIdx.x;
    int b = wg >> 8;
    int n = wg & 255;
    size_t gb = (size_t)(b * 256 + n) * 1792;
    float sx = shif[b * 2 + 0];
    float sy = shif[b * 2 + 1];
    for (int e = tid; e < 1792; e += 256) {
        qraw[e] = q1[gb + e];
        kraw[e] = k1[gb + e];
        int j = e / 28;
        int c = e - j * 28;
        vT[c * 68 + j] = v1[gb + e];
    }
    for (int e = tid; e < 272; e += 256) vT[28 * 68 + e] = 0;
    __syncthreads();
    if (tid < 64) {
        int j = tid;
        int x0, x1;
        float wx0, wx1;
        coords_(j, 64, sx, x0, x1, wx0, wx1);
        int rm = (j - 1) & 63;
        unsigned* row = (unsigned*)(augK + j * 68);
        const unsigned* src = (const unsigned*)(kraw + rm * 28);
#pragma unroll
        for (int h = 0; h < 14; ++h) row[h] = src[h];
#pragma unroll
        for (int h = 0; h < 14; ++h) {
            float a0 = wx0 * bf2f(kraw[x0 * 28 + 2 * h]) + wx1 * bf2f(kraw[x1 * 28 + 2 * h]);
            float a1 = wx0 * bf2f(kraw[x0 * 28 + 2 * h + 1]) + wx1 * bf2f(kraw[x1 * 28 + 2 * h + 1]);
            row[14 + h] = pk_bf16(a0, a1);
        }
#pragma unroll
        for (int h = 28; h < 34; ++h) row[h] = 0;
    }
    bf4 qf[4];
    {
        int i = 16 * w + li;
        int y0, y1;
        float wy0, wy1;
        coords_(i, 64, sy, y0, y1, wy0, wy1);
        int rm = (i - 1) & 63;
#pragma unroll
        for (int kt = 0; kt < 4; ++kt) {
            float qv[4];
#pragma unroll
            for (int e = 0; e < 4; ++e) {
                int d = 16 * kt + 4 * g + e;
                float v;
                if (d < 28) v = SCALE_ * bf2f(qraw[rm * 28 + d]);
                else if (d < 56)
                    v = SCALE_ * (wy0 * bf2f(qraw[y0 * 28 + d - 28]) +
                                  wy1 * bf2f(qraw[y1 * 28 + d - 28]));
                else v = 0.f;
                qv[e] = v;
            }
            union { unsigned u[2]; bf4 v; } cv;
            cv.u[0] = pk_bf16(qv[0], qv[1]);
            cv.u[1] = pk_bf16(qv[2], qv[3]);
            qf[kt] = cv.v;
        }
    }
    f4 Mv = *(const f4*)(P1M + b * 64 + 16 * w + 4 * g);
    __syncthreads();
    f4 acc[4];
#pragma unroll
    for (int nj = 0; nj < 4; ++nj)
        acc[nj] = *(const f4*)(P1T + (size_t)b * 4096 + (16 * nj + li) * 64 + 16 * w + 4 * g);
#pragma unroll
    for (int nj = 0; nj < 4; ++nj) {
        const unsigned short* kr = augK + (16 * nj + li) * 68 + 4 * g;
#pragma unroll
        for (int kt = 0; kt < 4; ++kt) {
            bf4 bk = *(const bf4*)(kr + 16 * kt);
            acc[nj] = mfma16(qf[kt], bk, acc[nj]);
        }
    }
    float lr[4] = {0.f, 0.f, 0.f, 0.f};
    unsigned short* Pww = Pw[w];
#pragma unroll
    for (int nj = 0; nj < 4; ++nj)
#pragma unroll
        for (int r = 0; r < 4; ++r) {
            float p = __expf(acc[nj][r] - Mv[r]);
            lr[r] += p;
            Pww[(4 * g + r) * 68 + 16 * nj + li] = f2bf(p);
        }
    f4 accv[2];
    accv[0] = (f4){0.f, 0.f, 0.f, 0.f};
    accv[1] = (f4){0.f, 0.f, 0.f, 0.f};
#pragma unroll
    for (int kt = 0; kt < 4; ++kt) {
        bf4 pa = *(const bf4*)(Pww + li * 68 + 16 * kt + 4 * g);
#pragma unroll
        for (int nc = 0; nc < 2; ++nc) {
            bf4 bv = *(const bf4*)(vT + (16 * nc + li) * 68 + 16 * kt + 4 * g);
            accv[nc] = mfma16(pa, bv, accv[nc]);
        }
    }
#pragma unroll
    for (int r = 0; r < 4; ++r) {
#pragma unroll
        for (int msk = 1; msk < 16; msk <<= 1) lr[r] += __shfl_xor(lr[r], msk);
        float invl = 1.0f / lr[r];
        int i = 16 * w + 4 * g + r;
        size_t wb = ((size_t)(b * 256 + n) * 64 + i) * 56;
        aout[wb + li] = f2bf(accv[0][r] * invl);
        if (li < 12) aout[wb + 16 + li] = f2bf(accv[1][r] * invl);
    }
}

// -------------------- K7: branch-2 cross-window attn, MFMA -----------------
__global__ __launch_bounds__(512) void k_attn2(const unsigned short* __restrict__ q2,
                                               const unsigned short* __restrict__ k2,
                                               const unsigned short* __restrict__ v2,
                                               const float* __restrict__ P2R,
                                               const float* __restrict__ P2M,
                                               const float* __restrict__ shif,
                                               unsigned short* __restrict__ aout) {
    extern __shared__ __align__(16) char smem[];
    unsigned short* augK = (unsigned short*)smem;                  // [256][68]
    unsigned short* vT = (unsigned short*)(smem + 34816);          // [28][260]
    int tid = threadIdx.x;
    int w = tid >> 6;
    int l = tid & 63;
    int g = l >> 4;
    int li = l & 15;
    unsigned short* Pw = (unsigned short*)(smem + 49376) + w * 2176;  // [32][68]
    int bm = blockIdx.x;
    int b = bm >> 6;
    int m = bm & 63;
    size_t gbase = (size_t)bm * 7168;
    float sx = shif[16 + b * 2 + 0];
    float sy = shif[16 + b * 2 + 1];
    if (tid < 256) {
        int j = tid;
        int x0, x1;
        float wx0, wx1;
        coords_(j, 256, sx, x0, x1, wx0, wx1);
        int rm = (j - 1) & 255;
        const unsigned short* krm = k2 + gbase + (size_t)rm * 28;
        const unsigned short* ka = k2 + gbase + (size_t)x0 * 28;
        const unsigned short* kb = k2 + gbase + (size_t)x1 * 28;
        unsigned* row = (unsigned*)(augK + j * 68);
        const unsigned* src = (const unsigned*)krm;
#pragma unroll
        for (int h = 0; h < 14; ++h) row[h] = src[h];
#pragma unroll
        for (int h = 0; h < 14; ++h) {
            float a0 = wx0 * bf2f(ka[2 * h]) + wx1 * bf2f(kb[2 * h]);
            float a1 = wx0 * bf2f(ka[2 * h + 1]) + wx1 * bf2f(kb[2 * h + 1]);
            row[14 + h] = pk_bf16(a0, a1);
        }
#pragma unroll
        for (int h = 28; h < 34; ++h) row[h] = 0;
    } else {
        int j = tid - 256;
        const unsigned short* vr = v2 + gbase + (size_t)j * 28;
#pragma unroll
        for (int c = 0; c < 28; ++c) vT[c * 260 + j] = vr[c];
    }
    bf4 qf[2][4];
#pragma unroll
    for (int mi = 0; mi < 2; ++mi) {
        int i = 32 * w + 16 * mi + li;
        int y0, y1;
        float wy0, wy1;
        coords_(i, 256, sy, y0, y1, wy0, wy1);
        int rm = (i - 1) & 255;
        const unsigned short* qrm = q2 + gbase + (size_t)rm * 28;
        const unsigned short* qa = q2 + gbase + (size_t)y0 * 28;
        const unsigned short* qb = q2 + gbase + (size_t)y1 * 28;
#pragma unroll
        for (int kt = 0; kt < 4; ++kt) {
            float qv[4];
#pragma unroll
            for (int e = 0; e < 4; ++e) {
                int d = 16 * kt + 4 * g + e;
                float v;
                if (d < 28) v = SCALE_ * bf2f(qrm[d]);
                else if (d < 56)
                    v = SCALE_ * (wy0 * bf2f(qa[d - 28]) + wy1 * bf2f(qb[d - 28]));
                else v = 0.f;
                qv[e] = v;
            }
            union { unsigned u[2]; bf4 v; } cv;
            cv.u[0] = pk_bf16(qv[0], qv[1]);
            cv.u[1] = pk_bf16(qv[2], qv[3]);
            qf[mi][kt] = cv.v;
        }
    }
    float M[2][4];
#pragma unroll
    for (int mi = 0; mi < 2; ++mi)
#pragma unroll
        for (int r = 0; r < 4; ++r)
            M[mi][r] = P2M[b * 256 + 32 * w + 16 * mi + 4 * g + r];
    __syncthreads();
    f4 accv[2][2];
#pragma unroll
    for (int mi = 0; mi < 2; ++mi)
#pragma unroll
        for (int nc = 0; nc < 2; ++nc) accv[mi][nc] = (f4){0.f, 0.f, 0.f, 0.f};
    float lrun[2][4];
#pragma unroll
    for (int mi = 0; mi < 2; ++mi)
#pragma unroll
        for (int r = 0; r < 4; ++r) lrun[mi][r] = 0.f;

    for (int jt = 0; jt < 4; ++jt) {
        f4 acc[2][4];
#pragma unroll
        for (int mi = 0; mi < 2; ++mi) {
            const float* pr = P2R + (size_t)b * 65536 +
                              (size_t)(32 * w + 16 * mi + 4 * g) * 256 + 64 * jt + li;
#pragma unroll
            for (int nj = 0; nj < 4; ++nj)
                acc[mi][nj] = (f4){pr[16 * nj], pr[16 * nj + 256],
                                   pr[16 * nj + 512], pr[16 * nj + 768]};
        }
#pragma unroll
        for (int nj = 0; nj < 4; ++nj) {
            const unsigned short* kr = augK + (64 * jt + 16 * nj + li) * 68 + 4 * g;
            bf4 bk[4];
#pragma unroll
            for (int kt = 0; kt < 4; ++kt) bk[kt] = *(const bf4*)(kr + 16 * kt);
#pragma unroll
            for (int mi = 0; mi < 2; ++mi)
#pragma unroll
                for (int kt = 0; kt < 4; ++kt)
                    acc[mi][nj] = mfma16(qf[mi][kt], bk[kt], acc[mi][nj]);
        }
#pragma unroll
        for (int mi = 0; mi < 2; ++mi)
#pragma unroll
            for (int nj = 0; nj < 4; ++nj)
#pragma unroll
                for (int r = 0; r < 4; ++r) {
                    float p = __expf(acc[mi][nj][r] - M[mi][r]);
                    lrun[mi][r] += p;
                    Pw[(16 * mi + 4 * g + r) * 68 + 16 * nj + li] = f2bf(p);
                }
#pragma unroll
        for (int kt = 0; kt < 4; ++kt) {
            bf4 pa[2];
#pragma unroll
            for (int mi = 0; mi < 2; ++mi)
                pa[mi] = *(const bf4*)(Pw + (16 * mi + li) * 68 + 16 * kt + 4 * g);
#pragma unroll
            for (int nc = 0; nc < 2; ++nc) {
                bf4 bv = *(const bf4*)(vT + (16 * nc + li) * 260 + 64 * jt + 16 * kt + 4 * g);
#pragma unroll
                for (int mi = 0; mi < 2; ++mi)
                    accv[mi][nc] = mfma16(pa[mi], bv, accv[mi][nc]);
            }
        }
    }
#pragma unroll
    for (int mi = 0; mi < 2; ++mi)
#pragma unroll
        for (int r = 0; r < 4; ++r) {
#pragma unroll
            for (int msk = 1; msk < 16; msk <<= 1)
                lrun[mi][r] += __shfl_xor(lrun[mi][r], msk);
            float invl = 1.0f / lrun[mi][r];
            int gi = 32 * w + 16 * mi + 4 * g + r;
            size_t wb = (((size_t)b * 256 + gi) * 64 + m) * 56 + 28;
            aout[wb + li] = f2bf(accv[mi][0][r] * invl);
            if (li < 12) aout[wb + 16 + li] = f2bf(accv[mi][1][r] * invl);
        }
}

// ---------------- K8: output projection + unwindow (MFMA, prepped B) -------
__global__ __launch_bounds__(256) void k_out(const unsigned short* __restrict__ aout,
                                             const unsigned short* __restrict__ WFo,
                                             const float* __restrict__ bout,
                                             float* __restrict__ out) {
    __shared__ __align__(16) unsigned short Ah[64 * 68];
    __shared__ __align__(16) float st[64 * 60];
    int tid = threadIdx.x;
    int w = tid >> 6;
    int l = tid & 63;
    int g = l >> 4;
    int li = l & 15;
    int pix0 = blockIdx.x * 64;
    // 14 uint2 per 56-u16 row: row = e/14, c4 = (e%14)*4; 4*e == row*56 + c4
    for (int e = tid; e < 896; e += 256) {
        int row = e / 14;
        int c4 = (e - row * 14) * 4;
        *(uint2*)(Ah + row * 68 + c4) = *(const uint2*)(aout + (size_t)pix0 * 56 + 4 * e);
    }
    for (int e = tid; e < 384; e += 256) {
        int row = e / 6;
        ((unsigned*)Ah)[row * 34 + 28 + (e - row * 6)] = 0;
    }
    bf4 Bo[4][4];
#pragma unroll
    for (int nt = 0; nt < 4; ++nt)
#pragma unroll
        for (int kt = 0; kt < 4; ++kt)
            Bo[nt][kt] = *(const bf4*)(WFo + ((nt * 4 + kt) * 64 + l) * 4);
    __syncthreads();
    f4 acc[4];
#pragma unroll
    for (int nt = 0; nt < 4; ++nt) acc[nt] = (f4){0.f, 0.f, 0.f, 0.f};
    bf4 ah[4];
#pragma unroll
    for (int kt = 0; kt < 4; ++kt)
        ah[kt] = *(const bf4*)(Ah + (16 * w + li) * 68 + 16 * kt + 4 * g);
#pragma unroll
    for (int nt = 0; nt < 4; ++nt)
#pragma unroll
        for (int kt = 0; kt < 4; ++kt)
            acc[nt] = mfma16(ah[kt], Bo[nt][kt], acc[nt]);
#pragma unroll
    for (int nt = 0; nt < 4; ++nt) {
        int col = 16 * nt + li;
        if (col < 56) {
#pragma unroll
            for (int r = 0; r < 4; ++r)
                st[(16 * w + 4 * g + r) * 60 + col] = acc[nt][r];
        }
    }
    __syncthreads();
    int row = tid >> 2;
    int qq = tid & 3;
    int pixel = pix0 + row;
    int b = pixel >> 14;
    int n = (pixel >> 6) & 255;
    int m = pixel & 63;
    int h = ((n >> 4) << 3) + (m >> 3);
    int ww = ((n & 15) << 3) + (m & 7);
    float* dst = out + (((size_t)b * 128 + h) * 128 + ww) * 56;
    const float* sr = st + row * 60;
#pragma unroll
    for (int cc = 0; cc < 14; ++cc) {
        int c = 14 * qq + cc;
        dst[c] = sr[c] + bout[c];
    }
}

// ---------------------------------------------------------------------------
extern "C" void kernel_launch(void* const* d_in, const int* in_sizes, int n_in,
                              void* d_out, int out_size, void* d_ws, size_t ws_size,
                              hipStream_t stream) {
    const float* x = (const float*)d_in[0];
    const float* pos1 = (const float*)d_in[1];
    const float* pos2 = (const float*)d_in[2];
    const float* Wq = (const float*)d_in[3];
    const float* Wkv = (const float*)d_in[4];
    const float* Wout = (const float*)d_in[5];
    const float* bout = (const float*)d_in[6];
    const float* c1w = (const float*)d_in[7];
    const float* c1b = (const float*)d_in[8];
    const float* c2w = (const float*)d_in[9];
    const float* c2b = (const float*)d_in[10];
    const float* f1w = (const float*)d_in[11];
    const float* f1b = (const float*)d_in[12];
    const float* f2w = (const float*)d_in[13];
    const float* f2b = (const float*)d_in[14];

    unsigned short* us = (unsigned short*)d_ws;
    unsigned short* q1 = us;
    unsigned short* k1 = us + 3670016;
    unsigned short* v1 = us + 7340032;
    unsigned short* q2 = us + 11010048;
    unsigned short* k2 = us + 14680064;
    unsigned short* v2 = us + 18350080;
    float* fb = (float*)d_ws + 11010048;
    unsigned short* ssb = (unsigned short*)fb;     // ssum bf16 [131072][56]
    unsigned short* aoutb = (unsigned short*)fb;   // aout bf16, overlays ssb
    unsigned short* c1o = (unsigned short*)(fb + 7340032);  // bf16 [16][16384][16]
    float* part = fb + 11534336;
    float* shif = fb + 11550720;
    float* P1T = fb + 11550752;
    float* P1M = fb + 11583520;
    float* P2R = fb + 11584032;
    float* P2M = fb + 12108320;
    unsigned short* WF = (unsigned short*)(fb + 12110368);
    unsigned short* WFo = WF + 11264;
    unsigned short* BF1 = WFo + 4096;   // 9216 u16 (hi 4608 | lo 4608)
    unsigned short* BF2 = BF1 + 9216;   // 4608 u16 (hi 2304 | lo 2304)
    float* outp = (float*)d_out;

    (void)hipFuncSetAttribute((const void*)k_qkv,
                              hipFuncAttributeMaxDynamicSharedMemorySize, 30720);
    (void)hipFuncSetAttribute((const void*)k_attn2,
                              hipFuncAttributeMaxDynamicSharedMemorySize, 84192);

    k_prep<<<87, 256, 0, stream>>>(Wq, Wkv, Wout, c1w, c2w, WF, WFo, BF1, BF2);
    k_qkv<<<2048, 256, 30720, stream>>>(x, WF, q1, k1, v1, q2, k2, v2, ssb);
    k_conv1<<<1024, 256, 0, stream>>>(ssb, BF1, c1b, c1o);
    k_conv2<<<1024, 256, 0, stream>>>(c1o, BF2, c2b, part);
    k_fc<<<1, 256, 0, stream>>>(part, f1w, f1b, f2w, f2b, shif);
    k_pos1<<<8, 256, 0, stream>>>(pos1, shif, P1T, P1M);
    k_pos2<<<2048, 256, 0, stream>>>(pos2, shif, P2R, P2M);
    k_attn1<<<2048, 256, 0, stream>>>(q1, k1, v1, P1T, P1M, shif, aoutb);
    k_attn2<<<512, 512, 84192, stream>>>(q2, k2, v2, P2R, P2M, shif, aoutb);
    k_out<<<2048, 256, 0, stream>>>(aoutb, WFo, bout, outp);
}

// Round 10
// 165.795 us; speedup vs baseline: 4.9918x; 1.0321x over previous
//
#include <hip/hip_runtime.h>
#include <cstdint>

// ---------------------------------------------------------------------------
// SS-MSA fused implementation, round 10.
// grid_shift(sim) factorizes: shifted[i,j] = SCALE*(q_{i-1}.k_{j-1} + q~_i.k~_j) + P[i,j]
// => both branches are plain attention with 56-dim augmented Q/K + bias P.
//
// Round-10 changes vs round 9:
//  - conv1 LDS tile stride 32->36 u16 (72B: bank stride 18 -> 16 distinct
//    banks; was 64B -> 8-way conflict, 8.4M SQ_LDS_BANK_CONFLICT ~= 14us).
//  - conv2 stride 16->20 u16 (40B, was 4-way conflict).
//  - k_posT: P2R -> P2T[b][j][i] transpose (2MB, ~1.5us); attn2 bias init is
//    now 32 aligned f4 loads instead of 128 scalar f32 loads per thread.
// ---------------------------------------------------------------------------

#define SCALE_ 0.18898223650461364f  // 28^-0.5

using f4 = __attribute__((ext_vector_type(4))) float;
using bf4 = __attribute__((ext_vector_type(4))) short;

__device__ __forceinline__ f4 mfma16(bf4 a, bf4 b, f4 c) {
#if __has_builtin(__builtin_amdgcn_mfma_f32_16x16x16bf16_1k)
    return __builtin_amdgcn_mfma_f32_16x16x16bf16_1k(a, b, c, 0, 0, 0);
#else
    f4 d;
    asm("v_mfma_f32_16x16x16_bf16 %0, %1, %2, %3" : "=v"(d) : "v"(a), "v"(b), "v"(c));
    return d;
#endif
}

__device__ __forceinline__ unsigned pk_bf16(float lo, float hi) {
    unsigned r;
    asm("v_cvt_pk_bf16_f32 %0, %1, %2" : "=v"(r) : "v"(lo), "v"(hi));
    return r;
}
__device__ __forceinline__ unsigned short f2bf(float f) {
    return (unsigned short)pk_bf16(f, f);
}
__device__ __forceinline__ float bf2f(unsigned short h) {
    return __uint_as_float(((unsigned)h) << 16);
}

__device__ __forceinline__ void coords_(int idx, int S, float s,
                                        int& i0, int& i1, float& w0, float& w1) {
    float g = -1.0f + 2.0f * (float)idx / (float)(S - 1);
    float c = (g + s * 2.0f / (float)S + 1.0f) * 0.5f * (float)(S - 1);
    float span = (float)(S - 1);
    c = fabsf(c);
    c = fmodf(c, 2.0f * span);
    if (c > span) c = 2.0f * span - c;
    int f = (int)floorf(c);
    f = max(0, min(f, S - 1));
    i0 = f;
    i1 = min(f + 1, S - 1);
    w1 = c - (float)f;
    w0 = 1.0f - w1;
}

// ------------------ K0: weight prep (fragment-ordered bf16) ----------------
__global__ __launch_bounds__(256) void k_prep(const float* __restrict__ Wq,
                                              const float* __restrict__ Wkv,
                                              const float* __restrict__ Wout,
                                              const float* __restrict__ c1w,
                                              const float* __restrict__ c2w,
                                              unsigned short* __restrict__ WF,
                                              unsigned short* __restrict__ WFo,
                                              unsigned short* __restrict__ BF1,
                                              unsigned short* __restrict__ BF2) {
    int tid = blockIdx.x * 256 + threadIdx.x;
    if (tid < 11264) {
        int e = tid & 3;
        int l = (tid >> 2) & 63;
        int kt = (tid >> 8) & 3;
        int nt = tid >> 10;
        int g = l >> 4, li = l & 15;
        int k = 16 * kt + 4 * g + e;
        int col = 16 * nt + li;
        float v = 0.f;
        if (k < 56 && col < 168)
            v = (col < 56) ? Wq[k * 56 + col] : Wkv[k * 112 + (col - 56)];
        WF[tid] = f2bf(v);
    } else if (tid < 15360) {
        int t2 = tid - 11264;
        int e = t2 & 3;
        int l = (t2 >> 2) & 63;
        int kt = (t2 >> 8) & 3;
        int nt = t2 >> 10;
        int g = l >> 4, li = l & 15;
        int k = 16 * kt + 4 * g + e;
        int col = 16 * nt + li;
        float v = (k < 56 && col < 56) ? Wout[k * 56 + col] : 0.f;
        WFo[t2] = f2bf(v);
    } else if (tid < 19968) {
        int t2 = tid - 15360;  // 4608 entries
        int e = t2 & 3;
        int l = (t2 >> 2) & 63;
        int rest = t2 >> 8;    // t*2+kg
        int kg = rest & 1;
        int t = rest >> 1;
        int g = l >> 4, li = l & 15;
        int c = 16 * kg + 4 * g + e;
        float v = (c < 28) ? c1w[li * 252 + c * 9 + t] : 0.f;
        unsigned short h = f2bf(v);
        BF1[t2] = h;
        BF1[4608 + t2] = f2bf(v - bf2f(h));
    } else if (tid < 22272) {
        int t2 = tid - 19968;  // 2304 entries
        int e = t2 & 3;
        int l = (t2 >> 2) & 63;
        int t = t2 >> 8;
        int g = l >> 4, li = l & 15;
        int c = 4 * g + e;
        float v = c2w[li * 144 + c * 9 + t];
        unsigned short h = f2bf(v);
        BF2[t2] = h;
        BF2[2304 + t2] = f2bf(v - bf2f(h));
    }
}

// ------------------- K1: QKV GEMM (bf16 MFMA, prepped B) -------------------
// Block: 64 pixels x 168 cols. LDS: Ah bf16 [64][68] 8704B | st bf16 [64][172]
// 22016B = 30720B total.
__global__ __launch_bounds__(256) void k_qkv(const float* __restrict__ x,
                                             const unsigned short* __restrict__ WF,
                                             unsigned short* __restrict__ q1,
                                             unsigned short* __restrict__ k1,
                                             unsigned short* __restrict__ v1,
                                             unsigned short* __restrict__ q2,
                                             unsigned short* __restrict__ k2,
                                             unsigned short* __restrict__ v2,
                                             unsigned short* __restrict__ ssum) {
    extern __shared__ __align__(16) char smem[];
    unsigned short* Ah = (unsigned short*)smem;            // [64][68]
    unsigned short* st = (unsigned short*)(smem + 8704);   // [64][172]
    int tid = threadIdx.x;
    int w = tid >> 6;
    int l = tid & 63;
    int g = l >> 4;
    int li = l & 15;
    int pix0 = blockIdx.x * 64;
    for (int e = tid; e < 1792; e += 256) {
        int row = e / 28;
        int hp = e - row * 28;
        float2 v = *(const float2*)(x + (size_t)pix0 * 56 + 2 * e);
        ((unsigned*)Ah)[row * 34 + hp] = pk_bf16(v.x, v.y);
    }
    for (int e = tid; e < 384; e += 256) {
        int row = e / 6;
        ((unsigned*)Ah)[row * 34 + 28 + (e - row * 6)] = 0;
    }
    int nt0 = 3 * w;
    int nnt = (w < 3) ? 3 : 2;
    bf4 B[3][4];
#pragma unroll
    for (int t = 0; t < 3; ++t) {
        if (t >= nnt) break;
#pragma unroll
        for (int kt = 0; kt < 4; ++kt)
            B[t][kt] = *(const bf4*)(WF + (((nt0 + t) * 4 + kt) * 64 + l) * 4);
    }
    __syncthreads();
    f4 acc[4][3];
#pragma unroll
    for (int mi = 0; mi < 4; ++mi)
#pragma unroll
        for (int t = 0; t < 3; ++t) acc[mi][t] = (f4){0.f, 0.f, 0.f, 0.f};
#pragma unroll
    for (int mi = 0; mi < 4; ++mi) {
        bf4 a[4];
#pragma unroll
        for (int kt = 0; kt < 4; ++kt)
            a[kt] = *(const bf4*)(Ah + (16 * mi + li) * 68 + 16 * kt + 4 * g);
#pragma unroll
        for (int t = 0; t < 3; ++t) {
            if (t >= nnt) break;
#pragma unroll
            for (int kt = 0; kt < 4; ++kt)
                acc[mi][t] = mfma16(a[kt], B[t][kt], acc[mi][t]);
        }
    }
#pragma unroll
    for (int mi = 0; mi < 4; ++mi)
#pragma unroll
        for (int t = 0; t < 3; ++t) {
            if (t >= nnt) break;
            int col = 16 * (nt0 + t) + li;
            if (col < 168) {
#pragma unroll
                for (int r = 0; r < 4; ++r)
                    st[(16 * mi + 4 * g + r) * 172 + col] = f2bf(acc[mi][t][r]);
            }
        }
    __syncthreads();
    // ---- ssum: one (row, 14-col slice) per thread; st cols: q|k|v at 0/56/112
    {
        int row = tid >> 2;
        int qq = tid & 3;
        int pixel = pix0 + row;
        int b = pixel >> 14;
        int rem = pixel & 16383;
        int hh = rem >> 7;
        int ww = rem & 127;
        int n = ((hh >> 3) << 4) + (ww >> 3);
        int m = ((hh & 7) << 3) + (ww & 7);
        size_t ob = ((size_t)(b * 256 + n) * 64 + m) * 56 + 14 * qq;
        const unsigned short* sr = st + row * 172 + 14 * qq;
#pragma unroll
        for (int h = 0; h < 7; ++h) {
            unsigned qw = *(const unsigned*)(sr + 2 * h);
            unsigned kw = *(const unsigned*)(sr + 56 + 2 * h);
            unsigned vw = *(const unsigned*)(sr + 112 + 2 * h);
            float s0 = __uint_as_float(qw << 16) + __uint_as_float(kw << 16) +
                       __uint_as_float(vw << 16);
            float s1 = __uint_as_float(qw & 0xffff0000u) + __uint_as_float(kw & 0xffff0000u) +
                       __uint_as_float(vw & 0xffff0000u);
            *(unsigned*)(ssum + ob + 2 * h) = pk_bf16(s0, s1);
        }
    }
    // ---- array half-rows: 384 tasks of 7 uint2 copies ----
    for (int e = tid; e < 384; e += 256) {
        int row = e / 6;
        int half = e - row * 6;
        int pixel = pix0 + row;
        int b = pixel >> 14;
        int rem = pixel & 16383;
        int hh = rem >> 7;
        int ww = rem & 127;
        int n = ((hh >> 3) << 4) + (ww >> 3);
        int m = ((hh & 7) << 3) + (ww & 7);
        size_t p1 = ((size_t)(b * 256 + n) * 64 + m) * 28;
        size_t p2 = ((size_t)(b * 64 + m) * 256 + n) * 28;
        unsigned short* base =
            (half < 2) ? (half == 0 ? q1 + p1 : q2 + p2)
                       : (half < 4) ? (half == 2 ? k1 + p1 : k2 + p2)
                                    : (half == 4 ? v1 + p1 : v2 + p2);
        const unsigned short* src = st + row * 172 + half * 28;
#pragma unroll
        for (int h = 0; h < 7; ++h)
            *(uint2*)(base + 4 * h) = *(const uint2*)(src + 4 * h);
    }
}

// ---------------- K2: conv1, implicit-GEMM MFMA (bf16, hi/lo B) ------------
// Tile stride 36 u16 (72B): bank stride 18 -> 16 distinct banks for the
// 16-lane A-fragment reads (was 32 u16 = 64B -> 8-way conflict).
__global__ __launch_bounds__(256) void k_conv1(const unsigned short* __restrict__ ssum,
                                               const unsigned short* __restrict__ BF1,
                                               const float* __restrict__ c1b,
                                               unsigned short* __restrict__ c1o) {
    __shared__ __align__(16) unsigned short tile[6 * 66 * 36];
    int tid = threadIdx.x;
    int w = tid >> 6;
    int l = tid & 63;
    int g = l >> 4;
    int li = l & 15;
    int wg = blockIdx.x;
    int br = wg >> 9;
    int b = (wg >> 6) & 7;
    int nt = wg & 63;
    int n0 = nt * 4;
    for (int e = tid; e < 11088; e += 256) {
        int c = e % 28;
        int rest = e / 28;
        int mm = rest % 66;
        int nr = rest / 66;
        int n = n0 - 1 + nr;
        int m = mm - 1;
        unsigned short v = 0;
        if (n >= 0 && n < 256 && m >= 0 && m < 64)
            v = ssum[(((size_t)b * 256 + n) * 64 + m) * 56 + br * 28 + c];
        tile[(nr * 66 + mm) * 36 + c] = v;
    }
    for (int e = tid; e < 1584; e += 256) {
        int rm = e >> 2;
        tile[rm * 36 + 28 + (e & 3)] = 0;
    }
    bf4 Bh[9][2], Bl[9][2];
#pragma unroll
    for (int t = 0; t < 9; ++t)
#pragma unroll
        for (int kg = 0; kg < 2; ++kg) {
            Bh[t][kg] = *(const bf4*)(BF1 + ((t * 2 + kg) * 64 + l) * 4);
            Bl[t][kg] = *(const bf4*)(BF1 + 4608 + ((t * 2 + kg) * 64 + l) * 4);
        }
    __syncthreads();
    f4 acc[4];
#pragma unroll
    for (int mt = 0; mt < 4; ++mt) acc[mt] = (f4){0.f, 0.f, 0.f, 0.f};
#pragma unroll
    for (int mt = 0; mt < 4; ++mt) {
#pragma unroll
        for (int t = 0; t < 9; ++t) {
            int ky = t / 3, kx = t - 3 * (t / 3);
#pragma unroll
            for (int kg = 0; kg < 2; ++kg) {
                bf4 a = *(const bf4*)(tile + ((w + ky) * 66 + 16 * mt + li + kx) * 36 +
                                      16 * kg + 4 * g);
                acc[mt] = mfma16(a, Bh[t][kg], acc[mt]);
                acc[mt] = mfma16(a, Bl[t][kg], acc[mt]);
            }
        }
    }
    float bias = c1b[li];
    size_t combo = (size_t)(br * 8 + b);
#pragma unroll
    for (int mt = 0; mt < 4; ++mt)
#pragma unroll
        for (int r = 0; r < 4; ++r) {
            int m = 16 * mt + 4 * g + r;
            float v = fmaxf(acc[mt][r] + bias, 0.f);
            c1o[(combo * 16384 + (size_t)(n0 + w) * 64 + m) * 16 + li] = f2bf(v);
        }
}

// ------------- K3: conv2 + pooled partials, implicit-GEMM MFMA -------------
// Tile stride 20 u16 (40B): bank stride 10 -> distinct banks (was 32B, 4-way).
__global__ __launch_bounds__(256) void k_conv2(const unsigned short* __restrict__ c1o,
                                               const unsigned short* __restrict__ BF2,
                                               const float* __restrict__ c2b,
                                               float* __restrict__ part) {
    __shared__ __align__(16) unsigned short tile[6 * 66 * 20];
    __shared__ float pbuf[4][16];
    int tid = threadIdx.x;
    int w = tid >> 6;
    int l = tid & 63;
    int g = l >> 4;
    int li = l & 15;
    int wg = blockIdx.x;
    int br = wg >> 9;
    int b = (wg >> 6) & 7;
    int nt = wg & 63;
    int n0 = nt * 4;
    size_t combo = (size_t)(br * 8 + b);
    for (int e = tid; e < 6336; e += 256) {
        int c = e & 15;
        int rest = e >> 4;
        int mm = rest % 66;
        int nr = rest / 66;
        int n = n0 - 1 + nr;
        int m = mm - 1;
        unsigned short v = 0;
        if (n >= 0 && n < 256 && m >= 0 && m < 64)
            v = c1o[(combo * 16384 + (size_t)n * 64 + m) * 16 + c];
        tile[(nr * 66 + mm) * 20 + c] = v;
    }
    bf4 Bh[9], Bl[9];
#pragma unroll
    for (int t = 0; t < 9; ++t) {
        Bh[t] = *(const bf4*)(BF2 + (t * 64 + l) * 4);
        Bl[t] = *(const bf4*)(BF2 + 2304 + (t * 64 + l) * 4);
    }
    __syncthreads();
    f4 acc[4];
#pragma unroll
    for (int mt = 0; mt < 4; ++mt) acc[mt] = (f4){0.f, 0.f, 0.f, 0.f};
#pragma unroll
    for (int mt = 0; mt < 4; ++mt) {
#pragma unroll
        for (int t = 0; t < 9; ++t) {
            int ky = t / 3, kx = t - 3 * (t / 3);
            bf4 a = *(const bf4*)(tile + ((w + ky) * 66 + 16 * mt + li + kx) * 20 + 4 * g);
            acc[mt] = mfma16(a, Bh[t], acc[mt]);
            acc[mt] = mfma16(a, Bl[t], acc[mt]);
        }
    }
    float bias = c2b[li];
    float s = 0.f;
#pragma unroll
    for (int mt = 0; mt < 4; ++mt)
#pragma unroll
        for (int r = 0; r < 4; ++r) s += fmaxf(acc[mt][r] + bias, 0.f);
    s += __shfl_xor(s, 16);
    s += __shfl_xor(s, 32);
    if (l < 16) pbuf[w][li] = s;
    __syncthreads();
    if (tid < 16) {
        float tot = pbuf[0][tid] + pbuf[1][tid] + pbuf[2][tid] + pbuf[3][tid];
        part[(combo * 64 + nt) * 16 + tid] = tot;
    }
}

// ------------------------- K4: reduce + FC -> shifts -----------------------
__global__ void k_fc(const float* __restrict__ part, const float* __restrict__ f1w,
                     const float* __restrict__ f1b, const float* __restrict__ f2w,
                     const float* __restrict__ f2b, float* __restrict__ shif) {
    __shared__ float sb[16][16];
    int t = threadIdx.x;
    int combo = t >> 4;
    int o = t & 15;
    float s = 0.f;
    for (int nt = 0; nt < 64; ++nt) s += part[((size_t)combo * 64 + nt) * 16 + o];
    sb[combo][o] = s * (1.0f / 16384.0f);
    __syncthreads();
    if (t < 16) {
        float p0 = f1b[0], p1 = f1b[1], rg = f2b[0];
        for (int oo = 0; oo < 16; ++oo) {
            float sv = sb[t][oo];
            p0 += sv * f1w[oo * 2 + 0];
            p1 += sv * f1w[oo * 2 + 1];
            rg += sv * f2w[oo];
        }
        shif[t * 2 + 0] = rg * tanhf(p0);
        shif[t * 2 + 1] = rg * tanhf(p1);
    }
}

// ------------------------- K5a/b: shifted pos precompute -------------------
__global__ __launch_bounds__(256) void k_pos1(const float* __restrict__ pos1,
                                              const float* __restrict__ shif,
                                              float* __restrict__ P1T,
                                              float* __restrict__ P1M) {
    __shared__ float plds[64 * 64];
    int b = blockIdx.x;
    float sx = shif[b * 2 + 0];
    float sy = shif[b * 2 + 1];
    for (int e = threadIdx.x; e < 4096; e += 256) {
        int j = e >> 6;
        int i = e & 63;
        int y0, y1, x0, x1;
        float wy0, wy1, wx0, wx1;
        coords_(i, 64, sy, y0, y1, wy0, wy1);
        coords_(j, 64, sx, x0, x1, wx0, wx1);
        float v = pos1[((i - 1) & 63) * 64 + ((j - 1) & 63)] +
                  wy0 * (wx0 * pos1[y0 * 64 + x0] + wx1 * pos1[y0 * 64 + x1]) +
                  wy1 * (wx0 * pos1[y1 * 64 + x0] + wx1 * pos1[y1 * 64 + x1]);
        P1T[(size_t)b * 4096 + j * 64 + i] = v;
        plds[j * 64 + i] = v;
    }
    __syncthreads();
    if (threadIdx.x < 64) {
        float mx = plds[threadIdx.x];
        for (int j = 1; j < 64; ++j) mx = fmaxf(mx, plds[j * 64 + threadIdx.x]);
        P1M[b * 64 + threadIdx.x] = mx;
    }
}

__global__ __launch_bounds__(256) void k_pos2(const float* __restrict__ pos2,
                                              const float* __restrict__ shif,
                                              float* __restrict__ P2R,
                                              float* __restrict__ P2M) {
    __shared__ float red[4];
    int wg = blockIdx.x;
    int b = wg >> 8;
    int i = wg & 255;
    float sx = shif[16 + b * 2 + 0];
    float sy = shif[16 + b * 2 + 1];
    int j = threadIdx.x;
    int y0, y1, x0, x1;
    float wy0, wy1, wx0, wx1;
    coords_(i, 256, sy, y0, y1, wy0, wy1);
    coords_(j, 256, sx, x0, x1, wx0, wx1);
    float v = pos2[((i - 1) & 255) * 256 + ((j - 1) & 255)] +
              wy0 * (wx0 * pos2[y0 * 256 + x0] + wx1 * pos2[y0 * 256 + x1]) +
              wy1 * (wx0 * pos2[y1 * 256 + x0] + wx1 * pos2[y1 * 256 + x1]);
    P2R[(size_t)b * 65536 + (size_t)i * 256 + j] = v;
    float mx = v;
#pragma unroll
    for (int msk = 1; msk < 64; msk <<= 1) mx = fmaxf(mx, __shfl_xor(mx, msk));
    if ((threadIdx.x & 63) == 0) red[threadIdx.x >> 6] = mx;
    __syncthreads();
    if (threadIdx.x == 0)
        P2M[b * 256 + i] = fmaxf(fmaxf(red[0], red[1]), fmaxf(red[2], red[3]));
}

// ---------------- K5c: transpose P2R -> P2T[b][j][i] (64x64 tiles) ---------
__global__ __launch_bounds__(256) void k_posT(const float* __restrict__ P2R,
                                              float* __restrict__ P2T) {
    __shared__ float t[64][65];
    int blk = blockIdx.x;     // 128 = 8 b x 16 tiles
    int b = blk >> 4;
    int t4 = blk & 15;
    int i0 = (t4 >> 2) * 64;
    int j0 = (t4 & 3) * 64;
    int tr = threadIdx.x >> 6;
    int tc = threadIdx.x & 63;
    for (int rr = 0; rr < 64; rr += 4)
        t[rr + tr][tc] = P2R[(size_t)b * 65536 + (size_t)(i0 + rr + tr) * 256 + j0 + tc];
    __syncthreads();
    for (int rr = 0; rr < 64; rr += 4)
        P2T[(size_t)b * 65536 + (size_t)(j0 + rr + tr) * 256 + i0 + tc] = t[tc][rr + tr];
}

// --------------- K6: branch-1 window attention (64x64), MFMA ---------------
__global__ __launch_bounds__(256) void k_attn1(const unsigned short* __restrict__ q1,
                                               const unsigned short* __restrict__ k1,
                                               const unsigned short* __restrict__ v1,
                                               const float* __restrict__ P1T,
                                               const float* __restrict__ P1M,
                                               const float* __restrict__ shif,
                                               unsigned short* __restrict__ aout) {
    __shared__ __align__(16) unsigned short qraw[64 * 28];
    __shared__ __align__(16) unsigned short kraw[64 * 28];
    __shared__ __align__(16) unsigned short augK[64 * 68];
    __shared__ __align__(16) unsigned short vT[32 * 68];
    __shared__ __align__(16) unsigned short Pw[4][16 * 68];
    int tid = threadIdx.x;
    int w = tid >> 6;
    int l = tid & 63;
    int g = l >> 4;
    int li = l & 15;
    int wg = blockIdx.x;
    int b = wg >> 8;
    int n = wg & 255;
    size_t gb = (size_t)(b * 256 + n) * 1792;
    float sx = shif[b * 2 + 0];
    float sy = shif[b * 2 + 1];
    for (int e = tid; e < 1792; e += 256) {
        qraw[e] = q1[gb + e];
        kraw[e] = k1[gb + e];
        int j = e / 28;
        int c = e - j * 28;
        vT[c * 68 + j] = v1[gb + e];
    }
    for (int e = tid; e < 272; e += 256) vT[28 * 68 + e] = 0;
    __syncthreads();
    if (tid < 64) {
        int j = tid;
        int x0, x1;
        float wx0, wx1;
        coords_(j, 64, sx, x0, x1, wx0, wx1);
        int rm = (j - 1) & 63;
        unsigned* row = (unsigned*)(augK + j * 68);
        const unsigned* src = (const unsigned*)(kraw + rm * 28);
#pragma unroll
        for (int h = 0; h < 14; ++h) row[h] = src[h];
#pragma unroll
        for (int h = 0; h < 14; ++h) {
            float a0 = wx0 * bf2f(kraw[x0 * 28 + 2 * h]) + wx1 * bf2f(kraw[x1 * 28 + 2 * h]);
            float a1 = wx0 * bf2f(kraw[x0 * 28 + 2 * h + 1]) + wx1 * bf2f(kraw[x1 * 28 + 2 * h + 1]);
            row[14 + h] = pk_bf16(a0, a1);
        }
#pragma unroll
        for (int h = 28; h < 34; ++h) row[h] = 0;
    }
    bf4 qf[4];
    {
        int i = 16 * w + li;
        int y0, y1;
        float wy0, wy1;
        coords_(i, 64, sy, y0, y1, wy0, wy1);
        int rm = (i - 1) & 63;
#pragma unroll
        for (int kt = 0; kt < 4; ++kt) {
            float qv[4];
#pragma unroll
            for (int e = 0; e < 4; ++e) {
                int d = 16 * kt + 4 * g + e;
                float v;
                if (d < 28) v = SCALE_ * bf2f(qraw[rm * 28 + d]);
                else if (d < 56)
                    v = SCALE_ * (wy0 * bf2f(qraw[y0 * 28 + d - 28]) +
                                  wy1 * bf2f(qraw[y1 * 28 + d - 28]));
                else v = 0.f;
                qv[e] = v;
            }
            union { unsigned u[2]; bf4 v; } cv;
            cv.u[0] = pk_bf16(qv[0], qv[1]);
            cv.u[1] = pk_bf16(qv[2], qv[3]);
            qf[kt] = cv.v;
        }
    }
    f4 Mv = *(const f4*)(P1M + b * 64 + 16 * w + 4 * g);
    __syncthreads();
    f4 acc[4];
#pragma unroll
    for (int nj = 0; nj < 4; ++nj)
        acc[nj] = *(const f4*)(P1T + (size_t)b * 4096 + (16 * nj + li) * 64 + 16 * w + 4 * g);
#pragma unroll
    for (int nj = 0; nj < 4; ++nj) {
        const unsigned short* kr = augK + (16 * nj + li) * 68 + 4 * g;
#pragma unroll
        for (int kt = 0; kt < 4; ++kt) {
            bf4 bk = *(const bf4*)(kr + 16 * kt);
            acc[nj] = mfma16(qf[kt], bk, acc[nj]);
        }
    }
    float lr[4] = {0.f, 0.f, 0.f, 0.f};
    unsigned short* Pww = Pw[w];
#pragma unroll
    for (int nj = 0; nj < 4; ++nj)
#pragma unroll
        for (int r = 0; r < 4; ++r) {
            float p = __expf(acc[nj][r] - Mv[r]);
            lr[r] += p;
            Pww[(4 * g + r) * 68 + 16 * nj + li] = f2bf(p);
        }
    f4 accv[2];
    accv[0] = (f4){0.f, 0.f, 0.f, 0.f};
    accv[1] = (f4){0.f, 0.f, 0.f, 0.f};
#pragma unroll
    for (int kt = 0; kt < 4; ++kt) {
        bf4 pa = *(const bf4*)(Pww + li * 68 + 16 * kt + 4 * g);
#pragma unroll
        for (int nc = 0; nc < 2; ++nc) {
            bf4 bv = *(const bf4*)(vT + (16 * nc + li) * 68 + 16 * kt + 4 * g);
            accv[nc] = mfma16(pa, bv, accv[nc]);
        }
    }
#pragma unroll
    for (int r = 0; r < 4; ++r) {
#pragma unroll
        for (int msk = 1; msk < 16; msk <<= 1) lr[r] += __shfl_xor(lr[r], msk);
        float invl = 1.0f / lr[r];
        int i = 16 * w + 4 * g + r;
        size_t wb = ((size_t)(b * 256 + n) * 64 + i) * 56;
        aout[wb + li] = f2bf(accv[0][r] * invl);
        if (li < 12) aout[wb + 16 + li] = f2bf(accv[1][r] * invl);
    }
}

// -------------------- K7: branch-2 cross-window attn, MFMA -----------------
__global__ __launch_bounds__(512) void k_attn2(const unsigned short* __restrict__ q2,
                                               const unsigned short* __restrict__ k2,
                                               const unsigned short* __restrict__ v2,
                                               const float* __restrict__ P2T,
                                               const float* __restrict__ P2M,
                                               const float* __restrict__ shif,
                                               unsigned short* __restrict__ aout) {
    extern __shared__ __align__(16) char smem[];
    unsigned short* augK = (unsigned short*)smem;                  // [256][68]
    unsigned short* vT = (unsigned short*)(smem + 34816);          // [28][260]
    int tid = threadIdx.x;
    int w = tid >> 6;
    int l = tid & 63;
    int g = l >> 4;
    int li = l & 15;
    unsigned short* Pw = (unsigned short*)(smem + 49376) + w * 2176;  // [32][68]
    int bm = blockIdx.x;
    int b = bm >> 6;
    int m = bm & 63;
    size_t gbase = (size_t)bm * 7168;
    float sx = shif[16 + b * 2 + 0];
    float sy = shif[16 + b * 2 + 1];
    if (tid < 256) {
        int j = tid;
        int x0, x1;
        float wx0, wx1;
        coords_(j, 256, sx, x0, x1, wx0, wx1);
        int rm = (j - 1) & 255;
        const unsigned short* krm = k2 + gbase + (size_t)rm * 28;
        const unsigned short* ka = k2 + gbase + (size_t)x0 * 28;
        const unsigned short* kb = k2 + gbase + (size_t)x1 * 28;
        unsigned* row = (unsigned*)(augK + j * 68);
        const unsigned* src = (const unsigned*)krm;
#pragma unroll
        for (int h = 0; h < 14; ++h) row[h] = src[h];
#pragma unroll
        for (int h = 0; h < 14; ++h) {
            float a0 = wx0 * bf2f(ka[2 * h]) + wx1 * bf2f(kb[2 * h]);
            float a1 = wx0 * bf2f(ka[2 * h + 1]) + wx1 * bf2f(kb[2 * h + 1]);
            row[14 + h] = pk_bf16(a0, a1);
        }
#pragma unroll
        for (int h = 28; h < 34; ++h) row[h] = 0;
    } else {
        int j = tid - 256;
        const unsigned short* vr = v2 + gbase + (size_t)j * 28;
#pragma unroll
        for (int c = 0; c < 28; ++c) vT[c * 260 + j] = vr[c];
    }
    bf4 qf[2][4];
#pragma unroll
    for (int mi = 0; mi < 2; ++mi) {
        int i = 32 * w + 16 * mi + li;
        int y0, y1;
        float wy0, wy1;
        coords_(i, 256, sy, y0, y1, wy0, wy1);
        int rm = (i - 1) & 255;
        const unsigned short* qrm = q2 + gbase + (size_t)rm * 28;
        const unsigned short* qa = q2 + gbase + (size_t)y0 * 28;
        const unsigned short* qb = q2 + gbase + (size_t)y1 * 28;
#pragma unroll
        for (int kt = 0; kt < 4; ++kt) {
            float qv[4];
#pragma unroll
            for (int e = 0; e < 4; ++e) {
                int d = 16 * kt + 4 * g + e;
                float v;
                if (d < 28) v = SCALE_ * bf2f(qrm[d]);
                else if (d < 56)
                    v = SCALE_ * (wy0 * bf2f(qa[d - 28]) + wy1 * bf2f(qb[d - 28]));
                else v = 0.f;
                qv[e] = v;
            }
            union { unsigned u[2]; bf4 v; } cv;
            cv.u[0] = pk_bf16(qv[0], qv[1]);
            cv.u[1] = pk_bf16(qv[2], qv[3]);
            qf[mi][kt] = cv.v;
        }
    }
    float M[2][4];
#pragma unroll
    for (int mi = 0; mi < 2; ++mi)
#pragma unroll
        for (int r = 0; r < 4; ++r)
            M[mi][r] = P2M[b * 256 + 32 * w + 16 * mi + 4 * g + r];
    __syncthreads();
    f4 accv[2][2];
#pragma unroll
    for (int mi = 0; mi < 2; ++mi)
#pragma unroll
        for (int nc = 0; nc < 2; ++nc) accv[mi][nc] = (f4){0.f, 0.f, 0.f, 0.f};
    float lrun[2][4];
#pragma unroll
    for (int mi = 0; mi < 2; ++mi)
#pragma unroll
        for (int r = 0; r < 4; ++r) lrun[mi][r] = 0.f;

    for (int jt = 0; jt < 4; ++jt) {
        f4 acc[2][4];
#pragma unroll
        for (int mi = 0; mi < 2; ++mi)
#pragma unroll
            for (int nj = 0; nj < 4; ++nj)
                acc[mi][nj] = *(const f4*)(P2T + (size_t)b * 65536 +
                                           (size_t)(64 * jt + 16 * nj + li) * 256 +
                                           32 * w + 16 * mi + 4 * g);
#pragma unroll
        for (int nj = 0; nj < 4; ++nj) {
            const unsigned short* kr = augK + (64 * jt + 16 * nj + li) * 68 + 4 * g;
            bf4 bk[4];
#pragma unroll
            for (int kt = 0; kt < 4; ++kt) bk[kt] = *(const bf4*)(kr + 16 * kt);
#pragma unroll
            for (int mi = 0; mi < 2; ++mi)
#pragma unroll
                for (int kt = 0; kt < 4; ++kt)
                    acc[mi][nj] = mfma16(qf[mi][kt], bk[kt], acc[mi][nj]);
        }
#pragma unroll
        for (int mi = 0; mi < 2; ++mi)
#pragma unroll
            for (int nj = 0; nj < 4; ++nj)
#pragma unroll
                for (int r = 0; r < 4; ++r) {
                    float p = __expf(acc[mi][nj][r] - M[mi][r]);
                    lrun[mi][r] += p;
                    Pw[(16 * mi + 4 * g + r) * 68 + 16 * nj + li] = f2bf(p);
                }
#pragma unroll
        for (int kt = 0; kt < 4; ++kt) {
            bf4 pa[2];
#pragma unroll
            for (int mi = 0; mi < 2; ++mi)
                pa[mi] = *(const bf4*)(Pw + (16 * mi + li) * 68 + 16 * kt + 4 * g);
#pragma unroll
            for (int nc = 0; nc < 2; ++nc) {
                bf4 bv = *(const bf4*)(vT + (16 * nc + li) * 260 + 64 * jt + 16 * kt + 4 * g);
#pragma unroll
                for (int mi = 0; mi < 2; ++mi)
                    accv[mi][nc] = mfma16(pa[mi], bv, accv[mi][nc]);
            }
        }
    }
#pragma unroll
    for (int mi = 0; mi < 2; ++mi)
#pragma unroll
        for (int r = 0; r < 4; ++r) {
#pragma unroll
            for (int msk = 1; msk < 16; msk <<= 1)
                lrun[mi][r] += __shfl_xor(lrun[mi][r], msk);
            float invl = 1.0f / lrun[mi][r];
            int gi = 32 * w + 16 * mi + 4 * g + r;
            size_t wb = (((size_t)b * 256 + gi) * 64 + m) * 56 + 28;
            aout[wb + li] = f2bf(accv[mi][0][r] * invl);
            if (li < 12) aout[wb + 16 + li] = f2bf(accv[mi][1][r] * invl);
        }
}

// ---------------- K8: output projection + unwindow (MFMA, prepped B) -------
__global__ __launch_bounds__(256) void k_out(const unsigned short* __restrict__ aout,
                                             const unsigned short* __restrict__ WFo,
                                             const float* __restrict__ bout,
                                             float* __restrict__ out) {
    __shared__ __align__(16) unsigned short Ah[64 * 68];
    __shared__ __align__(16) float st[64 * 60];
    int tid = threadIdx.x;
    int w = tid >> 6;
    int l = tid & 63;
    int g = l >> 4;
    int li = l & 15;
    int pix0 = blockIdx.x * 64;
    for (int e = tid; e < 896; e += 256) {
        int row = e / 14;
        int c4 = (e - row * 14) * 4;
        *(uint2*)(Ah + row * 68 + c4) = *(const uint2*)(aout + (size_t)pix0 * 56 + 4 * e);
    }
    for (int e = tid; e < 384; e += 256) {
        int row = e / 6;
        ((unsigned*)Ah)[row * 34 + 28 + (e - row * 6)] = 0;
    }
    bf4 Bo[4][4];
#pragma unroll
    for (int nt = 0; nt < 4; ++nt)
#pragma unroll
        for (int kt = 0; kt < 4; ++kt)
            Bo[nt][kt] = *(const bf4*)(WFo + ((nt * 4 + kt) * 64 + l) * 4);
    __syncthreads();
    f4 acc[4];
#pragma unroll
    for (int nt = 0; nt < 4; ++nt) acc[nt] = (f4){0.f, 0.f, 0.f, 0.f};
    bf4 ah[4];
#pragma unroll
    for (int kt = 0; kt < 4; ++kt)
        ah[kt] = *(const bf4*)(Ah + (16 * w + li) * 68 + 16 * kt + 4 * g);
#pragma unroll
    for (int nt = 0; nt < 4; ++nt)
#pragma unroll
        for (int kt = 0; kt < 4; ++kt)
            acc[nt] = mfma16(ah[kt], Bo[nt][kt], acc[nt]);
#pragma unroll
    for (int nt = 0; nt < 4; ++nt) {
        int col = 16 * nt + li;
        if (col < 56) {
#pragma unroll
            for (int r = 0; r < 4; ++r)
                st[(16 * w + 4 * g + r) * 60 + col] = acc[nt][r];
        }
    }
    __syncthreads();
    int row = tid >> 2;
    int qq = tid & 3;
    int pixel = pix0 + row;
    int b = pixel >> 14;
    int n = (pixel >> 6) & 255;
    int m = pixel & 63;
    int h = ((n >> 4) << 3) + (m >> 3);
    int ww = ((n & 15) << 3) + (m & 7);
    float* dst = out + (((size_t)b * 128 + h) * 128 + ww) * 56;
    const float* sr = st + row * 60;
#pragma unroll
    for (int cc = 0; cc < 14; ++cc) {
        int c = 14 * qq + cc;
        dst[c] = sr[c] + bout[c];
    }
}

// ---------------------------------------------------------------------------
extern "C" void kernel_launch(void* const* d_in, const int* in_sizes, int n_in,
                              void* d_out, int out_size, void* d_ws, size_t ws_size,
                              hipStream_t stream) {
    const float* x = (const float*)d_in[0];
    const float* pos1 = (const float*)d_in[1];
    const float* pos2 = (const float*)d_in[2];
    const float* Wq = (const float*)d_in[3];
    const float* Wkv = (const float*)d_in[4];
    const float* Wout = (const float*)d_in[5];
    const float* bout = (const float*)d_in[6];
    const float* c1w = (const float*)d_in[7];
    const float* c1b = (const float*)d_in[8];
    const float* c2w = (const float*)d_in[9];
    const float* c2b = (const float*)d_in[10];
    const float* f1w = (const float*)d_in[11];
    const float* f1b = (const float*)d_in[12];
    const float* f2w = (const float*)d_in[13];
    const float* f2b = (const float*)d_in[14];

    unsigned short* us = (unsigned short*)d_ws;
    unsigned short* q1 = us;
    unsigned short* k1 = us + 3670016;
    unsigned short* v1 = us + 7340032;
    unsigned short* q2 = us + 11010048;
    unsigned short* k2 = us + 14680064;
    unsigned short* v2 = us + 18350080;
    float* fb = (float*)d_ws + 11010048;
    unsigned short* ssb = (unsigned short*)fb;     // ssum bf16 [131072][56]
    unsigned short* aoutb = (unsigned short*)fb;   // aout bf16, overlays ssb
    unsigned short* c1o = (unsigned short*)(fb + 7340032);  // bf16 [16][16384][16]
    float* part = fb + 11534336;
    float* shif = fb + 11550720;
    float* P1T = fb + 11550752;
    float* P1M = fb + 11583520;
    float* P2R = fb + 11584032;
    float* P2M = fb + 12108320;
    unsigned short* WF = (unsigned short*)(fb + 12110368);
    unsigned short* WFo = WF + 11264;
    unsigned short* BF1 = WFo + 4096;   // 9216 u16 (hi 4608 | lo 4608)
    unsigned short* BF2 = BF1 + 9216;   // 4608 u16 (hi 2304 | lo 2304)
    float* P2T = (float*)(BF2 + 4608);  // [8][256][256] f32 (16B-aligned)
    float* outp = (float*)d_out;

    (void)hipFuncSetAttribute((const void*)k_qkv,
                              hipFuncAttributeMaxDynamicSharedMemorySize, 30720);
    (void)hipFuncSetAttribute((const void*)k_attn2,
                              hipFuncAttributeMaxDynamicSharedMemorySize, 84192);

    k_prep<<<87, 256, 0, stream>>>(Wq, Wkv, Wout, c1w, c2w, WF, WFo, BF1, BF2);
    k_qkv<<<2048, 256, 30720, stream>>>(x, WF, q1, k1, v1, q2, k2, v2, ssb);
    k_conv1<<<1024, 256, 0, stream>>>(ssb, BF1, c1b, c1o);
    k_conv2<<<1024, 256, 0, stream>>>(c1o, BF2, c2b, part);
    k_fc<<<1, 256, 0, stream>>>(part, f1w, f1b, f2w, f2b, shif);
    k_pos1<<<8, 256, 0, stream>>>(pos1, shif, P1T, P1M);
    k_pos2<<<2048, 256, 0, stream>>>(pos2, shif, P2R, P2M);
    k_posT<<<128, 256, 0, stream>>>(P2R, P2T);
    k_attn1<<<2048, 256, 0, stream>>>(q1, k1, v1, P1T, P1M, shif, aoutb);
    k_attn2<<<512, 512, 84192, stream>>>(q2, k2, v2, P2T, P2M, shif, aoutb);
    k_out<<<2048, 256, 0, stream>>>(aoutb, WFo, bout, outp);
}

// Round 11
// 160.350 us; speedup vs baseline: 5.1613x; 1.0340x over previous
//
#include <hip/hip_runtime.h>
#include <cstdint>

// ---------------------------------------------------------------------------
// SS-MSA fused implementation, round 11.
// grid_shift(sim) factorizes: shifted[i,j] = SCALE*(q_{i-1}.k_{j-1} + q~_i.k~_j) + P[i,j]
// => both branches are plain attention with 56-dim augmented Q/K + bias P.
//
// Round-11 changes vs round 10:
//  - k_attn2: process mi=0,1 SEQUENTIALLY per j-tile (QK->softmax->PV per mi).
//    Per-wave P tile halves to [16][68] -> LDS 84.2->66.8 KB -> 2 blocks/CU
//    (16 waves/CU, was 8). Bit-exact same math.
//  - k_pos: pos1+pos2 merged into one dispatch (blockIdx branch) -> one fewer
//    serialization boundary.
// ---------------------------------------------------------------------------

#define SCALE_ 0.18898223650461364f  // 28^-0.5

using f4 = __attribute__((ext_vector_type(4))) float;
using bf4 = __attribute__((ext_vector_type(4))) short;

__device__ __forceinline__ f4 mfma16(bf4 a, bf4 b, f4 c) {
#if __has_builtin(__builtin_amdgcn_mfma_f32_16x16x16bf16_1k)
    return __builtin_amdgcn_mfma_f32_16x16x16bf16_1k(a, b, c, 0, 0, 0);
#else
    f4 d;
    asm("v_mfma_f32_16x16x16_bf16 %0, %1, %2, %3" : "=v"(d) : "v"(a), "v"(b), "v"(c));
    return d;
#endif
}

__device__ __forceinline__ unsigned pk_bf16(float lo, float hi) {
    unsigned r;
    asm("v_cvt_pk_bf16_f32 %0, %1, %2" : "=v"(r) : "v"(lo), "v"(hi));
    return r;
}
__device__ __forceinline__ unsigned short f2bf(float f) {
    return (unsigned short)pk_bf16(f, f);
}
__device__ __forceinline__ float bf2f(unsigned short h) {
    return __uint_as_float(((unsigned)h) << 16);
}

__device__ __forceinline__ void coords_(int idx, int S, float s,
                                        int& i0, int& i1, float& w0, float& w1) {
    float g = -1.0f + 2.0f * (float)idx / (float)(S - 1);
    float c = (g + s * 2.0f / (float)S + 1.0f) * 0.5f * (float)(S - 1);
    float span = (float)(S - 1);
    c = fabsf(c);
    c = fmodf(c, 2.0f * span);
    if (c > span) c = 2.0f * span - c;
    int f = (int)floorf(c);
    f = max(0, min(f, S - 1));
    i0 = f;
    i1 = min(f + 1, S - 1);
    w1 = c - (float)f;
    w0 = 1.0f - w1;
}

// ------------------ K0: weight prep (fragment-ordered bf16) ----------------
__global__ __launch_bounds__(256) void k_prep(const float* __restrict__ Wq,
                                              const float* __restrict__ Wkv,
                                              const float* __restrict__ Wout,
                                              const float* __restrict__ c1w,
                                              const float* __restrict__ c2w,
                                              unsigned short* __restrict__ WF,
                                              unsigned short* __restrict__ WFo,
                                              unsigned short* __restrict__ BF1,
                                              unsigned short* __restrict__ BF2) {
    int tid = blockIdx.x * 256 + threadIdx.x;
    if (tid < 11264) {
        int e = tid & 3;
        int l = (tid >> 2) & 63;
        int kt = (tid >> 8) & 3;
        int nt = tid >> 10;
        int g = l >> 4, li = l & 15;
        int k = 16 * kt + 4 * g + e;
        int col = 16 * nt + li;
        float v = 0.f;
        if (k < 56 && col < 168)
            v = (col < 56) ? Wq[k * 56 + col] : Wkv[k * 112 + (col - 56)];
        WF[tid] = f2bf(v);
    } else if (tid < 15360) {
        int t2 = tid - 11264;
        int e = t2 & 3;
        int l = (t2 >> 2) & 63;
        int kt = (t2 >> 8) & 3;
        int nt = t2 >> 10;
        int g = l >> 4, li = l & 15;
        int k = 16 * kt + 4 * g + e;
        int col = 16 * nt + li;
        float v = (k < 56 && col < 56) ? Wout[k * 56 + col] : 0.f;
        WFo[t2] = f2bf(v);
    } else if (tid < 19968) {
        int t2 = tid - 15360;  // 4608 entries
        int e = t2 & 3;
        int l = (t2 >> 2) & 63;
        int rest = t2 >> 8;    // t*2+kg
        int kg = rest & 1;
        int t = rest >> 1;
        int g = l >> 4, li = l & 15;
        int c = 16 * kg + 4 * g + e;
        float v = (c < 28) ? c1w[li * 252 + c * 9 + t] : 0.f;
        unsigned short h = f2bf(v);
        BF1[t2] = h;
        BF1[4608 + t2] = f2bf(v - bf2f(h));
    } else if (tid < 22272) {
        int t2 = tid - 19968;  // 2304 entries
        int e = t2 & 3;
        int l = (t2 >> 2) & 63;
        int t = t2 >> 8;
        int g = l >> 4, li = l & 15;
        int c = 4 * g + e;
        float v = c2w[li * 144 + c * 9 + t];
        unsigned short h = f2bf(v);
        BF2[t2] = h;
        BF2[2304 + t2] = f2bf(v - bf2f(h));
    }
}

// ------------------- K1: QKV GEMM (bf16 MFMA, prepped B) -------------------
__global__ __launch_bounds__(256) void k_qkv(const float* __restrict__ x,
                                             const unsigned short* __restrict__ WF,
                                             unsigned short* __restrict__ q1,
                                             unsigned short* __restrict__ k1,
                                             unsigned short* __restrict__ v1,
                                             unsigned short* __restrict__ q2,
                                             unsigned short* __restrict__ k2,
                                             unsigned short* __restrict__ v2,
                                             unsigned short* __restrict__ ssum) {
    extern __shared__ __align__(16) char smem[];
    unsigned short* Ah = (unsigned short*)smem;            // [64][68]
    unsigned short* st = (unsigned short*)(smem + 8704);   // [64][172]
    int tid = threadIdx.x;
    int w = tid >> 6;
    int l = tid & 63;
    int g = l >> 4;
    int li = l & 15;
    int pix0 = blockIdx.x * 64;
    for (int e = tid; e < 1792; e += 256) {
        int row = e / 28;
        int hp = e - row * 28;
        float2 v = *(const float2*)(x + (size_t)pix0 * 56 + 2 * e);
        ((unsigned*)Ah)[row * 34 + hp] = pk_bf16(v.x, v.y);
    }
    for (int e = tid; e < 384; e += 256) {
        int row = e / 6;
        ((unsigned*)Ah)[row * 34 + 28 + (e - row * 6)] = 0;
    }
    int nt0 = 3 * w;
    int nnt = (w < 3) ? 3 : 2;
    bf4 B[3][4];
#pragma unroll
    for (int t = 0; t < 3; ++t) {
        if (t >= nnt) break;
#pragma unroll
        for (int kt = 0; kt < 4; ++kt)
            B[t][kt] = *(const bf4*)(WF + (((nt0 + t) * 4 + kt) * 64 + l) * 4);
    }
    __syncthreads();
    f4 acc[4][3];
#pragma unroll
    for (int mi = 0; mi < 4; ++mi)
#pragma unroll
        for (int t = 0; t < 3; ++t) acc[mi][t] = (f4){0.f, 0.f, 0.f, 0.f};
#pragma unroll
    for (int mi = 0; mi < 4; ++mi) {
        bf4 a[4];
#pragma unroll
        for (int kt = 0; kt < 4; ++kt)
            a[kt] = *(const bf4*)(Ah + (16 * mi + li) * 68 + 16 * kt + 4 * g);
#pragma unroll
        for (int t = 0; t < 3; ++t) {
            if (t >= nnt) break;
#pragma unroll
            for (int kt = 0; kt < 4; ++kt)
                acc[mi][t] = mfma16(a[kt], B[t][kt], acc[mi][t]);
        }
    }
#pragma unroll
    for (int mi = 0; mi < 4; ++mi)
#pragma unroll
        for (int t = 0; t < 3; ++t) {
            if (t >= nnt) break;
            int col = 16 * (nt0 + t) + li;
            if (col < 168) {
#pragma unroll
                for (int r = 0; r < 4; ++r)
                    st[(16 * mi + 4 * g + r) * 172 + col] = f2bf(acc[mi][t][r]);
            }
        }
    __syncthreads();
    // ---- ssum: one (row, 14-col slice) per thread; st cols: q|k|v at 0/56/112
    {
        int row = tid >> 2;
        int qq = tid & 3;
        int pixel = pix0 + row;
        int b = pixel >> 14;
        int rem = pixel & 16383;
        int hh = rem >> 7;
        int ww = rem & 127;
        int n = ((hh >> 3) << 4) + (ww >> 3);
        int m = ((hh & 7) << 3) + (ww & 7);
        size_t ob = ((size_t)(b * 256 + n) * 64 + m) * 56 + 14 * qq;
        const unsigned short* sr = st + row * 172 + 14 * qq;
#pragma unroll
        for (int h = 0; h < 7; ++h) {
            unsigned qw = *(const unsigned*)(sr + 2 * h);
            unsigned kw = *(const unsigned*)(sr + 56 + 2 * h);
            unsigned vw = *(const unsigned*)(sr + 112 + 2 * h);
            float s0 = __uint_as_float(qw << 16) + __uint_as_float(kw << 16) +
                       __uint_as_float(vw << 16);
            float s1 = __uint_as_float(qw & 0xffff0000u) + __uint_as_float(kw & 0xffff0000u) +
                       __uint_as_float(vw & 0xffff0000u);
            *(unsigned*)(ssum + ob + 2 * h) = pk_bf16(s0, s1);
        }
    }
    // ---- array half-rows: 384 tasks of 7 uint2 copies ----
    for (int e = tid; e < 384; e += 256) {
        int row = e / 6;
        int half = e - row * 6;
        int pixel = pix0 + row;
        int b = pixel >> 14;
        int rem = pixel & 16383;
        int hh = rem >> 7;
        int ww = rem & 127;
        int n = ((hh >> 3) << 4) + (ww >> 3);
        int m = ((hh & 7) << 3) + (ww & 7);
        size_t p1 = ((size_t)(b * 256 + n) * 64 + m) * 28;
        size_t p2 = ((size_t)(b * 64 + m) * 256 + n) * 28;
        unsigned short* base =
            (half < 2) ? (half == 0 ? q1 + p1 : q2 + p2)
                       : (half < 4) ? (half == 2 ? k1 + p1 : k2 + p2)
                                    : (half == 4 ? v1 + p1 : v2 + p2);
        const unsigned short* src = st + row * 172 + half * 28;
#pragma unroll
        for (int h = 0; h < 7; ++h)
            *(uint2*)(base + 4 * h) = *(const uint2*)(src + 4 * h);
    }
}

// ---------------- K2: conv1, implicit-GEMM MFMA (bf16, hi/lo B) ------------
__global__ __launch_bounds__(256) void k_conv1(const unsigned short* __restrict__ ssum,
                                               const unsigned short* __restrict__ BF1,
                                               const float* __restrict__ c1b,
                                               unsigned short* __restrict__ c1o) {
    __shared__ __align__(16) unsigned short tile[6 * 66 * 36];
    int tid = threadIdx.x;
    int w = tid >> 6;
    int l = tid & 63;
    int g = l >> 4;
    int li = l & 15;
    int wg = blockIdx.x;
    int br = wg >> 9;
    int b = (wg >> 6) & 7;
    int nt = wg & 63;
    int n0 = nt * 4;
    for (int e = tid; e < 11088; e += 256) {
        int c = e % 28;
        int rest = e / 28;
        int mm = rest % 66;
        int nr = rest / 66;
        int n = n0 - 1 + nr;
        int m = mm - 1;
        unsigned short v = 0;
        if (n >= 0 && n < 256 && m >= 0 && m < 64)
            v = ssum[(((size_t)b * 256 + n) * 64 + m) * 56 + br * 28 + c];
        tile[(nr * 66 + mm) * 36 + c] = v;
    }
    for (int e = tid; e < 1584; e += 256) {
        int rm = e >> 2;
        tile[rm * 36 + 28 + (e & 3)] = 0;
    }
    bf4 Bh[9][2], Bl[9][2];
#pragma unroll
    for (int t = 0; t < 9; ++t)
#pragma unroll
        for (int kg = 0; kg < 2; ++kg) {
            Bh[t][kg] = *(const bf4*)(BF1 + ((t * 2 + kg) * 64 + l) * 4);
            Bl[t][kg] = *(const bf4*)(BF1 + 4608 + ((t * 2 + kg) * 64 + l) * 4);
        }
    __syncthreads();
    f4 acc[4];
#pragma unroll
    for (int mt = 0; mt < 4; ++mt) acc[mt] = (f4){0.f, 0.f, 0.f, 0.f};
#pragma unroll
    for (int mt = 0; mt < 4; ++mt) {
#pragma unroll
        for (int t = 0; t < 9; ++t) {
            int ky = t / 3, kx = t - 3 * (t / 3);
#pragma unroll
            for (int kg = 0; kg < 2; ++kg) {
                bf4 a = *(const bf4*)(tile + ((w + ky) * 66 + 16 * mt + li + kx) * 36 +
                                      16 * kg + 4 * g);
                acc[mt] = mfma16(a, Bh[t][kg], acc[mt]);
                acc[mt] = mfma16(a, Bl[t][kg], acc[mt]);
            }
        }
    }
    float bias = c1b[li];
    size_t combo = (size_t)(br * 8 + b);
#pragma unroll
    for (int mt = 0; mt < 4; ++mt)
#pragma unroll
        for (int r = 0; r < 4; ++r) {
            int m = 16 * mt + 4 * g + r;
            float v = fmaxf(acc[mt][r] + bias, 0.f);
            c1o[(combo * 16384 + (size_t)(n0 + w) * 64 + m) * 16 + li] = f2bf(v);
        }
}

// ------------- K3: conv2 + pooled partials, implicit-GEMM MFMA -------------
__global__ __launch_bounds__(256) void k_conv2(const unsigned short* __restrict__ c1o,
                                               const unsigned short* __restrict__ BF2,
                                               const float* __restrict__ c2b,
                                               float* __restrict__ part) {
    __shared__ __align__(16) unsigned short tile[6 * 66 * 20];
    __shared__ float pbuf[4][16];
    int tid = threadIdx.x;
    int w = tid >> 6;
    int l = tid & 63;
    int g = l >> 4;
    int li = l & 15;
    int wg = blockIdx.x;
    int br = wg >> 9;
    int b = (wg >> 6) & 7;
    int nt = wg & 63;
    int n0 = nt * 4;
    size_t combo = (size_t)(br * 8 + b);
    for (int e = tid; e < 6336; e += 256) {
        int c = e & 15;
        int rest = e >> 4;
        int mm = rest % 66;
        int nr = rest / 66;
        int n = n0 - 1 + nr;
        int m = mm - 1;
        unsigned short v = 0;
        if (n >= 0 && n < 256 && m >= 0 && m < 64)
            v = c1o[(combo * 16384 + (size_t)n * 64 + m) * 16 + c];
        tile[(nr * 66 + mm) * 20 + c] = v;
    }
    bf4 Bh[9], Bl[9];
#pragma unroll
    for (int t = 0; t < 9; ++t) {
        Bh[t] = *(const bf4*)(BF2 + (t * 64 + l) * 4);
        Bl[t] = *(const bf4*)(BF2 + 2304 + (t * 64 + l) * 4);
    }
    __syncthreads();
    f4 acc[4];
#pragma unroll
    for (int mt = 0; mt < 4; ++mt) acc[mt] = (f4){0.f, 0.f, 0.f, 0.f};
#pragma unroll
    for (int mt = 0; mt < 4; ++mt) {
#pragma unroll
        for (int t = 0; t < 9; ++t) {
            int ky = t / 3, kx = t - 3 * (t / 3);
            bf4 a = *(const bf4*)(tile + ((w + ky) * 66 + 16 * mt + li + kx) * 20 + 4 * g);
            acc[mt] = mfma16(a, Bh[t], acc[mt]);
            acc[mt] = mfma16(a, Bl[t], acc[mt]);
        }
    }
    float bias = c2b[li];
    float s = 0.f;
#pragma unroll
    for (int mt = 0; mt < 4; ++mt)
#pragma unroll
        for (int r = 0; r < 4; ++r) s += fmaxf(acc[mt][r] + bias, 0.f);
    s += __shfl_xor(s, 16);
    s += __shfl_xor(s, 32);
    if (l < 16) pbuf[w][li] = s;
    __syncthreads();
    if (tid < 16) {
        float tot = pbuf[0][tid] + pbuf[1][tid] + pbuf[2][tid] + pbuf[3][tid];
        part[(combo * 64 + nt) * 16 + tid] = tot;
    }
}

// ------------------------- K4: reduce + FC -> shifts -----------------------
__global__ void k_fc(const float* __restrict__ part, const float* __restrict__ f1w,
                     const float* __restrict__ f1b, const float* __restrict__ f2w,
                     const float* __restrict__ f2b, float* __restrict__ shif) {
    __shared__ float sb[16][16];
    int t = threadIdx.x;
    int combo = t >> 4;
    int o = t & 15;
    float s = 0.f;
    for (int nt = 0; nt < 64; ++nt) s += part[((size_t)combo * 64 + nt) * 16 + o];
    sb[combo][o] = s * (1.0f / 16384.0f);
    __syncthreads();
    if (t < 16) {
        float p0 = f1b[0], p1 = f1b[1], rg = f2b[0];
        for (int oo = 0; oo < 16; ++oo) {
            float sv = sb[t][oo];
            p0 += sv * f1w[oo * 2 + 0];
            p1 += sv * f1w[oo * 2 + 1];
            rg += sv * f2w[oo];
        }
        shif[t * 2 + 0] = rg * tanhf(p0);
        shif[t * 2 + 1] = rg * tanhf(p1);
    }
}

// ----------------- K5: shifted pos precompute (pos2 | pos1) ----------------
// blocks 0..2047: pos2 (b,i); blocks 2048..2055: pos1 (b).
__global__ __launch_bounds__(256) void k_pos(const float* __restrict__ pos1,
                                             const float* __restrict__ pos2,
                                             const float* __restrict__ shif,
                                             float* __restrict__ P1T,
                                             float* __restrict__ P1M,
                                             float* __restrict__ P2R,
                                             float* __restrict__ P2M) {
    __shared__ float plds[64 * 64];
    if (blockIdx.x < 2048) {
        int wg = blockIdx.x;
        int b = wg >> 8;
        int i = wg & 255;
        float sx = shif[16 + b * 2 + 0];
        float sy = shif[16 + b * 2 + 1];
        int j = threadIdx.x;
        int y0, y1, x0, x1;
        float wy0, wy1, wx0, wx1;
        coords_(i, 256, sy, y0, y1, wy0, wy1);
        coords_(j, 256, sx, x0, x1, wx0, wx1);
        float v = pos2[((i - 1) & 255) * 256 + ((j - 1) & 255)] +
                  wy0 * (wx0 * pos2[y0 * 256 + x0] + wx1 * pos2[y0 * 256 + x1]) +
                  wy1 * (wx0 * pos2[y1 * 256 + x0] + wx1 * pos2[y1 * 256 + x1]);
        P2R[(size_t)b * 65536 + (size_t)i * 256 + j] = v;
        float mx = v;
#pragma unroll
        for (int msk = 1; msk < 64; msk <<= 1) mx = fmaxf(mx, __shfl_xor(mx, msk));
        if ((threadIdx.x & 63) == 0) plds[threadIdx.x >> 6] = mx;
        __syncthreads();
        if (threadIdx.x == 0)
            P2M[b * 256 + i] = fmaxf(fmaxf(plds[0], plds[1]), fmaxf(plds[2], plds[3]));
    } else {
        int b = blockIdx.x - 2048;
        float sx = shif[b * 2 + 0];
        float sy = shif[b * 2 + 1];
        for (int e = threadIdx.x; e < 4096; e += 256) {
            int j = e >> 6;
            int i = e & 63;
            int y0, y1, x0, x1;
            float wy0, wy1, wx0, wx1;
            coords_(i, 64, sy, y0, y1, wy0, wy1);
            coords_(j, 64, sx, x0, x1, wx0, wx1);
            float v = pos1[((i - 1) & 63) * 64 + ((j - 1) & 63)] +
                      wy0 * (wx0 * pos1[y0 * 64 + x0] + wx1 * pos1[y0 * 64 + x1]) +
                      wy1 * (wx0 * pos1[y1 * 64 + x0] + wx1 * pos1[y1 * 64 + x1]);
            P1T[(size_t)b * 4096 + j * 64 + i] = v;
            plds[j * 64 + i] = v;
        }
        __syncthreads();
        if (threadIdx.x < 64) {
            float mx = plds[threadIdx.x];
            for (int j = 1; j < 64; ++j) mx = fmaxf(mx, plds[j * 64 + threadIdx.x]);
            P1M[b * 64 + threadIdx.x] = mx;
        }
    }
}

// ---------------- K5c: transpose P2R -> P2T[b][j][i] (64x64 tiles) ---------
__global__ __launch_bounds__(256) void k_posT(const float* __restrict__ P2R,
                                              float* __restrict__ P2T) {
    __shared__ float t[64][65];
    int blk = blockIdx.x;     // 128 = 8 b x 16 tiles
    int b = blk >> 4;
    int t4 = blk & 15;
    int i0 = (t4 >> 2) * 64;
    int j0 = (t4 & 3) * 64;
    int tr = threadIdx.x >> 6;
    int tc = threadIdx.x & 63;
    for (int rr = 0; rr < 64; rr += 4)
        t[rr + tr][tc] = P2R[(size_t)b * 65536 + (size_t)(i0 + rr + tr) * 256 + j0 + tc];
    __syncthreads();
    for (int rr = 0; rr < 64; rr += 4)
        P2T[(size_t)b * 65536 + (size_t)(j0 + rr + tr) * 256 + i0 + tc] = t[tc][rr + tr];
}

// --------------- K6: branch-1 window attention (64x64), MFMA ---------------
__global__ __launch_bounds__(256) void k_attn1(const unsigned short* __restrict__ q1,
                                               const unsigned short* __restrict__ k1,
                                               const unsigned short* __restrict__ v1,
                                               const float* __restrict__ P1T,
                                               const float* __restrict__ P1M,
                                               const float* __restrict__ shif,
                                               unsigned short* __restrict__ aout) {
    __shared__ __align__(16) unsigned short qraw[64 * 28];
    __shared__ __align__(16) unsigned short kraw[64 * 28];
    __shared__ __align__(16) unsigned short augK[64 * 68];
    __shared__ __align__(16) unsigned short vT[32 * 68];
    __shared__ __align__(16) unsigned short Pw[4][16 * 68];
    int tid = threadIdx.x;
    int w = tid >> 6;
    int l = tid & 63;
    int g = l >> 4;
    int li = l & 15;
    int wg = blockIdx.x;
    int b = wg >> 8;
    int n = wg & 255;
    size_t gb = (size_t)(b * 256 + n) * 1792;
    float sx = shif[b * 2 + 0];
    float sy = shif[b * 2 + 1];
    for (int e = tid; e < 1792; e += 256) {
        qraw[e] = q1[gb + e];
        kraw[e] = k1[gb + e];
        int j = e / 28;
        int c = e - j * 28;
        vT[c * 68 + j] = v1[gb + e];
    }
    for (int e = tid; e < 272; e += 256) vT[28 * 68 + e] = 0;
    __syncthreads();
    if (tid < 64) {
        int j = tid;
        int x0, x1;
        float wx0, wx1;
        coords_(j, 64, sx, x0, x1, wx0, wx1);
        int rm = (j - 1) & 63;
        unsigned* row = (unsigned*)(augK + j * 68);
        const unsigned* src = (const unsigned*)(kraw + rm * 28);
#pragma unroll
        for (int h = 0; h < 14; ++h) row[h] = src[h];
#pragma unroll
        for (int h = 0; h < 14; ++h) {
            float a0 = wx0 * bf2f(kraw[x0 * 28 + 2 * h]) + wx1 * bf2f(kraw[x1 * 28 + 2 * h]);
            float a1 = wx0 * bf2f(kraw[x0 * 28 + 2 * h + 1]) + wx1 * bf2f(kraw[x1 * 28 + 2 * h + 1]);
            row[14 + h] = pk_bf16(a0, a1);
        }
#pragma unroll
        for (int h = 28; h < 34; ++h) row[h] = 0;
    }
    bf4 qf[4];
    {
        int i = 16 * w + li;
        int y0, y1;
        float wy0, wy1;
        coords_(i, 64, sy, y0, y1, wy0, wy1);
        int rm = (i - 1) & 63;
#pragma unroll
        for (int kt = 0; kt < 4; ++kt) {
            float qv[4];
#pragma unroll
            for (int e = 0; e < 4; ++e) {
                int d = 16 * kt + 4 * g + e;
                float v;
                if (d < 28) v = SCALE_ * bf2f(qraw[rm * 28 + d]);
                else if (d < 56)
                    v = SCALE_ * (wy0 * bf2f(qraw[y0 * 28 + d - 28]) +
                                  wy1 * bf2f(qraw[y1 * 28 + d - 28]));
                else v = 0.f;
                qv[e] = v;
            }
            union { unsigned u[2]; bf4 v; } cv;
            cv.u[0] = pk_bf16(qv[0], qv[1]);
            cv.u[1] = pk_bf16(qv[2], qv[3]);
            qf[kt] = cv.v;
        }
    }
    f4 Mv = *(const f4*)(P1M + b * 64 + 16 * w + 4 * g);
    __syncthreads();
    f4 acc[4];
#pragma unroll
    for (int nj = 0; nj < 4; ++nj)
        acc[nj] = *(const f4*)(P1T + (size_t)b * 4096 + (16 * nj + li) * 64 + 16 * w + 4 * g);
#pragma unroll
    for (int nj = 0; nj < 4; ++nj) {
        const unsigned short* kr = augK + (16 * nj + li) * 68 + 4 * g;
#pragma unroll
        for (int kt = 0; kt < 4; ++kt) {
            bf4 bk = *(const bf4*)(kr + 16 * kt);
            acc[nj] = mfma16(qf[kt], bk, acc[nj]);
        }
    }
    float lr[4] = {0.f, 0.f, 0.f, 0.f};
    unsigned short* Pww = Pw[w];
#pragma unroll
    for (int nj = 0; nj < 4; ++nj)
#pragma unroll
        for (int r = 0; r < 4; ++r) {
            float p = __expf(acc[nj][r] - Mv[r]);
            lr[r] += p;
            Pww[(4 * g + r) * 68 + 16 * nj + li] = f2bf(p);
        }
    f4 accv[2];
    accv[0] = (f4){0.f, 0.f, 0.f, 0.f};
    accv[1] = (f4){0.f, 0.f, 0.f, 0.f};
#pragma unroll
    for (int kt = 0; kt < 4; ++kt) {
        bf4 pa = *(const bf4*)(Pww + li * 68 + 16 * kt + 4 * g);
#pragma unroll
        for (int nc = 0; nc < 2; ++nc) {
            bf4 bv = *(const bf4*)(vT + (16 * nc + li) * 68 + 16 * kt + 4 * g);
            accv[nc] = mfma16(pa, bv, accv[nc]);
        }
    }
#pragma unroll
    for (int r = 0; r < 4; ++r) {
#pragma unroll
        for (int msk = 1; msk < 16; msk <<= 1) lr[r] += __shfl_xor(lr[r], msk);
        float invl = 1.0f / lr[r];
        int i = 16 * w + 4 * g + r;
        size_t wb = ((size_t)(b * 256 + n) * 64 + i) * 56;
        aout[wb + li] = f2bf(accv[0][r] * invl);
        if (li < 12) aout[wb + 16 + li] = f2bf(accv[1][r] * invl);
    }
}

// -------------------- K7: branch-2 cross-window attn, MFMA -----------------
// Sequential mi: per-wave P tile [16][68] -> LDS 66784B -> 2 blocks/CU.
__global__ __launch_bounds__(512) void k_attn2(const unsigned short* __restrict__ q2,
                                               const unsigned short* __restrict__ k2,
                                               const unsigned short* __restrict__ v2,
                                               const float* __restrict__ P2T,
                                               const float* __restrict__ P2M,
                                               const float* __restrict__ shif,
                                               unsigned short* __restrict__ aout) {
    extern __shared__ __align__(16) char smem[];
    unsigned short* augK = (unsigned short*)smem;                  // [256][68]
    unsigned short* vT = (unsigned short*)(smem + 34816);          // [28][260]
    int tid = threadIdx.x;
    int w = tid >> 6;
    int l = tid & 63;
    int g = l >> 4;
    int li = l & 15;
    unsigned short* Pw = (unsigned short*)(smem + 49376) + w * 1088;  // [16][68]
    int bm = blockIdx.x;
    int b = bm >> 6;
    int m = bm & 63;
    size_t gbase = (size_t)bm * 7168;
    float sx = shif[16 + b * 2 + 0];
    float sy = shif[16 + b * 2 + 1];
    if (tid < 256) {
        int j = tid;
        int x0, x1;
        float wx0, wx1;
        coords_(j, 256, sx, x0, x1, wx0, wx1);
        int rm = (j - 1) & 255;
        const unsigned short* krm = k2 + gbase + (size_t)rm * 28;
        const unsigned short* ka = k2 + gbase + (size_t)x0 * 28;
        const unsigned short* kb = k2 + gbase + (size_t)x1 * 28;
        unsigned* row = (unsigned*)(augK + j * 68);
        const unsigned* src = (const unsigned*)krm;
#pragma unroll
        for (int h = 0; h < 14; ++h) row[h] = src[h];
#pragma unroll
        for (int h = 0; h < 14; ++h) {
            float a0 = wx0 * bf2f(ka[2 * h]) + wx1 * bf2f(kb[2 * h]);
            float a1 = wx0 * bf2f(ka[2 * h + 1]) + wx1 * bf2f(kb[2 * h + 1]);
            row[14 + h] = pk_bf16(a0, a1);
        }
#pragma unroll
        for (int h = 28; h < 34; ++h) row[h] = 0;
    } else {
        int j = tid - 256;
        const unsigned short* vr = v2 + gbase + (size_t)j * 28;
#pragma unroll
        for (int c = 0; c < 28; ++c) vT[c * 260 + j] = vr[c];
    }
    bf4 qf[2][4];
#pragma unroll
    for (int mi = 0; mi < 2; ++mi) {
        int i = 32 * w + 16 * mi + li;
        int y0, y1;
        float wy0, wy1;
        coords_(i, 256, sy, y0, y1, wy0, wy1);
        int rm = (i - 1) & 255;
        const unsigned short* qrm = q2 + gbase + (size_t)rm * 28;
        const unsigned short* qa = q2 + gbase + (size_t)y0 * 28;
        const unsigned short* qb = q2 + gbase + (size_t)y1 * 28;
#pragma unroll
        for (int kt = 0; kt < 4; ++kt) {
            float qv[4];
#pragma unroll
            for (int e = 0; e < 4; ++e) {
                int d = 16 * kt + 4 * g + e;
                float v;
                if (d < 28) v = SCALE_ * bf2f(qrm[d]);
                else if (d < 56)
                    v = SCALE_ * (wy0 * bf2f(qa[d - 28]) + wy1 * bf2f(qb[d - 28]));
                else v = 0.f;
                qv[e] = v;
            }
            union { unsigned u[2]; bf4 v; } cv;
            cv.u[0] = pk_bf16(qv[0], qv[1]);
            cv.u[1] = pk_bf16(qv[2], qv[3]);
            qf[mi][kt] = cv.v;
        }
    }
    float M[2][4];
#pragma unroll
    for (int mi = 0; mi < 2; ++mi)
#pragma unroll
        for (int r = 0; r < 4; ++r)
            M[mi][r] = P2M[b * 256 + 32 * w + 16 * mi + 4 * g + r];
    __syncthreads();
    f4 accv[2][2];
#pragma unroll
    for (int mi = 0; mi < 2; ++mi)
#pragma unroll
        for (int nc = 0; nc < 2; ++nc) accv[mi][nc] = (f4){0.f, 0.f, 0.f, 0.f};
    float lrun[2][4];
#pragma unroll
    for (int mi = 0; mi < 2; ++mi)
#pragma unroll
        for (int r = 0; r < 4; ++r) lrun[mi][r] = 0.f;

    for (int jt = 0; jt < 4; ++jt) {
#pragma unroll
        for (int mi = 0; mi < 2; ++mi) {
            f4 acc[4];
#pragma unroll
            for (int nj = 0; nj < 4; ++nj)
                acc[nj] = *(const f4*)(P2T + (size_t)b * 65536 +
                                       (size_t)(64 * jt + 16 * nj + li) * 256 +
                                       32 * w + 16 * mi + 4 * g);
#pragma unroll
            for (int nj = 0; nj < 4; ++nj) {
                const unsigned short* kr = augK + (64 * jt + 16 * nj + li) * 68 + 4 * g;
#pragma unroll
                for (int kt = 0; kt < 4; ++kt) {
                    bf4 bk = *(const bf4*)(kr + 16 * kt);
                    acc[nj] = mfma16(qf[mi][kt], bk, acc[nj]);
                }
            }
#pragma unroll
            for (int nj = 0; nj < 4; ++nj)
#pragma unroll
                for (int r = 0; r < 4; ++r) {
                    float p = __expf(acc[nj][r] - M[mi][r]);
                    lrun[mi][r] += p;
                    Pw[(4 * g + r) * 68 + 16 * nj + li] = f2bf(p);
                }
#pragma unroll
            for (int kt = 0; kt < 4; ++kt) {
                bf4 pa = *(const bf4*)(Pw + li * 68 + 16 * kt + 4 * g);
#pragma unroll
                for (int nc = 0; nc < 2; ++nc) {
                    bf4 bv = *(const bf4*)(vT + (16 * nc + li) * 260 + 64 * jt + 16 * kt + 4 * g);
                    accv[mi][nc] = mfma16(pa, bv, accv[mi][nc]);
                }
            }
        }
    }
#pragma unroll
    for (int mi = 0; mi < 2; ++mi)
#pragma unroll
        for (int r = 0; r < 4; ++r) {
#pragma unroll
            for (int msk = 1; msk < 16; msk <<= 1)
                lrun[mi][r] += __shfl_xor(lrun[mi][r], msk);
            float invl = 1.0f / lrun[mi][r];
            int gi = 32 * w + 16 * mi + 4 * g + r;
            size_t wb = (((size_t)b * 256 + gi) * 64 + m) * 56 + 28;
            aout[wb + li] = f2bf(accv[mi][0][r] * invl);
            if (li < 12) aout[wb + 16 + li] = f2bf(accv[mi][1][r] * invl);
        }
}

// ---------------- K8: output projection + unwindow (MFMA, prepped B) -------
__global__ __launch_bounds__(256) void k_out(const unsigned short* __restrict__ aout,
                                             const unsigned short* __restrict__ WFo,
                                             const float* __restrict__ bout,
                                             float* __restrict__ out) {
    __shared__ __align__(16) unsigned short Ah[64 * 68];
    __shared__ __align__(16) float st[64 * 60];
    int tid = threadIdx.x;
    int w = tid >> 6;
    int l = tid & 63;
    int g = l >> 4;
    int li = l & 15;
    int pix0 = blockIdx.x * 64;
    for (int e = tid; e < 896; e += 256) {
        int row = e / 14;
        int c4 = (e - row * 14) * 4;
        *(uint2*)(Ah + row * 68 + c4) = *(const uint2*)(aout + (size_t)pix0 * 56 + 4 * e);
    }
    for (int e = tid; e < 384; e += 256) {
        int row = e / 6;
        ((unsigned*)Ah)[row * 34 + 28 + (e - row * 6)] = 0;
    }
    bf4 Bo[4][4];
#pragma unroll
    for (int nt = 0; nt < 4; ++nt)
#pragma unroll
        for (int kt = 0; kt < 4; ++kt)
            Bo[nt][kt] = *(const bf4*)(WFo + ((nt * 4 + kt) * 64 + l) * 4);
    __syncthreads();
    f4 acc[4];
#pragma unroll
    for (int nt = 0; nt < 4; ++nt) acc[nt] = (f4){0.f, 0.f, 0.f, 0.f};
    bf4 ah[4];
#pragma unroll
    for (int kt = 0; kt < 4; ++kt)
        ah[kt] = *(const bf4*)(Ah + (16 * w + li) * 68 + 16 * kt + 4 * g);
#pragma unroll
    for (int nt = 0; nt < 4; ++nt)
#pragma unroll
        for (int kt = 0; kt < 4; ++kt)
            acc[nt] = mfma16(ah[kt], Bo[nt][kt], acc[nt]);
#pragma unroll
    for (int nt = 0; nt < 4; ++nt) {
        int col = 16 * nt + li;
        if (col < 56) {
#pragma unroll
            for (int r = 0; r < 4; ++r)
                st[(16 * w + 4 * g + r) * 60 + col] = acc[nt][r];
        }
    }
    __syncthreads();
    int row = tid >> 2;
    int qq = tid & 3;
    int pixel = pix0 + row;
    int b = pixel >> 14;
    int n = (pixel >> 6) & 255;
    int m = pixel & 63;
    int h = ((n >> 4) << 3) + (m >> 3);
    int ww = ((n & 15) << 3) + (m & 7);
    float* dst = out + (((size_t)b * 128 + h) * 128 + ww) * 56;
    const float* sr = st + row * 60;
#pragma unroll
    for (int cc = 0; cc < 14; ++cc) {
        int c = 14 * qq + cc;
        dst[c] = sr[c] + bout[c];
    }
}

// ---------------------------------------------------------------------------
extern "C" void kernel_launch(void* const* d_in, const int* in_sizes, int n_in,
                              void* d_out, int out_size, void* d_ws, size_t ws_size,
                              hipStream_t stream) {
    const float* x = (const float*)d_in[0];
    const float* pos1 = (const float*)d_in[1];
    const float* pos2 = (const float*)d_in[2];
    const float* Wq = (const float*)d_in[3];
    const float* Wkv = (const float*)d_in[4];
    const float* Wout = (const float*)d_in[5];
    const float* bout = (const float*)d_in[6];
    const float* c1w = (const float*)d_in[7];
    const float* c1b = (const float*)d_in[8];
    const float* c2w = (const float*)d_in[9];
    const float* c2b = (const float*)d_in[10];
    const float* f1w = (const float*)d_in[11];
    const float* f1b = (const float*)d_in[12];
    const float* f2w = (const float*)d_in[13];
    const float* f2b = (const float*)d_in[14];

    unsigned short* us = (unsigned short*)d_ws;
    unsigned short* q1 = us;
    unsigned short* k1 = us + 3670016;
    unsigned short* v1 = us + 7340032;
    unsigned short* q2 = us + 11010048;
    unsigned short* k2 = us + 14680064;
    unsigned short* v2 = us + 18350080;
    float* fb = (float*)d_ws + 11010048;
    unsigned short* ssb = (unsigned short*)fb;     // ssum bf16 [131072][56]
    unsigned short* aoutb = (unsigned short*)fb;   // aout bf16, overlays ssb
    unsigned short* c1o = (unsigned short*)(fb + 7340032);  // bf16 [16][16384][16]
    float* part = fb + 11534336;
    float* shif = fb + 11550720;
    float* P1T = fb + 11550752;
    float* P1M = fb + 11583520;
    float* P2R = fb + 11584032;
    float* P2M = fb + 12108320;
    unsigned short* WF = (unsigned short*)(fb + 12110368);
    unsigned short* WFo = WF + 11264;
    unsigned short* BF1 = WFo + 4096;   // 9216 u16 (hi 4608 | lo 4608)
    unsigned short* BF2 = BF1 + 9216;   // 4608 u16 (hi 2304 | lo 2304)
    float* P2T = (float*)(BF2 + 4608);  // [8][256][256] f32 (16B-aligned)
    float* outp = (float*)d_out;

    (void)hipFuncSetAttribute((const void*)k_qkv,
                              hipFuncAttributeMaxDynamicSharedMemorySize, 30720);
    (void)hipFuncSetAttribute((const void*)k_attn2,
                              hipFuncAttributeMaxDynamicSharedMemorySize, 66784);

    k_prep<<<87, 256, 0, stream>>>(Wq, Wkv, Wout, c1w, c2w, WF, WFo, BF1, BF2);
    k_qkv<<<2048, 256, 30720, stream>>>(x, WF, q1, k1, v1, q2, k2, v2, ssb);
    k_conv1<<<1024, 256, 0, stream>>>(ssb, BF1, c1b, c1o);
    k_conv2<<<1024, 256, 0, stream>>>(c1o, BF2, c2b, part);
    k_fc<<<1, 256, 0, stream>>>(part, f1w, f1b, f2w, f2b, shif);
    k_pos<<<2056, 256, 0, stream>>>(pos1, pos2, shif, P1T, P1M, P2R, P2M);
    k_posT<<<128, 256, 0, stream>>>(P2R, P2T);
    k_attn1<<<2048, 256, 0, stream>>>(q1, k1, v1, P1T, P1M, shif, aoutb);
    k_attn2<<<512, 512, 66784, stream>>>(q2, k2, v2, P2T, P2M, shif, aoutb);
    k_out<<<2048, 256, 0, stream>>>(aoutb, WFo, bout, outp);
}

// Round 13
// 156.553 us; speedup vs baseline: 5.2865x; 1.0243x over previous
//
#include <hip/hip_runtime.h>
#include <cstdint>

// ---------------------------------------------------------------------------
// SS-MSA fused implementation, round 13 (= round 11 + isolated attn2 vector
// access change; round-12's bundle failed numerically and is discarded).
// grid_shift(sim) factorizes: shifted[i,j] = SCALE*(q_{i-1}.k_{j-1} + q~_i.k~_j) + P[i,j]
// => both branches are plain attention with 56-dim augmented Q/K + bias P.
//
// Round-13 change vs round 11 (passing, 160.3us):
//  - k_attn2 ONLY: Q fragments built from uint2 register loads with exact
//    per-(kt,g) source map (was ~42 scalar u16 global loads/thread); K/V
//    staging via uint2 loads (value-identical unpack). Everything else is
//    byte-identical to round 11.
// ---------------------------------------------------------------------------

#define SCALE_ 0.18898223650461364f  // 28^-0.5

using f4 = __attribute__((ext_vector_type(4))) float;
using bf4 = __attribute__((ext_vector_type(4))) short;

__device__ __forceinline__ f4 mfma16(bf4 a, bf4 b, f4 c) {
#if __has_builtin(__builtin_amdgcn_mfma_f32_16x16x16bf16_1k)
    return __builtin_amdgcn_mfma_f32_16x16x16bf16_1k(a, b, c, 0, 0, 0);
#else
    f4 d;
    asm("v_mfma_f32_16x16x16_bf16 %0, %1, %2, %3" : "=v"(d) : "v"(a), "v"(b), "v"(c));
    return d;
#endif
}

__device__ __forceinline__ unsigned pk_bf16(float lo, float hi) {
    unsigned r;
    asm("v_cvt_pk_bf16_f32 %0, %1, %2" : "=v"(r) : "v"(lo), "v"(hi));
    return r;
}
__device__ __forceinline__ unsigned short f2bf(float f) {
    return (unsigned short)pk_bf16(f, f);
}
__device__ __forceinline__ float bf2f(unsigned short h) {
    return __uint_as_float(((unsigned)h) << 16);
}
__device__ __forceinline__ bf4 pack4(float a, float b, float c, float d) {
    union { unsigned u[2]; bf4 v; } cv;
    cv.u[0] = pk_bf16(a, b);
    cv.u[1] = pk_bf16(c, d);
    return cv.v;
}

__device__ __forceinline__ void coords_(int idx, int S, float s,
                                        int& i0, int& i1, float& w0, float& w1) {
    float g = -1.0f + 2.0f * (float)idx / (float)(S - 1);
    float c = (g + s * 2.0f / (float)S + 1.0f) * 0.5f * (float)(S - 1);
    float span = (float)(S - 1);
    c = fabsf(c);
    c = fmodf(c, 2.0f * span);
    if (c > span) c = 2.0f * span - c;
    int f = (int)floorf(c);
    f = max(0, min(f, S - 1));
    i0 = f;
    i1 = min(f + 1, S - 1);
    w1 = c - (float)f;
    w0 = 1.0f - w1;
}

// ------------------ K0: weight prep (fragment-ordered bf16) ----------------
__global__ __launch_bounds__(256) void k_prep(const float* __restrict__ Wq,
                                              const float* __restrict__ Wkv,
                                              const float* __restrict__ Wout,
                                              const float* __restrict__ c1w,
                                              const float* __restrict__ c2w,
                                              unsigned short* __restrict__ WF,
                                              unsigned short* __restrict__ WFo,
                                              unsigned short* __restrict__ BF1,
                                              unsigned short* __restrict__ BF2) {
    int tid = blockIdx.x * 256 + threadIdx.x;
    if (tid < 11264) {
        int e = tid & 3;
        int l = (tid >> 2) & 63;
        int kt = (tid >> 8) & 3;
        int nt = tid >> 10;
        int g = l >> 4, li = l & 15;
        int k = 16 * kt + 4 * g + e;
        int col = 16 * nt + li;
        float v = 0.f;
        if (k < 56 && col < 168)
            v = (col < 56) ? Wq[k * 56 + col] : Wkv[k * 112 + (col - 56)];
        WF[tid] = f2bf(v);
    } else if (tid < 15360) {
        int t2 = tid - 11264;
        int e = t2 & 3;
        int l = (t2 >> 2) & 63;
        int kt = (t2 >> 8) & 3;
        int nt = t2 >> 10;
        int g = l >> 4, li = l & 15;
        int k = 16 * kt + 4 * g + e;
        int col = 16 * nt + li;
        float v = (k < 56 && col < 56) ? Wout[k * 56 + col] : 0.f;
        WFo[t2] = f2bf(v);
    } else if (tid < 19968) {
        int t2 = tid - 15360;  // 4608 entries
        int e = t2 & 3;
        int l = (t2 >> 2) & 63;
        int rest = t2 >> 8;    // t*2+kg
        int kg = rest & 1;
        int t = rest >> 1;
        int g = l >> 4, li = l & 15;
        int c = 16 * kg + 4 * g + e;
        float v = (c < 28) ? c1w[li * 252 + c * 9 + t] : 0.f;
        unsigned short h = f2bf(v);
        BF1[t2] = h;
        BF1[4608 + t2] = f2bf(v - bf2f(h));
    } else if (tid < 22272) {
        int t2 = tid - 19968;  // 2304 entries
        int e = t2 & 3;
        int l = (t2 >> 2) & 63;
        int t = t2 >> 8;
        int g = l >> 4, li = l & 15;
        int c = 4 * g + e;
        float v = c2w[li * 144 + c * 9 + t];
        unsigned short h = f2bf(v);
        BF2[t2] = h;
        BF2[2304 + t2] = f2bf(v - bf2f(h));
    }
}

// ------------------- K1: QKV GEMM (bf16 MFMA, prepped B) -------------------
__global__ __launch_bounds__(256) void k_qkv(const float* __restrict__ x,
                                             const unsigned short* __restrict__ WF,
                                             unsigned short* __restrict__ q1,
                                             unsigned short* __restrict__ k1,
                                             unsigned short* __restrict__ v1,
                                             unsigned short* __restrict__ q2,
                                             unsigned short* __restrict__ k2,
                                             unsigned short* __restrict__ v2,
                                             unsigned short* __restrict__ ssum) {
    extern __shared__ __align__(16) char smem[];
    unsigned short* Ah = (unsigned short*)smem;            // [64][68]
    unsigned short* st = (unsigned short*)(smem + 8704);   // [64][172]
    int tid = threadIdx.x;
    int w = tid >> 6;
    int l = tid & 63;
    int g = l >> 4;
    int li = l & 15;
    int pix0 = blockIdx.x * 64;
    for (int e = tid; e < 1792; e += 256) {
        int row = e / 28;
        int hp = e - row * 28;
        float2 v = *(const float2*)(x + (size_t)pix0 * 56 + 2 * e);
        ((unsigned*)Ah)[row * 34 + hp] = pk_bf16(v.x, v.y);
    }
    for (int e = tid; e < 384; e += 256) {
        int row = e / 6;
        ((unsigned*)Ah)[row * 34 + 28 + (e - row * 6)] = 0;
    }
    int nt0 = 3 * w;
    int nnt = (w < 3) ? 3 : 2;
    bf4 B[3][4];
#pragma unroll
    for (int t = 0; t < 3; ++t) {
        if (t >= nnt) break;
#pragma unroll
        for (int kt = 0; kt < 4; ++kt)
            B[t][kt] = *(const bf4*)(WF + (((nt0 + t) * 4 + kt) * 64 + l) * 4);
    }
    __syncthreads();
    f4 acc[4][3];
#pragma unroll
    for (int mi = 0; mi < 4; ++mi)
#pragma unroll
        for (int t = 0; t < 3; ++t) acc[mi][t] = (f4){0.f, 0.f, 0.f, 0.f};
#pragma unroll
    for (int mi = 0; mi < 4; ++mi) {
        bf4 a[4];
#pragma unroll
        for (int kt = 0; kt < 4; ++kt)
            a[kt] = *(const bf4*)(Ah + (16 * mi + li) * 68 + 16 * kt + 4 * g);
#pragma unroll
        for (int t = 0; t < 3; ++t) {
            if (t >= nnt) break;
#pragma unroll
            for (int kt = 0; kt < 4; ++kt)
                acc[mi][t] = mfma16(a[kt], B[t][kt], acc[mi][t]);
        }
    }
#pragma unroll
    for (int mi = 0; mi < 4; ++mi)
#pragma unroll
        for (int t = 0; t < 3; ++t) {
            if (t >= nnt) break;
            int col = 16 * (nt0 + t) + li;
            if (col < 168) {
#pragma unroll
                for (int r = 0; r < 4; ++r)
                    st[(16 * mi + 4 * g + r) * 172 + col] = f2bf(acc[mi][t][r]);
            }
        }
    __syncthreads();
    // ---- ssum: one (row, 14-col slice) per thread; st cols: q|k|v at 0/56/112
    {
        int row = tid >> 2;
        int qq = tid & 3;
        int pixel = pix0 + row;
        int b = pixel >> 14;
        int rem = pixel & 16383;
        int hh = rem >> 7;
        int ww = rem & 127;
        int n = ((hh >> 3) << 4) + (ww >> 3);
        int m = ((hh & 7) << 3) + (ww & 7);
        size_t ob = ((size_t)(b * 256 + n) * 64 + m) * 56 + 14 * qq;
        const unsigned short* sr = st + row * 172 + 14 * qq;
#pragma unroll
        for (int h = 0; h < 7; ++h) {
            unsigned qw = *(const unsigned*)(sr + 2 * h);
            unsigned kw = *(const unsigned*)(sr + 56 + 2 * h);
            unsigned vw = *(const unsigned*)(sr + 112 + 2 * h);
            float s0 = __uint_as_float(qw << 16) + __uint_as_float(kw << 16) +
                       __uint_as_float(vw << 16);
            float s1 = __uint_as_float(qw & 0xffff0000u) + __uint_as_float(kw & 0xffff0000u) +
                       __uint_as_float(vw & 0xffff0000u);
            *(unsigned*)(ssum + ob + 2 * h) = pk_bf16(s0, s1);
        }
    }
    // ---- array half-rows: 384 tasks of 7 uint2 copies ----
    for (int e = tid; e < 384; e += 256) {
        int row = e / 6;
        int half = e - row * 6;
        int pixel = pix0 + row;
        int b = pixel >> 14;
        int rem = pixel & 16383;
        int hh = rem >> 7;
        int ww = rem & 127;
        int n = ((hh >> 3) << 4) + (ww >> 3);
        int m = ((hh & 7) << 3) + (ww & 7);
        size_t p1 = ((size_t)(b * 256 + n) * 64 + m) * 28;
        size_t p2 = ((size_t)(b * 64 + m) * 256 + n) * 28;
        unsigned short* base =
            (half < 2) ? (half == 0 ? q1 + p1 : q2 + p2)
                       : (half < 4) ? (half == 2 ? k1 + p1 : k2 + p2)
                                    : (half == 4 ? v1 + p1 : v2 + p2);
        const unsigned short* src = st + row * 172 + half * 28;
#pragma unroll
        for (int h = 0; h < 7; ++h)
            *(uint2*)(base + 4 * h) = *(const uint2*)(src + 4 * h);
    }
}

// ---------------- K2: conv1, implicit-GEMM MFMA (bf16, hi/lo B) ------------
__global__ __launch_bounds__(256) void k_conv1(const unsigned short* __restrict__ ssum,
                                               const unsigned short* __restrict__ BF1,
                                               const float* __restrict__ c1b,
                                               unsigned short* __restrict__ c1o) {
    __shared__ __align__(16) unsigned short tile[6 * 66 * 36];
    int tid = threadIdx.x;
    int w = tid >> 6;
    int l = tid & 63;
    int g = l >> 4;
    int li = l & 15;
    int wg = blockIdx.x;
    int br = wg >> 9;
    int b = (wg >> 6) & 7;
    int nt = wg & 63;
    int n0 = nt * 4;
    for (int e = tid; e < 11088; e += 256) {
        int c = e % 28;
        int rest = e / 28;
        int mm = rest % 66;
        int nr = rest / 66;
        int n = n0 - 1 + nr;
        int m = mm - 1;
        unsigned short v = 0;
        if (n >= 0 && n < 256 && m >= 0 && m < 64)
            v = ssum[(((size_t)b * 256 + n) * 64 + m) * 56 + br * 28 + c];
        tile[(nr * 66 + mm) * 36 + c] = v;
    }
    for (int e = tid; e < 1584; e += 256) {
        int rm = e >> 2;
        tile[rm * 36 + 28 + (e & 3)] = 0;
    }
    bf4 Bh[9][2], Bl[9][2];
#pragma unroll
    for (int t = 0; t < 9; ++t)
#pragma unroll
        for (int kg = 0; kg < 2; ++kg) {
            Bh[t][kg] = *(const bf4*)(BF1 + ((t * 2 + kg) * 64 + l) * 4);
            Bl[t][kg] = *(const bf4*)(BF1 + 4608 + ((t * 2 + kg) * 64 + l) * 4);
        }
    __syncthreads();
    f4 acc[4];
#pragma unroll
    for (int mt = 0; mt < 4; ++mt) acc[mt] = (f4){0.f, 0.f, 0.f, 0.f};
#pragma unroll
    for (int mt = 0; mt < 4; ++mt) {
#pragma unroll
        for (int t = 0; t < 9; ++t) {
            int ky = t / 3, kx = t - 3 * (t / 3);
#pragma unroll
            for (int kg = 0; kg < 2; ++kg) {
                bf4 a = *(const bf4*)(tile + ((w + ky) * 66 + 16 * mt + li + kx) * 36 +
                                      16 * kg + 4 * g);
                acc[mt] = mfma16(a, Bh[t][kg], acc[mt]);
                acc[mt] = mfma16(a, Bl[t][kg], acc[mt]);
            }
        }
    }
    float bias = c1b[li];
    size_t combo = (size_t)(br * 8 + b);
#pragma unroll
    for (int mt = 0; mt < 4; ++mt)
#pragma unroll
        for (int r = 0; r < 4; ++r) {
            int m = 16 * mt + 4 * g + r;
            float v = fmaxf(acc[mt][r] + bias, 0.f);
            c1o[(combo * 16384 + (size_t)(n0 + w) * 64 + m) * 16 + li] = f2bf(v);
        }
}

// ------------- K3: conv2 + pooled partials, implicit-GEMM MFMA -------------
__global__ __launch_bounds__(256) void k_conv2(const unsigned short* __restrict__ c1o,
                                               const unsigned short* __restrict__ BF2,
                                               const float* __restrict__ c2b,
                                               float* __restrict__ part) {
    __shared__ __align__(16) unsigned short tile[6 * 66 * 20];
    __shared__ float pbuf[4][16];
    int tid = threadIdx.x;
    int w = tid >> 6;
    int l = tid & 63;
    int g = l >> 4;
    int li = l & 15;
    int wg = blockIdx.x;
    int br = wg >> 9;
    int b = (wg >> 6) & 7;
    int nt = wg & 63;
    int n0 = nt * 4;
    size_t combo = (size_t)(br * 8 + b);
    for (int e = tid; e < 6336; e += 256) {
        int c = e & 15;
        int rest = e >> 4;
        int mm = rest % 66;
        int nr = rest / 66;
        int n = n0 - 1 + nr;
        int m = mm - 1;
        unsigned short v = 0;
        if (n >= 0 && n < 256 && m >= 0 && m < 64)
            v = c1o[(combo * 16384 + (size_t)n * 64 + m) * 16 + c];
        tile[(nr * 66 + mm) * 20 + c] = v;
    }
    bf4 Bh[9], Bl[9];
#pragma unroll
    for (int t = 0; t < 9; ++t) {
        Bh[t] = *(const bf4*)(BF2 + (t * 64 + l) * 4);
        Bl[t] = *(const bf4*)(BF2 + 2304 + (t * 64 + l) * 4);
    }
    __syncthreads();
    f4 acc[4];
#pragma unroll
    for (int mt = 0; mt < 4; ++mt) acc[mt] = (f4){0.f, 0.f, 0.f, 0.f};
#pragma unroll
    for (int mt = 0; mt < 4; ++mt) {
#pragma unroll
        for (int t = 0; t < 9; ++t) {
            int ky = t / 3, kx = t - 3 * (t / 3);
            bf4 a = *(const bf4*)(tile + ((w + ky) * 66 + 16 * mt + li + kx) * 20 + 4 * g);
            acc[mt] = mfma16(a, Bh[t], acc[mt]);
            acc[mt] = mfma16(a, Bl[t], acc[mt]);
        }
    }
    float bias = c2b[li];
    float s = 0.f;
#pragma unroll
    for (int mt = 0; mt < 4; ++mt)
#pragma unroll
        for (int r = 0; r < 4; ++r) s += fmaxf(acc[mt][r] + bias, 0.f);
    s += __shfl_xor(s, 16);
    s += __shfl_xor(s, 32);
    if (l < 16) pbuf[w][li] = s;
    __syncthreads();
    if (tid < 16) {
        float tot = pbuf[0][tid] + pbuf[1][tid] + pbuf[2][tid] + pbuf[3][tid];
        part[(combo * 64 + nt) * 16 + tid] = tot;
    }
}

// ------------------------- K4: reduce + FC -> shifts -----------------------
__global__ void k_fc(const float* __restrict__ part, const float* __restrict__ f1w,
                     const float* __restrict__ f1b, const float* __restrict__ f2w,
                     const float* __restrict__ f2b, float* __restrict__ shif) {
    __shared__ float sb[16][16];
    int t = threadIdx.x;
    int combo = t >> 4;
    int o = t & 15;
    float s = 0.f;
    for (int nt = 0; nt < 64; ++nt) s += part[((size_t)combo * 64 + nt) * 16 + o];
    sb[combo][o] = s * (1.0f / 16384.0f);
    __syncthreads();
    if (t < 16) {
        float p0 = f1b[0], p1 = f1b[1], rg = f2b[0];
        for (int oo = 0; oo < 16; ++oo) {
            float sv = sb[t][oo];
            p0 += sv * f1w[oo * 2 + 0];
            p1 += sv * f1w[oo * 2 + 1];
            rg += sv * f2w[oo];
        }
        shif[t * 2 + 0] = rg * tanhf(p0);
        shif[t * 2 + 1] = rg * tanhf(p1);
    }
}

// ----------------- K5: shifted pos precompute (pos2 | pos1) ----------------
__global__ __launch_bounds__(256) void k_pos(const float* __restrict__ pos1,
                                             const float* __restrict__ pos2,
                                             const float* __restrict__ shif,
                                             float* __restrict__ P1T,
                                             float* __restrict__ P1M,
                                             float* __restrict__ P2R,
                                             float* __restrict__ P2M) {
    __shared__ float plds[64 * 64];
    if (blockIdx.x < 2048) {
        int wg = blockIdx.x;
        int b = wg >> 8;
        int i = wg & 255;
        float sx = shif[16 + b * 2 + 0];
        float sy = shif[16 + b * 2 + 1];
        int j = threadIdx.x;
        int y0, y1, x0, x1;
        float wy0, wy1, wx0, wx1;
        coords_(i, 256, sy, y0, y1, wy0, wy1);
        coords_(j, 256, sx, x0, x1, wx0, wx1);
        float v = pos2[((i - 1) & 255) * 256 + ((j - 1) & 255)] +
                  wy0 * (wx0 * pos2[y0 * 256 + x0] + wx1 * pos2[y0 * 256 + x1]) +
                  wy1 * (wx0 * pos2[y1 * 256 + x0] + wx1 * pos2[y1 * 256 + x1]);
        P2R[(size_t)b * 65536 + (size_t)i * 256 + j] = v;
        float mx = v;
#pragma unroll
        for (int msk = 1; msk < 64; msk <<= 1) mx = fmaxf(mx, __shfl_xor(mx, msk));
        if ((threadIdx.x & 63) == 0) plds[threadIdx.x >> 6] = mx;
        __syncthreads();
        if (threadIdx.x == 0)
            P2M[b * 256 + i] = fmaxf(fmaxf(plds[0], plds[1]), fmaxf(plds[2], plds[3]));
    } else {
        int b = blockIdx.x - 2048;
        float sx = shif[b * 2 + 0];
        float sy = shif[b * 2 + 1];
        for (int e = threadIdx.x; e < 4096; e += 256) {
            int j = e >> 6;
            int i = e & 63;
            int y0, y1, x0, x1;
            float wy0, wy1, wx0, wx1;
            coords_(i, 64, sy, y0, y1, wy0, wy1);
            coords_(j, 64, sx, x0, x1, wx0, wx1);
            float v = pos1[((i - 1) & 63) * 64 + ((j - 1) & 63)] +
                      wy0 * (wx0 * pos1[y0 * 64 + x0] + wx1 * pos1[y0 * 64 + x1]) +
                      wy1 * (wx0 * pos1[y1 * 64 + x0] + wx1 * pos1[y1 * 64 + x1]);
            P1T[(size_t)b * 4096 + j * 64 + i] = v;
            plds[j * 64 + i] = v;
        }
        __syncthreads();
        if (threadIdx.x < 64) {
            float mx = plds[threadIdx.x];
            for (int j = 1; j < 64; ++j) mx = fmaxf(mx, plds[j * 64 + threadIdx.x]);
            P1M[b * 64 + threadIdx.x] = mx;
        }
    }
}

// ---------------- K5c: transpose P2R -> P2T[b][j][i] (64x64 tiles) ---------
__global__ __launch_bounds__(256) void k_posT(const float* __restrict__ P2R,
                                              float* __restrict__ P2T) {
    __shared__ float t[64][65];
    int blk = blockIdx.x;     // 128 = 8 b x 16 tiles
    int b = blk >> 4;
    int t4 = blk & 15;
    int i0 = (t4 >> 2) * 64;
    int j0 = (t4 & 3) * 64;
    int tr = threadIdx.x >> 6;
    int tc = threadIdx.x & 63;
    for (int rr = 0; rr < 64; rr += 4)
        t[rr + tr][tc] = P2R[(size_t)b * 65536 + (size_t)(i0 + rr + tr) * 256 + j0 + tc];
    __syncthreads();
    for (int rr = 0; rr < 64; rr += 4)
        P2T[(size_t)b * 65536 + (size_t)(j0 + rr + tr) * 256 + i0 + tc] = t[tc][rr + tr];
}

// --------------- K6: branch-1 window attention (64x64), MFMA ---------------
__global__ __launch_bounds__(256) void k_attn1(const unsigned short* __restrict__ q1,
                                               const unsigned short* __restrict__ k1,
                                               const unsigned short* __restrict__ v1,
                                               const float* __restrict__ P1T,
                                               const float* __restrict__ P1M,
                                               const float* __restrict__ shif,
                                               unsigned short* __restrict__ aout) {
    __shared__ __align__(16) unsigned short qraw[64 * 28];
    __shared__ __align__(16) unsigned short kraw[64 * 28];
    __shared__ __align__(16) unsigned short augK[64 * 68];
    __shared__ __align__(16) unsigned short vT[32 * 68];
    __shared__ __align__(16) unsigned short Pw[4][16 * 68];
    int tid = threadIdx.x;
    int w = tid >> 6;
    int l = tid & 63;
    int g = l >> 4;
    int li = l & 15;
    int wg = blockIdx.x;
    int b = wg >> 8;
    int n = wg & 255;
    size_t gb = (size_t)(b * 256 + n) * 1792;
    float sx = shif[b * 2 + 0];
    float sy = shif[b * 2 + 1];
    for (int e = tid; e < 1792; e += 256) {
        qraw[e] = q1[gb + e];
        kraw[e] = k1[gb + e];
        int j = e / 28;
        int c = e - j * 28;
        vT[c * 68 + j] = v1[gb + e];
    }
    for (int e = tid; e < 272; e += 256) vT[28 * 68 + e] = 0;
    __syncthreads();
    if (tid < 64) {
        int j = tid;
        int x0, x1;
        float wx0, wx1;
        coords_(j, 64, sx, x0, x1, wx0, wx1);
        int rm = (j - 1) & 63;
        unsigned* row = (unsigned*)(augK + j * 68);
        const unsigned* src = (const unsigned*)(kraw + rm * 28);
#pragma unroll
        for (int h = 0; h < 14; ++h) row[h] = src[h];
#pragma unroll
        for (int h = 0; h < 14; ++h) {
            float a0 = wx0 * bf2f(kraw[x0 * 28 + 2 * h]) + wx1 * bf2f(kraw[x1 * 28 + 2 * h]);
            float a1 = wx0 * bf2f(kraw[x0 * 28 + 2 * h + 1]) + wx1 * bf2f(kraw[x1 * 28 + 2 * h + 1]);
            row[14 + h] = pk_bf16(a0, a1);
        }
#pragma unroll
        for (int h = 28; h < 34; ++h) row[h] = 0;
    }
    bf4 qf[4];
    {
        int i = 16 * w + li;
        int y0, y1;
        float wy0, wy1;
        coords_(i, 64, sy, y0, y1, wy0, wy1);
        int rm = (i - 1) & 63;
#pragma unroll
        for (int kt = 0; kt < 4; ++kt) {
            float qv[4];
#pragma unroll
            for (int e = 0; e < 4; ++e) {
                int d = 16 * kt + 4 * g + e;
                float v;
                if (d < 28) v = SCALE_ * bf2f(qraw[rm * 28 + d]);
                else if (d < 56)
                    v = SCALE_ * (wy0 * bf2f(qraw[y0 * 28 + d - 28]) +
                                  wy1 * bf2f(qraw[y1 * 28 + d - 28]));
                else v = 0.f;
                qv[e] = v;
            }
            union { unsigned u[2]; bf4 v; } cv;
            cv.u[0] = pk_bf16(qv[0], qv[1]);
            cv.u[1] = pk_bf16(qv[2], qv[3]);
            qf[kt] = cv.v;
        }
    }
    f4 Mv = *(const f4*)(P1M + b * 64 + 16 * w + 4 * g);
    __syncthreads();
    f4 acc[4];
#pragma unroll
    for (int nj = 0; nj < 4; ++nj)
        acc[nj] = *(const f4*)(P1T + (size_t)b * 4096 + (16 * nj + li) * 64 + 16 * w + 4 * g);
#pragma unroll
    for (int nj = 0; nj < 4; ++nj) {
        const unsigned short* kr = augK + (16 * nj + li) * 68 + 4 * g;
#pragma unroll
        for (int kt = 0; kt < 4; ++kt) {
            bf4 bk = *(const bf4*)(kr + 16 * kt);
            acc[nj] = mfma16(qf[kt], bk, acc[nj]);
        }
    }
    float lr[4] = {0.f, 0.f, 0.f, 0.f};
    unsigned short* Pww = Pw[w];
#pragma unroll
    for (int nj = 0; nj < 4; ++nj)
#pragma unroll
        for (int r = 0; r < 4; ++r) {
            float p = __expf(acc[nj][r] - Mv[r]);
            lr[r] += p;
            Pww[(4 * g + r) * 68 + 16 * nj + li] = f2bf(p);
        }
    f4 accv[2];
    accv[0] = (f4){0.f, 0.f, 0.f, 0.f};
    accv[1] = (f4){0.f, 0.f, 0.f, 0.f};
#pragma unroll
    for (int kt = 0; kt < 4; ++kt) {
        bf4 pa = *(const bf4*)(Pww + li * 68 + 16 * kt + 4 * g);
#pragma unroll
        for (int nc = 0; nc < 2; ++nc) {
            bf4 bv = *(const bf4*)(vT + (16 * nc + li) * 68 + 16 * kt + 4 * g);
            accv[nc] = mfma16(pa, bv, accv[nc]);
        }
    }
#pragma unroll
    for (int r = 0; r < 4; ++r) {
#pragma unroll
        for (int msk = 1; msk < 16; msk <<= 1) lr[r] += __shfl_xor(lr[r], msk);
        float invl = 1.0f / lr[r];
        int i = 16 * w + 4 * g + r;
        size_t wb = ((size_t)(b * 256 + n) * 64 + i) * 56;
        aout[wb + li] = f2bf(accv[0][r] * invl);
        if (li < 12) aout[wb + 16 + li] = f2bf(accv[1][r] * invl);
    }
}

// -------------------- K7: branch-2 cross-window attn, MFMA -----------------
// Sequential mi; Q fragments from uint2 register loads (per-(kt,g) map);
// K/V staging via uint2. LDS 66784B -> 2 blocks/CU. Values bit-identical
// to round 11.
__global__ __launch_bounds__(512) void k_attn2(const unsigned short* __restrict__ q2,
                                               const unsigned short* __restrict__ k2,
                                               const unsigned short* __restrict__ v2,
                                               const float* __restrict__ P2T,
                                               const float* __restrict__ P2M,
                                               const float* __restrict__ shif,
                                               unsigned short* __restrict__ aout) {
    extern __shared__ __align__(16) char smem[];
    unsigned short* augK = (unsigned short*)smem;                  // [256][68]
    unsigned short* vT = (unsigned short*)(smem + 34816);          // [28][260]
    int tid = threadIdx.x;
    int w = tid >> 6;
    int l = tid & 63;
    int g = l >> 4;
    int li = l & 15;
    unsigned short* Pw = (unsigned short*)(smem + 49376) + w * 1088;  // [16][68]
    int bm = blockIdx.x;
    int b = bm >> 6;
    int m = bm & 63;
    size_t gbase = (size_t)bm * 7168;
    float sx = shif[16 + b * 2 + 0];
    float sy = shif[16 + b * 2 + 1];
    if (tid < 256) {
        int j = tid;
        int x0, x1;
        float wx0, wx1;
        coords_(j, 256, sx, x0, x1, wx0, wx1);
        int rm = (j - 1) & 255;
        uint2* rowv = (uint2*)(augK + j * 68);
        const uint2* srcv = (const uint2*)(k2 + gbase + (size_t)rm * 28);
#pragma unroll
        for (int h = 0; h < 7; ++h) rowv[h] = srcv[h];
        const uint2* kav = (const uint2*)(k2 + gbase + (size_t)x0 * 28);
        const uint2* kbv = (const uint2*)(k2 + gbase + (size_t)x1 * 28);
        unsigned* row = (unsigned*)(augK + j * 68);
#pragma unroll
        for (int h = 0; h < 7; ++h) {
            uint2 va = kav[h], vb = kbv[h];
            float a0 = wx0 * bf2f((unsigned short)va.x) + wx1 * bf2f((unsigned short)vb.x);
            float a1 = wx0 * bf2f((unsigned short)(va.x >> 16)) +
                       wx1 * bf2f((unsigned short)(vb.x >> 16));
            float a2 = wx0 * bf2f((unsigned short)va.y) + wx1 * bf2f((unsigned short)vb.y);
            float a3 = wx0 * bf2f((unsigned short)(va.y >> 16)) +
                       wx1 * bf2f((unsigned short)(vb.y >> 16));
            row[14 + 2 * h] = pk_bf16(a0, a1);
            row[15 + 2 * h] = pk_bf16(a2, a3);
        }
#pragma unroll
        for (int h = 28; h < 34; ++h) row[h] = 0;
    } else {
        int j = tid - 256;
        const uint2* vrv = (const uint2*)(v2 + gbase + (size_t)j * 28);
#pragma unroll
        for (int h = 0; h < 7; ++h) {
            uint2 t = vrv[h];
            vT[(4 * h + 0) * 260 + j] = (unsigned short)t.x;
            vT[(4 * h + 1) * 260 + j] = (unsigned short)(t.x >> 16);
            vT[(4 * h + 2) * 260 + j] = (unsigned short)t.y;
            vT[(4 * h + 3) * 260 + j] = (unsigned short)(t.y >> 16);
        }
    }
    // ---- Q fragments via uint2 register loads; exact per-(kt,g) source map:
    //   kt0: d=4g+e           -> qrm uint2[g]          (plain)
    //   kt1: d=16+4g+e: g<3   -> qrm uint2[4+g] (plain); g==3 -> interp idx 0..3 = qa/qb uint2[0]
    //   kt2: d=32+4g+e        -> interp idx 4+4g+e  = qa/qb uint2[1+g]
    //   kt3: d=48+4g+e: g<2   -> interp idx 20+4g+e = qa/qb uint2[5+g]; g>=2 -> zero (d>=56)
    bf4 qf[2][4];
#pragma unroll
    for (int mi = 0; mi < 2; ++mi) {
        int i = 32 * w + 16 * mi + li;
        int y0, y1;
        float wy0, wy1;
        coords_(i, 256, sy, y0, y1, wy0, wy1);
        int rm = (i - 1) & 255;
        const uint2* qrmv = (const uint2*)(q2 + gbase + (size_t)rm * 28);
        const uint2* qav = (const uint2*)(q2 + gbase + (size_t)y0 * 28);
        const uint2* qbv = (const uint2*)(q2 + gbase + (size_t)y1 * 28);
        // kt0
        {
            uint2 r0 = qrmv[g];
            qf[mi][0] = pack4(SCALE_ * bf2f((unsigned short)r0.x),
                              SCALE_ * bf2f((unsigned short)(r0.x >> 16)),
                              SCALE_ * bf2f((unsigned short)r0.y),
                              SCALE_ * bf2f((unsigned short)(r0.y >> 16)));
        }
        // kt1
        if (g < 3) {
            uint2 r1 = qrmv[4 + g];
            qf[mi][1] = pack4(SCALE_ * bf2f((unsigned short)r1.x),
                              SCALE_ * bf2f((unsigned short)(r1.x >> 16)),
                              SCALE_ * bf2f((unsigned short)r1.y),
                              SCALE_ * bf2f((unsigned short)(r1.y >> 16)));
        } else {
            uint2 a = qav[0], bb = qbv[0];
            qf[mi][1] = pack4(
                SCALE_ * (wy0 * bf2f((unsigned short)a.x) + wy1 * bf2f((unsigned short)bb.x)),
                SCALE_ * (wy0 * bf2f((unsigned short)(a.x >> 16)) +
                          wy1 * bf2f((unsigned short)(bb.x >> 16))),
                SCALE_ * (wy0 * bf2f((unsigned short)a.y) + wy1 * bf2f((unsigned short)bb.y)),
                SCALE_ * (wy0 * bf2f((unsigned short)(a.y >> 16)) +
                          wy1 * bf2f((unsigned short)(bb.y >> 16))));
        }
        // kt2
        {
            uint2 a = qav[1 + g], bb = qbv[1 + g];
            qf[mi][2] = pack4(
                SCALE_ * (wy0 * bf2f((unsigned short)a.x) + wy1 * bf2f((unsigned short)bb.x)),
                SCALE_ * (wy0 * bf2f((unsigned short)(a.x >> 16)) +
                          wy1 * bf2f((unsigned short)(bb.x >> 16))),
                SCALE_ * (wy0 * bf2f((unsigned short)a.y) + wy1 * bf2f((unsigned short)bb.y)),
                SCALE_ * (wy0 * bf2f((unsigned short)(a.y >> 16)) +
                          wy1 * bf2f((unsigned short)(bb.y >> 16))));
        }
        // kt3
        if (g < 2) {
            uint2 a = qav[5 + g], bb = qbv[5 + g];
            qf[mi][3] = pack4(
                SCALE_ * (wy0 * bf2f((unsigned short)a.x) + wy1 * bf2f((unsigned short)bb.x)),
                SCALE_ * (wy0 * bf2f((unsigned short)(a.x >> 16)) +
                          wy1 * bf2f((unsigned short)(bb.x >> 16))),
                SCALE_ * (wy0 * bf2f((unsigned short)a.y) + wy1 * bf2f((unsigned short)bb.y)),
                SCALE_ * (wy0 * bf2f((unsigned short)(a.y >> 16)) +
                          wy1 * bf2f((unsigned short)(bb.y >> 16))));
        } else {
            union { unsigned u[2]; bf4 v; } cz;
            cz.u[0] = 0;
            cz.u[1] = 0;
            qf[mi][3] = cz.v;
        }
    }
    float M[2][4];
#pragma unroll
    for (int mi = 0; mi < 2; ++mi)
#pragma unroll
        for (int r = 0; r < 4; ++r)
            M[mi][r] = P2M[b * 256 + 32 * w + 16 * mi + 4 * g + r];
    __syncthreads();
    f4 accv[2][2];
#pragma unroll
    for (int mi = 0; mi < 2; ++mi)
#pragma unroll
        for (int nc = 0; nc < 2; ++nc) accv[mi][nc] = (f4){0.f, 0.f, 0.f, 0.f};
    float lrun[2][4];
#pragma unroll
    for (int mi = 0; mi < 2; ++mi)
#pragma unroll
        for (int r = 0; r < 4; ++r) lrun[mi][r] = 0.f;

    for (int jt = 0; jt < 4; ++jt) {
#pragma unroll
        for (int mi = 0; mi < 2; ++mi) {
            f4 acc[4];
#pragma unroll
            for (int nj = 0; nj < 4; ++nj)
                acc[nj] = *(const f4*)(P2T + (size_t)b * 65536 +
                                       (size_t)(64 * jt + 16 * nj + li) * 256 +
                                       32 * w + 16 * mi + 4 * g);
#pragma unroll
            for (int nj = 0; nj < 4; ++nj) {
                const unsigned short* kr = augK + (64 * jt + 16 * nj + li) * 68 + 4 * g;
#pragma unroll
                for (int kt = 0; kt < 4; ++kt) {
                    bf4 bk = *(const bf4*)(kr + 16 * kt);
                    acc[nj] = mfma16(qf[mi][kt], bk, acc[nj]);
                }
            }
#pragma unroll
            for (int nj = 0; nj < 4; ++nj)
#pragma unroll
                for (int r = 0; r < 4; ++r) {
                    float p = __expf(acc[nj][r] - M[mi][r]);
                    lrun[mi][r] += p;
                    Pw[(4 * g + r) * 68 + 16 * nj + li] = f2bf(p);
                }
#pragma unroll
            for (int kt = 0; kt < 4; ++kt) {
                bf4 pa = *(const bf4*)(Pw + li * 68 + 16 * kt + 4 * g);
#pragma unroll
                for (int nc = 0; nc < 2; ++nc) {
                    bf4 bv = *(const bf4*)(vT + (16 * nc + li) * 260 + 64 * jt + 16 * kt + 4 * g);
                    accv[mi][nc] = mfma16(pa, bv, accv[mi][nc]);
                }
            }
        }
    }
#pragma unroll
    for (int mi = 0; mi < 2; ++mi)
#pragma unroll
        for (int r = 0; r < 4; ++r) {
#pragma unroll
            for (int msk = 1; msk < 16; msk <<= 1)
                lrun[mi][r] += __shfl_xor(lrun[mi][r], msk);
            float invl = 1.0f / lrun[mi][r];
            int gi = 32 * w + 16 * mi + 4 * g + r;
            size_t wb = (((size_t)b * 256 + gi) * 64 + m) * 56 + 28;
            aout[wb + li] = f2bf(accv[mi][0][r] * invl);
            if (li < 12) aout[wb + 16 + li] = f2bf(accv[mi][1][r] * invl);
        }
}

// ---------------- K8: output projection + unwindow (MFMA, prepped B) -------
__global__ __launch_bounds__(256) void k_out(const unsigned short* __restrict__ aout,
                                             const unsigned short* __restrict__ WFo,
                                             const float* __restrict__ bout,
                                             float* __restrict__ out) {
    __shared__ __align__(16) unsigned short Ah[64 * 68];
    __shared__ __align__(16) float st[64 * 60];
    int tid = threadIdx.x;
    int w = tid >> 6;
    int l = tid & 63;
    int g = l >> 4;
    int li = l & 15;
    int pix0 = blockIdx.x * 64;
    for (int e = tid; e < 896; e += 256) {
        int row = e / 14;
        int c4 = (e - row * 14) * 4;
        *(uint2*)(Ah + row * 68 + c4) = *(const uint2*)(aout + (size_t)pix0 * 56 + 4 * e);
    }
    for (int e = tid; e < 384; e += 256) {
        int row = e / 6;
        ((unsigned*)Ah)[row * 34 + 28 + (e - row * 6)] = 0;
    }
    bf4 Bo[4][4];
#pragma unroll
    for (int nt = 0; nt < 4; ++nt)
#pragma unroll
        for (int kt = 0; kt < 4; ++kt)
            Bo[nt][kt] = *(const bf4*)(WFo + ((nt * 4 + kt) * 64 + l) * 4);
    __syncthreads();
    f4 acc[4];
#pragma unroll
    for (int nt = 0; nt < 4; ++nt) acc[nt] = (f4){0.f, 0.f, 0.f, 0.f};
    bf4 ah[4];
#pragma unroll
    for (int kt = 0; kt < 4; ++kt)
        ah[kt] = *(const bf4*)(Ah + (16 * w + li) * 68 + 16 * kt + 4 * g);
#pragma unroll
    for (int nt = 0; nt < 4; ++nt)
#pragma unroll
        for (int kt = 0; kt < 4; ++kt)
            acc[nt] = mfma16(ah[kt], Bo[nt][kt], acc[nt]);
#pragma unroll
    for (int nt = 0; nt < 4; ++nt) {
        int col = 16 * nt + li;
        if (col < 56) {
#pragma unroll
            for (int r = 0; r < 4; ++r)
                st[(16 * w + 4 * g + r) * 60 + col] = acc[nt][r];
        }
    }
    __syncthreads();
    int row = tid >> 2;
    int qq = tid & 3;
    int pixel = pix0 + row;
    int b = pixel >> 14;
    int n = (pixel >> 6) & 255;
    int m = pixel & 63;
    int h = ((n >> 4) << 3) + (m >> 3);
    int ww = ((n & 15) << 3) + (m & 7);
    float* dst = out + (((size_t)b * 128 + h) * 128 + ww) * 56;
    const float* sr = st + row * 60;
#pragma unroll
    for (int cc = 0; cc < 14; ++cc) {
        int c = 14 * qq + cc;
        dst[c] = sr[c] + bout[c];
    }
}

// ---------------------------------------------------------------------------
extern "C" void kernel_launch(void* const* d_in, const int* in_sizes, int n_in,
                              void* d_out, int out_size, void* d_ws, size_t ws_size,
                              hipStream_t stream) {
    const float* x = (const float*)d_in[0];
    const float* pos1 = (const float*)d_in[1];
    const float* pos2 = (const float*)d_in[2];
    const float* Wq = (const float*)d_in[3];
    const float* Wkv = (const float*)d_in[4];
    const float* Wout = (const float*)d_in[5];
    const float* bout = (const float*)d_in[6];
    const float* c1w = (const float*)d_in[7];
    const float* c1b = (const float*)d_in[8];
    const float* c2w = (const float*)d_in[9];
    const float* c2b = (const float*)d_in[10];
    const float* f1w = (const float*)d_in[11];
    const float* f1b = (const float*)d_in[12];
    const float* f2w = (const float*)d_in[13];
    const float* f2b = (const float*)d_in[14];

    unsigned short* us = (unsigned short*)d_ws;
    unsigned short* q1 = us;
    unsigned short* k1 = us + 3670016;
    unsigned short* v1 = us + 7340032;
    unsigned short* q2 = us + 11010048;
    unsigned short* k2 = us + 14680064;
    unsigned short* v2 = us + 18350080;
    float* fb = (float*)d_ws + 11010048;
    unsigned short* ssb = (unsigned short*)fb;     // ssum bf16 [131072][56]
    unsigned short* aoutb = (unsigned short*)fb;   // aout bf16, overlays ssb
    unsigned short* c1o = (unsigned short*)(fb + 7340032);  // bf16 [16][16384][16]
    float* part = fb + 11534336;
    float* shif = fb + 11550720;
    float* P1T = fb + 11550752;
    float* P1M = fb + 11583520;
    float* P2R = fb + 11584032;
    float* P2M = fb + 12108320;
    unsigned short* WF = (unsigned short*)(fb + 12110368);
    unsigned short* WFo = WF + 11264;
    unsigned short* BF1 = WFo + 4096;   // 9216 u16 (hi 4608 | lo 4608)
    unsigned short* BF2 = BF1 + 9216;   // 4608 u16 (hi 2304 | lo 2304)
    float* P2T = (float*)(BF2 + 4608);  // [8][256][256] f32 (16B-aligned)
    float* outp = (float*)d_out;

    (void)hipFuncSetAttribute((const void*)k_qkv,
                              hipFuncAttributeMaxDynamicSharedMemorySize, 30720);
    (void)hipFuncSetAttribute((const void*)k_attn2,
                              hipFuncAttributeMaxDynamicSharedMemorySize, 66784);

    k_prep<<<87, 256, 0, stream>>>(Wq, Wkv, Wout, c1w, c2w, WF, WFo, BF1, BF2);
    k_qkv<<<2048, 256, 30720, stream>>>(x, WF, q1, k1, v1, q2, k2, v2, ssb);
    k_conv1<<<1024, 256, 0, stream>>>(ssb, BF1, c1b, c1o);
    k_conv2<<<1024, 256, 0, stream>>>(c1o, BF2, c2b, part);
    k_fc<<<1, 256, 0, stream>>>(part, f1w, f1b, f2w, f2b, shif);
    k_pos<<<2056, 256, 0, stream>>>(pos1, pos2, shif, P1T, P1M, P2R, P2M);
    k_posT<<<128, 256, 0, stream>>>(P2R, P2T);
    k_attn1<<<2048, 256, 0, stream>>>(q1, k1, v1, P1T, P1M, shif, aoutb);
    k_attn2<<<512, 512, 66784, stream>>>(q2, k2, v2, P2T, P2M, shif, aoutb);
    k_out<<<2048, 256, 0, stream>>>(aoutb, WFo, bout, outp);
}

// Round 14
// 154.712 us; speedup vs baseline: 5.3494x; 1.0119x over previous
//
#include <hip/hip_runtime.h>
#include <cstdint>

// ---------------------------------------------------------------------------
// SS-MSA fused implementation, round 14 (= round 13 + the three value-
// identical access-width changes from round 12; the attn fusion piece stays
// excluded as the isolated suspect for R12's numeric failure).
// grid_shift(sim) factorizes: shifted[i,j] = SCALE*(q_{i-1}.k_{j-1} + q~_i.k~_j) + P[i,j]
// => both branches are plain attention with 56-dim augmented Q/K + bias P.
//
// Round-14 changes vs round 13 (passing, 156.6us):
//  - k_attn1: q/k staging via uint2 copies, V via uint2 + register scatter
//    (was 21 scalar u16 loads/thread ~= 11M VMEM issues).
//  - k_qkv: x staged via float4 (same pk_bf16 pair boundaries).
//  - k_out: float2 stores.
// ---------------------------------------------------------------------------

#define SCALE_ 0.18898223650461364f  // 28^-0.5

using f4 = __attribute__((ext_vector_type(4))) float;
using bf4 = __attribute__((ext_vector_type(4))) short;

__device__ __forceinline__ f4 mfma16(bf4 a, bf4 b, f4 c) {
#if __has_builtin(__builtin_amdgcn_mfma_f32_16x16x16bf16_1k)
    return __builtin_amdgcn_mfma_f32_16x16x16bf16_1k(a, b, c, 0, 0, 0);
#else
    f4 d;
    asm("v_mfma_f32_16x16x16_bf16 %0, %1, %2, %3" : "=v"(d) : "v"(a), "v"(b), "v"(c));
    return d;
#endif
}

__device__ __forceinline__ unsigned pk_bf16(float lo, float hi) {
    unsigned r;
    asm("v_cvt_pk_bf16_f32 %0, %1, %2" : "=v"(r) : "v"(lo), "v"(hi));
    return r;
}
__device__ __forceinline__ unsigned short f2bf(float f) {
    return (unsigned short)pk_bf16(f, f);
}
__device__ __forceinline__ float bf2f(unsigned short h) {
    return __uint_as_float(((unsigned)h) << 16);
}
__device__ __forceinline__ bf4 pack4(float a, float b, float c, float d) {
    union { unsigned u[2]; bf4 v; } cv;
    cv.u[0] = pk_bf16(a, b);
    cv.u[1] = pk_bf16(c, d);
    return cv.v;
}

__device__ __forceinline__ void coords_(int idx, int S, float s,
                                        int& i0, int& i1, float& w0, float& w1) {
    float g = -1.0f + 2.0f * (float)idx / (float)(S - 1);
    float c = (g + s * 2.0f / (float)S + 1.0f) * 0.5f * (float)(S - 1);
    float span = (float)(S - 1);
    c = fabsf(c);
    c = fmodf(c, 2.0f * span);
    if (c > span) c = 2.0f * span - c;
    int f = (int)floorf(c);
    f = max(0, min(f, S - 1));
    i0 = f;
    i1 = min(f + 1, S - 1);
    w1 = c - (float)f;
    w0 = 1.0f - w1;
}

// ------------------ K0: weight prep (fragment-ordered bf16) ----------------
__global__ __launch_bounds__(256) void k_prep(const float* __restrict__ Wq,
                                              const float* __restrict__ Wkv,
                                              const float* __restrict__ Wout,
                                              const float* __restrict__ c1w,
                                              const float* __restrict__ c2w,
                                              unsigned short* __restrict__ WF,
                                              unsigned short* __restrict__ WFo,
                                              unsigned short* __restrict__ BF1,
                                              unsigned short* __restrict__ BF2) {
    int tid = blockIdx.x * 256 + threadIdx.x;
    if (tid < 11264) {
        int e = tid & 3;
        int l = (tid >> 2) & 63;
        int kt = (tid >> 8) & 3;
        int nt = tid >> 10;
        int g = l >> 4, li = l & 15;
        int k = 16 * kt + 4 * g + e;
        int col = 16 * nt + li;
        float v = 0.f;
        if (k < 56 && col < 168)
            v = (col < 56) ? Wq[k * 56 + col] : Wkv[k * 112 + (col - 56)];
        WF[tid] = f2bf(v);
    } else if (tid < 15360) {
        int t2 = tid - 11264;
        int e = t2 & 3;
        int l = (t2 >> 2) & 63;
        int kt = (t2 >> 8) & 3;
        int nt = t2 >> 10;
        int g = l >> 4, li = l & 15;
        int k = 16 * kt + 4 * g + e;
        int col = 16 * nt + li;
        float v = (k < 56 && col < 56) ? Wout[k * 56 + col] : 0.f;
        WFo[t2] = f2bf(v);
    } else if (tid < 19968) {
        int t2 = tid - 15360;  // 4608 entries
        int e = t2 & 3;
        int l = (t2 >> 2) & 63;
        int rest = t2 >> 8;    // t*2+kg
        int kg = rest & 1;
        int t = rest >> 1;
        int g = l >> 4, li = l & 15;
        int c = 16 * kg + 4 * g + e;
        float v = (c < 28) ? c1w[li * 252 + c * 9 + t] : 0.f;
        unsigned short h = f2bf(v);
        BF1[t2] = h;
        BF1[4608 + t2] = f2bf(v - bf2f(h));
    } else if (tid < 22272) {
        int t2 = tid - 19968;  // 2304 entries
        int e = t2 & 3;
        int l = (t2 >> 2) & 63;
        int t = t2 >> 8;
        int g = l >> 4, li = l & 15;
        int c = 4 * g + e;
        float v = c2w[li * 144 + c * 9 + t];
        unsigned short h = f2bf(v);
        BF2[t2] = h;
        BF2[2304 + t2] = f2bf(v - bf2f(h));
    }
}

// ------------------- K1: QKV GEMM (bf16 MFMA, prepped B) -------------------
__global__ __launch_bounds__(256) void k_qkv(const float* __restrict__ x,
                                             const unsigned short* __restrict__ WF,
                                             unsigned short* __restrict__ q1,
                                             unsigned short* __restrict__ k1,
                                             unsigned short* __restrict__ v1,
                                             unsigned short* __restrict__ q2,
                                             unsigned short* __restrict__ k2,
                                             unsigned short* __restrict__ v2,
                                             unsigned short* __restrict__ ssum) {
    extern __shared__ __align__(16) char smem[];
    unsigned short* Ah = (unsigned short*)smem;            // [64][68]
    unsigned short* st = (unsigned short*)(smem + 8704);   // [64][172]
    int tid = threadIdx.x;
    int w = tid >> 6;
    int l = tid & 63;
    int g = l >> 4;
    int li = l & 15;
    int pix0 = blockIdx.x * 64;
    for (int e = tid; e < 896; e += 256) {
        int row = e / 14;
        int c4 = (e - row * 14) * 4;
        float4 v = *(const float4*)(x + (size_t)pix0 * 56 + 4 * e);
        uint2 p;
        p.x = pk_bf16(v.x, v.y);
        p.y = pk_bf16(v.z, v.w);
        *(uint2*)((unsigned*)Ah + row * 34 + (c4 >> 1)) = p;
    }
    for (int e = tid; e < 384; e += 256) {
        int row = e / 6;
        ((unsigned*)Ah)[row * 34 + 28 + (e - row * 6)] = 0;
    }
    int nt0 = 3 * w;
    int nnt = (w < 3) ? 3 : 2;
    bf4 B[3][4];
#pragma unroll
    for (int t = 0; t < 3; ++t) {
        if (t >= nnt) break;
#pragma unroll
        for (int kt = 0; kt < 4; ++kt)
            B[t][kt] = *(const bf4*)(WF + (((nt0 + t) * 4 + kt) * 64 + l) * 4);
    }
    __syncthreads();
    f4 acc[4][3];
#pragma unroll
    for (int mi = 0; mi < 4; ++mi)
#pragma unroll
        for (int t = 0; t < 3; ++t) acc[mi][t] = (f4){0.f, 0.f, 0.f, 0.f};
#pragma unroll
    for (int mi = 0; mi < 4; ++mi) {
        bf4 a[4];
#pragma unroll
        for (int kt = 0; kt < 4; ++kt)
            a[kt] = *(const bf4*)(Ah + (16 * mi + li) * 68 + 16 * kt + 4 * g);
#pragma unroll
        for (int t = 0; t < 3; ++t) {
            if (t >= nnt) break;
#pragma unroll
            for (int kt = 0; kt < 4; ++kt)
                acc[mi][t] = mfma16(a[kt], B[t][kt], acc[mi][t]);
        }
    }
#pragma unroll
    for (int mi = 0; mi < 4; ++mi)
#pragma unroll
        for (int t = 0; t < 3; ++t) {
            if (t >= nnt) break;
            int col = 16 * (nt0 + t) + li;
            if (col < 168) {
#pragma unroll
                for (int r = 0; r < 4; ++r)
                    st[(16 * mi + 4 * g + r) * 172 + col] = f2bf(acc[mi][t][r]);
            }
        }
    __syncthreads();
    // ---- ssum: one (row, 14-col slice) per thread; st cols: q|k|v at 0/56/112
    {
        int row = tid >> 2;
        int qq = tid & 3;
        int pixel = pix0 + row;
        int b = pixel >> 14;
        int rem = pixel & 16383;
        int hh = rem >> 7;
        int ww = rem & 127;
        int n = ((hh >> 3) << 4) + (ww >> 3);
        int m = ((hh & 7) << 3) + (ww & 7);
        size_t ob = ((size_t)(b * 256 + n) * 64 + m) * 56 + 14 * qq;
        const unsigned short* sr = st + row * 172 + 14 * qq;
#pragma unroll
        for (int h = 0; h < 7; ++h) {
            unsigned qw = *(const unsigned*)(sr + 2 * h);
            unsigned kw = *(const unsigned*)(sr + 56 + 2 * h);
            unsigned vw = *(const unsigned*)(sr + 112 + 2 * h);
            float s0 = __uint_as_float(qw << 16) + __uint_as_float(kw << 16) +
                       __uint_as_float(vw << 16);
            float s1 = __uint_as_float(qw & 0xffff0000u) + __uint_as_float(kw & 0xffff0000u) +
                       __uint_as_float(vw & 0xffff0000u);
            *(unsigned*)(ssum + ob + 2 * h) = pk_bf16(s0, s1);
        }
    }
    // ---- array half-rows: 384 tasks of 7 uint2 copies ----
    for (int e = tid; e < 384; e += 256) {
        int row = e / 6;
        int half = e - row * 6;
        int pixel = pix0 + row;
        int b = pixel >> 14;
        int rem = pixel & 16383;
        int hh = rem >> 7;
        int ww = rem & 127;
        int n = ((hh >> 3) << 4) + (ww >> 3);
        int m = ((hh & 7) << 3) + (ww & 7);
        size_t p1 = ((size_t)(b * 256 + n) * 64 + m) * 28;
        size_t p2 = ((size_t)(b * 64 + m) * 256 + n) * 28;
        unsigned short* base =
            (half < 2) ? (half == 0 ? q1 + p1 : q2 + p2)
                       : (half < 4) ? (half == 2 ? k1 + p1 : k2 + p2)
                                    : (half == 4 ? v1 + p1 : v2 + p2);
        const unsigned short* src = st + row * 172 + half * 28;
#pragma unroll
        for (int h = 0; h < 7; ++h)
            *(uint2*)(base + 4 * h) = *(const uint2*)(src + 4 * h);
    }
}

// ---------------- K2: conv1, implicit-GEMM MFMA (bf16, hi/lo B) ------------
__global__ __launch_bounds__(256) void k_conv1(const unsigned short* __restrict__ ssum,
                                               const unsigned short* __restrict__ BF1,
                                               const float* __restrict__ c1b,
                                               unsigned short* __restrict__ c1o) {
    __shared__ __align__(16) unsigned short tile[6 * 66 * 36];
    int tid = threadIdx.x;
    int w = tid >> 6;
    int l = tid & 63;
    int g = l >> 4;
    int li = l & 15;
    int wg = blockIdx.x;
    int br = wg >> 9;
    int b = (wg >> 6) & 7;
    int nt = wg & 63;
    int n0 = nt * 4;
    for (int e = tid; e < 11088; e += 256) {
        int c = e % 28;
        int rest = e / 28;
        int mm = rest % 66;
        int nr = rest / 66;
        int n = n0 - 1 + nr;
        int m = mm - 1;
        unsigned short v = 0;
        if (n >= 0 && n < 256 && m >= 0 && m < 64)
            v = ssum[(((size_t)b * 256 + n) * 64 + m) * 56 + br * 28 + c];
        tile[(nr * 66 + mm) * 36 + c] = v;
    }
    for (int e = tid; e < 1584; e += 256) {
        int rm = e >> 2;
        tile[rm * 36 + 28 + (e & 3)] = 0;
    }
    bf4 Bh[9][2], Bl[9][2];
#pragma unroll
    for (int t = 0; t < 9; ++t)
#pragma unroll
        for (int kg = 0; kg < 2; ++kg) {
            Bh[t][kg] = *(const bf4*)(BF1 + ((t * 2 + kg) * 64 + l) * 4);
            Bl[t][kg] = *(const bf4*)(BF1 + 4608 + ((t * 2 + kg) * 64 + l) * 4);
        }
    __syncthreads();
    f4 acc[4];
#pragma unroll
    for (int mt = 0; mt < 4; ++mt) acc[mt] = (f4){0.f, 0.f, 0.f, 0.f};
#pragma unroll
    for (int mt = 0; mt < 4; ++mt) {
#pragma unroll
        for (int t = 0; t < 9; ++t) {
            int ky = t / 3, kx = t - 3 * (t / 3);
#pragma unroll
            for (int kg = 0; kg < 2; ++kg) {
                bf4 a = *(const bf4*)(tile + ((w + ky) * 66 + 16 * mt + li + kx) * 36 +
                                      16 * kg + 4 * g);
                acc[mt] = mfma16(a, Bh[t][kg], acc[mt]);
                acc[mt] = mfma16(a, Bl[t][kg], acc[mt]);
            }
        }
    }
    float bias = c1b[li];
    size_t combo = (size_t)(br * 8 + b);
#pragma unroll
    for (int mt = 0; mt < 4; ++mt)
#pragma unroll
        for (int r = 0; r < 4; ++r) {
            int m = 16 * mt + 4 * g + r;
            float v = fmaxf(acc[mt][r] + bias, 0.f);
            c1o[(combo * 16384 + (size_t)(n0 + w) * 64 + m) * 16 + li] = f2bf(v);
        }
}

// ------------- K3: conv2 + pooled partials, implicit-GEMM MFMA -------------
__global__ __launch_bounds__(256) void k_conv2(const unsigned short* __restrict__ c1o,
                                               const unsigned short* __restrict__ BF2,
                                               const float* __restrict__ c2b,
                                               float* __restrict__ part) {
    __shared__ __align__(16) unsigned short tile[6 * 66 * 20];
    __shared__ float pbuf[4][16];
    int tid = threadIdx.x;
    int w = tid >> 6;
    int l = tid & 63;
    int g = l >> 4;
    int li = l & 15;
    int wg = blockIdx.x;
    int br = wg >> 9;
    int b = (wg >> 6) & 7;
    int nt = wg & 63;
    int n0 = nt * 4;
    size_t combo = (size_t)(br * 8 + b);
    for (int e = tid; e < 6336; e += 256) {
        int c = e & 15;
        int rest = e >> 4;
        int mm = rest % 66;
        int nr = rest / 66;
        int n = n0 - 1 + nr;
        int m = mm - 1;
        unsigned short v = 0;
        if (n >= 0 && n < 256 && m >= 0 && m < 64)
            v = c1o[(combo * 16384 + (size_t)n * 64 + m) * 16 + c];
        tile[(nr * 66 + mm) * 20 + c] = v;
    }
    bf4 Bh[9], Bl[9];
#pragma unroll
    for (int t = 0; t < 9; ++t) {
        Bh[t] = *(const bf4*)(BF2 + (t * 64 + l) * 4);
        Bl[t] = *(const bf4*)(BF2 + 2304 + (t * 64 + l) * 4);
    }
    __syncthreads();
    f4 acc[4];
#pragma unroll
    for (int mt = 0; mt < 4; ++mt) acc[mt] = (f4){0.f, 0.f, 0.f, 0.f};
#pragma unroll
    for (int mt = 0; mt < 4; ++mt) {
#pragma unroll
        for (int t = 0; t < 9; ++t) {
            int ky = t / 3, kx = t - 3 * (t / 3);
            bf4 a = *(const bf4*)(tile + ((w + ky) * 66 + 16 * mt + li + kx) * 20 + 4 * g);
            acc[mt] = mfma16(a, Bh[t], acc[mt]);
            acc[mt] = mfma16(a, Bl[t], acc[mt]);
        }
    }
    float bias = c2b[li];
    float s = 0.f;
#pragma unroll
    for (int mt = 0; mt < 4; ++mt)
#pragma unroll
        for (int r = 0; r < 4; ++r) s += fmaxf(acc[mt][r] + bias, 0.f);
    s += __shfl_xor(s, 16);
    s += __shfl_xor(s, 32);
    if (l < 16) pbuf[w][li] = s;
    __syncthreads();
    if (tid < 16) {
        float tot = pbuf[0][tid] + pbuf[1][tid] + pbuf[2][tid] + pbuf[3][tid];
        part[(combo * 64 + nt) * 16 + tid] = tot;
    }
}

// ------------------------- K4: reduce + FC -> shifts -----------------------
__global__ void k_fc(const float* __restrict__ part, const float* __restrict__ f1w,
                     const float* __restrict__ f1b, const float* __restrict__ f2w,
                     const float* __restrict__ f2b, float* __restrict__ shif) {
    __shared__ float sb[16][16];
    int t = threadIdx.x;
    int combo = t >> 4;
    int o = t & 15;
    float s = 0.f;
    for (int nt = 0; nt < 64; ++nt) s += part[((size_t)combo * 64 + nt) * 16 + o];
    sb[combo][o] = s * (1.0f / 16384.0f);
    __syncthreads();
    if (t < 16) {
        float p0 = f1b[0], p1 = f1b[1], rg = f2b[0];
        for (int oo = 0; oo < 16; ++oo) {
            float sv = sb[t][oo];
            p0 += sv * f1w[oo * 2 + 0];
            p1 += sv * f1w[oo * 2 + 1];
            rg += sv * f2w[oo];
        }
        shif[t * 2 + 0] = rg * tanhf(p0);
        shif[t * 2 + 1] = rg * tanhf(p1);
    }
}

// ----------------- K5: shifted pos precompute (pos2 | pos1) ----------------
__global__ __launch_bounds__(256) void k_pos(const float* __restrict__ pos1,
                                             const float* __restrict__ pos2,
                                             const float* __restrict__ shif,
                                             float* __restrict__ P1T,
                                             float* __restrict__ P1M,
                                             float* __restrict__ P2R,
                                             float* __restrict__ P2M) {
    __shared__ float plds[64 * 64];
    if (blockIdx.x < 2048) {
        int wg = blockIdx.x;
        int b = wg >> 8;
        int i = wg & 255;
        float sx = shif[16 + b * 2 + 0];
        float sy = shif[16 + b * 2 + 1];
        int j = threadIdx.x;
        int y0, y1, x0, x1;
        float wy0, wy1, wx0, wx1;
        coords_(i, 256, sy, y0, y1, wy0, wy1);
        coords_(j, 256, sx, x0, x1, wx0, wx1);
        float v = pos2[((i - 1) & 255) * 256 + ((j - 1) & 255)] +
                  wy0 * (wx0 * pos2[y0 * 256 + x0] + wx1 * pos2[y0 * 256 + x1]) +
                  wy1 * (wx0 * pos2[y1 * 256 + x0] + wx1 * pos2[y1 * 256 + x1]);
        P2R[(size_t)b * 65536 + (size_t)i * 256 + j] = v;
        float mx = v;
#pragma unroll
        for (int msk = 1; msk < 64; msk <<= 1) mx = fmaxf(mx, __shfl_xor(mx, msk));
        if ((threadIdx.x & 63) == 0) plds[threadIdx.x >> 6] = mx;
        __syncthreads();
        if (threadIdx.x == 0)
            P2M[b * 256 + i] = fmaxf(fmaxf(plds[0], plds[1]), fmaxf(plds[2], plds[3]));
    } else {
        int b = blockIdx.x - 2048;
        float sx = shif[b * 2 + 0];
        float sy = shif[b * 2 + 1];
        for (int e = threadIdx.x; e < 4096; e += 256) {
            int j = e >> 6;
            int i = e & 63;
            int y0, y1, x0, x1;
            float wy0, wy1, wx0, wx1;
            coords_(i, 64, sy, y0, y1, wy0, wy1);
            coords_(j, 64, sx, x0, x1, wx0, wx1);
            float v = pos1[((i - 1) & 63) * 64 + ((j - 1) & 63)] +
                      wy0 * (wx0 * pos1[y0 * 64 + x0] + wx1 * pos1[y0 * 64 + x1]) +
                      wy1 * (wx0 * pos1[y1 * 64 + x0] + wx1 * pos1[y1 * 64 + x1]);
            P1T[(size_t)b * 4096 + j * 64 + i] = v;
            plds[j * 64 + i] = v;
        }
        __syncthreads();
        if (threadIdx.x < 64) {
            float mx = plds[threadIdx.x];
            for (int j = 1; j < 64; ++j) mx = fmaxf(mx, plds[j * 64 + threadIdx.x]);
            P1M[b * 64 + threadIdx.x] = mx;
        }
    }
}

// ---------------- K5c: transpose P2R -> P2T[b][j][i] (64x64 tiles) ---------
__global__ __launch_bounds__(256) void k_posT(const float* __restrict__ P2R,
                                              float* __restrict__ P2T) {
    __shared__ float t[64][65];
    int blk = blockIdx.x;     // 128 = 8 b x 16 tiles
    int b = blk >> 4;
    int t4 = blk & 15;
    int i0 = (t4 >> 2) * 64;
    int j0 = (t4 & 3) * 64;
    int tr = threadIdx.x >> 6;
    int tc = threadIdx.x & 63;
    for (int rr = 0; rr < 64; rr += 4)
        t[rr + tr][tc] = P2R[(size_t)b * 65536 + (size_t)(i0 + rr + tr) * 256 + j0 + tc];
    __syncthreads();
    for (int rr = 0; rr < 64; rr += 4)
        P2T[(size_t)b * 65536 + (size_t)(j0 + rr + tr) * 256 + i0 + tc] = t[tc][rr + tr];
}

// --------------- K6: branch-1 window attention (64x64), MFMA ---------------
__global__ __launch_bounds__(256) void k_attn1(const unsigned short* __restrict__ q1,
                                               const unsigned short* __restrict__ k1,
                                               const unsigned short* __restrict__ v1,
                                               const float* __restrict__ P1T,
                                               const float* __restrict__ P1M,
                                               const float* __restrict__ shif,
                                               unsigned short* __restrict__ aout) {
    __shared__ __align__(16) unsigned short qraw[64 * 28];
    __shared__ __align__(16) unsigned short kraw[64 * 28];
    __shared__ __align__(16) unsigned short augK[64 * 68];
    __shared__ __align__(16) unsigned short vT[32 * 68];
    __shared__ __align__(16) unsigned short Pw[4][16 * 68];
    int tid = threadIdx.x;
    int w = tid >> 6;
    int l = tid & 63;
    int g = l >> 4;
    int li = l & 15;
    int wg = blockIdx.x;
    int b = wg >> 8;
    int n = wg & 255;
    size_t gb = (size_t)(b * 256 + n) * 1792;
    float sx = shif[b * 2 + 0];
    float sy = shif[b * 2 + 1];
    for (int e = tid; e < 448; e += 256) {
        *(uint2*)(qraw + 4 * e) = *(const uint2*)(q1 + gb + 4 * e);
        *(uint2*)(kraw + 4 * e) = *(const uint2*)(k1 + gb + 4 * e);
        uint2 t = *(const uint2*)(v1 + gb + 4 * e);
        int idx = 4 * e;
        int j0 = idx / 28, c0 = idx - 28 * j0;
        int j1 = (idx + 1) / 28, c1 = (idx + 1) - 28 * j1;
        int j2 = (idx + 2) / 28, c2 = (idx + 2) - 28 * j2;
        int j3 = (idx + 3) / 28, c3 = (idx + 3) - 28 * j3;
        vT[c0 * 68 + j0] = (unsigned short)t.x;
        vT[c1 * 68 + j1] = (unsigned short)(t.x >> 16);
        vT[c2 * 68 + j2] = (unsigned short)t.y;
        vT[c3 * 68 + j3] = (unsigned short)(t.y >> 16);
    }
    for (int e = tid; e < 272; e += 256) vT[28 * 68 + e] = 0;
    __syncthreads();
    if (tid < 64) {
        int j = tid;
        int x0, x1;
        float wx0, wx1;
        coords_(j, 64, sx, x0, x1, wx0, wx1);
        int rm = (j - 1) & 63;
        uint2* rowv = (uint2*)(augK + j * 68);
        const uint2* srcv = (const uint2*)(kraw + rm * 28);
#pragma unroll
        for (int h = 0; h < 7; ++h) rowv[h] = srcv[h];
        unsigned* row = (unsigned*)(augK + j * 68);
#pragma unroll
        for (int h = 0; h < 14; ++h) {
            float a0 = wx0 * bf2f(kraw[x0 * 28 + 2 * h]) + wx1 * bf2f(kraw[x1 * 28 + 2 * h]);
            float a1 = wx0 * bf2f(kraw[x0 * 28 + 2 * h + 1]) + wx1 * bf2f(kraw[x1 * 28 + 2 * h + 1]);
            row[14 + h] = pk_bf16(a0, a1);
        }
#pragma unroll
        for (int h = 28; h < 34; ++h) row[h] = 0;
    }
    bf4 qf[4];
    {
        int i = 16 * w + li;
        int y0, y1;
        float wy0, wy1;
        coords_(i, 64, sy, y0, y1, wy0, wy1);
        int rm = (i - 1) & 63;
#pragma unroll
        for (int kt = 0; kt < 4; ++kt) {
            float qv[4];
#pragma unroll
            for (int e = 0; e < 4; ++e) {
                int d = 16 * kt + 4 * g + e;
                float v;
                if (d < 28) v = SCALE_ * bf2f(qraw[rm * 28 + d]);
                else if (d < 56)
                    v = SCALE_ * (wy0 * bf2f(qraw[y0 * 28 + d - 28]) +
                                  wy1 * bf2f(qraw[y1 * 28 + d - 28]));
                else v = 0.f;
                qv[e] = v;
            }
            union { unsigned u[2]; bf4 v; } cv;
            cv.u[0] = pk_bf16(qv[0], qv[1]);
            cv.u[1] = pk_bf16(qv[2], qv[3]);
            qf[kt] = cv.v;
        }
    }
    f4 Mv = *(const f4*)(P1M + b * 64 + 16 * w + 4 * g);
    __syncthreads();
    f4 acc[4];
#pragma unroll
    for (int nj = 0; nj < 4; ++nj)
        acc[nj] = *(const f4*)(P1T + (size_t)b * 4096 + (16 * nj + li) * 64 + 16 * w + 4 * g);
#pragma unroll
    for (int nj = 0; nj < 4; ++nj) {
        const unsigned short* kr = augK + (16 * nj + li) * 68 + 4 * g;
#pragma unroll
        for (int kt = 0; kt < 4; ++kt) {
            bf4 bk = *(const bf4*)(kr + 16 * kt);
            acc[nj] = mfma16(qf[kt], bk, acc[nj]);
        }
    }
    float lr[4] = {0.f, 0.f, 0.f, 0.f};
    unsigned short* Pww = Pw[w];
#pragma unroll
    for (int nj = 0; nj < 4; ++nj)
#pragma unroll
        for (int r = 0; r < 4; ++r) {
            float p = __expf(acc[nj][r] - Mv[r]);
            lr[r] += p;
            Pww[(4 * g + r) * 68 + 16 * nj + li] = f2bf(p);
        }
    f4 accv[2];
    accv[0] = (f4){0.f, 0.f, 0.f, 0.f};
    accv[1] = (f4){0.f, 0.f, 0.f, 0.f};
#pragma unroll
    for (int kt = 0; kt < 4; ++kt) {
        bf4 pa = *(const bf4*)(Pww + li * 68 + 16 * kt + 4 * g);
#pragma unroll
        for (int nc = 0; nc < 2; ++nc) {
            bf4 bv = *(const bf4*)(vT + (16 * nc + li) * 68 + 16 * kt + 4 * g);
            accv[nc] = mfma16(pa, bv, accv[nc]);
        }
    }
#pragma unroll
    for (int r = 0; r < 4; ++r) {
#pragma unroll
        for (int msk = 1; msk < 16; msk <<= 1) lr[r] += __shfl_xor(lr[r], msk);
        float invl = 1.0f / lr[r];
        int i = 16 * w + 4 * g + r;
        size_t wb = ((size_t)(b * 256 + n) * 64 + i) * 56;
        aout[wb + li] = f2bf(accv[0][r] * invl);
        if (li < 12) aout[wb + 16 + li] = f2bf(accv[1][r] * invl);
    }
}

// -------------------- K7: branch-2 cross-window attn, MFMA -----------------
__global__ __launch_bounds__(512) void k_attn2(const unsigned short* __restrict__ q2,
                                               const unsigned short* __restrict__ k2,
                                               const unsigned short* __restrict__ v2,
                                               const float* __restrict__ P2T,
                                               const float* __restrict__ P2M,
                                               const float* __restrict__ shif,
                                               unsigned short* __restrict__ aout) {
    extern __shared__ __align__(16) char smem[];
    unsigned short* augK = (unsigned short*)smem;                  // [256][68]
    unsigned short* vT = (unsigned short*)(smem + 34816);          // [28][260]
    int tid = threadIdx.x;
    int w = tid >> 6;
    int l = tid & 63;
    int g = l >> 4;
    int li = l & 15;
    unsigned short* Pw = (unsigned short*)(smem + 49376) + w * 1088;  // [16][68]
    int bm = blockIdx.x;
    int b = bm >> 6;
    int m = bm & 63;
    size_t gbase = (size_t)bm * 7168;
    float sx = shif[16 + b * 2 + 0];
    float sy = shif[16 + b * 2 + 1];
    if (tid < 256) {
        int j = tid;
        int x0, x1;
        float wx0, wx1;
        coords_(j, 256, sx, x0, x1, wx0, wx1);
        int rm = (j - 1) & 255;
        uint2* rowv = (uint2*)(augK + j * 68);
        const uint2* srcv = (const uint2*)(k2 + gbase + (size_t)rm * 28);
#pragma unroll
        for (int h = 0; h < 7; ++h) rowv[h] = srcv[h];
        const uint2* kav = (const uint2*)(k2 + gbase + (size_t)x0 * 28);
        const uint2* kbv = (const uint2*)(k2 + gbase + (size_t)x1 * 28);
        unsigned* row = (unsigned*)(augK + j * 68);
#pragma unroll
        for (int h = 0; h < 7; ++h) {
            uint2 va = kav[h], vb = kbv[h];
            float a0 = wx0 * bf2f((unsigned short)va.x) + wx1 * bf2f((unsigned short)vb.x);
            float a1 = wx0 * bf2f((unsigned short)(va.x >> 16)) +
                       wx1 * bf2f((unsigned short)(vb.x >> 16));
            float a2 = wx0 * bf2f((unsigned short)va.y) + wx1 * bf2f((unsigned short)vb.y);
            float a3 = wx0 * bf2f((unsigned short)(va.y >> 16)) +
                       wx1 * bf2f((unsigned short)(vb.y >> 16));
            row[14 + 2 * h] = pk_bf16(a0, a1);
            row[15 + 2 * h] = pk_bf16(a2, a3);
        }
#pragma unroll
        for (int h = 28; h < 34; ++h) row[h] = 0;
    } else {
        int j = tid - 256;
        const uint2* vrv = (const uint2*)(v2 + gbase + (size_t)j * 28);
#pragma unroll
        for (int h = 0; h < 7; ++h) {
            uint2 t = vrv[h];
            vT[(4 * h + 0) * 260 + j] = (unsigned short)t.x;
            vT[(4 * h + 1) * 260 + j] = (unsigned short)(t.x >> 16);
            vT[(4 * h + 2) * 260 + j] = (unsigned short)t.y;
            vT[(4 * h + 3) * 260 + j] = (unsigned short)(t.y >> 16);
        }
    }
    // ---- Q fragments via uint2 register loads (exact per-(kt,g) source map)
    bf4 qf[2][4];
#pragma unroll
    for (int mi = 0; mi < 2; ++mi) {
        int i = 32 * w + 16 * mi + li;
        int y0, y1;
        float wy0, wy1;
        coords_(i, 256, sy, y0, y1, wy0, wy1);
        int rm = (i - 1) & 255;
        const uint2* qrmv = (const uint2*)(q2 + gbase + (size_t)rm * 28);
        const uint2* qav = (const uint2*)(q2 + gbase + (size_t)y0 * 28);
        const uint2* qbv = (const uint2*)(q2 + gbase + (size_t)y1 * 28);
        {
            uint2 r0 = qrmv[g];
            qf[mi][0] = pack4(SCALE_ * bf2f((unsigned short)r0.x),
                              SCALE_ * bf2f((unsigned short)(r0.x >> 16)),
                              SCALE_ * bf2f((unsigned short)r0.y),
                              SCALE_ * bf2f((unsigned short)(r0.y >> 16)));
        }
        if (g < 3) {
            uint2 r1 = qrmv[4 + g];
            qf[mi][1] = pack4(SCALE_ * bf2f((unsigned short)r1.x),
                              SCALE_ * bf2f((unsigned short)(r1.x >> 16)),
                              SCALE_ * bf2f((unsigned short)r1.y),
                              SCALE_ * bf2f((unsigned short)(r1.y >> 16)));
        } else {
            uint2 a = qav[0], bb = qbv[0];
            qf[mi][1] = pack4(
                SCALE_ * (wy0 * bf2f((unsigned short)a.x) + wy1 * bf2f((unsigned short)bb.x)),
                SCALE_ * (wy0 * bf2f((unsigned short)(a.x >> 16)) +
                          wy1 * bf2f((unsigned short)(bb.x >> 16))),
                SCALE_ * (wy0 * bf2f((unsigned short)a.y) + wy1 * bf2f((unsigned short)bb.y)),
                SCALE_ * (wy0 * bf2f((unsigned short)(a.y >> 16)) +
                          wy1 * bf2f((unsigned short)(bb.y >> 16))));
        }
        {
            uint2 a = qav[1 + g], bb = qbv[1 + g];
            qf[mi][2] = pack4(
                SCALE_ * (wy0 * bf2f((unsigned short)a.x) + wy1 * bf2f((unsigned short)bb.x)),
                SCALE_ * (wy0 * bf2f((unsigned short)(a.x >> 16)) +
                          wy1 * bf2f((unsigned short)(bb.x >> 16))),
                SCALE_ * (wy0 * bf2f((unsigned short)a.y) + wy1 * bf2f((unsigned short)bb.y)),
                SCALE_ * (wy0 * bf2f((unsigned short)(a.y >> 16)) +
                          wy1 * bf2f((unsigned short)(bb.y >> 16))));
        }
        if (g < 2) {
            uint2 a = qav[5 + g], bb = qbv[5 + g];
            qf[mi][3] = pack4(
                SCALE_ * (wy0 * bf2f((unsigned short)a.x) + wy1 * bf2f((unsigned short)bb.x)),
                SCALE_ * (wy0 * bf2f((unsigned short)(a.x >> 16)) +
                          wy1 * bf2f((unsigned short)(bb.x >> 16))),
                SCALE_ * (wy0 * bf2f((unsigned short)a.y) + wy1 * bf2f((unsigned short)bb.y)),
                SCALE_ * (wy0 * bf2f((unsigned short)(a.y >> 16)) +
                          wy1 * bf2f((unsigned short)(bb.y >> 16))));
        } else {
            union { unsigned u[2]; bf4 v; } cz;
            cz.u[0] = 0;
            cz.u[1] = 0;
            qf[mi][3] = cz.v;
        }
    }
    float M[2][4];
#pragma unroll
    for (int mi = 0; mi < 2; ++mi)
#pragma unroll
        for (int r = 0; r < 4; ++r)
            M[mi][r] = P2M[b * 256 + 32 * w + 16 * mi + 4 * g + r];
    __syncthreads();
    f4 accv[2][2];
#pragma unroll
    for (int mi = 0; mi < 2; ++mi)
#pragma unroll
        for (int nc = 0; nc < 2; ++nc) accv[mi][nc] = (f4){0.f, 0.f, 0.f, 0.f};
    float lrun[2][4];
#pragma unroll
    for (int mi = 0; mi < 2; ++mi)
#pragma unroll
        for (int r = 0; r < 4; ++r) lrun[mi][r] = 0.f;

    for (int jt = 0; jt < 4; ++jt) {
#pragma unroll
        for (int mi = 0; mi < 2; ++mi) {
            f4 acc[4];
#pragma unroll
            for (int nj = 0; nj < 4; ++nj)
                acc[nj] = *(const f4*)(P2T + (size_t)b * 65536 +
                                       (size_t)(64 * jt + 16 * nj + li) * 256 +
                                       32 * w + 16 * mi + 4 * g);
#pragma unroll
            for (int nj = 0; nj < 4; ++nj) {
                const unsigned short* kr = augK + (64 * jt + 16 * nj + li) * 68 + 4 * g;
#pragma unroll
                for (int kt = 0; kt < 4; ++kt) {
                    bf4 bk = *(const bf4*)(kr + 16 * kt);
                    acc[nj] = mfma16(qf[mi][kt], bk, acc[nj]);
                }
            }
#pragma unroll
            for (int nj = 0; nj < 4; ++nj)
#pragma unroll
                for (int r = 0; r < 4; ++r) {
                    float p = __expf(acc[nj][r] - M[mi][r]);
                    lrun[mi][r] += p;
                    Pw[(4 * g + r) * 68 + 16 * nj + li] = f2bf(p);
                }
#pragma unroll
            for (int kt = 0; kt < 4; ++kt) {
                bf4 pa = *(const bf4*)(Pw + li * 68 + 16 * kt + 4 * g);
#pragma unroll
                for (int nc = 0; nc < 2; ++nc) {
                    bf4 bv = *(const bf4*)(vT + (16 * nc + li) * 260 + 64 * jt + 16 * kt + 4 * g);
                    accv[mi][nc] = mfma16(pa, bv, accv[mi][nc]);
                }
            }
        }
    }
#pragma unroll
    for (int mi = 0; mi < 2; ++mi)
#pragma unroll
        for (int r = 0; r < 4; ++r) {
#pragma unroll
            for (int msk = 1; msk < 16; msk <<= 1)
                lrun[mi][r] += __shfl_xor(lrun[mi][r], msk);
            float invl = 1.0f / lrun[mi][r];
            int gi = 32 * w + 16 * mi + 4 * g + r;
            size_t wb = (((size_t)b * 256 + gi) * 64 + m) * 56 + 28;
            aout[wb + li] = f2bf(accv[mi][0][r] * invl);
            if (li < 12) aout[wb + 16 + li] = f2bf(accv[mi][1][r] * invl);
        }
}

// ---------------- K8: output projection + unwindow (MFMA, prepped B) -------
__global__ __launch_bounds__(256) void k_out(const unsigned short* __restrict__ aout,
                                             const unsigned short* __restrict__ WFo,
                                             const float* __restrict__ bout,
                                             float* __restrict__ out) {
    __shared__ __align__(16) unsigned short Ah[64 * 68];
    __shared__ __align__(16) float st[64 * 60];
    int tid = threadIdx.x;
    int w = tid >> 6;
    int l = tid & 63;
    int g = l >> 4;
    int li = l & 15;
    int pix0 = blockIdx.x * 64;
    for (int e = tid; e < 896; e += 256) {
        int row = e / 14;
        int c4 = (e - row * 14) * 4;
        *(uint2*)(Ah + row * 68 + c4) = *(const uint2*)(aout + (size_t)pix0 * 56 + 4 * e);
    }
    for (int e = tid; e < 384; e += 256) {
        int row = e / 6;
        ((unsigned*)Ah)[row * 34 + 28 + (e - row * 6)] = 0;
    }
    bf4 Bo[4][4];
#pragma unroll
    for (int nt = 0; nt < 4; ++nt)
#pragma unroll
        for (int kt = 0; kt < 4; ++kt)
            Bo[nt][kt] = *(const bf4*)(WFo + ((nt * 4 + kt) * 64 + l) * 4);
    __syncthreads();
    f4 acc[4];
#pragma unroll
    for (int nt = 0; nt < 4; ++nt) acc[nt] = (f4){0.f, 0.f, 0.f, 0.f};
    bf4 ah[4];
#pragma unroll
    for (int kt = 0; kt < 4; ++kt)
        ah[kt] = *(const bf4*)(Ah + (16 * w + li) * 68 + 16 * kt + 4 * g);
#pragma unroll
    for (int nt = 0; nt < 4; ++nt)
#pragma unroll
        for (int kt = 0; kt < 4; ++kt)
            acc[nt] = mfma16(ah[kt], Bo[nt][kt], acc[nt]);
#pragma unroll
    for (int nt = 0; nt < 4; ++nt) {
        int col = 16 * nt + li;
        if (col < 56) {
#pragma unroll
            for (int r = 0; r < 4; ++r)
                st[(16 * w + 4 * g + r) * 60 + col] = acc[nt][r];
        }
    }
    __syncthreads();
    int row = tid >> 2;
    int qq = tid & 3;
    int pixel = pix0 + row;
    int b = pixel >> 14;
    int n = (pixel >> 6) & 255;
    int m = pixel & 63;
    int h = ((n >> 4) << 3) + (m >> 3);
    int ww = ((n & 15) << 3) + (m & 7);
    float* dst = out + (((size_t)b * 128 + h) * 128 + ww) * 56;
    const float* sr = st + row * 60;
#pragma unroll
    for (int cc = 0; cc < 14; cc += 2) {
        int c = 14 * qq + cc;
        float2 o;
        o.x = sr[c] + bout[c];
        o.y = sr[c + 1] + bout[c + 1];
        *(float2*)(dst + c) = o;
    }
}

// ---------------------------------------------------------------------------
extern "C" void kernel_launch(void* const* d_in, const int* in_sizes, int n_in,
                              void* d_out, int out_size, void* d_ws, size_t ws_size,
                              hipStream_t stream) {
    const float* x = (const float*)d_in[0];
    const float* pos1 = (const float*)d_in[1];
    const float* pos2 = (const float*)d_in[2];
    const float* Wq = (const float*)d_in[3];
    const float* Wkv = (const float*)d_in[4];
    const float* Wout = (const float*)d_in[5];
    const float* bout = (const float*)d_in[6];
    const float* c1w = (const float*)d_in[7];
    const float* c1b = (const float*)d_in[8];
    const float* c2w = (const float*)d_in[9];
    const float* c2b = (const float*)d_in[10];
    const float* f1w = (const float*)d_in[11];
    const float* f1b = (const float*)d_in[12];
    const float* f2w = (const float*)d_in[13];
    const float* f2b = (const float*)d_in[14];

    unsigned short* us = (unsigned short*)d_ws;
    unsigned short* q1 = us;
    unsigned short* k1 = us + 3670016;
    unsigned short* v1 = us + 7340032;
    unsigned short* q2 = us + 11010048;
    unsigned short* k2 = us + 14680064;
    unsigned short* v2 = us + 18350080;
    float* fb = (float*)d_ws + 11010048;
    unsigned short* ssb = (unsigned short*)fb;     // ssum bf16 [131072][56]
    unsigned short* aoutb = (unsigned short*)fb;   // aout bf16, overlays ssb
    unsigned short* c1o = (unsigned short*)(fb + 7340032);  // bf16 [16][16384][16]
    float* part = fb + 11534336;
    float* shif = fb + 11550720;
    float* P1T = fb + 11550752;
    float* P1M = fb + 11583520;
    float* P2R = fb + 11584032;
    float* P2M = fb + 12108320;
    unsigned short* WF = (unsigned short*)(fb + 12110368);
    unsigned short* WFo = WF + 11264;
    unsigned short* BF1 = WFo + 4096;   // 9216 u16 (hi 4608 | lo 4608)
    unsigned short* BF2 = BF1 + 9216;   // 4608 u16 (hi 2304 | lo 2304)
    float* P2T = (float*)(BF2 + 4608);  // [8][256][256] f32 (16B-aligned)
    float* outp = (float*)d_out;

    (void)hipFuncSetAttribute((const void*)k_qkv,
                              hipFuncAttributeMaxDynamicSharedMemorySize, 30720);
    (void)hipFuncSetAttribute((const void*)k_attn2,
                              hipFuncAttributeMaxDynamicSharedMemorySize, 66784);

    k_prep<<<87, 256, 0, stream>>>(Wq, Wkv, Wout, c1w, c2w, WF, WFo, BF1, BF2);
    k_qkv<<<2048, 256, 30720, stream>>>(x, WF, q1, k1, v1, q2, k2, v2, ssb);
    k_conv1<<<1024, 256, 0, stream>>>(ssb, BF1, c1b, c1o);
    k_conv2<<<1024, 256, 0, stream>>>(c1o, BF2, c2b, part);
    k_fc<<<1, 256, 0, stream>>>(part, f1w, f1b, f2w, f2b, shif);
    k_pos<<<2056, 256, 0, stream>>>(pos1, pos2, shif, P1T, P1M, P2R, P2M);
    k_posT<<<128, 256, 0, stream>>>(P2R, P2T);
    k_attn1<<<2048, 256, 0, stream>>>(q1, k1, v1, P1T, P1M, shif, aoutb);
    k_attn2<<<512, 512, 66784, stream>>>(q2, k2, v2, P2T, P2M, shif, aoutb);
    k_out<<<2048, 256, 0, stream>>>(aoutb, WFo, bout, outp);
}